// Round 15
// baseline (2743.508 us; speedup 1.0000x reference)
//
#include <hip/hip_runtime.h>
#include <hip/hip_bf16.h>

#define N_NODES 10000
#define N_EDGES 160000
#define N_GRAPHS 64
#define NK 5
#define EPS 1e-5f
#define EPB 64           // edges per block (256 threads)
#define JP 648           // packed width for Pab halves
#define PSTRIDE 1296     // Pab row stride (bf16 elems): [Pa 648 | Pb 648]
#define TCOLS 648        // table row width (642 -> 648)
#define TROWS 12289      // d2 grid [0,96], h=1/128
#define IMAX 12287

__device__ __forceinline__ float silu(float x) { return x / (1.0f + __expf(-x)); }
__device__ __forceinline__ float4 f4fma(float s, float4 w, float4 a) {
    a.x = fmaf(s, w.x, a.x); a.y = fmaf(s, w.y, a.y);
    a.z = fmaf(s, w.z, a.z); a.w = fmaf(s, w.w, a.w);
    return a;
}
__device__ __forceinline__ float wave_sum64(float v) {
    #pragma unroll
    for (int off = 32; off > 0; off >>= 1) v += __shfl_xor(v, off, 64);
    return v;
}
// fp32 -> bf16 (round to nearest even), returned as raw bits
__device__ __forceinline__ unsigned short f2bf(float f) {
    unsigned int u = __float_as_uint(f);
    unsigned int r = u + 0x7FFFu + ((u >> 16) & 1u);
    return (unsigned short)(r >> 16);
}

// ---------------- embedding ----------------
__global__ __launch_bounds__(128) void k_embed(const int* __restrict__ atomids,
                                               const float* __restrict__ emb_w,
                                               float* __restrict__ feats_all) {
    int n = blockIdx.x, tid = threadIdx.x;
    feats_all[(size_t)n * 768 + tid] = emb_w[(size_t)atomids[n] * 128 + tid];
}

// ---------------- per-edge squared distance ----------------
__global__ __launch_bounds__(256) void k_d2(const float* __restrict__ coords,
                                            const int* __restrict__ eidx,
                                            float* __restrict__ d2g) {
    int e = blockIdx.x * 256 + threadIdx.x;
    if (e >= N_EDGES) return;
    int s = eidx[e], d = eidx[N_EDGES + e];
    float dx = coords[s * 3 + 0] - coords[d * 3 + 0];
    float dy = coords[s * 3 + 1] - coords[d * 3 + 1];
    float dz = coords[s * 3 + 2] - coords[d * 3 + 2];
    d2g[e] = dx * dx + dy * dy + dz * dz;
}

// ---------------- in-degree (layer-invariant) ----------------
__global__ __launch_bounds__(256) void k_cnt(const int* __restrict__ eidx,
                                             float* __restrict__ cnt) {
    int e = blockIdx.x * 256 + threadIdx.x;
    if (e >= N_EDGES) return;
    atomicAdd(&cnt[eidx[N_EDGES + e]], 1.0f);
}

// ---------------- counting sort of edges by i0 (T-row index) ----------------
__global__ __launch_bounds__(256) void k_hist(const float* __restrict__ d2g,
                                              int* __restrict__ hist) {
    int e = blockIdx.x * 256 + threadIdx.x;
    if (e >= N_EDGES) return;
    int i0 = (int)(d2g[e] * 128.0f);
    if (i0 > IMAX) i0 = IMAX;
    atomicAdd(&hist[i0], 1);
}

__global__ __launch_bounds__(256) void k_scan(const int* __restrict__ hist,
                                              int* __restrict__ offs) {
    __shared__ int buf[256];
    __shared__ int carryS;
    int tid = threadIdx.x;
    if (tid == 0) carryS = 0;
    __syncthreads();
    for (int base = 0; base < TROWS; base += 256) {
        int v = (base + tid < TROWS) ? hist[base + tid] : 0;
        buf[tid] = v;
        __syncthreads();
        for (int off = 1; off < 256; off <<= 1) {
            int t = (tid >= off) ? buf[tid - off] : 0;
            __syncthreads();
            buf[tid] += t;
            __syncthreads();
        }
        if (base + tid < TROWS) offs[base + tid] = carryS + buf[tid] - v;  // exclusive
        __syncthreads();
        if (tid == 0) carryS += buf[255];
        __syncthreads();
    }
}

__global__ __launch_bounds__(256) void k_copyi(const int* __restrict__ a,
                                               int* __restrict__ b) {
    int i = blockIdx.x * 256 + threadIdx.x;
    if (i < TROWS) b[i] = a[i];
}

__global__ __launch_bounds__(256) void k_scatter(const int* __restrict__ eidx,
                                                 const float* __restrict__ d2g,
                                                 int* __restrict__ cursor,
                                                 int* __restrict__ ssiP,
                                                 int* __restrict__ dsiP,
                                                 int* __restrict__ i0P,
                                                 float* __restrict__ frP) {
    int e = blockIdx.x * 256 + threadIdx.x;
    if (e >= N_EDGES) return;
    float t = d2g[e] * 128.0f;
    int i0 = (int)t;
    if (i0 > IMAX) i0 = IMAX;
    float fr = t - (float)i0;
    int pos = atomicAdd(&cursor[i0], 1);
    ssiP[pos] = eidx[e];
    dsiP[pos] = eidx[N_EDGES + e];
    i0P[pos] = i0;
    frP[pos] = fr;
}

// ---------------- dst-CSR over sorted positions (for atomic-free S aggregation) ----------------
__global__ __launch_bounds__(256) void k_hist_d(const int* __restrict__ dsiP,
                                                int* __restrict__ hist) {
    int p = blockIdx.x * 256 + threadIdx.x;
    if (p >= N_EDGES) return;
    atomicAdd(&hist[dsiP[p]], 1);
}

__global__ __launch_bounds__(256) void k_scatter_d(const int* __restrict__ dsiP,
                                                   int* __restrict__ cursorD,
                                                   int* __restrict__ eixD) {
    int p = blockIdx.x * 256 + threadIdx.x;
    if (p >= N_EDGES) return;
    int pos = atomicAdd(&cursorD[dsiP[p]], 1);
    eixD[pos] = p;
}

// ---------------- CSR aggregation fused with mean + LN: writes H0[:,128:160] ----------------
__global__ __launch_bounds__(128) void k_agg_ln(const float* __restrict__ M,
                                                const int* __restrict__ offsD,
                                                const int* __restrict__ eixD,
                                                const float* __restrict__ cnt,
                                                const float* __restrict__ eng,
                                                const float* __restrict__ enb,
                                                float* __restrict__ H0) {
    int n = blockIdx.x * 4 + (threadIdx.x >> 5);
    int col = threadIdx.x & 31;
    if (n >= N_NODES) return;
    float acc = 0.f;
    int p0 = offsD[n], p1 = offsD[n + 1];
    for (int p = p0; p < p1; ++p)
        acc += M[(size_t)eixD[p] * 32 + col];
    float inv = 1.0f / fmaxf(cnt[n], 1.0f);
    float v = acc * inv;
    float s = v, q = v * v;
    #pragma unroll
    for (int off = 16; off > 0; off >>= 1) {
        s += __shfl_xor(s, off, 64);
        q += __shfl_xor(q, off, 64);
    }
    float m2 = s * (1.0f / 32.0f);
    float va = q * (1.0f / 32.0f) - m2 * m2;
    float rs = 1.0f / sqrtf(va + EPS);
    H0[(size_t)n * 160 + 128 + col] = (v - m2) * rs * eng[col] + enb[col];
}

// ---------------- fallback (no-CSR): S -> mean -> LN -> H0[:,128:160] ----------------
__global__ __launch_bounds__(128) void k_s_ln(const float* __restrict__ S,
                                              const float* __restrict__ cnt,
                                              const float* __restrict__ eng,
                                              const float* __restrict__ enb,
                                              float* __restrict__ H0) {
    int n = blockIdx.x * 4 + (threadIdx.x >> 5);
    int col = threadIdx.x & 31;
    if (n >= N_NODES) return;
    float inv = 1.0f / fmaxf(cnt[n], 1.0f);
    float v = S[(size_t)n * 32 + col] * inv;
    float s = v, q = v * v;
    #pragma unroll
    for (int off = 16; off > 0; off >>= 1) {
        s += __shfl_xor(s, off, 64);
        q += __shfl_xor(q, off, 64);
    }
    float m2 = s * (1.0f / 32.0f);
    float va = q * (1.0f / 32.0f) - m2 * m2;
    float rs = 1.0f / sqrtf(va + EPS);
    H0[(size_t)n * 160 + 128 + col] = (v - m2) * rs * eng[col] + enb[col];
}

// ---------------- fourier features on the d2 GRID (once) ----------------
__global__ __launch_bounds__(256) void k_feg(float* __restrict__ feG) {  // [TROWS][68]
    int g = blockIdx.x * 256 + threadIdx.x;
    if (g >= TROWS) return;
    float d2v = (float)g * 0.0078125f;   // g / 128, exact
    float* o = feG + (size_t)g * 68;
    float sc = 1.0f;
    #pragma unroll
    for (int i = 0; i < 32; ++i) {
        float x = d2v * sc;
        o[i] = sinf(x);
        o[32 + i] = cosf(x);
        sc *= 0.5f;
    }
    o[64] = d2v;
}

// ---------------- per-layer q-table: T[g][j] = fe(g/128) @ W1c + b1 ----------------
__global__ __launch_bounds__(256) void k_tab(const float* __restrict__ feG,   // [TROWS][68]
                                             const float* __restrict__ W1cp,  // [65][768]
                                             const float* __restrict__ b1p,   // [768]
                                             float* __restrict__ T) {         // [TROWS][648]
    __shared__ float feGs[32 * 68];
    __shared__ float W1s[65 * 36];
    const int tid = threadIdx.x;
    const int g0 = blockIdx.x * 32;
    for (int idx = tid; idx < 32 * 17; idx += 256) {
        int r = idx / 17, c = idx - r * 17;
        int gi = g0 + r;
        float4 v = make_float4(0, 0, 0, 0);
        if (gi < TROWS) v = *(const float4*)(feG + (size_t)gi * 68 + 4 * c);
        *(float4*)&feGs[r * 68 + 4 * c] = v;
    }
    const int gt = tid >> 3, ct = tid & 7;
    for (int jc = 0; jc < TCOLS; jc += 32) {
        __syncthreads();
        for (int idx = tid; idx < 65 * 32; idx += 256) {
            int k = idx >> 5, j = idx & 31;
            W1s[k * 36 + j] = W1cp[(size_t)k * 768 + jc + j];
        }
        __syncthreads();
        int gj = jc + 4 * ct;
        float4 q = *(const float4*)(b1p + gj);
        #pragma unroll 5
        for (int k = 0; k < 65; ++k) {
            float f = feGs[gt * 68 + k];
            float4 w = *(const float4*)&W1s[k * 36 + 4 * ct];
            q = f4fma(f, w, q);
        }
        int g = g0 + gt;
        if (g < TROWS && gj < TCOLS)
            *(float4*)(T + (size_t)g * TCOLS + gj) = q;
    }
}

// ---------------- W1ab prestage, all 5 layers: [5][128][1296] = [W1a|0|W1b|0] packed ----------------
__global__ __launch_bounds__(256) void k_w1ab5(const float* __restrict__ eW1,
                                               float* __restrict__ W1ab5) {
    int k = blockIdx.y;
    const float* W1 = eW1 + (size_t)k * 321 * 642;
    float* W1ab = W1ab5 + (size_t)k * 128 * 1296;
    int idx = blockIdx.x * 256 + threadIdx.x;
    if (idx >= 128 * 1296) return;
    int r = idx / 1296;
    int j = idx - r * 1296;
    float v = 0.f;
    if (j < 642) v = W1[(size_t)r * 642 + j];
    else if (j >= 648 && j < 1290) v = W1[(size_t)(128 + r) * 642 + (j - 648)];
    W1ab[idx] = v;
}

// ---------------- padded edge-weight prestage (all 5 layers) ----------------
__global__ __launch_bounds__(256) void k_wpre5(const float* __restrict__ eW1,
                                               const float* __restrict__ eb1,
                                               const float* __restrict__ eW2,
                                               float* __restrict__ W1cp5,   // [5][65][768]
                                               float* __restrict__ b1p5,    // [5][768]
                                               float* __restrict__ W2p5) {  // [5][768][32]
    int k = blockIdx.y;
    const float* W1 = eW1 + (size_t)k * 321 * 642;
    const float* b1 = eb1 + (size_t)k * 642;
    const float* W2 = eW2 + (size_t)k * 642 * 32;
    float* W1cp = W1cp5 + (size_t)k * 65 * 768;
    float* b1p  = b1p5 + (size_t)k * 768;
    float* W2p  = W2p5 + (size_t)k * 768 * 32;
    int idx = blockIdx.x * 256 + threadIdx.x;
    if (idx < 65 * 768) {
        int r = idx / 768, j = idx - r * 768;
        W1cp[idx] = (j < 642) ? W1[(size_t)(256 + r) * 642 + j] : 0.f;
    } else if (idx < 65 * 768 + 768) {
        int j = idx - 65 * 768;
        b1p[j] = (j < 642) ? b1[j] : 0.f;
    } else if (idx < 65 * 768 + 768 + 768 * 32) {
        int t = idx - (65 * 768 + 768);
        int j = t >> 5, c = t & 31;
        W2p[t] = (j < 642) ? W2[(size_t)j * 32 + c] : 0.f;
    }
}

// ---------------- fp32 GEMM 128x128 tile, BF16 OUTPUT (Pab only) ----------------
// Compute fully in fp32 (bit-identical accumulation), convert to bf16 RNE on store.
// Halves the C write (51.8 -> 25.9 MB) and, more importantly, halves k_edge's
// dominant Pab L2-miss stream.
__global__ __launch_bounds__(256) void k_gemm(const float* __restrict__ A, int lda,
                                              const float* __restrict__ B, int ldb,
                                              const float* __restrict__ bias,
                                              float* __restrict__ C, int ldc,  // treated as ushort*
                                              int M, int N, int K, int siluA, int siluOut) {
    __shared__ float As[32 * 132];
    __shared__ float Bs[32 * 132];
    const int tid = threadIdx.x;
    const int m0 = blockIdx.x * 128, n0 = blockIdx.y * 128;
    const int tm = tid >> 4, tn = tid & 15;

    float4 acc[8][2];
    #pragma unroll
    for (int r = 0; r < 8; ++r) { acc[r][0] = make_float4(0,0,0,0); acc[r][1] = make_float4(0,0,0,0); }

    float4 ra[4], rb[4];

#define GLOAD(kc_) do { \
    _Pragma("unroll") \
    for (int i_ = 0; i_ < 4; ++i_) { \
        int idx_ = tid + i_ * 256; \
        int m_ = idx_ >> 3, kq_ = idx_ & 7; \
        int gm_ = m0 + m_; \
        int cm_ = (gm_ < M) ? gm_ : (M - 1); \
        float4 a_ = *(const float4*)(A + (size_t)cm_ * lda + (kc_) + 4 * kq_); \
        if (gm_ >= M) a_ = make_float4(0,0,0,0); \
        ra[i_] = a_; \
    } \
    _Pragma("unroll") \
    for (int i_ = 0; i_ < 4; ++i_) { \
        int idx_ = tid + i_ * 256; \
        int r_ = idx_ >> 5, cq_ = idx_ & 31; \
        int gn_ = n0 + 4 * cq_; \
        float4 b_ = make_float4(0,0,0,0); \
        if (gn_ < N) b_ = *(const float4*)(B + (size_t)((kc_) + r_) * ldb + gn_); \
        rb[i_] = b_; \
    } \
} while (0)

    GLOAD(0);

    for (int kc = 0; kc < K; kc += 32) {
        #pragma unroll
        for (int i = 0; i < 4; ++i) {
            int idx = tid + i * 256;
            int m = idx >> 3, kq = idx & 7;
            float4 a = ra[i];
            if (siluA) { a.x = silu(a.x); a.y = silu(a.y); a.z = silu(a.z); a.w = silu(a.w); }
            As[(4 * kq + 0) * 132 + m] = a.x;
            As[(4 * kq + 1) * 132 + m] = a.y;
            As[(4 * kq + 2) * 132 + m] = a.z;
            As[(4 * kq + 3) * 132 + m] = a.w;
        }
        #pragma unroll
        for (int i = 0; i < 4; ++i) {
            int idx = tid + i * 256;
            int r = idx >> 5, cq = idx & 31;
            *(float4*)&Bs[r * 132 + 4 * cq] = rb[i];
        }
        __syncthreads();
        if (kc + 32 < K) GLOAD(kc + 32);   // in flight during FMA below
        #pragma unroll 4
        for (int kk = 0; kk < 32; ++kk) {
            float4 a0 = *(const float4*)&As[kk * 132 + 8 * tm];
            float4 a1 = *(const float4*)&As[kk * 132 + 8 * tm + 4];
            float4 b0 = *(const float4*)&Bs[kk * 132 + 4 * tn];
            float4 b1 = *(const float4*)&Bs[kk * 132 + 64 + 4 * tn];
            acc[0][0] = f4fma(a0.x, b0, acc[0][0]); acc[0][1] = f4fma(a0.x, b1, acc[0][1]);
            acc[1][0] = f4fma(a0.y, b0, acc[1][0]); acc[1][1] = f4fma(a0.y, b1, acc[1][1]);
            acc[2][0] = f4fma(a0.z, b0, acc[2][0]); acc[2][1] = f4fma(a0.z, b1, acc[2][1]);
            acc[3][0] = f4fma(a0.w, b0, acc[3][0]); acc[3][1] = f4fma(a0.w, b1, acc[3][1]);
            acc[4][0] = f4fma(a1.x, b0, acc[4][0]); acc[4][1] = f4fma(a1.x, b1, acc[4][1]);
            acc[5][0] = f4fma(a1.y, b0, acc[5][0]); acc[5][1] = f4fma(a1.y, b1, acc[5][1]);
            acc[6][0] = f4fma(a1.z, b0, acc[6][0]); acc[6][1] = f4fma(a1.z, b1, acc[6][1]);
            acc[7][0] = f4fma(a1.w, b0, acc[7][0]); acc[7][1] = f4fma(a1.w, b1, acc[7][1]);
        }
        __syncthreads();
    }
#undef GLOAD

    unsigned short* C16 = (unsigned short*)C;
    const int gnl = n0 + 4 * tn, gnh = n0 + 64 + 4 * tn;
    #pragma unroll
    for (int r = 0; r < 8; ++r) {
        int gm = m0 + 8 * tm + r;
        if (gm >= M) continue;
        float4 v0 = acc[r][0], v1 = acc[r][1];
        if (gnl < N) {
            if (bias) { v0.x += bias[gnl+0]; v0.y += bias[gnl+1]; v0.z += bias[gnl+2]; v0.w += bias[gnl+3]; }
            if (siluOut) { v0.x = silu(v0.x); v0.y = silu(v0.y); v0.z = silu(v0.z); v0.w = silu(v0.w); }
            ushort4 s0; s0.x = f2bf(v0.x); s0.y = f2bf(v0.y); s0.z = f2bf(v0.z); s0.w = f2bf(v0.w);
            *(ushort4*)&C16[(size_t)gm * ldc + gnl] = s0;
        }
        if (gnh < N) {
            if (bias) { v1.x += bias[gnh+0]; v1.y += bias[gnh+1]; v1.z += bias[gnh+2]; v1.w += bias[gnh+3]; }
            if (siluOut) { v1.x = silu(v1.x); v1.y = silu(v1.y); v1.z = silu(v1.z); v1.w = silu(v1.w); }
            ushort4 s1; s1.x = f2bf(v1.x); s1.y = f2bf(v1.y); s1.z = f2bf(v1.z); s1.w = f2bf(v1.w);
            *(ushort4*)&C16[(size_t)gm * ldc + gnh] = s1;
        }
    }
}

// ---------------- fp32 GEMM 64x128 tile: for small-N dispatches (grid fill) ----------------
__global__ __launch_bounds__(256) void k_gemm64(const float* __restrict__ A, int lda,
                                                const float* __restrict__ B, int ldb,
                                                const float* __restrict__ bias,
                                                float* __restrict__ C, int ldc,
                                                int M, int N, int K, int siluA, int siluOut) {
    __shared__ float As[32 * 68];
    __shared__ float Bs[32 * 132];
    const int tid = threadIdx.x;
    const int m0 = blockIdx.x * 64, n0 = blockIdx.y * 128;
    const int tm = tid >> 4, tn = tid & 15;

    float4 acc[4][2];
    #pragma unroll
    for (int r = 0; r < 4; ++r) { acc[r][0] = make_float4(0,0,0,0); acc[r][1] = make_float4(0,0,0,0); }

    float4 ra[2], rb[4];

#define GLOAD64(kc_) do { \
    _Pragma("unroll") \
    for (int i_ = 0; i_ < 2; ++i_) { \
        int idx_ = tid + i_ * 256; \
        int m_ = idx_ >> 3, kq_ = idx_ & 7; \
        int gm_ = m0 + m_; \
        int cm_ = (gm_ < M) ? gm_ : (M - 1); \
        float4 a_ = *(const float4*)(A + (size_t)cm_ * lda + (kc_) + 4 * kq_); \
        if (gm_ >= M) a_ = make_float4(0,0,0,0); \
        ra[i_] = a_; \
    } \
    _Pragma("unroll") \
    for (int i_ = 0; i_ < 4; ++i_) { \
        int idx_ = tid + i_ * 256; \
        int r_ = idx_ >> 5, cq_ = idx_ & 31; \
        int gn_ = n0 + 4 * cq_; \
        float4 b_ = make_float4(0,0,0,0); \
        if (gn_ < N) b_ = *(const float4*)(B + (size_t)((kc_) + r_) * ldb + gn_); \
        rb[i_] = b_; \
    } \
} while (0)

    GLOAD64(0);

    for (int kc = 0; kc < K; kc += 32) {
        #pragma unroll
        for (int i = 0; i < 2; ++i) {
            int idx = tid + i * 256;
            int m = idx >> 3, kq = idx & 7;
            float4 a = ra[i];
            if (siluA) { a.x = silu(a.x); a.y = silu(a.y); a.z = silu(a.z); a.w = silu(a.w); }
            As[(4 * kq + 0) * 68 + m] = a.x;
            As[(4 * kq + 1) * 68 + m] = a.y;
            As[(4 * kq + 2) * 68 + m] = a.z;
            As[(4 * kq + 3) * 68 + m] = a.w;
        }
        #pragma unroll
        for (int i = 0; i < 4; ++i) {
            int idx = tid + i * 256;
            int r = idx >> 5, cq = idx & 31;
            *(float4*)&Bs[r * 132 + 4 * cq] = rb[i];
        }
        __syncthreads();
        if (kc + 32 < K) GLOAD64(kc + 32);   // in flight during FMA below
        #pragma unroll 4
        for (int kk = 0; kk < 32; ++kk) {
            float4 av = *(const float4*)&As[kk * 68 + 4 * tm];
            float4 b0 = *(const float4*)&Bs[kk * 132 + 4 * tn];
            float4 b1 = *(const float4*)&Bs[kk * 132 + 64 + 4 * tn];
            acc[0][0] = f4fma(av.x, b0, acc[0][0]); acc[0][1] = f4fma(av.x, b1, acc[0][1]);
            acc[1][0] = f4fma(av.y, b0, acc[1][0]); acc[1][1] = f4fma(av.y, b1, acc[1][1]);
            acc[2][0] = f4fma(av.z, b0, acc[2][0]); acc[2][1] = f4fma(av.z, b1, acc[2][1]);
            acc[3][0] = f4fma(av.w, b0, acc[3][0]); acc[3][1] = f4fma(av.w, b1, acc[3][1]);
        }
        __syncthreads();
    }
#undef GLOAD64

    const int gnl = n0 + 4 * tn, gnh = n0 + 64 + 4 * tn;
    #pragma unroll
    for (int r = 0; r < 4; ++r) {
        int gm = m0 + 4 * tm + r;
        if (gm >= M) continue;
        float4 v0 = acc[r][0], v1 = acc[r][1];
        if (gnl < N) {
            if (bias) { v0.x += bias[gnl+0]; v0.y += bias[gnl+1]; v0.z += bias[gnl+2]; v0.w += bias[gnl+3]; }
            if (siluOut) { v0.x = silu(v0.x); v0.y = silu(v0.y); v0.z = silu(v0.z); v0.w = silu(v0.w); }
            *(float4*)&C[(size_t)gm * ldc + gnl] = v0;
        }
        if (gnh < N) {
            if (bias) { v1.x += bias[gnh+0]; v1.y += bias[gnh+1]; v1.z += bias[gnh+2]; v1.w += bias[gnh+3]; }
            if (siluOut) { v1.x = silu(v1.x); v1.y = silu(v1.y); v1.z = silu(v1.z); v1.w = silu(v1.w); }
            *(float4*)&C[(size_t)gm * ldc + gnh] = v1;
        }
    }
}

// ---------------- fused H2 GEMM + LN + residual ----------------
__global__ __launch_bounds__(256) void k_gemm_ln(const float* __restrict__ A,   // H1 [M][256]
                                                 const float* __restrict__ B,   // nW2 [256][128]
                                                 const float* __restrict__ bias,// nb2 [128]
                                                 float* __restrict__ feats_all, int layer,
                                                 const float* __restrict__ g,
                                                 const float* __restrict__ b,
                                                 int M, int K) {
    __shared__ float As[32 * 68];
    __shared__ float Bs[32 * 132];
    const int tid = threadIdx.x;
    const int m0 = blockIdx.x * 64;
    const int tm = tid >> 4, tn = tid & 15;

    float4 acc[4][2];
    #pragma unroll
    for (int r = 0; r < 4; ++r) { acc[r][0] = make_float4(0,0,0,0); acc[r][1] = make_float4(0,0,0,0); }

    float4 ra[2], rb[4];

#define GLOADL(kc_) do { \
    _Pragma("unroll") \
    for (int i_ = 0; i_ < 2; ++i_) { \
        int idx_ = tid + i_ * 256; \
        int m_ = idx_ >> 3, kq_ = idx_ & 7; \
        int gm_ = m0 + m_; \
        int cm_ = (gm_ < M) ? gm_ : (M - 1); \
        float4 a_ = *(const float4*)(A + (size_t)cm_ * 256 + (kc_) + 4 * kq_); \
        if (gm_ >= M) a_ = make_float4(0,0,0,0); \
        ra[i_] = a_; \
    } \
    _Pragma("unroll") \
    for (int i_ = 0; i_ < 4; ++i_) { \
        int idx_ = tid + i_ * 256; \
        int r_ = idx_ >> 5, cq_ = idx_ & 31; \
        float4 b_ = make_float4(0,0,0,0); \
        if (4 * cq_ < 128) b_ = *(const float4*)(B + (size_t)((kc_) + r_) * 128 + 4 * cq_); \
        rb[i_] = b_; \
    } \
} while (0)

    GLOADL(0);

    for (int kc = 0; kc < K; kc += 32) {
        #pragma unroll
        for (int i = 0; i < 2; ++i) {
            int idx = tid + i * 256;
            int m = idx >> 3, kq = idx & 7;
            float4 a = ra[i];
            As[(4 * kq + 0) * 68 + m] = a.x;
            As[(4 * kq + 1) * 68 + m] = a.y;
            As[(4 * kq + 2) * 68 + m] = a.z;
            As[(4 * kq + 3) * 68 + m] = a.w;
        }
        #pragma unroll
        for (int i = 0; i < 4; ++i) {
            int idx = tid + i * 256;
            int r = idx >> 5, cq = idx & 31;
            if (cq < 32) *(float4*)&Bs[r * 132 + 4 * cq] = rb[i];
        }
        __syncthreads();
        if (kc + 32 < K) GLOADL(kc + 32);
        #pragma unroll 4
        for (int kk = 0; kk < 32; ++kk) {
            float4 av = *(const float4*)&As[kk * 68 + 4 * tm];
            float4 b0 = *(const float4*)&Bs[kk * 132 + 4 * tn];
            float4 b1 = *(const float4*)&Bs[kk * 132 + 64 + 4 * tn];
            acc[0][0] = f4fma(av.x, b0, acc[0][0]); acc[0][1] = f4fma(av.x, b1, acc[0][1]);
            acc[1][0] = f4fma(av.y, b0, acc[1][0]); acc[1][1] = f4fma(av.y, b1, acc[1][1]);
            acc[2][0] = f4fma(av.z, b0, acc[2][0]); acc[2][1] = f4fma(av.z, b1, acc[2][1]);
            acc[3][0] = f4fma(av.w, b0, acc[3][0]); acc[3][1] = f4fma(av.w, b1, acc[3][1]);
        }
        __syncthreads();
    }
#undef GLOADL

    const int cl = 4 * tn, chh = 64 + 4 * tn;
    float4 gl = *(const float4*)(g + cl),  gh = *(const float4*)(g + chh);
    float4 bl = *(const float4*)(b + cl),  bh = *(const float4*)(b + chh);
    float4 wl = *(const float4*)(bias + cl), wh = *(const float4*)(bias + chh);
    #pragma unroll
    for (int r = 0; r < 4; ++r) {
        int gm = m0 + 4 * tm + r;
        if (gm >= M) continue;   // uniform across the 16-lane tn-group (same tm,r)
        float4 v0 = acc[r][0], v1 = acc[r][1];
        v0.x += wl.x; v0.y += wl.y; v0.z += wl.z; v0.w += wl.w;
        v1.x += wh.x; v1.y += wh.y; v1.z += wh.z; v1.w += wh.w;
        float s  = v0.x + v0.y + v0.z + v0.w + v1.x + v1.y + v1.z + v1.w;
        float ss = v0.x*v0.x + v0.y*v0.y + v0.z*v0.z + v0.w*v0.w
                 + v1.x*v1.x + v1.y*v1.y + v1.z*v1.z + v1.w*v1.w;
        s  += __shfl_xor(s, 1, 64);  ss += __shfl_xor(ss, 1, 64);
        s  += __shfl_xor(s, 2, 64);  ss += __shfl_xor(ss, 2, 64);
        s  += __shfl_xor(s, 4, 64);  ss += __shfl_xor(ss, 4, 64);
        s  += __shfl_xor(s, 8, 64);  ss += __shfl_xor(ss, 8, 64);
        float mean = s * (1.0f / 128.0f);
        float var  = ss * (1.0f / 128.0f) - mean * mean;
        float rstd = 1.0f / sqrtf(var + EPS);
        float* fp = feats_all + (size_t)gm * 768 + layer * 128;
        float4 f0 = *(const float4*)(fp + cl);
        float4 f1 = *(const float4*)(fp + chh);
        float4 o0, o1;
        o0.x = f0.x + (v0.x - mean) * rstd * gl.x + bl.x;
        o0.y = f0.y + (v0.y - mean) * rstd * gl.y + bl.y;
        o0.z = f0.z + (v0.z - mean) * rstd * gl.z + bl.z;
        o0.w = f0.w + (v0.w - mean) * rstd * gl.w + bl.w;
        o1.x = f1.x + (v1.x - mean) * rstd * gh.x + bh.x;
        o1.y = f1.y + (v1.y - mean) * rstd * gh.y + bh.y;
        o1.z = f1.z + (v1.z - mean) * rstd * gh.z + bh.z;
        o1.w = f1.w + (v1.w - mean) * rstd * gh.w + bh.w;
        float* op = feats_all + (size_t)gm * 768 + (layer + 1) * 128;
        *(float4*)(op + cl)  = o0;
        *(float4*)(op + chh) = o1;
    }
}

// ---------------- fused edge kernel v12: i0-sort, CSR store epilogue, BF16 Pab ----------------
// Pab now bf16 [N_NODES][1296]: each 8-col slice is one uint4 (16B) load instead of two
// float4 -> Pab L2-miss traffic halves (the dominant FETCH term), prefetch regs shrink
// 64->32 VGPR. Unpack via bit-shift (bf16 -> fp32 exact). T stays fp32 (L2-resident).
__global__ __launch_bounds__(256, 3) void k_edge(const int* __restrict__ ssiP,
                                                 const int* __restrict__ dsiP,
                                                 const int* __restrict__ i0P,
                                                 const float* __restrict__ frP,
                                                 const float* __restrict__ T,     // [TROWS][648]
                                                 const unsigned short* __restrict__ Pab, // [N_NODES][1296] bf16
                                                 const float* __restrict__ W2p,   // [768][32]
                                                 const float* __restrict__ b2,
                                                 const float* __restrict__ eng,
                                                 const float* __restrict__ enb,
                                                 float* __restrict__ S,
                                                 float* __restrict__ Mout,
                                                 int csr) {
    __shared__ float Zs[64 * 70];        // 17920 B; overlaid by m2s[64][36] in epilogue
    __shared__ float W2s[64 * 36];       // single-buffered W2 chunk, 9216 B
    __shared__ int dsi[EPB], ssi[EPB], i0s[EPB];
    __shared__ float frs[EPB];
    __shared__ float cpar[96];

    const int tid = threadIdx.x;
    // XCD-chunked bijective swizzle (nwg=2500, 8 XCDs: q=312, r=4 -> first 4 XCDs 313 blocks)
    const int bid = blockIdx.x;
    const int xcd = bid & 7, bpos = bid >> 3;
    const int wg = (xcd < 4) ? xcd * 313 + bpos : 1252 + (xcd - 4) * 312 + bpos;
    const int eb = wg * EPB;
    const int lane = tid & 31;           // edge-pair index (both phases)
    const int grp = tid >> 5;            // col group: phase-1 8 cols, phase-2 4 out-cols

    if (tid < EPB) {
        ssi[tid] = ssiP[eb + tid];
        dsi[tid] = dsiP[eb + tid];
        i0s[tid] = i0P[eb + tid];
        frs[tid] = frP[eb + tid];
    }
    if (tid < 32) cpar[tid] = b2[tid];
    else if (tid < 64) cpar[tid] = eng[tid - 32];
    else if (tid < 96) cpar[tid] = enb[tid - 64];
    __syncthreads();

    int dsr[2], ssr[2], i0r[2];
    float frr[2];
    #pragma unroll
    for (int i = 0; i < 2; ++i) {
        int e = 2 * lane + i;
        dsr[i] = dsi[e]; ssr[i] = ssi[e];
        i0r[i] = i0s[e]; frr[i] = frs[e];
    }

    float4 accm[2];
    accm[0] = make_float4(0,0,0,0);
    accm[1] = make_float4(0,0,0,0);

    float4 rA0[2], rA1[2], rB0[2], rB1[2];
    uint4 rp[2], rq[2];                  // 8 bf16 each (Pa / Pb slices)
    float4 rw0, rw1;

#define PREFETCH(cn) do { \
    const int colb_ = 64 * (cn) + 8 * grp; \
    if (colb_ < TCOLS) { \
        _Pragma("unroll") \
        for (int i_ = 0; i_ < 2; ++i_) { \
            const float* t0_ = T + (size_t)i0r[i_] * TCOLS + colb_; \
            rA0[i_] = *(const float4*)t0_; \
            rA1[i_] = *(const float4*)(t0_ + 4); \
            rB0[i_] = *(const float4*)(t0_ + TCOLS); \
            rB1[i_] = *(const float4*)(t0_ + TCOLS + 4); \
            rp[i_] = *(const uint4*)(Pab + (size_t)dsr[i_] * PSTRIDE + colb_); \
            rq[i_] = *(const uint4*)(Pab + (size_t)ssr[i_] * PSTRIDE + JP + colb_); \
        } \
    } \
    const float* ws_ = W2p + (size_t)(64 * (cn)) * 32 + 8 * tid; \
    rw0 = *(const float4*)ws_; rw1 = *(const float4*)(ws_ + 4); \
} while (0)

    PREFETCH(0);

    for (int ch = 0; ch < 11; ++ch) {
        const int colb = 64 * ch + 8 * grp;

        // ---- compute qa from prefetched regs (vmcnt wait lands here, post-FMA) ----
        float qa[2][8];
        if (colb < TCOLS) {
            #pragma unroll
            for (int i = 0; i < 2; ++i) {
                float f = frr[i];
                float pa[8], pb[8];
                pa[0] = __uint_as_float(rp[i].x << 16); pa[1] = __uint_as_float(rp[i].x & 0xFFFF0000u);
                pa[2] = __uint_as_float(rp[i].y << 16); pa[3] = __uint_as_float(rp[i].y & 0xFFFF0000u);
                pa[4] = __uint_as_float(rp[i].z << 16); pa[5] = __uint_as_float(rp[i].z & 0xFFFF0000u);
                pa[6] = __uint_as_float(rp[i].w << 16); pa[7] = __uint_as_float(rp[i].w & 0xFFFF0000u);
                pb[0] = __uint_as_float(rq[i].x << 16); pb[1] = __uint_as_float(rq[i].x & 0xFFFF0000u);
                pb[2] = __uint_as_float(rq[i].y << 16); pb[3] = __uint_as_float(rq[i].y & 0xFFFF0000u);
                pb[4] = __uint_as_float(rq[i].z << 16); pb[5] = __uint_as_float(rq[i].z & 0xFFFF0000u);
                pb[6] = __uint_as_float(rq[i].w << 16); pb[7] = __uint_as_float(rq[i].w & 0xFFFF0000u);
                qa[i][0] = silu(fmaf(f, rB0[i].x - rA0[i].x, rA0[i].x) + pa[0] + pb[0]);
                qa[i][1] = silu(fmaf(f, rB0[i].y - rA0[i].y, rA0[i].y) + pa[1] + pb[1]);
                qa[i][2] = silu(fmaf(f, rB0[i].z - rA0[i].z, rA0[i].z) + pa[2] + pb[2]);
                qa[i][3] = silu(fmaf(f, rB0[i].w - rA0[i].w, rA0[i].w) + pa[3] + pb[3]);
                qa[i][4] = silu(fmaf(f, rB1[i].x - rA1[i].x, rA1[i].x) + pa[4] + pb[4]);
                qa[i][5] = silu(fmaf(f, rB1[i].y - rA1[i].y, rA1[i].y) + pa[5] + pb[5]);
                qa[i][6] = silu(fmaf(f, rB1[i].z - rA1[i].z, rA1[i].z) + pa[6] + pb[6]);
                qa[i][7] = silu(fmaf(f, rB1[i].w - rA1[i].w, rA1[i].w) + pa[7] + pb[7]);
            }
        } else {
            #pragma unroll
            for (int i = 0; i < 2; ++i)
                #pragma unroll
                for (int c = 0; c < 8; ++c) qa[i][c] = 0.f;
        }

        __syncthreads();   // bA: previous FMA done -> Zs + W2s free for overwrite

        #pragma unroll
        for (int jj = 0; jj < 8; ++jj) {
            float2 z2;
            z2.x = qa[0][jj]; z2.y = qa[1][jj];
            *(float2*)&Zs[(8 * grp + jj) * 70 + 2 * lane] = z2;
        }
        {
            int wrow = tid >> 2;
            int wc0 = (2 * tid) & 7;
            *(float4*)&W2s[wrow * 36 + 4 * wc0] = rw0;
            *(float4*)&W2s[wrow * 36 + 4 * (wc0 + 1)] = rw1;
        }

        __syncthreads();   // bB: Zs + W2s published

        if (ch < 10) PREFETCH(ch + 1);   // issued BEFORE FMA -> in flight during it

        #pragma unroll 8
        for (int kk = 0; kk < 64; ++kk) {
            float2 z2 = *(const float2*)&Zs[kk * 70 + 2 * lane];
            float4 w4 = *(const float4*)&W2s[kk * 36 + 4 * grp];
            accm[0] = f4fma(z2.x, w4, accm[0]);
            accm[1] = f4fma(z2.y, w4, accm[1]);
        }
    }
#undef PREFETCH

    // ---- epilogue: m2 = silu(accm + b2), LN, store (CSR) / scatter (fallback) ----
    __syncthreads();
    float* m2s = Zs;
    {
        float4 bb2 = *(const float4*)&cpar[4 * grp];
        #pragma unroll
        for (int i = 0; i < 2; ++i) {
            int e = 2 * lane + i;
            float4 o;
            o.x = silu(accm[i].x + bb2.x);
            o.y = silu(accm[i].y + bb2.y);
            o.z = silu(accm[i].z + bb2.z);
            o.w = silu(accm[i].w + bb2.w);
            *(float4*)&m2s[e * 36 + 4 * grp] = o;
        }
    }
    __syncthreads();
    {
        int e = tid >> 2, q = tid & 3;
        float4 v0 = *(const float4*)&m2s[e * 36 + 8 * q];
        float4 v1 = *(const float4*)&m2s[e * 36 + 8 * q + 4];
        float s  = v0.x + v0.y + v0.z + v0.w + v1.x + v1.y + v1.z + v1.w;
        float ss = v0.x*v0.x + v0.y*v0.y + v0.z*v0.z + v0.w*v0.w
                 + v1.x*v1.x + v1.y*v1.y + v1.z*v1.z + v1.w*v1.w;
        s  += __shfl_xor(s, 1, 64);  ss += __shfl_xor(ss, 1, 64);
        s  += __shfl_xor(s, 2, 64);  ss += __shfl_xor(ss, 2, 64);
        float mean = s * 0.03125f;
        float var = ss * 0.03125f - mean * mean;
        float rstd = 1.0f / sqrtf(var + EPS);
        const float* gg = cpar + 32 + 8 * q;
        const float* bbv = cpar + 64 + 8 * q;
        float vv[8] = {v0.x, v0.y, v0.z, v0.w, v1.x, v1.y, v1.z, v1.w};
        float o[8];
        #pragma unroll
        for (int c = 0; c < 8; ++c) o[c] = (vv[c] - mean) * rstd * gg[c] + bbv[c];
        if (csr) {
            float* Mp = Mout + (size_t)(eb + e) * 32 + 8 * q;
            *(float4*)Mp       = make_float4(o[0], o[1], o[2], o[3]);
            *(float4*)(Mp + 4) = make_float4(o[4], o[5], o[6], o[7]);
        } else {
            int d = dsi[e];
            float* Sp = S + (size_t)d * 32 + 8 * q;
            #pragma unroll
            for (int c = 0; c < 8; ++c) atomicAdd(&Sp[c], o[c]);
        }
    }
}

// ---------------- node prep: H0[:,0:128] = LN(feats) ----------------
__global__ __launch_bounds__(128) void k_prep(const float* __restrict__ featsk,
                                              const float* __restrict__ nn1g,
                                              const float* __restrict__ nn1b,
                                              float* __restrict__ H0) {
    int n = blockIdx.x, tid = threadIdx.x;
    __shared__ float red[4];
    float x = featsk[(size_t)n * 768 + tid];
    float s = wave_sum64(x), ss = wave_sum64(x * x);
    if ((tid & 63) == 0) { red[(tid >> 6) * 2] = s; red[(tid >> 6) * 2 + 1] = ss; }
    __syncthreads();
    float S1 = red[0] + red[2], S2 = red[1] + red[3];
    float mean = S1 * (1.0f / 128.0f);
    float var = S2 * (1.0f / 128.0f) - mean * mean;
    float rstd = 1.0f / sqrtf(var + EPS);
    H0[(size_t)n * 160 + tid] = (x - mean) * rstd * nn1g[tid] + nn1b[tid];
}

// ---------------- graph pooling (batch sorted -> run-length accum) ----------------
__global__ __launch_bounds__(256) void k_pool(const float* __restrict__ F,
                                              const int* __restrict__ batch,
                                              float* __restrict__ G,
                                              float* __restrict__ cntg) {
    __shared__ int bL[32];
    int b0 = blockIdx.x * 32;
    int tid = threadIdx.x;
    int nmax = min(32, N_NODES - b0);
    if (nmax <= 0) return;
    if (tid < nmax) bL[tid] = batch[b0 + tid];
    __syncthreads();
    float accv = 0.f;
    int cur = -1;
    for (int i = 0; i < nmax; ++i) {
        int g = bL[i];
        if (g != cur) {
            if (cur >= 0) atomicAdd(&G[(size_t)cur * 256 + tid], accv);
            cur = g; accv = 0.f;
        }
        accv += F[(size_t)(b0 + i) * 256 + tid];
    }
    if (cur >= 0) atomicAdd(&G[(size_t)cur * 256 + tid], accv);
    if (tid == 0)
        for (int i = 0; i < nmax; ++i) atomicAdd(&cntg[bL[i]], 1.0f);
}

// ---------------- per-graph MLP head ----------------
__global__ __launch_bounds__(256) void k_graph(const float* __restrict__ G,
                                               const float* __restrict__ cntg,
                                               const float* __restrict__ g1W,
                                               const float* __restrict__ g1b,
                                               const float* __restrict__ g2W,
                                               const float* __restrict__ g2b,
                                               const float* __restrict__ g3W,
                                               const float* __restrict__ g3b,
                                               float* __restrict__ out) {
    __shared__ float X[256], Y[256], red[4];
    int g = blockIdx.x, tid = threadIdx.x;
    float inv = 1.0f / fmaxf(cntg[g], 1.0f);
    X[tid] = G[(size_t)g * 256 + tid] * inv;
    __syncthreads();
    float a = g1b[tid];
    for (int j = 0; j < 256; ++j) a = fmaf(X[j], g1W[(size_t)j * 256 + tid], a);
    Y[tid] = silu(a);
    __syncthreads();
    a = g2b[tid];
    for (int j = 0; j < 256; ++j) a = fmaf(Y[j], g2W[(size_t)j * 256 + tid], a);
    float z = silu(a);
    float p = z * g3W[tid];
    p = wave_sum64(p);
    if ((tid & 63) == 0) red[tid >> 6] = p;
    __syncthreads();
    if (tid == 0) out[g] = red[0] + red[1] + red[2] + red[3] + g3b[0];
}

extern "C" void kernel_launch(void* const* d_in, const int* in_sizes, int n_in,
                              void* d_out, int out_size, void* d_ws, size_t ws_size,
                              hipStream_t stream) {
    const int*   atomids = (const int*)d_in[0];
    const float* coords  = (const float*)d_in[1];
    const int*   eidx    = (const int*)d_in[2];
    const int*   batch   = (const int*)d_in[3];
    const float* emb_w   = (const float*)d_in[4];
    const float* eW1     = (const float*)d_in[5];
    const float* eb1     = (const float*)d_in[6];
    const float* eW2     = (const float*)d_in[7];
    const float* eb2     = (const float*)d_in[8];
    const float* en_g    = (const float*)d_in[9];
    const float* en_b    = (const float*)d_in[10];
    const float* nn1_g   = (const float*)d_in[11];
    const float* nn1_b   = (const float*)d_in[12];
    const float* nW1     = (const float*)d_in[13];
    const float* nb1     = (const float*)d_in[14];
    const float* nW2     = (const float*)d_in[15];
    const float* nb2     = (const float*)d_in[16];
    const float* nn2_g   = (const float*)d_in[17];
    const float* nn2_b   = (const float*)d_in[18];
    const float* f1W     = (const float*)d_in[19];
    const float* f1b     = (const float*)d_in[20];
    const float* f2W     = (const float*)d_in[21];
    const float* f2b     = (const float*)d_in[22];
    const float* f3W     = (const float*)d_in[23];
    const float* f3b     = (const float*)d_in[24];
    const float* g1W     = (const float*)d_in[25];
    const float* g1b     = (const float*)d_in[26];
    const float* g2W     = (const float*)d_in[27];
    const float* g2b     = (const float*)d_in[28];
    const float* g3W     = (const float*)d_in[29];
    const float* g3b     = (const float*)d_in[30];
    float* out = (float*)d_out;

    float* ws = (float*)d_ws;
    float* feats_all = ws;                        // [10000][768]
    float* d2g   = ws + 7680000;                  // [160000]
    float* Pab   = ws + 7840000;                  // region: bf16 [10000][1296] = 25.9MB of 51.8MB
    float* S     = ws + 20800000;                 // [10000][32] (fallback path only)
    float* cnt   = ws + 21120000;                 // [10000]
    float* W1ab5 = ws + 21130000;                 // [5][128][1296]
    float* W1cp5 = ws + 21959440;                 // [5][65][768]
    float* b1p5  = ws + 22209040;                 // [5][768]
    float* W2p5  = ws + 22212880;                 // [5][768][32]
    float* feG   = ws + 22335760;                 // [12289][68]
    float* T     = ws + 23171412;                 // [12289][648]
    float* G     = ws + 31134684;                 // [64][256]
    float* cntg  = ws + 31151068;                 // [64]
    int*   histI = (int*)(ws + 31151132);         // [12304]
    int*   offs  = (int*)(ws + 31163436);         // [12304] (persists as dst-CSR offsD)
    int*   cursor= (int*)(ws + 31175740);         // [12304]
    int*   ssiP  = (int*)(ws + 31188044);         // [160000]
    int*   dsiP  = (int*)(ws + 31348044);         // [160000]
    int*   i0P   = (int*)(ws + 31508044);         // [160000]
    float* frP   = ws + 31668044;                 // [160000]
    int*   eixD  = (int*)(ws + 31828044);         // [160000]
    float* Mbuf  = ws + 31988044;                 // [160000][32] = 20.5 MB (end 148.4 MB)
    const int useCSR = (ws_size >= (size_t)(31988044 + 5120000) * sizeof(float)) ? 1 : 0;
    unsigned short* PabU = (unsigned short*)Pab;  // bf16 view
    // node-phase temporaries overlay Pab region (dead between phases)
    float* H0 = Pab;                              // [10000][160]
    float* H1 = Pab + 1600000;                    // [10000][256]
    float* F1 = Pab;                              // [10000][256]
    float* F2 = Pab + 2560000;                    // [10000][256]
    float* F3 = Pab + 5120000;                    // [10000][256]

    k_embed<<<N_NODES, 128, 0, stream>>>(atomids, emb_w, feats_all);
    k_d2<<<(N_EDGES + 255) / 256, 256, 0, stream>>>(coords, eidx, d2g);
    hipMemsetAsync(cnt, 0, 10000 * sizeof(float), stream);
    k_cnt<<<(N_EDGES + 255) / 256, 256, 0, stream>>>(eidx, cnt);
    hipMemsetAsync(histI, 0, 12304 * sizeof(int), stream);
    k_hist<<<(N_EDGES + 255) / 256, 256, 0, stream>>>(d2g, histI);
    k_scan<<<1, 256, 0, stream>>>(histI, offs);
    k_copyi<<<(TROWS + 255) / 256, 256, 0, stream>>>(offs, cursor);
    k_scatter<<<(N_EDGES + 255) / 256, 256, 0, stream>>>(eidx, d2g, cursor,
                                                         ssiP, dsiP, i0P, frP);
    if (useCSR) {
        hipMemsetAsync(histI, 0, 12304 * sizeof(int), stream);
        k_hist_d<<<(N_EDGES + 255) / 256, 256, 0, stream>>>(dsiP, histI);
        k_scan<<<1, 256, 0, stream>>>(histI, offs);
        k_copyi<<<(TROWS + 255) / 256, 256, 0, stream>>>(offs, cursor);
        k_scatter_d<<<(N_EDGES + 255) / 256, 256, 0, stream>>>(dsiP, cursor, eixD);
    }
    k_feg<<<(TROWS + 255) / 256, 256, 0, stream>>>(feG);
    k_w1ab5<<<dim3(648, 5), 256, 0, stream>>>(eW1, W1ab5);
    k_wpre5<<<dim3(294, 5), 256, 0, stream>>>(eW1, eb1, eW2, W1cp5, b1p5, W2p5);

    for (int k = 0; k < NK; ++k) {
        const float* eb2k = eb2 + (size_t)k * 32;
        const float* engk = en_g + (size_t)k * 32;
        const float* enbk = en_b + (size_t)k * 32;
        const float* nn1gk = nn1_g + (size_t)k * 128;
        const float* nn1bk = nn1_b + (size_t)k * 128;
        const float* nW1k = nW1 + (size_t)k * 160 * 256;
        const float* nb1k = nb1 + (size_t)k * 256;
        const float* nW2k = nW2 + (size_t)k * 256 * 128;
        const float* nb2k = nb2 + (size_t)k * 128;
        const float* nn2gk = nn2_g + (size_t)k * 128;
        const float* nn2bk = nn2_b + (size_t)k * 128;

        k_tab<<<(TROWS + 31) / 32, 256, 0, stream>>>(feG,
                                                     W1cp5 + (size_t)k * 65 * 768,
                                                     b1p5 + (size_t)k * 768, T);
        // MUST write all 1296 Pab columns (k_edge reads zero-padding up to col 1295)
        k_gemm<<<dim3(79, 11), 256, 0, stream>>>(feats_all + k * 128, 768,
                                                 W1ab5 + (size_t)k * 128 * 1296, 1296,
                                                 nullptr, Pab, 1296, N_NODES, 1296, 128, 0, 0);
        if (!useCSR)
            hipMemsetAsync(S, 0, (size_t)320000 * sizeof(float), stream);
        k_edge<<<N_EDGES / EPB, 256, 0, stream>>>(ssiP, dsiP, i0P, frP, T, PabU,
                                                  W2p5 + (size_t)k * 768 * 32,
                                                  eb2k, engk, enbk, S, Mbuf, useCSR);
        if (useCSR)
            k_agg_ln<<<(N_NODES + 3) / 4, 128, 0, stream>>>(Mbuf, offs, eixD, cnt,
                                                            engk, enbk, H0);
        else
            k_s_ln<<<(N_NODES + 3) / 4, 128, 0, stream>>>(S, cnt, engk, enbk, H0);
        k_prep<<<N_NODES, 128, 0, stream>>>(feats_all + k * 128, nn1gk, nn1bk, H0);
        k_gemm64<<<dim3(157, 2), 256, 0, stream>>>(H0, 160, nW1k, 256, nb1k, H1, 256,
                                                   N_NODES, 256, 160, 0, 1);
        k_gemm_ln<<<dim3(157), 256, 0, stream>>>(H1, nW2k, nb2k, feats_all, k,
                                                 nn2gk, nn2bk, N_NODES, 256);
    }

    // final node MLP (F1/F2/F3 overlay Pab)
    k_gemm64<<<dim3(157, 2), 256, 0, stream>>>(feats_all, 768, f1W, 256, f1b, F1, 256,
                                               N_NODES, 256, 768, 1, 1);
    k_gemm64<<<dim3(157, 2), 256, 0, stream>>>(F1, 256, f2W, 256, f2b, F2, 256,
                                               N_NODES, 256, 256, 0, 1);
    k_gemm64<<<dim3(157, 2), 256, 0, stream>>>(F2, 256, f3W, 256, f3b, F3, 256,
                                               N_NODES, 256, 256, 0, 1);

    hipMemsetAsync(G, 0, (size_t)(16384 + 64) * sizeof(float), stream);
    k_pool<<<313, 256, 0, stream>>>(F3, batch, G, cntg);
    k_graph<<<N_GRAPHS, 256, 0, stream>>>(G, cntg, g1W, g1b, g2W, g2b, g3W, g3b, out);
}

// Round 16
// 2484.326 us; speedup vs baseline: 1.1043x; 1.1043x over previous
//
#include <hip/hip_runtime.h>
#include <hip/hip_bf16.h>

#define N_NODES 10000
#define N_EDGES 160000
#define N_GRAPHS 64
#define NK 5
#define EPS 1e-5f
#define EPB 64           // edges per block (256 threads)
#define JP 648           // packed width for Pab halves
#define PSTRIDE 1296     // Pab row stride (bf16 elems): [Pa 648 | Pb 648]
#define TCOLS 648        // table row width (642 -> 648)
#define TROWS 12289      // d2 grid [0,96], h=1/128
#define IMAX 12287

// MFMA fragment types: gfx950 mfma_f32_16x16x32_bf16 takes v8bf16 operands (LLVM PR #116312).
// NOTE: ext_vector_type(8) short FAILS to type-check against this builtin (root cause of the
// two container failures) -- __bf16 vector is the correct operand type.
typedef __attribute__((ext_vector_type(8))) __bf16 bf16v8;
typedef __attribute__((ext_vector_type(4))) float f32x4;

__device__ __forceinline__ float silu(float x) { return x / (1.0f + __expf(-x)); }
__device__ __forceinline__ float4 f4fma(float s, float4 w, float4 a) {
    a.x = fmaf(s, w.x, a.x); a.y = fmaf(s, w.y, a.y);
    a.z = fmaf(s, w.z, a.z); a.w = fmaf(s, w.w, a.w);
    return a;
}
__device__ __forceinline__ float wave_sum64(float v) {
    #pragma unroll
    for (int off = 32; off > 0; off >>= 1) v += __shfl_xor(v, off, 64);
    return v;
}
// fp32 -> bf16 (round to nearest even), returned as raw bits
__device__ __forceinline__ unsigned short f2bf(float f) {
    unsigned int u = __float_as_uint(f);
    unsigned int r = u + 0x7FFFu + ((u >> 16) & 1u);
    return (unsigned short)(r >> 16);
}

// ---------------- embedding ----------------
__global__ __launch_bounds__(128) void k_embed(const int* __restrict__ atomids,
                                               const float* __restrict__ emb_w,
                                               float* __restrict__ feats_all) {
    int n = blockIdx.x, tid = threadIdx.x;
    feats_all[(size_t)n * 768 + tid] = emb_w[(size_t)atomids[n] * 128 + tid];
}

// ---------------- per-edge squared distance ----------------
__global__ __launch_bounds__(256) void k_d2(const float* __restrict__ coords,
                                            const int* __restrict__ eidx,
                                            float* __restrict__ d2g) {
    int e = blockIdx.x * 256 + threadIdx.x;
    if (e >= N_EDGES) return;
    int s = eidx[e], d = eidx[N_EDGES + e];
    float dx = coords[s * 3 + 0] - coords[d * 3 + 0];
    float dy = coords[s * 3 + 1] - coords[d * 3 + 1];
    float dz = coords[s * 3 + 2] - coords[d * 3 + 2];
    d2g[e] = dx * dx + dy * dy + dz * dz;
}

// ---------------- in-degree (layer-invariant) ----------------
__global__ __launch_bounds__(256) void k_cnt(const int* __restrict__ eidx,
                                             float* __restrict__ cnt) {
    int e = blockIdx.x * 256 + threadIdx.x;
    if (e >= N_EDGES) return;
    atomicAdd(&cnt[eidx[N_EDGES + e]], 1.0f);
}

// ---------------- counting sort of edges by i0 (T-row index) ----------------
__global__ __launch_bounds__(256) void k_hist(const float* __restrict__ d2g,
                                              int* __restrict__ hist) {
    int e = blockIdx.x * 256 + threadIdx.x;
    if (e >= N_EDGES) return;
    int i0 = (int)(d2g[e] * 128.0f);
    if (i0 > IMAX) i0 = IMAX;
    atomicAdd(&hist[i0], 1);
}

__global__ __launch_bounds__(256) void k_scan(const int* __restrict__ hist,
                                              int* __restrict__ offs) {
    __shared__ int buf[256];
    __shared__ int carryS;
    int tid = threadIdx.x;
    if (tid == 0) carryS = 0;
    __syncthreads();
    for (int base = 0; base < TROWS; base += 256) {
        int v = (base + tid < TROWS) ? hist[base + tid] : 0;
        buf[tid] = v;
        __syncthreads();
        for (int off = 1; off < 256; off <<= 1) {
            int t = (tid >= off) ? buf[tid - off] : 0;
            __syncthreads();
            buf[tid] += t;
            __syncthreads();
        }
        if (base + tid < TROWS) offs[base + tid] = carryS + buf[tid] - v;  // exclusive
        __syncthreads();
        if (tid == 0) carryS += buf[255];
        __syncthreads();
    }
}

__global__ __launch_bounds__(256) void k_copyi(const int* __restrict__ a,
                                               int* __restrict__ b) {
    int i = blockIdx.x * 256 + threadIdx.x;
    if (i < TROWS) b[i] = a[i];
}

__global__ __launch_bounds__(256) void k_scatter(const int* __restrict__ eidx,
                                                 const float* __restrict__ d2g,
                                                 int* __restrict__ cursor,
                                                 int* __restrict__ ssiP,
                                                 int* __restrict__ dsiP,
                                                 int* __restrict__ i0P,
                                                 float* __restrict__ frP) {
    int e = blockIdx.x * 256 + threadIdx.x;
    if (e >= N_EDGES) return;
    float t = d2g[e] * 128.0f;
    int i0 = (int)t;
    if (i0 > IMAX) i0 = IMAX;
    float fr = t - (float)i0;
    int pos = atomicAdd(&cursor[i0], 1);
    ssiP[pos] = eidx[e];
    dsiP[pos] = eidx[N_EDGES + e];
    i0P[pos] = i0;
    frP[pos] = fr;
}

// ---------------- dst-CSR over sorted positions (for atomic-free S aggregation) ----------------
__global__ __launch_bounds__(256) void k_hist_d(const int* __restrict__ dsiP,
                                                int* __restrict__ hist) {
    int p = blockIdx.x * 256 + threadIdx.x;
    if (p >= N_EDGES) return;
    atomicAdd(&hist[dsiP[p]], 1);
}

__global__ __launch_bounds__(256) void k_scatter_d(const int* __restrict__ dsiP,
                                                   int* __restrict__ cursorD,
                                                   int* __restrict__ eixD) {
    int p = blockIdx.x * 256 + threadIdx.x;
    if (p >= N_EDGES) return;
    int pos = atomicAdd(&cursorD[dsiP[p]], 1);
    eixD[pos] = p;
}

// ---------------- CSR aggregation fused with mean + LN: writes H0[:,128:160] ----------------
__global__ __launch_bounds__(128) void k_agg_ln(const float* __restrict__ M,
                                                const int* __restrict__ offsD,
                                                const int* __restrict__ eixD,
                                                const float* __restrict__ cnt,
                                                const float* __restrict__ eng,
                                                const float* __restrict__ enb,
                                                float* __restrict__ H0) {
    int n = blockIdx.x * 4 + (threadIdx.x >> 5);
    int col = threadIdx.x & 31;
    if (n >= N_NODES) return;
    float acc = 0.f;
    int p0 = offsD[n], p1 = offsD[n + 1];
    for (int p = p0; p < p1; ++p)
        acc += M[(size_t)eixD[p] * 32 + col];
    float inv = 1.0f / fmaxf(cnt[n], 1.0f);
    float v = acc * inv;
    float s = v, q = v * v;
    #pragma unroll
    for (int off = 16; off > 0; off >>= 1) {
        s += __shfl_xor(s, off, 64);
        q += __shfl_xor(q, off, 64);
    }
    float m2 = s * (1.0f / 32.0f);
    float va = q * (1.0f / 32.0f) - m2 * m2;
    float rs = 1.0f / sqrtf(va + EPS);
    H0[(size_t)n * 160 + 128 + col] = (v - m2) * rs * eng[col] + enb[col];
}

// ---------------- fallback (no-CSR): S -> mean -> LN -> H0[:,128:160] ----------------
__global__ __launch_bounds__(128) void k_s_ln(const float* __restrict__ S,
                                              const float* __restrict__ cnt,
                                              const float* __restrict__ eng,
                                              const float* __restrict__ enb,
                                              float* __restrict__ H0) {
    int n = blockIdx.x * 4 + (threadIdx.x >> 5);
    int col = threadIdx.x & 31;
    if (n >= N_NODES) return;
    float inv = 1.0f / fmaxf(cnt[n], 1.0f);
    float v = S[(size_t)n * 32 + col] * inv;
    float s = v, q = v * v;
    #pragma unroll
    for (int off = 16; off > 0; off >>= 1) {
        s += __shfl_xor(s, off, 64);
        q += __shfl_xor(q, off, 64);
    }
    float m2 = s * (1.0f / 32.0f);
    float va = q * (1.0f / 32.0f) - m2 * m2;
    float rs = 1.0f / sqrtf(va + EPS);
    H0[(size_t)n * 160 + 128 + col] = (v - m2) * rs * eng[col] + enb[col];
}

// ---------------- fourier features on the d2 GRID (once) ----------------
__global__ __launch_bounds__(256) void k_feg(float* __restrict__ feG) {  // [TROWS][68]
    int g = blockIdx.x * 256 + threadIdx.x;
    if (g >= TROWS) return;
    float d2v = (float)g * 0.0078125f;   // g / 128, exact
    float* o = feG + (size_t)g * 68;
    float sc = 1.0f;
    #pragma unroll
    for (int i = 0; i < 32; ++i) {
        float x = d2v * sc;
        o[i] = sinf(x);
        o[32 + i] = cosf(x);
        sc *= 0.5f;
    }
    o[64] = d2v;
}

// ---------------- per-layer q-table: T[g][j] = fe(g/128) @ W1c + b1 ----------------
__global__ __launch_bounds__(256) void k_tab(const float* __restrict__ feG,   // [TROWS][68]
                                             const float* __restrict__ W1cp,  // [65][768]
                                             const float* __restrict__ b1p,   // [768]
                                             float* __restrict__ T) {         // [TROWS][648]
    __shared__ float feGs[32 * 68];
    __shared__ float W1s[65 * 36];
    const int tid = threadIdx.x;
    const int g0 = blockIdx.x * 32;
    for (int idx = tid; idx < 32 * 17; idx += 256) {
        int r = idx / 17, c = idx - r * 17;
        int gi = g0 + r;
        float4 v = make_float4(0, 0, 0, 0);
        if (gi < TROWS) v = *(const float4*)(feG + (size_t)gi * 68 + 4 * c);
        *(float4*)&feGs[r * 68 + 4 * c] = v;
    }
    const int gt = tid >> 3, ct = tid & 7;
    for (int jc = 0; jc < TCOLS; jc += 32) {
        __syncthreads();
        for (int idx = tid; idx < 65 * 32; idx += 256) {
            int k = idx >> 5, j = idx & 31;
            W1s[k * 36 + j] = W1cp[(size_t)k * 768 + jc + j];
        }
        __syncthreads();
        int gj = jc + 4 * ct;
        float4 q = *(const float4*)(b1p + gj);
        #pragma unroll 5
        for (int k = 0; k < 65; ++k) {
            float f = feGs[gt * 68 + k];
            float4 w = *(const float4*)&W1s[k * 36 + 4 * ct];
            q = f4fma(f, w, q);
        }
        int g = g0 + gt;
        if (g < TROWS && gj < TCOLS)
            *(float4*)(T + (size_t)g * TCOLS + gj) = q;
    }
}

// ---------------- W1ab prestage (fp32, fallback path only) ----------------
__global__ __launch_bounds__(256) void k_w1ab5(const float* __restrict__ eW1,
                                               float* __restrict__ W1ab5) {
    int k = blockIdx.y;
    const float* W1 = eW1 + (size_t)k * 321 * 642;
    float* W1ab = W1ab5 + (size_t)k * 128 * 1296;
    int idx = blockIdx.x * 256 + threadIdx.x;
    if (idx >= 128 * 1296) return;
    int r = idx / 1296;
    int j = idx - r * 1296;
    float v = 0.f;
    if (j < 642) v = W1[(size_t)r * 642 + j];
    else if (j >= 648 && j < 1290) v = W1[(size_t)(128 + r) * 642 + (j - 648)];
    W1ab[idx] = v;
}

// ---------------- MFMA B-fragment prestage: Bpack[5][16][1296][8] bf16 ----------------
// Bpack[k][kg][c][jj] = W1ab(row = kg*8+jj, col c) as bf16. One 16B load per B-frag.
__global__ __launch_bounds__(256) void k_bpack5(const float* __restrict__ eW1,
                                                unsigned short* __restrict__ Bp5) {
    int idx = blockIdx.x * 256 + threadIdx.x;
    if (idx >= 16 * 1296 * 8) return;
    int k = blockIdx.y;
    int kg = idx / (1296 * 8);
    int rem = idx - kg * (1296 * 8);
    int c = rem >> 3, jj = rem & 7;
    int r = kg * 8 + jj;             // K index 0..127
    const float* W1 = eW1 + (size_t)k * 321 * 642;
    float v = 0.f;
    if (c < 642) v = W1[(size_t)r * 642 + c];
    else if (c >= 648 && c < 1290) v = W1[(size_t)(128 + r) * 642 + (c - 648)];
    Bp5[(size_t)k * 165888 + idx] = f2bf(v);
}

// ---------------- MFMA A-fragment staging (per layer): Apack[16][10000][8] bf16 ----------------
__global__ __launch_bounds__(256) void k_apack(const float* __restrict__ feats, // + k*128, stride 768
                                               unsigned short* __restrict__ Ap) {
    int t = blockIdx.x * 256 + threadIdx.x;   // t: m = t>>4, kg = t&15
    if (t >= N_NODES * 16) return;
    int m = t >> 4, kg = t & 15;
    const float* src = feats + (size_t)m * 768 + kg * 8;
    unsigned short* dst = Ap + ((size_t)kg * N_NODES + m) * 8;
    #pragma unroll
    for (int j = 0; j < 8; ++j) dst[j] = f2bf(src[j]);
}

// ---------------- Pab GEMM on matrix cores: bf16 in, fp32 MFMA accum, bf16 out ----------------
// Block 64x64 tile, 4 waves (2x2), each wave 32x32 = 2x2 mfma_f32_16x16x32_bf16 tiles.
// A-frag: lane l -> row = l&15, k = 8*(l>>4)+j (prepacked -> one 16B load).
// B-frag: lane l -> col = l&15, same k (prepacked). D: row=(l>>4)*4+reg, col=l&15 (guide-verified).
__global__ __launch_bounds__(256) void k_gemm_mfma(const unsigned short* __restrict__ Ap, // [16][M][8]
                                                   const unsigned short* __restrict__ Bp, // [16][1296][8]
                                                   unsigned short* __restrict__ C,        // [M][1296] bf16
                                                   int M) {
    const int tid = threadIdx.x;
    const int w = tid >> 6, l = tid & 63;
    const int m0 = blockIdx.x * 64 + (w >> 1) * 32;
    const int n0 = blockIdx.y * 64 + (w & 1) * 32;
    const int lr = l & 15, lg = l >> 4;

    f32x4 acc[2][2] = {};
    for (int kb = 0; kb < 4; ++kb) {
        const int kg = kb * 4 + lg;
        bf16v8 a[2], b[2];
        #pragma unroll
        for (int i = 0; i < 2; ++i) {
            int mrow = m0 + i * 16 + lr; if (mrow >= M) mrow = M - 1;
            a[i] = *(const bf16v8*)(Ap + ((size_t)kg * M + mrow) * 8);
            int ncol = n0 + i * 16 + lr; if (ncol > 1295) ncol = 1295;
            b[i] = *(const bf16v8*)(Bp + ((size_t)kg * 1296 + ncol) * 8);
        }
        #pragma unroll
        for (int mi = 0; mi < 2; ++mi)
            #pragma unroll
            for (int ni = 0; ni < 2; ++ni)
                acc[mi][ni] = __builtin_amdgcn_mfma_f32_16x16x32_bf16(a[mi], b[ni], acc[mi][ni], 0, 0, 0);
    }
    #pragma unroll
    for (int mi = 0; mi < 2; ++mi)
        #pragma unroll
        for (int ni = 0; ni < 2; ++ni)
            #pragma unroll
            for (int j = 0; j < 4; ++j) {
                int gm = m0 + mi * 16 + lg * 4 + j;
                int gn = n0 + ni * 16 + lr;
                if (gm < M && gn < 1296)
                    C[(size_t)gm * 1296 + gn] = f2bf(acc[mi][ni][j]);
            }
}

// ---------------- padded edge-weight prestage (all 5 layers) ----------------
__global__ __launch_bounds__(256) void k_wpre5(const float* __restrict__ eW1,
                                               const float* __restrict__ eb1,
                                               const float* __restrict__ eW2,
                                               float* __restrict__ W1cp5,   // [5][65][768]
                                               float* __restrict__ b1p5,    // [5][768]
                                               float* __restrict__ W2p5) {  // [5][768][32]
    int k = blockIdx.y;
    const float* W1 = eW1 + (size_t)k * 321 * 642;
    const float* b1 = eb1 + (size_t)k * 642;
    const float* W2 = eW2 + (size_t)k * 642 * 32;
    float* W1cp = W1cp5 + (size_t)k * 65 * 768;
    float* b1p  = b1p5 + (size_t)k * 768;
    float* W2p  = W2p5 + (size_t)k * 768 * 32;
    int idx = blockIdx.x * 256 + threadIdx.x;
    if (idx < 65 * 768) {
        int r = idx / 768, j = idx - r * 768;
        W1cp[idx] = (j < 642) ? W1[(size_t)(256 + r) * 642 + j] : 0.f;
    } else if (idx < 65 * 768 + 768) {
        int j = idx - 65 * 768;
        b1p[j] = (j < 642) ? b1[j] : 0.f;
    } else if (idx < 65 * 768 + 768 + 768 * 32) {
        int t = idx - (65 * 768 + 768);
        int j = t >> 5, c = t & 31;
        W2p[t] = (j < 642) ? W2[(size_t)j * 32 + c] : 0.f;
    }
}

// ---------------- fp32 GEMM 128x128 tile, BF16 OUTPUT (Pab fallback path) ----------------
__global__ __launch_bounds__(256) void k_gemm(const float* __restrict__ A, int lda,
                                              const float* __restrict__ B, int ldb,
                                              const float* __restrict__ bias,
                                              float* __restrict__ C, int ldc,  // treated as ushort*
                                              int M, int N, int K, int siluA, int siluOut) {
    __shared__ float As[32 * 132];
    __shared__ float Bs[32 * 132];
    const int tid = threadIdx.x;
    const int m0 = blockIdx.x * 128, n0 = blockIdx.y * 128;
    const int tm = tid >> 4, tn = tid & 15;

    float4 acc[8][2];
    #pragma unroll
    for (int r = 0; r < 8; ++r) { acc[r][0] = make_float4(0,0,0,0); acc[r][1] = make_float4(0,0,0,0); }

    float4 ra[4], rb[4];

#define GLOAD(kc_) do { \
    _Pragma("unroll") \
    for (int i_ = 0; i_ < 4; ++i_) { \
        int idx_ = tid + i_ * 256; \
        int m_ = idx_ >> 3, kq_ = idx_ & 7; \
        int gm_ = m0 + m_; \
        int cm_ = (gm_ < M) ? gm_ : (M - 1); \
        float4 a_ = *(const float4*)(A + (size_t)cm_ * lda + (kc_) + 4 * kq_); \
        if (gm_ >= M) a_ = make_float4(0,0,0,0); \
        ra[i_] = a_; \
    } \
    _Pragma("unroll") \
    for (int i_ = 0; i_ < 4; ++i_) { \
        int idx_ = tid + i_ * 256; \
        int r_ = idx_ >> 5, cq_ = idx_ & 31; \
        int gn_ = n0 + 4 * cq_; \
        float4 b_ = make_float4(0,0,0,0); \
        if (gn_ < N) b_ = *(const float4*)(B + (size_t)((kc_) + r_) * ldb + gn_); \
        rb[i_] = b_; \
    } \
} while (0)

    GLOAD(0);

    for (int kc = 0; kc < K; kc += 32) {
        #pragma unroll
        for (int i = 0; i < 4; ++i) {
            int idx = tid + i * 256;
            int m = idx >> 3, kq = idx & 7;
            float4 a = ra[i];
            if (siluA) { a.x = silu(a.x); a.y = silu(a.y); a.z = silu(a.z); a.w = silu(a.w); }
            As[(4 * kq + 0) * 132 + m] = a.x;
            As[(4 * kq + 1) * 132 + m] = a.y;
            As[(4 * kq + 2) * 132 + m] = a.z;
            As[(4 * kq + 3) * 132 + m] = a.w;
        }
        #pragma unroll
        for (int i = 0; i < 4; ++i) {
            int idx = tid + i * 256;
            int r = idx >> 5, cq = idx & 31;
            *(float4*)&Bs[r * 132 + 4 * cq] = rb[i];
        }
        __syncthreads();
        if (kc + 32 < K) GLOAD(kc + 32);   // in flight during FMA below
        #pragma unroll 4
        for (int kk = 0; kk < 32; ++kk) {
            float4 a0 = *(const float4*)&As[kk * 132 + 8 * tm];
            float4 a1 = *(const float4*)&As[kk * 132 + 8 * tm + 4];
            float4 b0 = *(const float4*)&Bs[kk * 132 + 4 * tn];
            float4 b1 = *(const float4*)&Bs[kk * 132 + 64 + 4 * tn];
            acc[0][0] = f4fma(a0.x, b0, acc[0][0]); acc[0][1] = f4fma(a0.x, b1, acc[0][1]);
            acc[1][0] = f4fma(a0.y, b0, acc[1][0]); acc[1][1] = f4fma(a0.y, b1, acc[1][1]);
            acc[2][0] = f4fma(a0.z, b0, acc[2][0]); acc[2][1] = f4fma(a0.z, b1, acc[2][1]);
            acc[3][0] = f4fma(a0.w, b0, acc[3][0]); acc[3][1] = f4fma(a0.w, b1, acc[3][1]);
            acc[4][0] = f4fma(a1.x, b0, acc[4][0]); acc[4][1] = f4fma(a1.x, b1, acc[4][1]);
            acc[5][0] = f4fma(a1.y, b0, acc[5][0]); acc[5][1] = f4fma(a1.y, b1, acc[5][1]);
            acc[6][0] = f4fma(a1.z, b0, acc[6][0]); acc[6][1] = f4fma(a1.z, b1, acc[6][1]);
            acc[7][0] = f4fma(a1.w, b0, acc[7][0]); acc[7][1] = f4fma(a1.w, b1, acc[7][1]);
        }
        __syncthreads();
    }
#undef GLOAD

    unsigned short* C16 = (unsigned short*)C;
    const int gnl = n0 + 4 * tn, gnh = n0 + 64 + 4 * tn;
    #pragma unroll
    for (int r = 0; r < 8; ++r) {
        int gm = m0 + 8 * tm + r;
        if (gm >= M) continue;
        float4 v0 = acc[r][0], v1 = acc[r][1];
        if (gnl < N) {
            if (bias) { v0.x += bias[gnl+0]; v0.y += bias[gnl+1]; v0.z += bias[gnl+2]; v0.w += bias[gnl+3]; }
            if (siluOut) { v0.x = silu(v0.x); v0.y = silu(v0.y); v0.z = silu(v0.z); v0.w = silu(v0.w); }
            ushort4 s0; s0.x = f2bf(v0.x); s0.y = f2bf(v0.y); s0.z = f2bf(v0.z); s0.w = f2bf(v0.w);
            *(ushort4*)&C16[(size_t)gm * ldc + gnl] = s0;
        }
        if (gnh < N) {
            if (bias) { v1.x += bias[gnh+0]; v1.y += bias[gnh+1]; v1.z += bias[gnh+2]; v1.w += bias[gnh+3]; }
            if (siluOut) { v1.x = silu(v1.x); v1.y = silu(v1.y); v1.z = silu(v1.z); v1.w = silu(v1.w); }
            ushort4 s1; s1.x = f2bf(v1.x); s1.y = f2bf(v1.y); s1.z = f2bf(v1.z); s1.w = f2bf(v1.w);
            *(ushort4*)&C16[(size_t)gm * ldc + gnh] = s1;
        }
    }
}

// ---------------- fp32 GEMM 64x128 tile: for small-N dispatches (grid fill) ----------------
__global__ __launch_bounds__(256) void k_gemm64(const float* __restrict__ A, int lda,
                                                const float* __restrict__ B, int ldb,
                                                const float* __restrict__ bias,
                                                float* __restrict__ C, int ldc,
                                                int M, int N, int K, int siluA, int siluOut) {
    __shared__ float As[32 * 68];
    __shared__ float Bs[32 * 132];
    const int tid = threadIdx.x;
    const int m0 = blockIdx.x * 64, n0 = blockIdx.y * 128;
    const int tm = tid >> 4, tn = tid & 15;

    float4 acc[4][2];
    #pragma unroll
    for (int r = 0; r < 4; ++r) { acc[r][0] = make_float4(0,0,0,0); acc[r][1] = make_float4(0,0,0,0); }

    float4 ra[2], rb[4];

#define GLOAD64(kc_) do { \
    _Pragma("unroll") \
    for (int i_ = 0; i_ < 2; ++i_) { \
        int idx_ = tid + i_ * 256; \
        int m_ = idx_ >> 3, kq_ = idx_ & 7; \
        int gm_ = m0 + m_; \
        int cm_ = (gm_ < M) ? gm_ : (M - 1); \
        float4 a_ = *(const float4*)(A + (size_t)cm_ * lda + (kc_) + 4 * kq_); \
        if (gm_ >= M) a_ = make_float4(0,0,0,0); \
        ra[i_] = a_; \
    } \
    _Pragma("unroll") \
    for (int i_ = 0; i_ < 4; ++i_) { \
        int idx_ = tid + i_ * 256; \
        int r_ = idx_ >> 5, cq_ = idx_ & 31; \
        int gn_ = n0 + 4 * cq_; \
        float4 b_ = make_float4(0,0,0,0); \
        if (gn_ < N) b_ = *(const float4*)(B + (size_t)((kc_) + r_) * ldb + gn_); \
        rb[i_] = b_; \
    } \
} while (0)

    GLOAD64(0);

    for (int kc = 0; kc < K; kc += 32) {
        #pragma unroll
        for (int i = 0; i < 2; ++i) {
            int idx = tid + i * 256;
            int m = idx >> 3, kq = idx & 7;
            float4 a = ra[i];
            if (siluA) { a.x = silu(a.x); a.y = silu(a.y); a.z = silu(a.z); a.w = silu(a.w); }
            As[(4 * kq + 0) * 68 + m] = a.x;
            As[(4 * kq + 1) * 68 + m] = a.y;
            As[(4 * kq + 2) * 68 + m] = a.z;
            As[(4 * kq + 3) * 68 + m] = a.w;
        }
        #pragma unroll
        for (int i = 0; i < 4; ++i) {
            int idx = tid + i * 256;
            int r = idx >> 5, cq = idx & 31;
            *(float4*)&Bs[r * 132 + 4 * cq] = rb[i];
        }
        __syncthreads();
        if (kc + 32 < K) GLOAD64(kc + 32);   // in flight during FMA below
        #pragma unroll 4
        for (int kk = 0; kk < 32; ++kk) {
            float4 av = *(const float4*)&As[kk * 68 + 4 * tm];
            float4 b0 = *(const float4*)&Bs[kk * 132 + 4 * tn];
            float4 b1 = *(const float4*)&Bs[kk * 132 + 64 + 4 * tn];
            acc[0][0] = f4fma(av.x, b0, acc[0][0]); acc[0][1] = f4fma(av.x, b1, acc[0][1]);
            acc[1][0] = f4fma(av.y, b0, acc[1][0]); acc[1][1] = f4fma(av.y, b1, acc[1][1]);
            acc[2][0] = f4fma(av.z, b0, acc[2][0]); acc[2][1] = f4fma(av.z, b1, acc[2][1]);
            acc[3][0] = f4fma(av.w, b0, acc[3][0]); acc[3][1] = f4fma(av.w, b1, acc[3][1]);
        }
        __syncthreads();
    }
#undef GLOAD64

    const int gnl = n0 + 4 * tn, gnh = n0 + 64 + 4 * tn;
    #pragma unroll
    for (int r = 0; r < 4; ++r) {
        int gm = m0 + 4 * tm + r;
        if (gm >= M) continue;
        float4 v0 = acc[r][0], v1 = acc[r][1];
        if (gnl < N) {
            if (bias) { v0.x += bias[gnl+0]; v0.y += bias[gnl+1]; v0.z += bias[gnl+2]; v0.w += bias[gnl+3]; }
            if (siluOut) { v0.x = silu(v0.x); v0.y = silu(v0.y); v0.z = silu(v0.z); v0.w = silu(v0.w); }
            *(float4*)&C[(size_t)gm * ldc + gnl] = v0;
        }
        if (gnh < N) {
            if (bias) { v1.x += bias[gnh+0]; v1.y += bias[gnh+1]; v1.z += bias[gnh+2]; v1.w += bias[gnh+3]; }
            if (siluOut) { v1.x = silu(v1.x); v1.y = silu(v1.y); v1.z = silu(v1.z); v1.w = silu(v1.w); }
            *(float4*)&C[(size_t)gm * ldc + gnh] = v1;
        }
    }
}

// ---------------- fused H2 GEMM + LN + residual ----------------
__global__ __launch_bounds__(256) void k_gemm_ln(const float* __restrict__ A,   // H1 [M][256]
                                                 const float* __restrict__ B,   // nW2 [256][128]
                                                 const float* __restrict__ bias,// nb2 [128]
                                                 float* __restrict__ feats_all, int layer,
                                                 const float* __restrict__ g,
                                                 const float* __restrict__ b,
                                                 int M, int K) {
    __shared__ float As[32 * 68];
    __shared__ float Bs[32 * 132];
    const int tid = threadIdx.x;
    const int m0 = blockIdx.x * 64;
    const int tm = tid >> 4, tn = tid & 15;

    float4 acc[4][2];
    #pragma unroll
    for (int r = 0; r < 4; ++r) { acc[r][0] = make_float4(0,0,0,0); acc[r][1] = make_float4(0,0,0,0); }

    float4 ra[2], rb[4];

#define GLOADL(kc_) do { \
    _Pragma("unroll") \
    for (int i_ = 0; i_ < 2; ++i_) { \
        int idx_ = tid + i_ * 256; \
        int m_ = idx_ >> 3, kq_ = idx_ & 7; \
        int gm_ = m0 + m_; \
        int cm_ = (gm_ < M) ? gm_ : (M - 1); \
        float4 a_ = *(const float4*)(A + (size_t)cm_ * 256 + (kc_) + 4 * kq_); \
        if (gm_ >= M) a_ = make_float4(0,0,0,0); \
        ra[i_] = a_; \
    } \
    _Pragma("unroll") \
    for (int i_ = 0; i_ < 4; ++i_) { \
        int idx_ = tid + i_ * 256; \
        int r_ = idx_ >> 5, cq_ = idx_ & 31; \
        float4 b_ = make_float4(0,0,0,0); \
        if (4 * cq_ < 128) b_ = *(const float4*)(B + (size_t)((kc_) + r_) * 128 + 4 * cq_); \
        rb[i_] = b_; \
    } \
} while (0)

    GLOADL(0);

    for (int kc = 0; kc < K; kc += 32) {
        #pragma unroll
        for (int i = 0; i < 2; ++i) {
            int idx = tid + i * 256;
            int m = idx >> 3, kq = idx & 7;
            float4 a = ra[i];
            As[(4 * kq + 0) * 68 + m] = a.x;
            As[(4 * kq + 1) * 68 + m] = a.y;
            As[(4 * kq + 2) * 68 + m] = a.z;
            As[(4 * kq + 3) * 68 + m] = a.w;
        }
        #pragma unroll
        for (int i = 0; i < 4; ++i) {
            int idx = tid + i * 256;
            int r = idx >> 5, cq = idx & 31;
            if (cq < 32) *(float4*)&Bs[r * 132 + 4 * cq] = rb[i];
        }
        __syncthreads();
        if (kc + 32 < K) GLOADL(kc + 32);
        #pragma unroll 4
        for (int kk = 0; kk < 32; ++kk) {
            float4 av = *(const float4*)&As[kk * 68 + 4 * tm];
            float4 b0 = *(const float4*)&Bs[kk * 132 + 4 * tn];
            float4 b1 = *(const float4*)&Bs[kk * 132 + 64 + 4 * tn];
            acc[0][0] = f4fma(av.x, b0, acc[0][0]); acc[0][1] = f4fma(av.x, b1, acc[0][1]);
            acc[1][0] = f4fma(av.y, b0, acc[1][0]); acc[1][1] = f4fma(av.y, b1, acc[1][1]);
            acc[2][0] = f4fma(av.z, b0, acc[2][0]); acc[2][1] = f4fma(av.z, b1, acc[2][1]);
            acc[3][0] = f4fma(av.w, b0, acc[3][0]); acc[3][1] = f4fma(av.w, b1, acc[3][1]);
        }
        __syncthreads();
    }
#undef GLOADL

    const int cl = 4 * tn, chh = 64 + 4 * tn;
    float4 gl = *(const float4*)(g + cl),  gh = *(const float4*)(g + chh);
    float4 bl = *(const float4*)(b + cl),  bh = *(const float4*)(b + chh);
    float4 wl = *(const float4*)(bias + cl), wh = *(const float4*)(bias + chh);
    #pragma unroll
    for (int r = 0; r < 4; ++r) {
        int gm = m0 + 4 * tm + r;
        if (gm >= M) continue;   // uniform across the 16-lane tn-group (same tm,r)
        float4 v0 = acc[r][0], v1 = acc[r][1];
        v0.x += wl.x; v0.y += wl.y; v0.z += wl.z; v0.w += wl.w;
        v1.x += wh.x; v1.y += wh.y; v1.z += wh.z; v1.w += wh.w;
        float s  = v0.x + v0.y + v0.z + v0.w + v1.x + v1.y + v1.z + v1.w;
        float ss = v0.x*v0.x + v0.y*v0.y + v0.z*v0.z + v0.w*v0.w
                 + v1.x*v1.x + v1.y*v1.y + v1.z*v1.z + v1.w*v1.w;
        s  += __shfl_xor(s, 1, 64);  ss += __shfl_xor(ss, 1, 64);
        s  += __shfl_xor(s, 2, 64);  ss += __shfl_xor(ss, 2, 64);
        s  += __shfl_xor(s, 4, 64);  ss += __shfl_xor(ss, 4, 64);
        s  += __shfl_xor(s, 8, 64);  ss += __shfl_xor(ss, 8, 64);
        float mean = s * (1.0f / 128.0f);
        float var  = ss * (1.0f / 128.0f) - mean * mean;
        float rstd = 1.0f / sqrtf(var + EPS);
        float* fp = feats_all + (size_t)gm * 768 + layer * 128;
        float4 f0 = *(const float4*)(fp + cl);
        float4 f1 = *(const float4*)(fp + chh);
        float4 o0, o1;
        o0.x = f0.x + (v0.x - mean) * rstd * gl.x + bl.x;
        o0.y = f0.y + (v0.y - mean) * rstd * gl.y + bl.y;
        o0.z = f0.z + (v0.z - mean) * rstd * gl.z + bl.z;
        o0.w = f0.w + (v0.w - mean) * rstd * gl.w + bl.w;
        o1.x = f1.x + (v1.x - mean) * rstd * gh.x + bh.x;
        o1.y = f1.y + (v1.y - mean) * rstd * gh.y + bh.y;
        o1.z = f1.z + (v1.z - mean) * rstd * gh.z + bh.z;
        o1.w = f1.w + (v1.w - mean) * rstd * gh.w + bh.w;
        float* op = feats_all + (size_t)gm * 768 + (layer + 1) * 128;
        *(float4*)(op + cl)  = o0;
        *(float4*)(op + chh) = o1;
    }
}

// ---------------- fused edge kernel (v12): i0-sort, CSR store epilogue, BF16 Pab ----------------
__global__ __launch_bounds__(256, 3) void k_edge(const int* __restrict__ ssiP,
                                                 const int* __restrict__ dsiP,
                                                 const int* __restrict__ i0P,
                                                 const float* __restrict__ frP,
                                                 const float* __restrict__ T,     // [TROWS][648]
                                                 const unsigned short* __restrict__ Pab, // [N_NODES][1296] bf16
                                                 const float* __restrict__ W2p,   // [768][32]
                                                 const float* __restrict__ b2,
                                                 const float* __restrict__ eng,
                                                 const float* __restrict__ enb,
                                                 float* __restrict__ S,
                                                 float* __restrict__ Mout,
                                                 int csr) {
    __shared__ float Zs[64 * 70];        // 17920 B; overlaid by m2s[64][36] in epilogue
    __shared__ float W2s[64 * 36];       // single-buffered W2 chunk, 9216 B
    __shared__ int dsi[EPB], ssi[EPB], i0s[EPB];
    __shared__ float frs[EPB];
    __shared__ float cpar[96];

    const int tid = threadIdx.x;
    // XCD-chunked bijective swizzle (nwg=2500, 8 XCDs: q=312, r=4 -> first 4 XCDs 313 blocks)
    const int bid = blockIdx.x;
    const int xcd = bid & 7, bpos = bid >> 3;
    const int wg = (xcd < 4) ? xcd * 313 + bpos : 1252 + (xcd - 4) * 312 + bpos;
    const int eb = wg * EPB;
    const int lane = tid & 31;           // edge-pair index (both phases)
    const int grp = tid >> 5;            // col group: phase-1 8 cols, phase-2 4 out-cols

    if (tid < EPB) {
        ssi[tid] = ssiP[eb + tid];
        dsi[tid] = dsiP[eb + tid];
        i0s[tid] = i0P[eb + tid];
        frs[tid] = frP[eb + tid];
    }
    if (tid < 32) cpar[tid] = b2[tid];
    else if (tid < 64) cpar[tid] = eng[tid - 32];
    else if (tid < 96) cpar[tid] = enb[tid - 64];
    __syncthreads();

    int dsr[2], ssr[2], i0r[2];
    float frr[2];
    #pragma unroll
    for (int i = 0; i < 2; ++i) {
        int e = 2 * lane + i;
        dsr[i] = dsi[e]; ssr[i] = ssi[e];
        i0r[i] = i0s[e]; frr[i] = frs[e];
    }

    float4 accm[2];
    accm[0] = make_float4(0,0,0,0);
    accm[1] = make_float4(0,0,0,0);

    float4 rA0[2], rA1[2], rB0[2], rB1[2];
    uint4 rp[2], rq[2];                  // 8 bf16 each (Pa / Pb slices)
    float4 rw0, rw1;

#define PREFETCH(cn) do { \
    const int colb_ = 64 * (cn) + 8 * grp; \
    if (colb_ < TCOLS) { \
        _Pragma("unroll") \
        for (int i_ = 0; i_ < 2; ++i_) { \
            const float* t0_ = T + (size_t)i0r[i_] * TCOLS + colb_; \
            rA0[i_] = *(const float4*)t0_; \
            rA1[i_] = *(const float4*)(t0_ + 4); \
            rB0[i_] = *(const float4*)(t0_ + TCOLS); \
            rB1[i_] = *(const float4*)(t0_ + TCOLS + 4); \
            rp[i_] = *(const uint4*)(Pab + (size_t)dsr[i_] * PSTRIDE + colb_); \
            rq[i_] = *(const uint4*)(Pab + (size_t)ssr[i_] * PSTRIDE + JP + colb_); \
        } \
    } \
    const float* ws_ = W2p + (size_t)(64 * (cn)) * 32 + 8 * tid; \
    rw0 = *(const float4*)ws_; rw1 = *(const float4*)(ws_ + 4); \
} while (0)

    PREFETCH(0);

    for (int ch = 0; ch < 11; ++ch) {
        const int colb = 64 * ch + 8 * grp;

        // ---- compute qa from prefetched regs (vmcnt wait lands here, post-FMA) ----
        float qa[2][8];
        if (colb < TCOLS) {
            #pragma unroll
            for (int i = 0; i < 2; ++i) {
                float f = frr[i];
                float pa[8], pb[8];
                pa[0] = __uint_as_float(rp[i].x << 16); pa[1] = __uint_as_float(rp[i].x & 0xFFFF0000u);
                pa[2] = __uint_as_float(rp[i].y << 16); pa[3] = __uint_as_float(rp[i].y & 0xFFFF0000u);
                pa[4] = __uint_as_float(rp[i].z << 16); pa[5] = __uint_as_float(rp[i].z & 0xFFFF0000u);
                pa[6] = __uint_as_float(rp[i].w << 16); pa[7] = __uint_as_float(rp[i].w & 0xFFFF0000u);
                pb[0] = __uint_as_float(rq[i].x << 16); pb[1] = __uint_as_float(rq[i].x & 0xFFFF0000u);
                pb[2] = __uint_as_float(rq[i].y << 16); pb[3] = __uint_as_float(rq[i].y & 0xFFFF0000u);
                pb[4] = __uint_as_float(rq[i].z << 16); pb[5] = __uint_as_float(rq[i].z & 0xFFFF0000u);
                pb[6] = __uint_as_float(rq[i].w << 16); pb[7] = __uint_as_float(rq[i].w & 0xFFFF0000u);
                qa[i][0] = silu(fmaf(f, rB0[i].x - rA0[i].x, rA0[i].x) + pa[0] + pb[0]);
                qa[i][1] = silu(fmaf(f, rB0[i].y - rA0[i].y, rA0[i].y) + pa[1] + pb[1]);
                qa[i][2] = silu(fmaf(f, rB0[i].z - rA0[i].z, rA0[i].z) + pa[2] + pb[2]);
                qa[i][3] = silu(fmaf(f, rB0[i].w - rA0[i].w, rA0[i].w) + pa[3] + pb[3]);
                qa[i][4] = silu(fmaf(f, rB1[i].x - rA1[i].x, rA1[i].x) + pa[4] + pb[4]);
                qa[i][5] = silu(fmaf(f, rB1[i].y - rA1[i].y, rA1[i].y) + pa[5] + pb[5]);
                qa[i][6] = silu(fmaf(f, rB1[i].z - rA1[i].z, rA1[i].z) + pa[6] + pb[6]);
                qa[i][7] = silu(fmaf(f, rB1[i].w - rA1[i].w, rA1[i].w) + pa[7] + pb[7]);
            }
        } else {
            #pragma unroll
            for (int i = 0; i < 2; ++i)
                #pragma unroll
                for (int c = 0; c < 8; ++c) qa[i][c] = 0.f;
        }

        __syncthreads();   // bA: previous FMA done -> Zs + W2s free for overwrite

        #pragma unroll
        for (int jj = 0; jj < 8; ++jj) {
            float2 z2;
            z2.x = qa[0][jj]; z2.y = qa[1][jj];
            *(float2*)&Zs[(8 * grp + jj) * 70 + 2 * lane] = z2;
        }
        {
            int wrow = tid >> 2;
            int wc0 = (2 * tid) & 7;
            *(float4*)&W2s[wrow * 36 + 4 * wc0] = rw0;
            *(float4*)&W2s[wrow * 36 + 4 * (wc0 + 1)] = rw1;
        }

        __syncthreads();   // bB: Zs + W2s published

        if (ch < 10) PREFETCH(ch + 1);   // issued BEFORE FMA -> in flight during it

        #pragma unroll 8
        for (int kk = 0; kk < 64; ++kk) {
            float2 z2 = *(const float2*)&Zs[kk * 70 + 2 * lane];
            float4 w4 = *(const float4*)&W2s[kk * 36 + 4 * grp];
            accm[0] = f4fma(z2.x, w4, accm[0]);
            accm[1] = f4fma(z2.y, w4, accm[1]);
        }
    }
#undef PREFETCH

    // ---- epilogue: m2 = silu(accm + b2), LN, store (CSR) / scatter (fallback) ----
    __syncthreads();
    float* m2s = Zs;
    {
        float4 bb2 = *(const float4*)&cpar[4 * grp];
        #pragma unroll
        for (int i = 0; i < 2; ++i) {
            int e = 2 * lane + i;
            float4 o;
            o.x = silu(accm[i].x + bb2.x);
            o.y = silu(accm[i].y + bb2.y);
            o.z = silu(accm[i].z + bb2.z);
            o.w = silu(accm[i].w + bb2.w);
            *(float4*)&m2s[e * 36 + 4 * grp] = o;
        }
    }
    __syncthreads();
    {
        int e = tid >> 2, q = tid & 3;
        float4 v0 = *(const float4*)&m2s[e * 36 + 8 * q];
        float4 v1 = *(const float4*)&m2s[e * 36 + 8 * q + 4];
        float s  = v0.x + v0.y + v0.z + v0.w + v1.x + v1.y + v1.z + v1.w;
        float ss = v0.x*v0.x + v0.y*v0.y + v0.z*v0.z + v0.w*v0.w
                 + v1.x*v1.x + v1.y*v1.y + v1.z*v1.z + v1.w*v1.w;
        s  += __shfl_xor(s, 1, 64);  ss += __shfl_xor(ss, 1, 64);
        s  += __shfl_xor(s, 2, 64);  ss += __shfl_xor(ss, 2, 64);
        float mean = s * 0.03125f;
        float var = ss * 0.03125f - mean * mean;
        float rstd = 1.0f / sqrtf(var + EPS);
        const float* gg = cpar + 32 + 8 * q;
        const float* bbv = cpar + 64 + 8 * q;
        float vv[8] = {v0.x, v0.y, v0.z, v0.w, v1.x, v1.y, v1.z, v1.w};
        float o[8];
        #pragma unroll
        for (int c = 0; c < 8; ++c) o[c] = (vv[c] - mean) * rstd * gg[c] + bbv[c];
        if (csr) {
            float* Mp = Mout + (size_t)(eb + e) * 32 + 8 * q;
            *(float4*)Mp       = make_float4(o[0], o[1], o[2], o[3]);
            *(float4*)(Mp + 4) = make_float4(o[4], o[5], o[6], o[7]);
        } else {
            int d = dsi[e];
            float* Sp = S + (size_t)d * 32 + 8 * q;
            #pragma unroll
            for (int c = 0; c < 8; ++c) atomicAdd(&Sp[c], o[c]);
        }
    }
}

// ---------------- node prep: H0[:,0:128] = LN(feats) ----------------
__global__ __launch_bounds__(128) void k_prep(const float* __restrict__ featsk,
                                              const float* __restrict__ nn1g,
                                              const float* __restrict__ nn1b,
                                              float* __restrict__ H0) {
    int n = blockIdx.x, tid = threadIdx.x;
    __shared__ float red[4];
    float x = featsk[(size_t)n * 768 + tid];
    float s = wave_sum64(x), ss = wave_sum64(x * x);
    if ((tid & 63) == 0) { red[(tid >> 6) * 2] = s; red[(tid >> 6) * 2 + 1] = ss; }
    __syncthreads();
    float S1 = red[0] + red[2], S2 = red[1] + red[3];
    float mean = S1 * (1.0f / 128.0f);
    float var = S2 * (1.0f / 128.0f) - mean * mean;
    float rstd = 1.0f / sqrtf(var + EPS);
    H0[(size_t)n * 160 + tid] = (x - mean) * rstd * nn1g[tid] + nn1b[tid];
}

// ---------------- graph pooling (batch sorted -> run-length accum) ----------------
__global__ __launch_bounds__(256) void k_pool(const float* __restrict__ F,
                                              const int* __restrict__ batch,
                                              float* __restrict__ G,
                                              float* __restrict__ cntg) {
    __shared__ int bL[32];
    int b0 = blockIdx.x * 32;
    int tid = threadIdx.x;
    int nmax = min(32, N_NODES - b0);
    if (nmax <= 0) return;
    if (tid < nmax) bL[tid] = batch[b0 + tid];
    __syncthreads();
    float accv = 0.f;
    int cur = -1;
    for (int i = 0; i < nmax; ++i) {
        int g = bL[i];
        if (g != cur) {
            if (cur >= 0) atomicAdd(&G[(size_t)cur * 256 + tid], accv);
            cur = g; accv = 0.f;
        }
        accv += F[(size_t)(b0 + i) * 256 + tid];
    }
    if (cur >= 0) atomicAdd(&G[(size_t)cur * 256 + tid], accv);
    if (tid == 0)
        for (int i = 0; i < nmax; ++i) atomicAdd(&cntg[bL[i]], 1.0f);
}

// ---------------- per-graph MLP head ----------------
__global__ __launch_bounds__(256) void k_graph(const float* __restrict__ G,
                                               const float* __restrict__ cntg,
                                               const float* __restrict__ g1W,
                                               const float* __restrict__ g1b,
                                               const float* __restrict__ g2W,
                                               const float* __restrict__ g2b,
                                               const float* __restrict__ g3W,
                                               const float* __restrict__ g3b,
                                               float* __restrict__ out) {
    __shared__ float X[256], Y[256], red[4];
    int g = blockIdx.x, tid = threadIdx.x;
    float inv = 1.0f / fmaxf(cntg[g], 1.0f);
    X[tid] = G[(size_t)g * 256 + tid] * inv;
    __syncthreads();
    float a = g1b[tid];
    for (int j = 0; j < 256; ++j) a = fmaf(X[j], g1W[(size_t)j * 256 + tid], a);
    Y[tid] = silu(a);
    __syncthreads();
    a = g2b[tid];
    for (int j = 0; j < 256; ++j) a = fmaf(Y[j], g2W[(size_t)j * 256 + tid], a);
    float z = silu(a);
    float p = z * g3W[tid];
    p = wave_sum64(p);
    if ((tid & 63) == 0) red[tid >> 6] = p;
    __syncthreads();
    if (tid == 0) out[g] = red[0] + red[1] + red[2] + red[3] + g3b[0];
}

extern "C" void kernel_launch(void* const* d_in, const int* in_sizes, int n_in,
                              void* d_out, int out_size, void* d_ws, size_t ws_size,
                              hipStream_t stream) {
    const int*   atomids = (const int*)d_in[0];
    const float* coords  = (const float*)d_in[1];
    const int*   eidx    = (const int*)d_in[2];
    const int*   batch   = (const int*)d_in[3];
    const float* emb_w   = (const float*)d_in[4];
    const float* eW1     = (const float*)d_in[5];
    const float* eb1     = (const float*)d_in[6];
    const float* eW2     = (const float*)d_in[7];
    const float* eb2     = (const float*)d_in[8];
    const float* en_g    = (const float*)d_in[9];
    const float* en_b    = (const float*)d_in[10];
    const float* nn1_g   = (const float*)d_in[11];
    const float* nn1_b   = (const float*)d_in[12];
    const float* nW1     = (const float*)d_in[13];
    const float* nb1     = (const float*)d_in[14];
    const float* nW2     = (const float*)d_in[15];
    const float* nb2     = (const float*)d_in[16];
    const float* nn2_g   = (const float*)d_in[17];
    const float* nn2_b   = (const float*)d_in[18];
    const float* f1W     = (const float*)d_in[19];
    const float* f1b     = (const float*)d_in[20];
    const float* f2W     = (const float*)d_in[21];
    const float* f2b     = (const float*)d_in[22];
    const float* f3W     = (const float*)d_in[23];
    const float* f3b     = (const float*)d_in[24];
    const float* g1W     = (const float*)d_in[25];
    const float* g1b     = (const float*)d_in[26];
    const float* g2W     = (const float*)d_in[27];
    const float* g2b     = (const float*)d_in[28];
    const float* g3W     = (const float*)d_in[29];
    const float* g3b     = (const float*)d_in[30];
    float* out = (float*)d_out;

    float* ws = (float*)d_ws;
    float* feats_all = ws;                        // [10000][768]
    float* d2g   = ws + 7680000;                  // [160000]
    float* Pab   = ws + 7840000;                  // region: bf16 [10000][1296] = 25.9MB of 51.8MB
    float* S     = ws + 20800000;                 // [10000][32] (fallback path only)
    float* cnt   = ws + 21120000;                 // [10000]
    float* W1ab5 = ws + 21130000;                 // [5][128][1296] fp32 (fallback only)
    float* W1cp5 = ws + 21959440;                 // [5][65][768]
    float* b1p5  = ws + 22209040;                 // [5][768]
    float* W2p5  = ws + 22212880;                 // [5][768][32]
    float* feG   = ws + 22335760;                 // [12289][68]
    float* T     = ws + 23171412;                 // [12289][648]
    float* G     = ws + 31134684;                 // [64][256]
    float* cntg  = ws + 31151068;                 // [64]
    int*   histI = (int*)(ws + 31151132);         // [12304]
    int*   offs  = (int*)(ws + 31163436);         // [12304] (persists as dst-CSR offsD)
    int*   cursor= (int*)(ws + 31175740);         // [12304]
    int*   ssiP  = (int*)(ws + 31188044);         // [160000]
    int*   dsiP  = (int*)(ws + 31348044);         // [160000]
    int*   i0P   = (int*)(ws + 31508044);         // [160000]
    float* frP   = ws + 31668044;                 // [160000]
    int*   eixD  = (int*)(ws + 31828044);         // [160000]
    float* Mbuf  = ws + 31988044;                 // [160000][32] (end 37,108,044)
    unsigned short* Bp5U  = (unsigned short*)(ws + 37108044);  // [5][16][1296][8] bf16 (414,720 fl)
    unsigned short* ApackU= (unsigned short*)(ws + 37522764);  // [16][10000][8] bf16 (640,000 fl)
    const int useCSR  = (ws_size >= (size_t)(31988044 + 5120000) * sizeof(float)) ? 1 : 0;
    const int useMFMA = (ws_size >= (size_t)38162764 * sizeof(float)) ? 1 : 0;
    unsigned short* PabU = (unsigned short*)Pab;  // bf16 view
    // node-phase temporaries overlay Pab region (dead between phases)
    float* H0 = Pab;                              // [10000][160]
    float* H1 = Pab + 1600000;                    // [10000][256]
    float* F1 = Pab;                              // [10000][256]
    float* F2 = Pab + 2560000;                    // [10000][256]
    float* F3 = Pab + 5120000;                    // [10000][256]

    k_embed<<<N_NODES, 128, 0, stream>>>(atomids, emb_w, feats_all);
    k_d2<<<(N_EDGES + 255) / 256, 256, 0, stream>>>(coords, eidx, d2g);
    hipMemsetAsync(cnt, 0, 10000 * sizeof(float), stream);
    k_cnt<<<(N_EDGES + 255) / 256, 256, 0, stream>>>(eidx, cnt);
    hipMemsetAsync(histI, 0, 12304 * sizeof(int), stream);
    k_hist<<<(N_EDGES + 255) / 256, 256, 0, stream>>>(d2g, histI);
    k_scan<<<1, 256, 0, stream>>>(histI, offs);
    k_copyi<<<(TROWS + 255) / 256, 256, 0, stream>>>(offs, cursor);
    k_scatter<<<(N_EDGES + 255) / 256, 256, 0, stream>>>(eidx, d2g, cursor,
                                                         ssiP, dsiP, i0P, frP);
    if (useCSR) {
        hipMemsetAsync(histI, 0, 12304 * sizeof(int), stream);
        k_hist_d<<<(N_EDGES + 255) / 256, 256, 0, stream>>>(dsiP, histI);
        k_scan<<<1, 256, 0, stream>>>(histI, offs);
        k_copyi<<<(TROWS + 255) / 256, 256, 0, stream>>>(offs, cursor);
        k_scatter_d<<<(N_EDGES + 255) / 256, 256, 0, stream>>>(dsiP, cursor, eixD);
    }
    k_feg<<<(TROWS + 255) / 256, 256, 0, stream>>>(feG);
    if (useMFMA)
        k_bpack5<<<dim3(648, 5), 256, 0, stream>>>(eW1, Bp5U);
    else
        k_w1ab5<<<dim3(648, 5), 256, 0, stream>>>(eW1, W1ab5);
    k_wpre5<<<dim3(294, 5), 256, 0, stream>>>(eW1, eb1, eW2, W1cp5, b1p5, W2p5);

    for (int k = 0; k < NK; ++k) {
        const float* eb2k = eb2 + (size_t)k * 32;
        const float* engk = en_g + (size_t)k * 32;
        const float* enbk = en_b + (size_t)k * 32;
        const float* nn1gk = nn1_g + (size_t)k * 128;
        const float* nn1bk = nn1_b + (size_t)k * 128;
        const float* nW1k = nW1 + (size_t)k * 160 * 256;
        const float* nb1k = nb1 + (size_t)k * 256;
        const float* nW2k = nW2 + (size_t)k * 256 * 128;
        const float* nb2k = nb2 + (size_t)k * 128;
        const float* nn2gk = nn2_g + (size_t)k * 128;
        const float* nn2bk = nn2_b + (size_t)k * 128;

        k_tab<<<(TROWS + 31) / 32, 256, 0, stream>>>(feG,
                                                     W1cp5 + (size_t)k * 65 * 768,
                                                     b1p5 + (size_t)k * 768, T);
        // MUST write all 1296 Pab columns (k_edge reads zero-padding up to col 1295)
        if (useMFMA) {
            k_apack<<<(N_NODES * 16 + 255) / 256, 256, 0, stream>>>(feats_all + k * 128, ApackU);
            k_gemm_mfma<<<dim3(157, 21), 256, 0, stream>>>(ApackU, Bp5U + (size_t)k * 165888,
                                                           PabU, N_NODES);
        } else {
            k_gemm<<<dim3(79, 11), 256, 0, stream>>>(feats_all + k * 128, 768,
                                                     W1ab5 + (size_t)k * 128 * 1296, 1296,
                                                     nullptr, Pab, 1296, N_NODES, 1296, 128, 0, 0);
        }
        if (!useCSR)
            hipMemsetAsync(S, 0, (size_t)320000 * sizeof(float), stream);
        k_edge<<<N_EDGES / EPB, 256, 0, stream>>>(ssiP, dsiP, i0P, frP, T, PabU,
                                                  W2p5 + (size_t)k * 768 * 32,
                                                  eb2k, engk, enbk, S, Mbuf, useCSR);
        if (useCSR)
            k_agg_ln<<<(N_NODES + 3) / 4, 128, 0, stream>>>(Mbuf, offs, eixD, cnt,
                                                            engk, enbk, H0);
        else
            k_s_ln<<<(N_NODES + 3) / 4, 128, 0, stream>>>(S, cnt, engk, enbk, H0);
        k_prep<<<N_NODES, 128, 0, stream>>>(feats_all + k * 128, nn1gk, nn1bk, H0);
        k_gemm64<<<dim3(157, 2), 256, 0, stream>>>(H0, 160, nW1k, 256, nb1k, H1, 256,
                                                   N_NODES, 256, 160, 0, 1);
        k_gemm_ln<<<dim3(157), 256, 0, stream>>>(H1, nW2k, nb2k, feats_all, k,
                                                 nn2gk, nn2bk, N_NODES, 256);
    }

    // final node MLP (F1/F2/F3 overlay Pab)
    k_gemm64<<<dim3(157, 2), 256, 0, stream>>>(feats_all, 768, f1W, 256, f1b, F1, 256,
                                               N_NODES, 256, 768, 1, 1);
    k_gemm64<<<dim3(157, 2), 256, 0, stream>>>(F1, 256, f2W, 256, f2b, F2, 256,
                                               N_NODES, 256, 256, 0, 1);
    k_gemm64<<<dim3(157, 2), 256, 0, stream>>>(F2, 256, f3W, 256, f3b, F3, 256,
                                               N_NODES, 256, 256, 0, 1);

    hipMemsetAsync(G, 0, (size_t)(16384 + 64) * sizeof(float), stream);
    k_pool<<<313, 256, 0, stream>>>(F3, batch, G, cntg);
    k_graph<<<N_GRAPHS, 256, 0, stream>>>(G, cntg, g1W, g1b, g2W, g2b, g3W, g3b, out);
}

// Round 17
// 2441.965 us; speedup vs baseline: 1.1235x; 1.0173x over previous
//
#include <hip/hip_runtime.h>
#include <hip/hip_bf16.h>

#define N_NODES 10000
#define N_EDGES 160000
#define N_GRAPHS 64
#define NK 5
#define EPS 1e-5f
#define EPB 64           // edges per block (256 threads)
#define JP 648           // packed width for Pab halves
#define PSTRIDE 1296     // Pab row stride (bf16 elems): [Pa 648 | Pb 648]
#define TCOLS 648        // table row width (642 -> 648)
#define TROWS 12289      // d2 grid [0,96], h=1/128
#define IMAX 12287

// MFMA fragment types: gfx950 mfma_f32_16x16x32_bf16 takes v8bf16 operands.
typedef __attribute__((ext_vector_type(8))) __bf16 bf16v8;
typedef __attribute__((ext_vector_type(4))) float f32x4;

__device__ __forceinline__ float silu(float x) { return x / (1.0f + __expf(-x)); }
__device__ __forceinline__ float4 f4fma(float s, float4 w, float4 a) {
    a.x = fmaf(s, w.x, a.x); a.y = fmaf(s, w.y, a.y);
    a.z = fmaf(s, w.z, a.z); a.w = fmaf(s, w.w, a.w);
    return a;
}
__device__ __forceinline__ float wave_sum64(float v) {
    #pragma unroll
    for (int off = 32; off > 0; off >>= 1) v += __shfl_xor(v, off, 64);
    return v;
}
// fp32 -> bf16 (round to nearest even), returned as raw bits
__device__ __forceinline__ unsigned short f2bf(float f) {
    unsigned int u = __float_as_uint(f);
    unsigned int r = u + 0x7FFFu + ((u >> 16) & 1u);
    return (unsigned short)(r >> 16);
}

// ---------------- embedding ----------------
__global__ __launch_bounds__(128) void k_embed(const int* __restrict__ atomids,
                                               const float* __restrict__ emb_w,
                                               float* __restrict__ feats_all) {
    int n = blockIdx.x, tid = threadIdx.x;
    feats_all[(size_t)n * 768 + tid] = emb_w[(size_t)atomids[n] * 128 + tid];
}

// ---------------- per-edge squared distance ----------------
__global__ __launch_bounds__(256) void k_d2(const float* __restrict__ coords,
                                            const int* __restrict__ eidx,
                                            float* __restrict__ d2g) {
    int e = blockIdx.x * 256 + threadIdx.x;
    if (e >= N_EDGES) return;
    int s = eidx[e], d = eidx[N_EDGES + e];
    float dx = coords[s * 3 + 0] - coords[d * 3 + 0];
    float dy = coords[s * 3 + 1] - coords[d * 3 + 1];
    float dz = coords[s * 3 + 2] - coords[d * 3 + 2];
    d2g[e] = dx * dx + dy * dy + dz * dz;
}

// ---------------- in-degree (layer-invariant) ----------------
__global__ __launch_bounds__(256) void k_cnt(const int* __restrict__ eidx,
                                             float* __restrict__ cnt) {
    int e = blockIdx.x * 256 + threadIdx.x;
    if (e >= N_EDGES) return;
    atomicAdd(&cnt[eidx[N_EDGES + e]], 1.0f);
}

// ---------------- counting sort of edges by i0 (T-row index) ----------------
__global__ __launch_bounds__(256) void k_hist(const float* __restrict__ d2g,
                                              int* __restrict__ hist) {
    int e = blockIdx.x * 256 + threadIdx.x;
    if (e >= N_EDGES) return;
    int i0 = (int)(d2g[e] * 128.0f);
    if (i0 > IMAX) i0 = IMAX;
    atomicAdd(&hist[i0], 1);
}

__global__ __launch_bounds__(256) void k_scan(const int* __restrict__ hist,
                                              int* __restrict__ offs) {
    __shared__ int buf[256];
    __shared__ int carryS;
    int tid = threadIdx.x;
    if (tid == 0) carryS = 0;
    __syncthreads();
    for (int base = 0; base < TROWS; base += 256) {
        int v = (base + tid < TROWS) ? hist[base + tid] : 0;
        buf[tid] = v;
        __syncthreads();
        for (int off = 1; off < 256; off <<= 1) {
            int t = (tid >= off) ? buf[tid - off] : 0;
            __syncthreads();
            buf[tid] += t;
            __syncthreads();
        }
        if (base + tid < TROWS) offs[base + tid] = carryS + buf[tid] - v;  // exclusive
        __syncthreads();
        if (tid == 0) carryS += buf[255];
        __syncthreads();
    }
}

__global__ __launch_bounds__(256) void k_copyi(const int* __restrict__ a,
                                               int* __restrict__ b) {
    int i = blockIdx.x * 256 + threadIdx.x;
    if (i < TROWS) b[i] = a[i];
}

__global__ __launch_bounds__(256) void k_scatter(const int* __restrict__ eidx,
                                                 const float* __restrict__ d2g,
                                                 int* __restrict__ cursor,
                                                 int* __restrict__ ssiP,
                                                 int* __restrict__ dsiP,
                                                 int* __restrict__ i0P,
                                                 float* __restrict__ frP) {
    int e = blockIdx.x * 256 + threadIdx.x;
    if (e >= N_EDGES) return;
    float t = d2g[e] * 128.0f;
    int i0 = (int)t;
    if (i0 > IMAX) i0 = IMAX;
    float fr = t - (float)i0;
    int pos = atomicAdd(&cursor[i0], 1);
    ssiP[pos] = eidx[e];
    dsiP[pos] = eidx[N_EDGES + e];
    i0P[pos] = i0;
    frP[pos] = fr;
}

// ---------------- dst-CSR over sorted positions (for atomic-free S aggregation) ----------------
__global__ __launch_bounds__(256) void k_hist_d(const int* __restrict__ dsiP,
                                                int* __restrict__ hist) {
    int p = blockIdx.x * 256 + threadIdx.x;
    if (p >= N_EDGES) return;
    atomicAdd(&hist[dsiP[p]], 1);
}

__global__ __launch_bounds__(256) void k_scatter_d(const int* __restrict__ dsiP,
                                                   int* __restrict__ cursorD,
                                                   int* __restrict__ eixD) {
    int p = blockIdx.x * 256 + threadIdx.x;
    if (p >= N_EDGES) return;
    int pos = atomicAdd(&cursorD[dsiP[p]], 1);
    eixD[pos] = p;
}

// ---------------- CSR aggregation fused with mean + LN: writes H0[:,128:160] ----------------
__global__ __launch_bounds__(128) void k_agg_ln(const float* __restrict__ M,
                                                const int* __restrict__ offsD,
                                                const int* __restrict__ eixD,
                                                const float* __restrict__ cnt,
                                                const float* __restrict__ eng,
                                                const float* __restrict__ enb,
                                                float* __restrict__ H0) {
    int n = blockIdx.x * 4 + (threadIdx.x >> 5);
    int col = threadIdx.x & 31;
    if (n >= N_NODES) return;
    float acc = 0.f;
    int p0 = offsD[n], p1 = offsD[n + 1];
    for (int p = p0; p < p1; ++p)
        acc += M[(size_t)eixD[p] * 32 + col];
    float inv = 1.0f / fmaxf(cnt[n], 1.0f);
    float v = acc * inv;
    float s = v, q = v * v;
    #pragma unroll
    for (int off = 16; off > 0; off >>= 1) {
        s += __shfl_xor(s, off, 64);
        q += __shfl_xor(q, off, 64);
    }
    float m2 = s * (1.0f / 32.0f);
    float va = q * (1.0f / 32.0f) - m2 * m2;
    float rs = 1.0f / sqrtf(va + EPS);
    H0[(size_t)n * 160 + 128 + col] = (v - m2) * rs * eng[col] + enb[col];
}

// ---------------- fallback (no-CSR): S -> mean -> LN -> H0[:,128:160] ----------------
__global__ __launch_bounds__(128) void k_s_ln(const float* __restrict__ S,
                                              const float* __restrict__ cnt,
                                              const float* __restrict__ eng,
                                              const float* __restrict__ enb,
                                              float* __restrict__ H0) {
    int n = blockIdx.x * 4 + (threadIdx.x >> 5);
    int col = threadIdx.x & 31;
    if (n >= N_NODES) return;
    float inv = 1.0f / fmaxf(cnt[n], 1.0f);
    float v = S[(size_t)n * 32 + col] * inv;
    float s = v, q = v * v;
    #pragma unroll
    for (int off = 16; off > 0; off >>= 1) {
        s += __shfl_xor(s, off, 64);
        q += __shfl_xor(q, off, 64);
    }
    float m2 = s * (1.0f / 32.0f);
    float va = q * (1.0f / 32.0f) - m2 * m2;
    float rs = 1.0f / sqrtf(va + EPS);
    H0[(size_t)n * 160 + 128 + col] = (v - m2) * rs * eng[col] + enb[col];
}

// ---------------- fourier features on the d2 GRID (once) ----------------
__global__ __launch_bounds__(256) void k_feg(float* __restrict__ feG) {  // [TROWS][68]
    int g = blockIdx.x * 256 + threadIdx.x;
    if (g >= TROWS) return;
    float d2v = (float)g * 0.0078125f;   // g / 128, exact
    float* o = feG + (size_t)g * 68;
    float sc = 1.0f;
    #pragma unroll
    for (int i = 0; i < 32; ++i) {
        float x = d2v * sc;
        o[i] = sinf(x);
        o[32 + i] = cosf(x);
        sc *= 0.5f;
    }
    o[64] = d2v;
}

// ---------------- per-layer q-table: T[g][j] = fe(g/128) @ W1c + b1 ----------------
__global__ __launch_bounds__(256) void k_tab(const float* __restrict__ feG,   // [TROWS][68]
                                             const float* __restrict__ W1cp,  // [65][768]
                                             const float* __restrict__ b1p,   // [768]
                                             float* __restrict__ T) {         // [TROWS][648]
    __shared__ float feGs[32 * 68];
    __shared__ float W1s[65 * 36];
    const int tid = threadIdx.x;
    const int g0 = blockIdx.x * 32;
    for (int idx = tid; idx < 32 * 17; idx += 256) {
        int r = idx / 17, c = idx - r * 17;
        int gi = g0 + r;
        float4 v = make_float4(0, 0, 0, 0);
        if (gi < TROWS) v = *(const float4*)(feG + (size_t)gi * 68 + 4 * c);
        *(float4*)&feGs[r * 68 + 4 * c] = v;
    }
    const int gt = tid >> 3, ct = tid & 7;
    for (int jc = 0; jc < TCOLS; jc += 32) {
        __syncthreads();
        for (int idx = tid; idx < 65 * 32; idx += 256) {
            int k = idx >> 5, j = idx & 31;
            W1s[k * 36 + j] = W1cp[(size_t)k * 768 + jc + j];
        }
        __syncthreads();
        int gj = jc + 4 * ct;
        float4 q = *(const float4*)(b1p + gj);
        #pragma unroll 5
        for (int k = 0; k < 65; ++k) {
            float f = feGs[gt * 68 + k];
            float4 w = *(const float4*)&W1s[k * 36 + 4 * ct];
            q = f4fma(f, w, q);
        }
        int g = g0 + gt;
        if (g < TROWS && gj < TCOLS)
            *(float4*)(T + (size_t)g * TCOLS + gj) = q;
    }
}

// ---------------- W1ab prestage (fp32, fallback path only) ----------------
__global__ __launch_bounds__(256) void k_w1ab5(const float* __restrict__ eW1,
                                               float* __restrict__ W1ab5) {
    int k = blockIdx.y;
    const float* W1 = eW1 + (size_t)k * 321 * 642;
    float* W1ab = W1ab5 + (size_t)k * 128 * 1296;
    int idx = blockIdx.x * 256 + threadIdx.x;
    if (idx >= 128 * 1296) return;
    int r = idx / 1296;
    int j = idx - r * 1296;
    float v = 0.f;
    if (j < 642) v = W1[(size_t)r * 642 + j];
    else if (j >= 648 && j < 1290) v = W1[(size_t)(128 + r) * 642 + (j - 648)];
    W1ab[idx] = v;
}

// ---------------- MFMA B-fragment prestage: Bpack[5][16][1296][8] bf16 ----------------
__global__ __launch_bounds__(256) void k_bpack5(const float* __restrict__ eW1,
                                                unsigned short* __restrict__ Bp5) {
    int idx = blockIdx.x * 256 + threadIdx.x;
    if (idx >= 16 * 1296 * 8) return;
    int k = blockIdx.y;
    int kg = idx / (1296 * 8);
    int rem = idx - kg * (1296 * 8);
    int c = rem >> 3, jj = rem & 7;
    int r = kg * 8 + jj;             // K index 0..127
    const float* W1 = eW1 + (size_t)k * 321 * 642;
    float v = 0.f;
    if (c < 642) v = W1[(size_t)r * 642 + c];
    else if (c >= 648 && c < 1290) v = W1[(size_t)(128 + r) * 642 + (c - 648)];
    Bp5[(size_t)k * 165888 + idx] = f2bf(v);
}

// ---------------- generic MFMA B-pack for N=256 weights: dst[kg][256][8] ----------------
__global__ __launch_bounds__(256) void k_bpack2(const float* __restrict__ W,   // [K][256]
                                                int K,
                                                unsigned short* __restrict__ dst) {
    int idx = blockIdx.x * 256 + threadIdx.x;
    if (idx >= K * 256) return;
    int kg = idx / (256 * 8);
    int rem = idx - kg * (256 * 8);
    int c = rem >> 3, jj = rem & 7;
    int r = kg * 8 + jj;
    dst[idx] = f2bf(W[(size_t)r * 256 + c]);
}

// ---------------- generic MFMA A-pack: dst[kg][M][8] from fp32 [M][stride], optional silu ----------------
__global__ __launch_bounds__(256) void k_apack2(const float* __restrict__ src, int stride,
                                                int Kg, int doSilu,
                                                unsigned short* __restrict__ dst) {
    int t = blockIdx.x * 256 + threadIdx.x;
    if (t >= N_NODES * Kg) return;
    int kg = t / N_NODES, m = t - kg * N_NODES;
    const float* s = src + (size_t)m * stride + kg * 8;
    unsigned short* d = dst + ((size_t)kg * N_NODES + m) * 8;
    #pragma unroll
    for (int j = 0; j < 8; ++j) {
        float v = s[j];
        if (doSilu) v = silu(v);
        d[j] = f2bf(v);
    }
}

// ---------------- MFMA A-fragment staging (per layer): Apack[16][10000][8] bf16 ----------------
__global__ __launch_bounds__(256) void k_apack(const float* __restrict__ feats, // + k*128, stride 768
                                               unsigned short* __restrict__ Ap) {
    int t = blockIdx.x * 256 + threadIdx.x;   // t: m = t>>4, kg = t&15
    if (t >= N_NODES * 16) return;
    int m = t >> 4, kg = t & 15;
    const float* src = feats + (size_t)m * 768 + kg * 8;
    unsigned short* dst = Ap + ((size_t)kg * N_NODES + m) * 8;
    #pragma unroll
    for (int j = 0; j < 8; ++j) dst[j] = f2bf(src[j]);
}

// ---------------- Pab GEMM on matrix cores: bf16 in, fp32 MFMA accum, bf16 out ----------------
__global__ __launch_bounds__(256) void k_gemm_mfma(const unsigned short* __restrict__ Ap, // [16][M][8]
                                                   const unsigned short* __restrict__ Bp, // [16][1296][8]
                                                   unsigned short* __restrict__ C,        // [M][1296] bf16
                                                   int M) {
    const int tid = threadIdx.x;
    const int w = tid >> 6, l = tid & 63;
    const int m0 = blockIdx.x * 64 + (w >> 1) * 32;
    const int n0 = blockIdx.y * 64 + (w & 1) * 32;
    const int lr = l & 15, lg = l >> 4;

    f32x4 acc[2][2] = {};
    for (int kb = 0; kb < 4; ++kb) {
        const int kg = kb * 4 + lg;
        bf16v8 a[2], b[2];
        #pragma unroll
        for (int i = 0; i < 2; ++i) {
            int mrow = m0 + i * 16 + lr; if (mrow >= M) mrow = M - 1;
            a[i] = *(const bf16v8*)(Ap + ((size_t)kg * M + mrow) * 8);
            int ncol = n0 + i * 16 + lr; if (ncol > 1295) ncol = 1295;
            b[i] = *(const bf16v8*)(Bp + ((size_t)kg * 1296 + ncol) * 8);
        }
        #pragma unroll
        for (int mi = 0; mi < 2; ++mi)
            #pragma unroll
            for (int ni = 0; ni < 2; ++ni)
                acc[mi][ni] = __builtin_amdgcn_mfma_f32_16x16x32_bf16(a[mi], b[ni], acc[mi][ni], 0, 0, 0);
    }
    #pragma unroll
    for (int mi = 0; mi < 2; ++mi)
        #pragma unroll
        for (int ni = 0; ni < 2; ++ni)
            #pragma unroll
            for (int j = 0; j < 4; ++j) {
                int gm = m0 + mi * 16 + lg * 4 + j;
                int gn = n0 + ni * 16 + lr;
                if (gm < M && gn < 1296)
                    C[(size_t)gm * 1296 + gn] = f2bf(acc[mi][ni][j]);
            }
}

// ---------------- generic MFMA GEMM, N=256, fp32 out: C = silu(A@B + bias) ----------------
// Same fragment mapping as k_gemm_mfma (verified). KB = K/32. Used for H1 and the F-chain.
__global__ __launch_bounds__(256) void k_gemm_mfma2(const unsigned short* __restrict__ Ap, // [Kg][M][8]
                                                    const unsigned short* __restrict__ Bp, // [Kg][256][8]
                                                    const float* __restrict__ bias,        // [256]
                                                    float* __restrict__ C,                 // [M][256]
                                                    int M, int KB) {
    const int tid = threadIdx.x;
    const int w = tid >> 6, l = tid & 63;
    const int m0 = blockIdx.x * 64 + (w >> 1) * 32;
    const int n0 = blockIdx.y * 64 + (w & 1) * 32;
    const int lr = l & 15, lg = l >> 4;

    f32x4 acc[2][2] = {};
    for (int kb = 0; kb < KB; ++kb) {
        const int kg = kb * 4 + lg;
        bf16v8 a[2], b[2];
        #pragma unroll
        for (int i = 0; i < 2; ++i) {
            int mrow = m0 + i * 16 + lr; if (mrow >= M) mrow = M - 1;
            a[i] = *(const bf16v8*)(Ap + ((size_t)kg * M + mrow) * 8);
            int ncol = n0 + i * 16 + lr;   // always < 256
            b[i] = *(const bf16v8*)(Bp + ((size_t)kg * 256 + ncol) * 8);
        }
        #pragma unroll
        for (int mi = 0; mi < 2; ++mi)
            #pragma unroll
            for (int ni = 0; ni < 2; ++ni)
                acc[mi][ni] = __builtin_amdgcn_mfma_f32_16x16x32_bf16(a[mi], b[ni], acc[mi][ni], 0, 0, 0);
    }
    #pragma unroll
    for (int mi = 0; mi < 2; ++mi)
        #pragma unroll
        for (int ni = 0; ni < 2; ++ni)
            #pragma unroll
            for (int j = 0; j < 4; ++j) {
                int gm = m0 + mi * 16 + lg * 4 + j;
                int gn = n0 + ni * 16 + lr;
                if (gm < M)
                    C[(size_t)gm * 256 + gn] = silu(acc[mi][ni][j] + bias[gn]);
            }
}

// ---------------- padded edge-weight prestage (all 5 layers) ----------------
__global__ __launch_bounds__(256) void k_wpre5(const float* __restrict__ eW1,
                                               const float* __restrict__ eb1,
                                               const float* __restrict__ eW2,
                                               float* __restrict__ W1cp5,   // [5][65][768]
                                               float* __restrict__ b1p5,    // [5][768]
                                               float* __restrict__ W2p5) {  // [5][768][32]
    int k = blockIdx.y;
    const float* W1 = eW1 + (size_t)k * 321 * 642;
    const float* b1 = eb1 + (size_t)k * 642;
    const float* W2 = eW2 + (size_t)k * 642 * 32;
    float* W1cp = W1cp5 + (size_t)k * 65 * 768;
    float* b1p  = b1p5 + (size_t)k * 768;
    float* W2p  = W2p5 + (size_t)k * 768 * 32;
    int idx = blockIdx.x * 256 + threadIdx.x;
    if (idx < 65 * 768) {
        int r = idx / 768, j = idx - r * 768;
        W1cp[idx] = (j < 642) ? W1[(size_t)(256 + r) * 642 + j] : 0.f;
    } else if (idx < 65 * 768 + 768) {
        int j = idx - 65 * 768;
        b1p[j] = (j < 642) ? b1[j] : 0.f;
    } else if (idx < 65 * 768 + 768 + 768 * 32) {
        int t = idx - (65 * 768 + 768);
        int j = t >> 5, c = t & 31;
        W2p[t] = (j < 642) ? W2[(size_t)j * 32 + c] : 0.f;
    }
}

// ---------------- fp32 GEMM 128x128 tile, BF16 OUTPUT (Pab fallback path) ----------------
__global__ __launch_bounds__(256) void k_gemm(const float* __restrict__ A, int lda,
                                              const float* __restrict__ B, int ldb,
                                              const float* __restrict__ bias,
                                              float* __restrict__ C, int ldc,  // treated as ushort*
                                              int M, int N, int K, int siluA, int siluOut) {
    __shared__ float As[32 * 132];
    __shared__ float Bs[32 * 132];
    const int tid = threadIdx.x;
    const int m0 = blockIdx.x * 128, n0 = blockIdx.y * 128;
    const int tm = tid >> 4, tn = tid & 15;

    float4 acc[8][2];
    #pragma unroll
    for (int r = 0; r < 8; ++r) { acc[r][0] = make_float4(0,0,0,0); acc[r][1] = make_float4(0,0,0,0); }

    float4 ra[4], rb[4];

#define GLOAD(kc_) do { \
    _Pragma("unroll") \
    for (int i_ = 0; i_ < 4; ++i_) { \
        int idx_ = tid + i_ * 256; \
        int m_ = idx_ >> 3, kq_ = idx_ & 7; \
        int gm_ = m0 + m_; \
        int cm_ = (gm_ < M) ? gm_ : (M - 1); \
        float4 a_ = *(const float4*)(A + (size_t)cm_ * lda + (kc_) + 4 * kq_); \
        if (gm_ >= M) a_ = make_float4(0,0,0,0); \
        ra[i_] = a_; \
    } \
    _Pragma("unroll") \
    for (int i_ = 0; i_ < 4; ++i_) { \
        int idx_ = tid + i_ * 256; \
        int r_ = idx_ >> 5, cq_ = idx_ & 31; \
        int gn_ = n0 + 4 * cq_; \
        float4 b_ = make_float4(0,0,0,0); \
        if (gn_ < N) b_ = *(const float4*)(B + (size_t)((kc_) + r_) * ldb + gn_); \
        rb[i_] = b_; \
    } \
} while (0)

    GLOAD(0);

    for (int kc = 0; kc < K; kc += 32) {
        #pragma unroll
        for (int i = 0; i < 4; ++i) {
            int idx = tid + i * 256;
            int m = idx >> 3, kq = idx & 7;
            float4 a = ra[i];
            if (siluA) { a.x = silu(a.x); a.y = silu(a.y); a.z = silu(a.z); a.w = silu(a.w); }
            As[(4 * kq + 0) * 132 + m] = a.x;
            As[(4 * kq + 1) * 132 + m] = a.y;
            As[(4 * kq + 2) * 132 + m] = a.z;
            As[(4 * kq + 3) * 132 + m] = a.w;
        }
        #pragma unroll
        for (int i = 0; i < 4; ++i) {
            int idx = tid + i * 256;
            int r = idx >> 5, cq = idx & 31;
            *(float4*)&Bs[r * 132 + 4 * cq] = rb[i];
        }
        __syncthreads();
        if (kc + 32 < K) GLOAD(kc + 32);   // in flight during FMA below
        #pragma unroll 4
        for (int kk = 0; kk < 32; ++kk) {
            float4 a0 = *(const float4*)&As[kk * 132 + 8 * tm];
            float4 a1 = *(const float4*)&As[kk * 132 + 8 * tm + 4];
            float4 b0 = *(const float4*)&Bs[kk * 132 + 4 * tn];
            float4 b1 = *(const float4*)&Bs[kk * 132 + 64 + 4 * tn];
            acc[0][0] = f4fma(a0.x, b0, acc[0][0]); acc[0][1] = f4fma(a0.x, b1, acc[0][1]);
            acc[1][0] = f4fma(a0.y, b0, acc[1][0]); acc[1][1] = f4fma(a0.y, b1, acc[1][1]);
            acc[2][0] = f4fma(a0.z, b0, acc[2][0]); acc[2][1] = f4fma(a0.z, b1, acc[2][1]);
            acc[3][0] = f4fma(a0.w, b0, acc[3][0]); acc[3][1] = f4fma(a0.w, b1, acc[3][1]);
            acc[4][0] = f4fma(a1.x, b0, acc[4][0]); acc[4][1] = f4fma(a1.x, b1, acc[4][1]);
            acc[5][0] = f4fma(a1.y, b0, acc[5][0]); acc[5][1] = f4fma(a1.y, b1, acc[5][1]);
            acc[6][0] = f4fma(a1.z, b0, acc[6][0]); acc[6][1] = f4fma(a1.z, b1, acc[6][1]);
            acc[7][0] = f4fma(a1.w, b0, acc[7][0]); acc[7][1] = f4fma(a1.w, b1, acc[7][1]);
        }
        __syncthreads();
    }
#undef GLOAD

    unsigned short* C16 = (unsigned short*)C;
    const int gnl = n0 + 4 * tn, gnh = n0 + 64 + 4 * tn;
    #pragma unroll
    for (int r = 0; r < 8; ++r) {
        int gm = m0 + 8 * tm + r;
        if (gm >= M) continue;
        float4 v0 = acc[r][0], v1 = acc[r][1];
        if (gnl < N) {
            if (bias) { v0.x += bias[gnl+0]; v0.y += bias[gnl+1]; v0.z += bias[gnl+2]; v0.w += bias[gnl+3]; }
            if (siluOut) { v0.x = silu(v0.x); v0.y = silu(v0.y); v0.z = silu(v0.z); v0.w = silu(v0.w); }
            ushort4 s0; s0.x = f2bf(v0.x); s0.y = f2bf(v0.y); s0.z = f2bf(v0.z); s0.w = f2bf(v0.w);
            *(ushort4*)&C16[(size_t)gm * ldc + gnl] = s0;
        }
        if (gnh < N) {
            if (bias) { v1.x += bias[gnh+0]; v1.y += bias[gnh+1]; v1.z += bias[gnh+2]; v1.w += bias[gnh+3]; }
            if (siluOut) { v1.x = silu(v1.x); v1.y = silu(v1.y); v1.z = silu(v1.z); v1.w = silu(v1.w); }
            ushort4 s1; s1.x = f2bf(v1.x); s1.y = f2bf(v1.y); s1.z = f2bf(v1.z); s1.w = f2bf(v1.w);
            *(ushort4*)&C16[(size_t)gm * ldc + gnh] = s1;
        }
    }
}

// ---------------- fp32 GEMM 64x128 tile (fallback for small-N dispatches) ----------------
__global__ __launch_bounds__(256) void k_gemm64(const float* __restrict__ A, int lda,
                                                const float* __restrict__ B, int ldb,
                                                const float* __restrict__ bias,
                                                float* __restrict__ C, int ldc,
                                                int M, int N, int K, int siluA, int siluOut) {
    __shared__ float As[32 * 68];
    __shared__ float Bs[32 * 132];
    const int tid = threadIdx.x;
    const int m0 = blockIdx.x * 64, n0 = blockIdx.y * 128;
    const int tm = tid >> 4, tn = tid & 15;

    float4 acc[4][2];
    #pragma unroll
    for (int r = 0; r < 4; ++r) { acc[r][0] = make_float4(0,0,0,0); acc[r][1] = make_float4(0,0,0,0); }

    float4 ra[2], rb[4];

#define GLOAD64(kc_) do { \
    _Pragma("unroll") \
    for (int i_ = 0; i_ < 2; ++i_) { \
        int idx_ = tid + i_ * 256; \
        int m_ = idx_ >> 3, kq_ = idx_ & 7; \
        int gm_ = m0 + m_; \
        int cm_ = (gm_ < M) ? gm_ : (M - 1); \
        float4 a_ = *(const float4*)(A + (size_t)cm_ * lda + (kc_) + 4 * kq_); \
        if (gm_ >= M) a_ = make_float4(0,0,0,0); \
        ra[i_] = a_; \
    } \
    _Pragma("unroll") \
    for (int i_ = 0; i_ < 4; ++i_) { \
        int idx_ = tid + i_ * 256; \
        int r_ = idx_ >> 5, cq_ = idx_ & 31; \
        int gn_ = n0 + 4 * cq_; \
        float4 b_ = make_float4(0,0,0,0); \
        if (gn_ < N) b_ = *(const float4*)(B + (size_t)((kc_) + r_) * ldb + gn_); \
        rb[i_] = b_; \
    } \
} while (0)

    GLOAD64(0);

    for (int kc = 0; kc < K; kc += 32) {
        #pragma unroll
        for (int i = 0; i < 2; ++i) {
            int idx = tid + i * 256;
            int m = idx >> 3, kq = idx & 7;
            float4 a = ra[i];
            if (siluA) { a.x = silu(a.x); a.y = silu(a.y); a.z = silu(a.z); a.w = silu(a.w); }
            As[(4 * kq + 0) * 68 + m] = a.x;
            As[(4 * kq + 1) * 68 + m] = a.y;
            As[(4 * kq + 2) * 68 + m] = a.z;
            As[(4 * kq + 3) * 68 + m] = a.w;
        }
        #pragma unroll
        for (int i = 0; i < 4; ++i) {
            int idx = tid + i * 256;
            int r = idx >> 5, cq = idx & 31;
            *(float4*)&Bs[r * 132 + 4 * cq] = rb[i];
        }
        __syncthreads();
        if (kc + 32 < K) GLOAD64(kc + 32);   // in flight during FMA below
        #pragma unroll 4
        for (int kk = 0; kk < 32; ++kk) {
            float4 av = *(const float4*)&As[kk * 68 + 4 * tm];
            float4 b0 = *(const float4*)&Bs[kk * 132 + 4 * tn];
            float4 b1 = *(const float4*)&Bs[kk * 132 + 64 + 4 * tn];
            acc[0][0] = f4fma(av.x, b0, acc[0][0]); acc[0][1] = f4fma(av.x, b1, acc[0][1]);
            acc[1][0] = f4fma(av.y, b0, acc[1][0]); acc[1][1] = f4fma(av.y, b1, acc[1][1]);
            acc[2][0] = f4fma(av.z, b0, acc[2][0]); acc[2][1] = f4fma(av.z, b1, acc[2][1]);
            acc[3][0] = f4fma(av.w, b0, acc[3][0]); acc[3][1] = f4fma(av.w, b1, acc[3][1]);
        }
        __syncthreads();
    }
#undef GLOAD64

    const int gnl = n0 + 4 * tn, gnh = n0 + 64 + 4 * tn;
    #pragma unroll
    for (int r = 0; r < 4; ++r) {
        int gm = m0 + 4 * tm + r;
        if (gm >= M) continue;
        float4 v0 = acc[r][0], v1 = acc[r][1];
        if (gnl < N) {
            if (bias) { v0.x += bias[gnl+0]; v0.y += bias[gnl+1]; v0.z += bias[gnl+2]; v0.w += bias[gnl+3]; }
            if (siluOut) { v0.x = silu(v0.x); v0.y = silu(v0.y); v0.z = silu(v0.z); v0.w = silu(v0.w); }
            *(float4*)&C[(size_t)gm * ldc + gnl] = v0;
        }
        if (gnh < N) {
            if (bias) { v1.x += bias[gnh+0]; v1.y += bias[gnh+1]; v1.z += bias[gnh+2]; v1.w += bias[gnh+3]; }
            if (siluOut) { v1.x = silu(v1.x); v1.y = silu(v1.y); v1.z = silu(v1.z); v1.w = silu(v1.w); }
            *(float4*)&C[(size_t)gm * ldc + gnh] = v1;
        }
    }
}

// ---------------- fused H2 GEMM + LN + residual ----------------
__global__ __launch_bounds__(256) void k_gemm_ln(const float* __restrict__ A,   // H1 [M][256]
                                                 const float* __restrict__ B,   // nW2 [256][128]
                                                 const float* __restrict__ bias,// nb2 [128]
                                                 float* __restrict__ feats_all, int layer,
                                                 const float* __restrict__ g,
                                                 const float* __restrict__ b,
                                                 int M, int K) {
    __shared__ float As[32 * 68];
    __shared__ float Bs[32 * 132];
    const int tid = threadIdx.x;
    const int m0 = blockIdx.x * 64;
    const int tm = tid >> 4, tn = tid & 15;

    float4 acc[4][2];
    #pragma unroll
    for (int r = 0; r < 4; ++r) { acc[r][0] = make_float4(0,0,0,0); acc[r][1] = make_float4(0,0,0,0); }

    float4 ra[2], rb[4];

#define GLOADL(kc_) do { \
    _Pragma("unroll") \
    for (int i_ = 0; i_ < 2; ++i_) { \
        int idx_ = tid + i_ * 256; \
        int m_ = idx_ >> 3, kq_ = idx_ & 7; \
        int gm_ = m0 + m_; \
        int cm_ = (gm_ < M) ? gm_ : (M - 1); \
        float4 a_ = *(const float4*)(A + (size_t)cm_ * 256 + (kc_) + 4 * kq_); \
        if (gm_ >= M) a_ = make_float4(0,0,0,0); \
        ra[i_] = a_; \
    } \
    _Pragma("unroll") \
    for (int i_ = 0; i_ < 4; ++i_) { \
        int idx_ = tid + i_ * 256; \
        int r_ = idx_ >> 5, cq_ = idx_ & 31; \
        float4 b_ = make_float4(0,0,0,0); \
        if (4 * cq_ < 128) b_ = *(const float4*)(B + (size_t)((kc_) + r_) * 128 + 4 * cq_); \
        rb[i_] = b_; \
    } \
} while (0)

    GLOADL(0);

    for (int kc = 0; kc < K; kc += 32) {
        #pragma unroll
        for (int i = 0; i < 2; ++i) {
            int idx = tid + i * 256;
            int m = idx >> 3, kq = idx & 7;
            float4 a = ra[i];
            As[(4 * kq + 0) * 68 + m] = a.x;
            As[(4 * kq + 1) * 68 + m] = a.y;
            As[(4 * kq + 2) * 68 + m] = a.z;
            As[(4 * kq + 3) * 68 + m] = a.w;
        }
        #pragma unroll
        for (int i = 0; i < 4; ++i) {
            int idx = tid + i * 256;
            int r = idx >> 5, cq = idx & 31;
            if (cq < 32) *(float4*)&Bs[r * 132 + 4 * cq] = rb[i];
        }
        __syncthreads();
        if (kc + 32 < K) GLOADL(kc + 32);
        #pragma unroll 4
        for (int kk = 0; kk < 32; ++kk) {
            float4 av = *(const float4*)&As[kk * 68 + 4 * tm];
            float4 b0 = *(const float4*)&Bs[kk * 132 + 4 * tn];
            float4 b1 = *(const float4*)&Bs[kk * 132 + 64 + 4 * tn];
            acc[0][0] = f4fma(av.x, b0, acc[0][0]); acc[0][1] = f4fma(av.x, b1, acc[0][1]);
            acc[1][0] = f4fma(av.y, b0, acc[1][0]); acc[1][1] = f4fma(av.y, b1, acc[1][1]);
            acc[2][0] = f4fma(av.z, b0, acc[2][0]); acc[2][1] = f4fma(av.z, b1, acc[2][1]);
            acc[3][0] = f4fma(av.w, b0, acc[3][0]); acc[3][1] = f4fma(av.w, b1, acc[3][1]);
        }
        __syncthreads();
    }
#undef GLOADL

    const int cl = 4 * tn, chh = 64 + 4 * tn;
    float4 gl = *(const float4*)(g + cl),  gh = *(const float4*)(g + chh);
    float4 bl = *(const float4*)(b + cl),  bh = *(const float4*)(b + chh);
    float4 wl = *(const float4*)(bias + cl), wh = *(const float4*)(bias + chh);
    #pragma unroll
    for (int r = 0; r < 4; ++r) {
        int gm = m0 + 4 * tm + r;
        if (gm >= M) continue;   // uniform across the 16-lane tn-group (same tm,r)
        float4 v0 = acc[r][0], v1 = acc[r][1];
        v0.x += wl.x; v0.y += wl.y; v0.z += wl.z; v0.w += wl.w;
        v1.x += wh.x; v1.y += wh.y; v1.z += wh.z; v1.w += wh.w;
        float s  = v0.x + v0.y + v0.z + v0.w + v1.x + v1.y + v1.z + v1.w;
        float ss = v0.x*v0.x + v0.y*v0.y + v0.z*v0.z + v0.w*v0.w
                 + v1.x*v1.x + v1.y*v1.y + v1.z*v1.z + v1.w*v1.w;
        s  += __shfl_xor(s, 1, 64);  ss += __shfl_xor(ss, 1, 64);
        s  += __shfl_xor(s, 2, 64);  ss += __shfl_xor(ss, 2, 64);
        s  += __shfl_xor(s, 4, 64);  ss += __shfl_xor(ss, 4, 64);
        s  += __shfl_xor(s, 8, 64);  ss += __shfl_xor(ss, 8, 64);
        float mean = s * (1.0f / 128.0f);
        float var  = ss * (1.0f / 128.0f) - mean * mean;
        float rstd = 1.0f / sqrtf(var + EPS);
        float* fp = feats_all + (size_t)gm * 768 + layer * 128;
        float4 f0 = *(const float4*)(fp + cl);
        float4 f1 = *(const float4*)(fp + chh);
        float4 o0, o1;
        o0.x = f0.x + (v0.x - mean) * rstd * gl.x + bl.x;
        o0.y = f0.y + (v0.y - mean) * rstd * gl.y + bl.y;
        o0.z = f0.z + (v0.z - mean) * rstd * gl.z + bl.z;
        o0.w = f0.w + (v0.w - mean) * rstd * gl.w + bl.w;
        o1.x = f1.x + (v1.x - mean) * rstd * gh.x + bh.x;
        o1.y = f1.y + (v1.y - mean) * rstd * gh.y + bh.y;
        o1.z = f1.z + (v1.z - mean) * rstd * gh.z + bh.z;
        o1.w = f1.w + (v1.w - mean) * rstd * gh.w + bh.w;
        float* op = feats_all + (size_t)gm * 768 + (layer + 1) * 128;
        *(float4*)(op + cl)  = o0;
        *(float4*)(op + chh) = o1;
    }
}

// ---------------- fused edge kernel (v12): i0-sort, CSR store epilogue, BF16 Pab ----------------
__global__ __launch_bounds__(256, 3) void k_edge(const int* __restrict__ ssiP,
                                                 const int* __restrict__ dsiP,
                                                 const int* __restrict__ i0P,
                                                 const float* __restrict__ frP,
                                                 const float* __restrict__ T,     // [TROWS][648]
                                                 const unsigned short* __restrict__ Pab, // [N_NODES][1296] bf16
                                                 const float* __restrict__ W2p,   // [768][32]
                                                 const float* __restrict__ b2,
                                                 const float* __restrict__ eng,
                                                 const float* __restrict__ enb,
                                                 float* __restrict__ S,
                                                 float* __restrict__ Mout,
                                                 int csr) {
    __shared__ float Zs[64 * 70];        // 17920 B; overlaid by m2s[64][36] in epilogue
    __shared__ float W2s[64 * 36];       // single-buffered W2 chunk, 9216 B
    __shared__ int dsi[EPB], ssi[EPB], i0s[EPB];
    __shared__ float frs[EPB];
    __shared__ float cpar[96];

    const int tid = threadIdx.x;
    // XCD-chunked bijective swizzle (nwg=2500, 8 XCDs: q=312, r=4 -> first 4 XCDs 313 blocks)
    const int bid = blockIdx.x;
    const int xcd = bid & 7, bpos = bid >> 3;
    const int wg = (xcd < 4) ? xcd * 313 + bpos : 1252 + (xcd - 4) * 312 + bpos;
    const int eb = wg * EPB;
    const int lane = tid & 31;           // edge-pair index (both phases)
    const int grp = tid >> 5;            // col group: phase-1 8 cols, phase-2 4 out-cols

    if (tid < EPB) {
        ssi[tid] = ssiP[eb + tid];
        dsi[tid] = dsiP[eb + tid];
        i0s[tid] = i0P[eb + tid];
        frs[tid] = frP[eb + tid];
    }
    if (tid < 32) cpar[tid] = b2[tid];
    else if (tid < 64) cpar[tid] = eng[tid - 32];
    else if (tid < 96) cpar[tid] = enb[tid - 64];
    __syncthreads();

    int dsr[2], ssr[2], i0r[2];
    float frr[2];
    #pragma unroll
    for (int i = 0; i < 2; ++i) {
        int e = 2 * lane + i;
        dsr[i] = dsi[e]; ssr[i] = ssi[e];
        i0r[i] = i0s[e]; frr[i] = frs[e];
    }

    float4 accm[2];
    accm[0] = make_float4(0,0,0,0);
    accm[1] = make_float4(0,0,0,0);

    float4 rA0[2], rA1[2], rB0[2], rB1[2];
    uint4 rp[2], rq[2];                  // 8 bf16 each (Pa / Pb slices)
    float4 rw0, rw1;

#define PREFETCH(cn) do { \
    const int colb_ = 64 * (cn) + 8 * grp; \
    if (colb_ < TCOLS) { \
        _Pragma("unroll") \
        for (int i_ = 0; i_ < 2; ++i_) { \
            const float* t0_ = T + (size_t)i0r[i_] * TCOLS + colb_; \
            rA0[i_] = *(const float4*)t0_; \
            rA1[i_] = *(const float4*)(t0_ + 4); \
            rB0[i_] = *(const float4*)(t0_ + TCOLS); \
            rB1[i_] = *(const float4*)(t0_ + TCOLS + 4); \
            rp[i_] = *(const uint4*)(Pab + (size_t)dsr[i_] * PSTRIDE + colb_); \
            rq[i_] = *(const uint4*)(Pab + (size_t)ssr[i_] * PSTRIDE + JP + colb_); \
        } \
    } \
    const float* ws_ = W2p + (size_t)(64 * (cn)) * 32 + 8 * tid; \
    rw0 = *(const float4*)ws_; rw1 = *(const float4*)(ws_ + 4); \
} while (0)

    PREFETCH(0);

    for (int ch = 0; ch < 11; ++ch) {
        const int colb = 64 * ch + 8 * grp;

        // ---- compute qa from prefetched regs (vmcnt wait lands here, post-FMA) ----
        float qa[2][8];
        if (colb < TCOLS) {
            #pragma unroll
            for (int i = 0; i < 2; ++i) {
                float f = frr[i];
                float pa[8], pb[8];
                pa[0] = __uint_as_float(rp[i].x << 16); pa[1] = __uint_as_float(rp[i].x & 0xFFFF0000u);
                pa[2] = __uint_as_float(rp[i].y << 16); pa[3] = __uint_as_float(rp[i].y & 0xFFFF0000u);
                pa[4] = __uint_as_float(rp[i].z << 16); pa[5] = __uint_as_float(rp[i].z & 0xFFFF0000u);
                pa[6] = __uint_as_float(rp[i].w << 16); pa[7] = __uint_as_float(rp[i].w & 0xFFFF0000u);
                pb[0] = __uint_as_float(rq[i].x << 16); pb[1] = __uint_as_float(rq[i].x & 0xFFFF0000u);
                pb[2] = __uint_as_float(rq[i].y << 16); pb[3] = __uint_as_float(rq[i].y & 0xFFFF0000u);
                pb[4] = __uint_as_float(rq[i].z << 16); pb[5] = __uint_as_float(rq[i].z & 0xFFFF0000u);
                pb[6] = __uint_as_float(rq[i].w << 16); pb[7] = __uint_as_float(rq[i].w & 0xFFFF0000u);
                qa[i][0] = silu(fmaf(f, rB0[i].x - rA0[i].x, rA0[i].x) + pa[0] + pb[0]);
                qa[i][1] = silu(fmaf(f, rB0[i].y - rA0[i].y, rA0[i].y) + pa[1] + pb[1]);
                qa[i][2] = silu(fmaf(f, rB0[i].z - rA0[i].z, rA0[i].z) + pa[2] + pb[2]);
                qa[i][3] = silu(fmaf(f, rB0[i].w - rA0[i].w, rA0[i].w) + pa[3] + pb[3]);
                qa[i][4] = silu(fmaf(f, rB1[i].x - rA1[i].x, rA1[i].x) + pa[4] + pb[4]);
                qa[i][5] = silu(fmaf(f, rB1[i].y - rA1[i].y, rA1[i].y) + pa[5] + pb[5]);
                qa[i][6] = silu(fmaf(f, rB1[i].z - rA1[i].z, rA1[i].z) + pa[6] + pb[6]);
                qa[i][7] = silu(fmaf(f, rB1[i].w - rA1[i].w, rA1[i].w) + pa[7] + pb[7]);
            }
        } else {
            #pragma unroll
            for (int i = 0; i < 2; ++i)
                #pragma unroll
                for (int c = 0; c < 8; ++c) qa[i][c] = 0.f;
        }

        __syncthreads();   // bA: previous FMA done -> Zs + W2s free for overwrite

        #pragma unroll
        for (int jj = 0; jj < 8; ++jj) {
            float2 z2;
            z2.x = qa[0][jj]; z2.y = qa[1][jj];
            *(float2*)&Zs[(8 * grp + jj) * 70 + 2 * lane] = z2;
        }
        {
            int wrow = tid >> 2;
            int wc0 = (2 * tid) & 7;
            *(float4*)&W2s[wrow * 36 + 4 * wc0] = rw0;
            *(float4*)&W2s[wrow * 36 + 4 * (wc0 + 1)] = rw1;
        }

        __syncthreads();   // bB: Zs + W2s published

        if (ch < 10) PREFETCH(ch + 1);   // issued BEFORE FMA -> in flight during it

        #pragma unroll 8
        for (int kk = 0; kk < 64; ++kk) {
            float2 z2 = *(const float2*)&Zs[kk * 70 + 2 * lane];
            float4 w4 = *(const float4*)&W2s[kk * 36 + 4 * grp];
            accm[0] = f4fma(z2.x, w4, accm[0]);
            accm[1] = f4fma(z2.y, w4, accm[1]);
        }
    }
#undef PREFETCH

    // ---- epilogue: m2 = silu(accm + b2), LN, store (CSR) / scatter (fallback) ----
    __syncthreads();
    float* m2s = Zs;
    {
        float4 bb2 = *(const float4*)&cpar[4 * grp];
        #pragma unroll
        for (int i = 0; i < 2; ++i) {
            int e = 2 * lane + i;
            float4 o;
            o.x = silu(accm[i].x + bb2.x);
            o.y = silu(accm[i].y + bb2.y);
            o.z = silu(accm[i].z + bb2.z);
            o.w = silu(accm[i].w + bb2.w);
            *(float4*)&m2s[e * 36 + 4 * grp] = o;
        }
    }
    __syncthreads();
    {
        int e = tid >> 2, q = tid & 3;
        float4 v0 = *(const float4*)&m2s[e * 36 + 8 * q];
        float4 v1 = *(const float4*)&m2s[e * 36 + 8 * q + 4];
        float s  = v0.x + v0.y + v0.z + v0.w + v1.x + v1.y + v1.z + v1.w;
        float ss = v0.x*v0.x + v0.y*v0.y + v0.z*v0.z + v0.w*v0.w
                 + v1.x*v1.x + v1.y*v1.y + v1.z*v1.z + v1.w*v1.w;
        s  += __shfl_xor(s, 1, 64);  ss += __shfl_xor(ss, 1, 64);
        s  += __shfl_xor(s, 2, 64);  ss += __shfl_xor(ss, 2, 64);
        float mean = s * 0.03125f;
        float var = ss * 0.03125f - mean * mean;
        float rstd = 1.0f / sqrtf(var + EPS);
        const float* gg = cpar + 32 + 8 * q;
        const float* bbv = cpar + 64 + 8 * q;
        float vv[8] = {v0.x, v0.y, v0.z, v0.w, v1.x, v1.y, v1.z, v1.w};
        float o[8];
        #pragma unroll
        for (int c = 0; c < 8; ++c) o[c] = (vv[c] - mean) * rstd * gg[c] + bbv[c];
        if (csr) {
            float* Mp = Mout + (size_t)(eb + e) * 32 + 8 * q;
            *(float4*)Mp       = make_float4(o[0], o[1], o[2], o[3]);
            *(float4*)(Mp + 4) = make_float4(o[4], o[5], o[6], o[7]);
        } else {
            int d = dsi[e];
            float* Sp = S + (size_t)d * 32 + 8 * q;
            #pragma unroll
            for (int c = 0; c < 8; ++c) atomicAdd(&Sp[c], o[c]);
        }
    }
}

// ---------------- node prep: H0[:,0:128] = LN(feats) ----------------
__global__ __launch_bounds__(128) void k_prep(const float* __restrict__ featsk,
                                              const float* __restrict__ nn1g,
                                              const float* __restrict__ nn1b,
                                              float* __restrict__ H0) {
    int n = blockIdx.x, tid = threadIdx.x;
    __shared__ float red[4];
    float x = featsk[(size_t)n * 768 + tid];
    float s = wave_sum64(x), ss = wave_sum64(x * x);
    if ((tid & 63) == 0) { red[(tid >> 6) * 2] = s; red[(tid >> 6) * 2 + 1] = ss; }
    __syncthreads();
    float S1 = red[0] + red[2], S2 = red[1] + red[3];
    float mean = S1 * (1.0f / 128.0f);
    float var = S2 * (1.0f / 128.0f) - mean * mean;
    float rstd = 1.0f / sqrtf(var + EPS);
    H0[(size_t)n * 160 + tid] = (x - mean) * rstd * nn1g[tid] + nn1b[tid];
}

// ---------------- graph pooling (batch sorted -> run-length accum) ----------------
__global__ __launch_bounds__(256) void k_pool(const float* __restrict__ F,
                                              const int* __restrict__ batch,
                                              float* __restrict__ G,
                                              float* __restrict__ cntg) {
    __shared__ int bL[32];
    int b0 = blockIdx.x * 32;
    int tid = threadIdx.x;
    int nmax = min(32, N_NODES - b0);
    if (nmax <= 0) return;
    if (tid < nmax) bL[tid] = batch[b0 + tid];
    __syncthreads();
    float accv = 0.f;
    int cur = -1;
    for (int i = 0; i < nmax; ++i) {
        int g = bL[i];
        if (g != cur) {
            if (cur >= 0) atomicAdd(&G[(size_t)cur * 256 + tid], accv);
            cur = g; accv = 0.f;
        }
        accv += F[(size_t)(b0 + i) * 256 + tid];
    }
    if (cur >= 0) atomicAdd(&G[(size_t)cur * 256 + tid], accv);
    if (tid == 0)
        for (int i = 0; i < nmax; ++i) atomicAdd(&cntg[bL[i]], 1.0f);
}

// ---------------- per-graph MLP head ----------------
__global__ __launch_bounds__(256) void k_graph(const float* __restrict__ G,
                                               const float* __restrict__ cntg,
                                               const float* __restrict__ g1W,
                                               const float* __restrict__ g1b,
                                               const float* __restrict__ g2W,
                                               const float* __restrict__ g2b,
                                               const float* __restrict__ g3W,
                                               const float* __restrict__ g3b,
                                               float* __restrict__ out) {
    __shared__ float X[256], Y[256], red[4];
    int g = blockIdx.x, tid = threadIdx.x;
    float inv = 1.0f / fmaxf(cntg[g], 1.0f);
    X[tid] = G[(size_t)g * 256 + tid] * inv;
    __syncthreads();
    float a = g1b[tid];
    for (int j = 0; j < 256; ++j) a = fmaf(X[j], g1W[(size_t)j * 256 + tid], a);
    Y[tid] = silu(a);
    __syncthreads();
    a = g2b[tid];
    for (int j = 0; j < 256; ++j) a = fmaf(Y[j], g2W[(size_t)j * 256 + tid], a);
    float z = silu(a);
    float p = z * g3W[tid];
    p = wave_sum64(p);
    if ((tid & 63) == 0) red[tid >> 6] = p;
    __syncthreads();
    if (tid == 0) out[g] = red[0] + red[1] + red[2] + red[3] + g3b[0];
}

extern "C" void kernel_launch(void* const* d_in, const int* in_sizes, int n_in,
                              void* d_out, int out_size, void* d_ws, size_t ws_size,
                              hipStream_t stream) {
    const int*   atomids = (const int*)d_in[0];
    const float* coords  = (const float*)d_in[1];
    const int*   eidx    = (const int*)d_in[2];
    const int*   batch   = (const int*)d_in[3];
    const float* emb_w   = (const float*)d_in[4];
    const float* eW1     = (const float*)d_in[5];
    const float* eb1     = (const float*)d_in[6];
    const float* eW2     = (const float*)d_in[7];
    const float* eb2     = (const float*)d_in[8];
    const float* en_g    = (const float*)d_in[9];
    const float* en_b    = (const float*)d_in[10];
    const float* nn1_g   = (const float*)d_in[11];
    const float* nn1_b   = (const float*)d_in[12];
    const float* nW1     = (const float*)d_in[13];
    const float* nb1     = (const float*)d_in[14];
    const float* nW2     = (const float*)d_in[15];
    const float* nb2     = (const float*)d_in[16];
    const float* nn2_g   = (const float*)d_in[17];
    const float* nn2_b   = (const float*)d_in[18];
    const float* f1W     = (const float*)d_in[19];
    const float* f1b     = (const float*)d_in[20];
    const float* f2W     = (const float*)d_in[21];
    const float* f2b     = (const float*)d_in[22];
    const float* f3W     = (const float*)d_in[23];
    const float* f3b     = (const float*)d_in[24];
    const float* g1W     = (const float*)d_in[25];
    const float* g1b     = (const float*)d_in[26];
    const float* g2W     = (const float*)d_in[27];
    const float* g2b     = (const float*)d_in[28];
    const float* g3W     = (const float*)d_in[29];
    const float* g3b     = (const float*)d_in[30];
    float* out = (float*)d_out;

    float* ws = (float*)d_ws;
    float* feats_all = ws;                        // [10000][768]
    float* d2g   = ws + 7680000;                  // [160000]
    float* Pab   = ws + 7840000;                  // region: bf16 [10000][1296] = 25.9MB of 51.8MB
    float* S     = ws + 20800000;                 // [10000][32] (fallback path only)
    float* cnt   = ws + 21120000;                 // [10000]
    float* W1ab5 = ws + 21130000;                 // [5][128][1296] fp32 (fallback only)
    float* W1cp5 = ws + 21959440;                 // [5][65][768]
    float* b1p5  = ws + 22209040;                 // [5][768]
    float* W2p5  = ws + 22212880;                 // [5][768][32]
    float* feG   = ws + 22335760;                 // [12289][68]
    float* T     = ws + 23171412;                 // [12289][648]
    float* G     = ws + 31134684;                 // [64][256]
    float* cntg  = ws + 31151068;                 // [64]
    int*   histI = (int*)(ws + 31151132);         // [12304]
    int*   offs  = (int*)(ws + 31163436);         // [12304] (persists as dst-CSR offsD)
    int*   cursor= (int*)(ws + 31175740);         // [12304]
    int*   ssiP  = (int*)(ws + 31188044);         // [160000]
    int*   dsiP  = (int*)(ws + 31348044);         // [160000]
    int*   i0P   = (int*)(ws + 31508044);         // [160000]
    float* frP   = ws + 31668044;                 // [160000]
    int*   eixD  = (int*)(ws + 31828044);         // [160000]
    float* Mbuf  = ws + 31988044;                 // [160000][32] (end 37,108,044)
    unsigned short* Bp5U  = (unsigned short*)(ws + 37108044);  // [5][16][1296][8] bf16 (414,720 fl)
    unsigned short* ApackU= (unsigned short*)(ws + 37522764);  // [16][10000][8] bf16 (640,000 fl)
    unsigned short* nW1p5 = (unsigned short*)(ws + 38162764);  // 5 x [20][256][8] bf16 (102,400 fl)
    unsigned short* f1Wp  = (unsigned short*)(ws + 38265164);  // [96][256][8] bf16 (98,304 fl)
    unsigned short* f2Wp  = (unsigned short*)(ws + 38363468);  // [32][256][8] bf16 (32,768 fl)
    unsigned short* f3Wp  = (unsigned short*)(ws + 38396236);  // [32][256][8] bf16 (32,768 fl; end 38,429,004)
    const int useCSR   = (ws_size >= (size_t)(31988044 + 5120000) * sizeof(float)) ? 1 : 0;
    const int useMFMA  = (ws_size >= (size_t)38162764 * sizeof(float)) ? 1 : 0;
    const int useMFMA2 = (ws_size >= (size_t)38429004 * sizeof(float)) ? 1 : 0;
    unsigned short* PabU = (unsigned short*)Pab;  // bf16 view
    // node-phase temporaries overlay Pab region (dead between phases)
    float* H0 = Pab;                              // [10000][160]
    float* H1 = Pab + 1600000;                    // [10000][256]
    float* F1 = Pab;                              // [10000][256]
    float* F2 = Pab + 2560000;                    // [10000][256]
    float* F3 = Pab + 5120000;                    // [10000][256]
    // Ap2 scratch for N=256 MFMA A-packs: overlays free top of Pab region
    // [7.68M, 11.52M) fl -- disjoint from Pab-bf16 [0,6.48M), H0/H1, F1/F2/F3.
    unsigned short* Ap2 = (unsigned short*)(Pab + 7680000);   // up to [96][10000][8] bf16

    k_embed<<<N_NODES, 128, 0, stream>>>(atomids, emb_w, feats_all);
    k_d2<<<(N_EDGES + 255) / 256, 256, 0, stream>>>(coords, eidx, d2g);
    hipMemsetAsync(cnt, 0, 10000 * sizeof(float), stream);
    k_cnt<<<(N_EDGES + 255) / 256, 256, 0, stream>>>(eidx, cnt);
    hipMemsetAsync(histI, 0, 12304 * sizeof(int), stream);
    k_hist<<<(N_EDGES + 255) / 256, 256, 0, stream>>>(d2g, histI);
    k_scan<<<1, 256, 0, stream>>>(histI, offs);
    k_copyi<<<(TROWS + 255) / 256, 256, 0, stream>>>(offs, cursor);
    k_scatter<<<(N_EDGES + 255) / 256, 256, 0, stream>>>(eidx, d2g, cursor,
                                                         ssiP, dsiP, i0P, frP);
    if (useCSR) {
        hipMemsetAsync(histI, 0, 12304 * sizeof(int), stream);
        k_hist_d<<<(N_EDGES + 255) / 256, 256, 0, stream>>>(dsiP, histI);
        k_scan<<<1, 256, 0, stream>>>(histI, offs);
        k_copyi<<<(TROWS + 255) / 256, 256, 0, stream>>>(offs, cursor);
        k_scatter_d<<<(N_EDGES + 255) / 256, 256, 0, stream>>>(dsiP, cursor, eixD);
    }
    k_feg<<<(TROWS + 255) / 256, 256, 0, stream>>>(feG);
    if (useMFMA)
        k_bpack5<<<dim3(648, 5), 256, 0, stream>>>(eW1, Bp5U);
    else
        k_w1ab5<<<dim3(648, 5), 256, 0, stream>>>(eW1, W1ab5);
    k_wpre5<<<dim3(294, 5), 256, 0, stream>>>(eW1, eb1, eW2, W1cp5, b1p5, W2p5);
    if (useMFMA2) {
        for (int k = 0; k < NK; ++k)
            k_bpack2<<<160, 256, 0, stream>>>(nW1 + (size_t)k * 160 * 256, 160,
                                              nW1p5 + (size_t)k * 40960);
        k_bpack2<<<768, 256, 0, stream>>>(f1W, 768, f1Wp);
        k_bpack2<<<256, 256, 0, stream>>>(f2W, 256, f2Wp);
        k_bpack2<<<256, 256, 0, stream>>>(f3W, 256, f3Wp);
    }

    for (int k = 0; k < NK; ++k) {
        const float* eb2k = eb2 + (size_t)k * 32;
        const float* engk = en_g + (size_t)k * 32;
        const float* enbk = en_b + (size_t)k * 32;
        const float* nn1gk = nn1_g + (size_t)k * 128;
        const float* nn1bk = nn1_b + (size_t)k * 128;
        const float* nW1k = nW1 + (size_t)k * 160 * 256;
        const float* nb1k = nb1 + (size_t)k * 256;
        const float* nW2k = nW2 + (size_t)k * 256 * 128;
        const float* nb2k = nb2 + (size_t)k * 128;
        const float* nn2gk = nn2_g + (size_t)k * 128;
        const float* nn2bk = nn2_b + (size_t)k * 128;

        k_tab<<<(TROWS + 31) / 32, 256, 0, stream>>>(feG,
                                                     W1cp5 + (size_t)k * 65 * 768,
                                                     b1p5 + (size_t)k * 768, T);
        // MUST write all 1296 Pab columns (k_edge reads zero-padding up to col 1295)
        if (useMFMA) {
            k_apack<<<(N_NODES * 16 + 255) / 256, 256, 0, stream>>>(feats_all + k * 128, ApackU);
            k_gemm_mfma<<<dim3(157, 21), 256, 0, stream>>>(ApackU, Bp5U + (size_t)k * 165888,
                                                           PabU, N_NODES);
        } else {
            k_gemm<<<dim3(79, 11), 256, 0, stream>>>(feats_all + k * 128, 768,
                                                     W1ab5 + (size_t)k * 128 * 1296, 1296,
                                                     nullptr, Pab, 1296, N_NODES, 1296, 128, 0, 0);
        }
        if (!useCSR)
            hipMemsetAsync(S, 0, (size_t)320000 * sizeof(float), stream);
        k_edge<<<N_EDGES / EPB, 256, 0, stream>>>(ssiP, dsiP, i0P, frP, T, PabU,
                                                  W2p5 + (size_t)k * 768 * 32,
                                                  eb2k, engk, enbk, S, Mbuf, useCSR);
        if (useCSR)
            k_agg_ln<<<(N_NODES + 3) / 4, 128, 0, stream>>>(Mbuf, offs, eixD, cnt,
                                                            engk, enbk, H0);
        else
            k_s_ln<<<(N_NODES + 3) / 4, 128, 0, stream>>>(S, cnt, engk, enbk, H0);
        k_prep<<<N_NODES, 128, 0, stream>>>(feats_all + k * 128, nn1gk, nn1bk, H0);
        if (useMFMA2) {
            k_apack2<<<(N_NODES * 20 + 255) / 256, 256, 0, stream>>>(H0, 160, 20, 0, Ap2);
            k_gemm_mfma2<<<dim3(157, 4), 256, 0, stream>>>(Ap2, nW1p5 + (size_t)k * 40960,
                                                           nb1k, H1, N_NODES, 5);
        } else {
            k_gemm64<<<dim3(157, 2), 256, 0, stream>>>(H0, 160, nW1k, 256, nb1k, H1, 256,
                                                       N_NODES, 256, 160, 0, 1);
        }
        k_gemm_ln<<<dim3(157), 256, 0, stream>>>(H1, nW2k, nb2k, feats_all, k,
                                                 nn2gk, nn2bk, N_NODES, 256);
    }

    // final node MLP (F1/F2/F3 overlay Pab)
    if (useMFMA2) {
        k_apack2<<<(N_NODES * 96 + 255) / 256, 256, 0, stream>>>(feats_all, 768, 96, 1, Ap2);
        k_gemm_mfma2<<<dim3(157, 4), 256, 0, stream>>>(Ap2, f1Wp, f1b, F1, N_NODES, 24);
        k_apack2<<<(N_NODES * 32 + 255) / 256, 256, 0, stream>>>(F1, 256, 32, 0, Ap2);
        k_gemm_mfma2<<<dim3(157, 4), 256, 0, stream>>>(Ap2, f2Wp, f2b, F2, N_NODES, 8);
        k_apack2<<<(N_NODES * 32 + 255) / 256, 256, 0, stream>>>(F2, 256, 32, 0, Ap2);
        k_gemm_mfma2<<<dim3(157, 4), 256, 0, stream>>>(Ap2, f3Wp, f3b, F3, N_NODES, 8);
    } else {
        k_gemm64<<<dim3(157, 2), 256, 0, stream>>>(feats_all, 768, f1W, 256, f1b, F1, 256,
                                                   N_NODES, 256, 768, 1, 1);
        k_gemm64<<<dim3(157, 2), 256, 0, stream>>>(F1, 256, f2W, 256, f2b, F2, 256,
                                                   N_NODES, 256, 256, 0, 1);
        k_gemm64<<<dim3(157, 2), 256, 0, stream>>>(F2, 256, f3W, 256, f3b, F3, 256,
                                                   N_NODES, 256, 256, 0, 1);
    }

    hipMemsetAsync(G, 0, (size_t)(16384 + 64) * sizeof(float), stream);
    k_pool<<<313, 256, 0, stream>>>(F3, batch, G, cntg);
    k_graph<<<N_GRAPHS, 256, 0, stream>>>(G, cntg, g1W, g1b, g2W, g2b, g3W, g3b, out);
}

// Round 18
// 2119.711 us; speedup vs baseline: 1.2943x; 1.1520x over previous
//
#include <hip/hip_runtime.h>
#include <hip/hip_bf16.h>

#define N_NODES 10000
#define N_EDGES 160000
#define N_GRAPHS 64
#define NK 5
#define EPS 1e-5f
#define EPB 64           // edges per block (256 threads)
#define JP 648           // packed width for Pab halves
#define PSTRIDE 1296     // Pab row stride (bf16 elems): [Pa 648 | Pb 648]
#define TCOLS 648        // table row width (642 -> 648)
#define TROWS 12289      // d2 grid [0,96], h=1/128
#define IMAX 12287

// MFMA fragment types: gfx950 mfma_f32_16x16x32_bf16 takes v8bf16 operands.
typedef __attribute__((ext_vector_type(8))) __bf16 bf16v8;
typedef __attribute__((ext_vector_type(4))) float f32x4;

__device__ __forceinline__ float silu(float x) { return x / (1.0f + __expf(-x)); }
__device__ __forceinline__ float4 f4fma(float s, float4 w, float4 a) {
    a.x = fmaf(s, w.x, a.x); a.y = fmaf(s, w.y, a.y);
    a.z = fmaf(s, w.z, a.z); a.w = fmaf(s, w.w, a.w);
    return a;
}
__device__ __forceinline__ float wave_sum64(float v) {
    #pragma unroll
    for (int off = 32; off > 0; off >>= 1) v += __shfl_xor(v, off, 64);
    return v;
}
// fp32 -> bf16 (round to nearest even), returned as raw bits
__device__ __forceinline__ unsigned short f2bf(float f) {
    unsigned int u = __float_as_uint(f);
    unsigned int r = u + 0x7FFFu + ((u >> 16) & 1u);
    return (unsigned short)(r >> 16);
}

// ---------------- embedding ----------------
__global__ __launch_bounds__(128) void k_embed(const int* __restrict__ atomids,
                                               const float* __restrict__ emb_w,
                                               float* __restrict__ feats_all) {
    int n = blockIdx.x, tid = threadIdx.x;
    feats_all[(size_t)n * 768 + tid] = emb_w[(size_t)atomids[n] * 128 + tid];
}

// ---------------- per-edge squared distance ----------------
__global__ __launch_bounds__(256) void k_d2(const float* __restrict__ coords,
                                            const int* __restrict__ eidx,
                                            float* __restrict__ d2g) {
    int e = blockIdx.x * 256 + threadIdx.x;
    if (e >= N_EDGES) return;
    int s = eidx[e], d = eidx[N_EDGES + e];
    float dx = coords[s * 3 + 0] - coords[d * 3 + 0];
    float dy = coords[s * 3 + 1] - coords[d * 3 + 1];
    float dz = coords[s * 3 + 2] - coords[d * 3 + 2];
    d2g[e] = dx * dx + dy * dy + dz * dz;
}

// ---------------- in-degree (layer-invariant) ----------------
__global__ __launch_bounds__(256) void k_cnt(const int* __restrict__ eidx,
                                             float* __restrict__ cnt) {
    int e = blockIdx.x * 256 + threadIdx.x;
    if (e >= N_EDGES) return;
    atomicAdd(&cnt[eidx[N_EDGES + e]], 1.0f);
}

// ---------------- counting sort of edges by i0 (T-row index) ----------------
__global__ __launch_bounds__(256) void k_hist(const float* __restrict__ d2g,
                                              int* __restrict__ hist) {
    int e = blockIdx.x * 256 + threadIdx.x;
    if (e >= N_EDGES) return;
    int i0 = (int)(d2g[e] * 128.0f);
    if (i0 > IMAX) i0 = IMAX;
    atomicAdd(&hist[i0], 1);
}

__global__ __launch_bounds__(256) void k_scan(const int* __restrict__ hist,
                                              int* __restrict__ offs) {
    __shared__ int buf[256];
    __shared__ int carryS;
    int tid = threadIdx.x;
    if (tid == 0) carryS = 0;
    __syncthreads();
    for (int base = 0; base < TROWS; base += 256) {
        int v = (base + tid < TROWS) ? hist[base + tid] : 0;
        buf[tid] = v;
        __syncthreads();
        for (int off = 1; off < 256; off <<= 1) {
            int t = (tid >= off) ? buf[tid - off] : 0;
            __syncthreads();
            buf[tid] += t;
            __syncthreads();
        }
        if (base + tid < TROWS) offs[base + tid] = carryS + buf[tid] - v;  // exclusive
        __syncthreads();
        if (tid == 0) carryS += buf[255];
        __syncthreads();
    }
}

__global__ __launch_bounds__(256) void k_copyi(const int* __restrict__ a,
                                               int* __restrict__ b) {
    int i = blockIdx.x * 256 + threadIdx.x;
    if (i < TROWS) b[i] = a[i];
}

__global__ __launch_bounds__(256) void k_scatter(const int* __restrict__ eidx,
                                                 const float* __restrict__ d2g,
                                                 int* __restrict__ cursor,
                                                 int* __restrict__ ssiP,
                                                 int* __restrict__ dsiP,
                                                 int* __restrict__ i0P,
                                                 float* __restrict__ frP) {
    int e = blockIdx.x * 256 + threadIdx.x;
    if (e >= N_EDGES) return;
    float t = d2g[e] * 128.0f;
    int i0 = (int)t;
    if (i0 > IMAX) i0 = IMAX;
    float fr = t - (float)i0;
    int pos = atomicAdd(&cursor[i0], 1);
    ssiP[pos] = eidx[e];
    dsiP[pos] = eidx[N_EDGES + e];
    i0P[pos] = i0;
    frP[pos] = fr;
}

// ---------------- dst-CSR over sorted positions (for atomic-free S aggregation) ----------------
__global__ __launch_bounds__(256) void k_hist_d(const int* __restrict__ dsiP,
                                                int* __restrict__ hist) {
    int p = blockIdx.x * 256 + threadIdx.x;
    if (p >= N_EDGES) return;
    atomicAdd(&hist[dsiP[p]], 1);
}

__global__ __launch_bounds__(256) void k_scatter_d(const int* __restrict__ dsiP,
                                                   int* __restrict__ cursorD,
                                                   int* __restrict__ eixD) {
    int p = blockIdx.x * 256 + threadIdx.x;
    if (p >= N_EDGES) return;
    int pos = atomicAdd(&cursorD[dsiP[p]], 1);
    eixD[pos] = p;
}

// ---------------- CSR aggregation fused with mean + LN: writes H0[:,128:160] ----------------
__global__ __launch_bounds__(128) void k_agg_ln(const float* __restrict__ M,
                                                const int* __restrict__ offsD,
                                                const int* __restrict__ eixD,
                                                const float* __restrict__ cnt,
                                                const float* __restrict__ eng,
                                                const float* __restrict__ enb,
                                                float* __restrict__ H0) {
    int n = blockIdx.x * 4 + (threadIdx.x >> 5);
    int col = threadIdx.x & 31;
    if (n >= N_NODES) return;
    float acc = 0.f;
    int p0 = offsD[n], p1 = offsD[n + 1];
    for (int p = p0; p < p1; ++p)
        acc += M[(size_t)eixD[p] * 32 + col];
    float inv = 1.0f / fmaxf(cnt[n], 1.0f);
    float v = acc * inv;
    float s = v, q = v * v;
    #pragma unroll
    for (int off = 16; off > 0; off >>= 1) {
        s += __shfl_xor(s, off, 64);
        q += __shfl_xor(q, off, 64);
    }
    float m2 = s * (1.0f / 32.0f);
    float va = q * (1.0f / 32.0f) - m2 * m2;
    float rs = 1.0f / sqrtf(va + EPS);
    H0[(size_t)n * 160 + 128 + col] = (v - m2) * rs * eng[col] + enb[col];
}

// ---------------- fallback (no-CSR): S -> mean -> LN -> H0[:,128:160] ----------------
__global__ __launch_bounds__(128) void k_s_ln(const float* __restrict__ S,
                                              const float* __restrict__ cnt,
                                              const float* __restrict__ eng,
                                              const float* __restrict__ enb,
                                              float* __restrict__ H0) {
    int n = blockIdx.x * 4 + (threadIdx.x >> 5);
    int col = threadIdx.x & 31;
    if (n >= N_NODES) return;
    float inv = 1.0f / fmaxf(cnt[n], 1.0f);
    float v = S[(size_t)n * 32 + col] * inv;
    float s = v, q = v * v;
    #pragma unroll
    for (int off = 16; off > 0; off >>= 1) {
        s += __shfl_xor(s, off, 64);
        q += __shfl_xor(q, off, 64);
    }
    float m2 = s * (1.0f / 32.0f);
    float va = q * (1.0f / 32.0f) - m2 * m2;
    float rs = 1.0f / sqrtf(va + EPS);
    H0[(size_t)n * 160 + 128 + col] = (v - m2) * rs * eng[col] + enb[col];
}

// ---------------- fourier features on the d2 GRID (once) ----------------
__global__ __launch_bounds__(256) void k_feg(float* __restrict__ feG) {  // [TROWS][68]
    int g = blockIdx.x * 256 + threadIdx.x;
    if (g >= TROWS) return;
    float d2v = (float)g * 0.0078125f;   // g / 128, exact
    float* o = feG + (size_t)g * 68;
    float sc = 1.0f;
    #pragma unroll
    for (int i = 0; i < 32; ++i) {
        float x = d2v * sc;
        o[i] = sinf(x);
        o[32 + i] = cosf(x);
        sc *= 0.5f;
    }
    o[64] = d2v;
}

// ---------------- per-layer q-table (fp32 fallback): T[g][j] = fe(g/128) @ W1c + b1 ----------------
__global__ __launch_bounds__(256) void k_tab(const float* __restrict__ feG,   // [TROWS][68]
                                             const float* __restrict__ W1cp,  // [65][768]
                                             const float* __restrict__ b1p,   // [768]
                                             float* __restrict__ T) {         // [TROWS][648]
    __shared__ float feGs[32 * 68];
    __shared__ float W1s[65 * 36];
    const int tid = threadIdx.x;
    const int g0 = blockIdx.x * 32;
    for (int idx = tid; idx < 32 * 17; idx += 256) {
        int r = idx / 17, c = idx - r * 17;
        int gi = g0 + r;
        float4 v = make_float4(0, 0, 0, 0);
        if (gi < TROWS) v = *(const float4*)(feG + (size_t)gi * 68 + 4 * c);
        *(float4*)&feGs[r * 68 + 4 * c] = v;
    }
    const int gt = tid >> 3, ct = tid & 7;
    for (int jc = 0; jc < TCOLS; jc += 32) {
        __syncthreads();
        for (int idx = tid; idx < 65 * 32; idx += 256) {
            int k = idx >> 5, j = idx & 31;
            W1s[k * 36 + j] = W1cp[(size_t)k * 768 + jc + j];
        }
        __syncthreads();
        int gj = jc + 4 * ct;
        float4 q = *(const float4*)(b1p + gj);
        #pragma unroll 5
        for (int k = 0; k < 65; ++k) {
            float f = feGs[gt * 68 + k];
            float4 w = *(const float4*)&W1s[k * 36 + 4 * ct];
            q = f4fma(f, w, q);
        }
        int g = g0 + gt;
        if (g < TROWS && gj < TCOLS)
            *(float4*)(T + (size_t)g * TCOLS + gj) = q;
    }
}

// ---------------- W1ab prestage (fp32, fallback path only) ----------------
__global__ __launch_bounds__(256) void k_w1ab5(const float* __restrict__ eW1,
                                               float* __restrict__ W1ab5) {
    int k = blockIdx.y;
    const float* W1 = eW1 + (size_t)k * 321 * 642;
    float* W1ab = W1ab5 + (size_t)k * 128 * 1296;
    int idx = blockIdx.x * 256 + threadIdx.x;
    if (idx >= 128 * 1296) return;
    int r = idx / 1296;
    int j = idx - r * 1296;
    float v = 0.f;
    if (j < 642) v = W1[(size_t)r * 642 + j];
    else if (j >= 648 && j < 1290) v = W1[(size_t)(128 + r) * 642 + (j - 648)];
    W1ab[idx] = v;
}

// ---------------- MFMA B-fragment prestage: Bpack[5][16][1296][8] bf16 ----------------
__global__ __launch_bounds__(256) void k_bpack5(const float* __restrict__ eW1,
                                                unsigned short* __restrict__ Bp5) {
    int idx = blockIdx.x * 256 + threadIdx.x;
    if (idx >= 16 * 1296 * 8) return;
    int k = blockIdx.y;
    int kg = idx / (1296 * 8);
    int rem = idx - kg * (1296 * 8);
    int c = rem >> 3, jj = rem & 7;
    int r = kg * 8 + jj;             // K index 0..127
    const float* W1 = eW1 + (size_t)k * 321 * 642;
    float v = 0.f;
    if (c < 642) v = W1[(size_t)r * 642 + c];
    else if (c >= 648 && c < 1290) v = W1[(size_t)(128 + r) * 642 + (c - 648)];
    Bp5[(size_t)k * 165888 + idx] = f2bf(v);
}

// ---------------- generic MFMA B-pack for N=256 weights: dst[kg][256][8] ----------------
__global__ __launch_bounds__(256) void k_bpack2(const float* __restrict__ W,   // [K][256]
                                                int K,
                                                unsigned short* __restrict__ dst) {
    int idx = blockIdx.x * 256 + threadIdx.x;
    if (idx >= K * 256) return;
    int kg = idx / (256 * 8);
    int rem = idx - kg * (256 * 8);
    int c = rem >> 3, jj = rem & 7;
    int r = kg * 8 + jj;
    dst[idx] = f2bf(W[(size_t)r * 256 + c]);
}

// ---------------- k_tab MFMA B-pack: Bt[5][12][648][8] from W1cp5 (rows>=65 zero) ----------------
__global__ __launch_bounds__(256) void k_bpack3(const float* __restrict__ W1cp5,
                                                unsigned short* __restrict__ Bt5) {
    int idx = blockIdx.x * 256 + threadIdx.x;
    if (idx >= 12 * 648 * 8) return;
    int k = blockIdx.y;
    int kg = idx / (648 * 8);
    int rem = idx - kg * (648 * 8);
    int c = rem >> 3, jj = rem & 7;
    int r = kg * 8 + jj;
    float v = (r < 65) ? W1cp5[(size_t)k * 65 * 768 + (size_t)r * 768 + c] : 0.f;
    Bt5[(size_t)k * 62208 + idx] = f2bf(v);
}

// ---------------- k_tab MFMA A-pack: Ag[12][TROWS][8] from feG (k>=68 zero), once ----------------
__global__ __launch_bounds__(256) void k_apack3(const float* __restrict__ feG,
                                                unsigned short* __restrict__ Ag) {
    int t = blockIdx.x * 256 + threadIdx.x;
    if (t >= TROWS * 12) return;
    int kg = t / TROWS, m = t - kg * TROWS;
    const float* s = feG + (size_t)m * 68;
    unsigned short* d = Ag + ((size_t)kg * TROWS + m) * 8;
    #pragma unroll
    for (int j = 0; j < 8; ++j) {
        int kk = kg * 8 + j;
        d[j] = (kk < 68) ? f2bf(s[kk]) : (unsigned short)0;
    }
}

// ---------------- generic MFMA A-pack: dst[kg][M][8] from fp32 [M][stride], optional silu ----------------
__global__ __launch_bounds__(256) void k_apack2(const float* __restrict__ src, int stride,
                                                int Kg, int doSilu,
                                                unsigned short* __restrict__ dst) {
    int t = blockIdx.x * 256 + threadIdx.x;
    if (t >= N_NODES * Kg) return;
    int kg = t / N_NODES, m = t - kg * N_NODES;
    const float* s = src + (size_t)m * stride + kg * 8;
    unsigned short* d = dst + ((size_t)kg * N_NODES + m) * 8;
    #pragma unroll
    for (int j = 0; j < 8; ++j) {
        float v = s[j];
        if (doSilu) v = silu(v);
        d[j] = f2bf(v);
    }
}

// ---------------- MFMA A-fragment staging (per layer): Apack[16][10000][8] bf16 ----------------
__global__ __launch_bounds__(256) void k_apack(const float* __restrict__ feats, // + k*128, stride 768
                                               unsigned short* __restrict__ Ap) {
    int t = blockIdx.x * 256 + threadIdx.x;   // t: m = t>>4, kg = t&15
    if (t >= N_NODES * 16) return;
    int m = t >> 4, kg = t & 15;
    const float* src = feats + (size_t)m * 768 + kg * 8;
    unsigned short* dst = Ap + ((size_t)kg * N_NODES + m) * 8;
    #pragma unroll
    for (int j = 0; j < 8; ++j) dst[j] = f2bf(src[j]);
}

// ---------------- Pab GEMM on matrix cores: bf16 in, fp32 MFMA accum, bf16 out ----------------
__global__ __launch_bounds__(256) void k_gemm_mfma(const unsigned short* __restrict__ Ap, // [16][M][8]
                                                   const unsigned short* __restrict__ Bp, // [16][1296][8]
                                                   unsigned short* __restrict__ C,        // [M][1296] bf16
                                                   int M) {
    const int tid = threadIdx.x;
    const int w = tid >> 6, l = tid & 63;
    const int m0 = blockIdx.x * 64 + (w >> 1) * 32;
    const int n0 = blockIdx.y * 64 + (w & 1) * 32;
    const int lr = l & 15, lg = l >> 4;

    f32x4 acc[2][2] = {};
    for (int kb = 0; kb < 4; ++kb) {
        const int kg = kb * 4 + lg;
        bf16v8 a[2], b[2];
        #pragma unroll
        for (int i = 0; i < 2; ++i) {
            int mrow = m0 + i * 16 + lr; if (mrow >= M) mrow = M - 1;
            a[i] = *(const bf16v8*)(Ap + ((size_t)kg * M + mrow) * 8);
            int ncol = n0 + i * 16 + lr; if (ncol > 1295) ncol = 1295;
            b[i] = *(const bf16v8*)(Bp + ((size_t)kg * 1296 + ncol) * 8);
        }
        #pragma unroll
        for (int mi = 0; mi < 2; ++mi)
            #pragma unroll
            for (int ni = 0; ni < 2; ++ni)
                acc[mi][ni] = __builtin_amdgcn_mfma_f32_16x16x32_bf16(a[mi], b[ni], acc[mi][ni], 0, 0, 0);
    }
    #pragma unroll
    for (int mi = 0; mi < 2; ++mi)
        #pragma unroll
        for (int ni = 0; ni < 2; ++ni)
            #pragma unroll
            for (int j = 0; j < 4; ++j) {
                int gm = m0 + mi * 16 + lg * 4 + j;
                int gn = n0 + ni * 16 + lr;
                if (gm < M && gn < 1296)
                    C[(size_t)gm * 1296 + gn] = f2bf(acc[mi][ni][j]);
            }
}

// ---------------- generic MFMA GEMM, N=256, fp32 out: C = silu(A@B + bias) ----------------
__global__ __launch_bounds__(256) void k_gemm_mfma2(const unsigned short* __restrict__ Ap, // [Kg][M][8]
                                                    const unsigned short* __restrict__ Bp, // [Kg][256][8]
                                                    const float* __restrict__ bias,        // [256]
                                                    float* __restrict__ C,                 // [M][256]
                                                    int M, int KB) {
    const int tid = threadIdx.x;
    const int w = tid >> 6, l = tid & 63;
    const int m0 = blockIdx.x * 64 + (w >> 1) * 32;
    const int n0 = blockIdx.y * 64 + (w & 1) * 32;
    const int lr = l & 15, lg = l >> 4;

    f32x4 acc[2][2] = {};
    for (int kb = 0; kb < KB; ++kb) {
        const int kg = kb * 4 + lg;
        bf16v8 a[2], b[2];
        #pragma unroll
        for (int i = 0; i < 2; ++i) {
            int mrow = m0 + i * 16 + lr; if (mrow >= M) mrow = M - 1;
            a[i] = *(const bf16v8*)(Ap + ((size_t)kg * M + mrow) * 8);
            int ncol = n0 + i * 16 + lr;   // always < 256
            b[i] = *(const bf16v8*)(Bp + ((size_t)kg * 256 + ncol) * 8);
        }
        #pragma unroll
        for (int mi = 0; mi < 2; ++mi)
            #pragma unroll
            for (int ni = 0; ni < 2; ++ni)
                acc[mi][ni] = __builtin_amdgcn_mfma_f32_16x16x32_bf16(a[mi], b[ni], acc[mi][ni], 0, 0, 0);
    }
    #pragma unroll
    for (int mi = 0; mi < 2; ++mi)
        #pragma unroll
        for (int ni = 0; ni < 2; ++ni)
            #pragma unroll
            for (int j = 0; j < 4; ++j) {
                int gm = m0 + mi * 16 + lg * 4 + j;
                int gn = n0 + ni * 16 + lr;
                if (gm < M)
                    C[(size_t)gm * 256 + gn] = silu(acc[mi][ni][j] + bias[gn]);
            }
}

// ---------------- k_tab MFMA GEMM: T[TROWS][648] = Ag @ Bt + b1 (fp32 out) ----------------
// KB=3 (K padded 65->96). Same fragment mapping as verified k_gemm_mfma.
__global__ __launch_bounds__(256) void k_gemm_mfma3(const unsigned short* __restrict__ Ag, // [12][TROWS][8]
                                                    const unsigned short* __restrict__ Bt, // [12][648][8]
                                                    const float* __restrict__ bias,        // [768] (b1p)
                                                    float* __restrict__ T) {               // [TROWS][648]
    const int tid = threadIdx.x;
    const int w = tid >> 6, l = tid & 63;
    const int m0 = blockIdx.x * 64 + (w >> 1) * 32;
    const int n0 = blockIdx.y * 64 + (w & 1) * 32;
    const int lr = l & 15, lg = l >> 4;

    f32x4 acc[2][2] = {};
    for (int kb = 0; kb < 3; ++kb) {
        const int kg = kb * 4 + lg;
        bf16v8 a[2], b[2];
        #pragma unroll
        for (int i = 0; i < 2; ++i) {
            int mrow = m0 + i * 16 + lr; if (mrow >= TROWS) mrow = TROWS - 1;
            a[i] = *(const bf16v8*)(Ag + ((size_t)kg * TROWS + mrow) * 8);
            int ncol = n0 + i * 16 + lr; if (ncol > 647) ncol = 647;
            b[i] = *(const bf16v8*)(Bt + ((size_t)kg * 648 + ncol) * 8);
        }
        #pragma unroll
        for (int mi = 0; mi < 2; ++mi)
            #pragma unroll
            for (int ni = 0; ni < 2; ++ni)
                acc[mi][ni] = __builtin_amdgcn_mfma_f32_16x16x32_bf16(a[mi], b[ni], acc[mi][ni], 0, 0, 0);
    }
    #pragma unroll
    for (int mi = 0; mi < 2; ++mi)
        #pragma unroll
        for (int ni = 0; ni < 2; ++ni)
            #pragma unroll
            for (int j = 0; j < 4; ++j) {
                int gm = m0 + mi * 16 + lg * 4 + j;
                int gn = n0 + ni * 16 + lr;
                if (gm < TROWS && gn < TCOLS)
                    T[(size_t)gm * TCOLS + gn] = acc[mi][ni][j] + bias[gn];
            }
}

// ---------------- padded edge-weight prestage (all 5 layers) ----------------
__global__ __launch_bounds__(256) void k_wpre5(const float* __restrict__ eW1,
                                               const float* __restrict__ eb1,
                                               const float* __restrict__ eW2,
                                               float* __restrict__ W1cp5,   // [5][65][768]
                                               float* __restrict__ b1p5,    // [5][768]
                                               float* __restrict__ W2p5) {  // [5][768][32]
    int k = blockIdx.y;
    const float* W1 = eW1 + (size_t)k * 321 * 642;
    const float* b1 = eb1 + (size_t)k * 642;
    const float* W2 = eW2 + (size_t)k * 642 * 32;
    float* W1cp = W1cp5 + (size_t)k * 65 * 768;
    float* b1p  = b1p5 + (size_t)k * 768;
    float* W2p  = W2p5 + (size_t)k * 768 * 32;
    int idx = blockIdx.x * 256 + threadIdx.x;
    if (idx < 65 * 768) {
        int r = idx / 768, j = idx - r * 768;
        W1cp[idx] = (j < 642) ? W1[(size_t)(256 + r) * 642 + j] : 0.f;
    } else if (idx < 65 * 768 + 768) {
        int j = idx - 65 * 768;
        b1p[j] = (j < 642) ? b1[j] : 0.f;
    } else if (idx < 65 * 768 + 768 + 768 * 32) {
        int t = idx - (65 * 768 + 768);
        int j = t >> 5, c = t & 31;
        W2p[t] = (j < 642) ? W2[(size_t)j * 32 + c] : 0.f;
    }
}

// ---------------- fp32 GEMM 128x128 tile, BF16 OUTPUT (Pab fallback path) ----------------
__global__ __launch_bounds__(256) void k_gemm(const float* __restrict__ A, int lda,
                                              const float* __restrict__ B, int ldb,
                                              const float* __restrict__ bias,
                                              float* __restrict__ C, int ldc,  // treated as ushort*
                                              int M, int N, int K, int siluA, int siluOut) {
    __shared__ float As[32 * 132];
    __shared__ float Bs[32 * 132];
    const int tid = threadIdx.x;
    const int m0 = blockIdx.x * 128, n0 = blockIdx.y * 128;
    const int tm = tid >> 4, tn = tid & 15;

    float4 acc[8][2];
    #pragma unroll
    for (int r = 0; r < 8; ++r) { acc[r][0] = make_float4(0,0,0,0); acc[r][1] = make_float4(0,0,0,0); }

    float4 ra[4], rb[4];

#define GLOAD(kc_) do { \
    _Pragma("unroll") \
    for (int i_ = 0; i_ < 4; ++i_) { \
        int idx_ = tid + i_ * 256; \
        int m_ = idx_ >> 3, kq_ = idx_ & 7; \
        int gm_ = m0 + m_; \
        int cm_ = (gm_ < M) ? gm_ : (M - 1); \
        float4 a_ = *(const float4*)(A + (size_t)cm_ * lda + (kc_) + 4 * kq_); \
        if (gm_ >= M) a_ = make_float4(0,0,0,0); \
        ra[i_] = a_; \
    } \
    _Pragma("unroll") \
    for (int i_ = 0; i_ < 4; ++i_) { \
        int idx_ = tid + i_ * 256; \
        int r_ = idx_ >> 5, cq_ = idx_ & 31; \
        int gn_ = n0 + 4 * cq_; \
        float4 b_ = make_float4(0,0,0,0); \
        if (gn_ < N) b_ = *(const float4*)(B + (size_t)((kc_) + r_) * ldb + gn_); \
        rb[i_] = b_; \
    } \
} while (0)

    GLOAD(0);

    for (int kc = 0; kc < K; kc += 32) {
        #pragma unroll
        for (int i = 0; i < 4; ++i) {
            int idx = tid + i * 256;
            int m = idx >> 3, kq = idx & 7;
            float4 a = ra[i];
            if (siluA) { a.x = silu(a.x); a.y = silu(a.y); a.z = silu(a.z); a.w = silu(a.w); }
            As[(4 * kq + 0) * 132 + m] = a.x;
            As[(4 * kq + 1) * 132 + m] = a.y;
            As[(4 * kq + 2) * 132 + m] = a.z;
            As[(4 * kq + 3) * 132 + m] = a.w;
        }
        #pragma unroll
        for (int i = 0; i < 4; ++i) {
            int idx = tid + i * 256;
            int r = idx >> 5, cq = idx & 31;
            *(float4*)&Bs[r * 132 + 4 * cq] = rb[i];
        }
        __syncthreads();
        if (kc + 32 < K) GLOAD(kc + 32);   // in flight during FMA below
        #pragma unroll 4
        for (int kk = 0; kk < 32; ++kk) {
            float4 a0 = *(const float4*)&As[kk * 132 + 8 * tm];
            float4 a1 = *(const float4*)&As[kk * 132 + 8 * tm + 4];
            float4 b0 = *(const float4*)&Bs[kk * 132 + 4 * tn];
            float4 b1 = *(const float4*)&Bs[kk * 132 + 64 + 4 * tn];
            acc[0][0] = f4fma(a0.x, b0, acc[0][0]); acc[0][1] = f4fma(a0.x, b1, acc[0][1]);
            acc[1][0] = f4fma(a0.y, b0, acc[1][0]); acc[1][1] = f4fma(a0.y, b1, acc[1][1]);
            acc[2][0] = f4fma(a0.z, b0, acc[2][0]); acc[2][1] = f4fma(a0.z, b1, acc[2][1]);
            acc[3][0] = f4fma(a0.w, b0, acc[3][0]); acc[3][1] = f4fma(a0.w, b1, acc[3][1]);
            acc[4][0] = f4fma(a1.x, b0, acc[4][0]); acc[4][1] = f4fma(a1.x, b1, acc[4][1]);
            acc[5][0] = f4fma(a1.y, b0, acc[5][0]); acc[5][1] = f4fma(a1.y, b1, acc[5][1]);
            acc[6][0] = f4fma(a1.z, b0, acc[6][0]); acc[6][1] = f4fma(a1.z, b1, acc[6][1]);
            acc[7][0] = f4fma(a1.w, b0, acc[7][0]); acc[7][1] = f4fma(a1.w, b1, acc[7][1]);
        }
        __syncthreads();
    }
#undef GLOAD

    unsigned short* C16 = (unsigned short*)C;
    const int gnl = n0 + 4 * tn, gnh = n0 + 64 + 4 * tn;
    #pragma unroll
    for (int r = 0; r < 8; ++r) {
        int gm = m0 + 8 * tm + r;
        if (gm >= M) continue;
        float4 v0 = acc[r][0], v1 = acc[r][1];
        if (gnl < N) {
            if (bias) { v0.x += bias[gnl+0]; v0.y += bias[gnl+1]; v0.z += bias[gnl+2]; v0.w += bias[gnl+3]; }
            if (siluOut) { v0.x = silu(v0.x); v0.y = silu(v0.y); v0.z = silu(v0.z); v0.w = silu(v0.w); }
            ushort4 s0; s0.x = f2bf(v0.x); s0.y = f2bf(v0.y); s0.z = f2bf(v0.z); s0.w = f2bf(v0.w);
            *(ushort4*)&C16[(size_t)gm * ldc + gnl] = s0;
        }
        if (gnh < N) {
            if (bias) { v1.x += bias[gnh+0]; v1.y += bias[gnh+1]; v1.z += bias[gnh+2]; v1.w += bias[gnh+3]; }
            if (siluOut) { v1.x = silu(v1.x); v1.y = silu(v1.y); v1.z = silu(v1.z); v1.w = silu(v1.w); }
            ushort4 s1; s1.x = f2bf(v1.x); s1.y = f2bf(v1.y); s1.z = f2bf(v1.z); s1.w = f2bf(v1.w);
            *(ushort4*)&C16[(size_t)gm * ldc + gnh] = s1;
        }
    }
}

// ---------------- fp32 GEMM 64x128 tile (fallback for small-N dispatches) ----------------
__global__ __launch_bounds__(256) void k_gemm64(const float* __restrict__ A, int lda,
                                                const float* __restrict__ B, int ldb,
                                                const float* __restrict__ bias,
                                                float* __restrict__ C, int ldc,
                                                int M, int N, int K, int siluA, int siluOut) {
    __shared__ float As[32 * 68];
    __shared__ float Bs[32 * 132];
    const int tid = threadIdx.x;
    const int m0 = blockIdx.x * 64, n0 = blockIdx.y * 128;
    const int tm = tid >> 4, tn = tid & 15;

    float4 acc[4][2];
    #pragma unroll
    for (int r = 0; r < 4; ++r) { acc[r][0] = make_float4(0,0,0,0); acc[r][1] = make_float4(0,0,0,0); }

    float4 ra[2], rb[4];

#define GLOAD64(kc_) do { \
    _Pragma("unroll") \
    for (int i_ = 0; i_ < 2; ++i_) { \
        int idx_ = tid + i_ * 256; \
        int m_ = idx_ >> 3, kq_ = idx_ & 7; \
        int gm_ = m0 + m_; \
        int cm_ = (gm_ < M) ? gm_ : (M - 1); \
        float4 a_ = *(const float4*)(A + (size_t)cm_ * lda + (kc_) + 4 * kq_); \
        if (gm_ >= M) a_ = make_float4(0,0,0,0); \
        ra[i_] = a_; \
    } \
    _Pragma("unroll") \
    for (int i_ = 0; i_ < 4; ++i_) { \
        int idx_ = tid + i_ * 256; \
        int r_ = idx_ >> 5, cq_ = idx_ & 31; \
        int gn_ = n0 + 4 * cq_; \
        float4 b_ = make_float4(0,0,0,0); \
        if (gn_ < N) b_ = *(const float4*)(B + (size_t)((kc_) + r_) * ldb + gn_); \
        rb[i_] = b_; \
    } \
} while (0)

    GLOAD64(0);

    for (int kc = 0; kc < K; kc += 32) {
        #pragma unroll
        for (int i = 0; i < 2; ++i) {
            int idx = tid + i * 256;
            int m = idx >> 3, kq = idx & 7;
            float4 a = ra[i];
            if (siluA) { a.x = silu(a.x); a.y = silu(a.y); a.z = silu(a.z); a.w = silu(a.w); }
            As[(4 * kq + 0) * 68 + m] = a.x;
            As[(4 * kq + 1) * 68 + m] = a.y;
            As[(4 * kq + 2) * 68 + m] = a.z;
            As[(4 * kq + 3) * 68 + m] = a.w;
        }
        #pragma unroll
        for (int i = 0; i < 4; ++i) {
            int idx = tid + i * 256;
            int r = idx >> 5, cq = idx & 31;
            *(float4*)&Bs[r * 132 + 4 * cq] = rb[i];
        }
        __syncthreads();
        if (kc + 32 < K) GLOAD64(kc + 32);   // in flight during FMA below
        #pragma unroll 4
        for (int kk = 0; kk < 32; ++kk) {
            float4 av = *(const float4*)&As[kk * 68 + 4 * tm];
            float4 b0 = *(const float4*)&Bs[kk * 132 + 4 * tn];
            float4 b1 = *(const float4*)&Bs[kk * 132 + 64 + 4 * tn];
            acc[0][0] = f4fma(av.x, b0, acc[0][0]); acc[0][1] = f4fma(av.x, b1, acc[0][1]);
            acc[1][0] = f4fma(av.y, b0, acc[1][0]); acc[1][1] = f4fma(av.y, b1, acc[1][1]);
            acc[2][0] = f4fma(av.z, b0, acc[2][0]); acc[2][1] = f4fma(av.z, b1, acc[2][1]);
            acc[3][0] = f4fma(av.w, b0, acc[3][0]); acc[3][1] = f4fma(av.w, b1, acc[3][1]);
        }
        __syncthreads();
    }
#undef GLOAD64

    const int gnl = n0 + 4 * tn, gnh = n0 + 64 + 4 * tn;
    #pragma unroll
    for (int r = 0; r < 4; ++r) {
        int gm = m0 + 4 * tm + r;
        if (gm >= M) continue;
        float4 v0 = acc[r][0], v1 = acc[r][1];
        if (gnl < N) {
            if (bias) { v0.x += bias[gnl+0]; v0.y += bias[gnl+1]; v0.z += bias[gnl+2]; v0.w += bias[gnl+3]; }
            if (siluOut) { v0.x = silu(v0.x); v0.y = silu(v0.y); v0.z = silu(v0.z); v0.w = silu(v0.w); }
            *(float4*)&C[(size_t)gm * ldc + gnl] = v0;
        }
        if (gnh < N) {
            if (bias) { v1.x += bias[gnh+0]; v1.y += bias[gnh+1]; v1.z += bias[gnh+2]; v1.w += bias[gnh+3]; }
            if (siluOut) { v1.x = silu(v1.x); v1.y = silu(v1.y); v1.z = silu(v1.z); v1.w = silu(v1.w); }
            *(float4*)&C[(size_t)gm * ldc + gnh] = v1;
        }
    }
}

// ---------------- fused H2 GEMM + LN + residual ----------------
__global__ __launch_bounds__(256) void k_gemm_ln(const float* __restrict__ A,   // H1 [M][256]
                                                 const float* __restrict__ B,   // nW2 [256][128]
                                                 const float* __restrict__ bias,// nb2 [128]
                                                 float* __restrict__ feats_all, int layer,
                                                 const float* __restrict__ g,
                                                 const float* __restrict__ b,
                                                 int M, int K) {
    __shared__ float As[32 * 68];
    __shared__ float Bs[32 * 132];
    const int tid = threadIdx.x;
    const int m0 = blockIdx.x * 64;
    const int tm = tid >> 4, tn = tid & 15;

    float4 acc[4][2];
    #pragma unroll
    for (int r = 0; r < 4; ++r) { acc[r][0] = make_float4(0,0,0,0); acc[r][1] = make_float4(0,0,0,0); }

    float4 ra[2], rb[4];

#define GLOADL(kc_) do { \
    _Pragma("unroll") \
    for (int i_ = 0; i_ < 2; ++i_) { \
        int idx_ = tid + i_ * 256; \
        int m_ = idx_ >> 3, kq_ = idx_ & 7; \
        int gm_ = m0 + m_; \
        int cm_ = (gm_ < M) ? gm_ : (M - 1); \
        float4 a_ = *(const float4*)(A + (size_t)cm_ * 256 + (kc_) + 4 * kq_); \
        if (gm_ >= M) a_ = make_float4(0,0,0,0); \
        ra[i_] = a_; \
    } \
    _Pragma("unroll") \
    for (int i_ = 0; i_ < 4; ++i_) { \
        int idx_ = tid + i_ * 256; \
        int r_ = idx_ >> 5, cq_ = idx_ & 31; \
        float4 b_ = make_float4(0,0,0,0); \
        if (4 * cq_ < 128) b_ = *(const float4*)(B + (size_t)((kc_) + r_) * 128 + 4 * cq_); \
        rb[i_] = b_; \
    } \
} while (0)

    GLOADL(0);

    for (int kc = 0; kc < K; kc += 32) {
        #pragma unroll
        for (int i = 0; i < 2; ++i) {
            int idx = tid + i * 256;
            int m = idx >> 3, kq = idx & 7;
            float4 a = ra[i];
            As[(4 * kq + 0) * 68 + m] = a.x;
            As[(4 * kq + 1) * 68 + m] = a.y;
            As[(4 * kq + 2) * 68 + m] = a.z;
            As[(4 * kq + 3) * 68 + m] = a.w;
        }
        #pragma unroll
        for (int i = 0; i < 4; ++i) {
            int idx = tid + i * 256;
            int r = idx >> 5, cq = idx & 31;
            if (cq < 32) *(float4*)&Bs[r * 132 + 4 * cq] = rb[i];
        }
        __syncthreads();
        if (kc + 32 < K) GLOADL(kc + 32);
        #pragma unroll 4
        for (int kk = 0; kk < 32; ++kk) {
            float4 av = *(const float4*)&As[kk * 68 + 4 * tm];
            float4 b0 = *(const float4*)&Bs[kk * 132 + 4 * tn];
            float4 b1 = *(const float4*)&Bs[kk * 132 + 64 + 4 * tn];
            acc[0][0] = f4fma(av.x, b0, acc[0][0]); acc[0][1] = f4fma(av.x, b1, acc[0][1]);
            acc[1][0] = f4fma(av.y, b0, acc[1][0]); acc[1][1] = f4fma(av.y, b1, acc[1][1]);
            acc[2][0] = f4fma(av.z, b0, acc[2][0]); acc[2][1] = f4fma(av.z, b1, acc[2][1]);
            acc[3][0] = f4fma(av.w, b0, acc[3][0]); acc[3][1] = f4fma(av.w, b1, acc[3][1]);
        }
        __syncthreads();
    }
#undef GLOADL

    const int cl = 4 * tn, chh = 64 + 4 * tn;
    float4 gl = *(const float4*)(g + cl),  gh = *(const float4*)(g + chh);
    float4 bl = *(const float4*)(b + cl),  bh = *(const float4*)(b + chh);
    float4 wl = *(const float4*)(bias + cl), wh = *(const float4*)(bias + chh);
    #pragma unroll
    for (int r = 0; r < 4; ++r) {
        int gm = m0 + 4 * tm + r;
        if (gm >= M) continue;   // uniform across the 16-lane tn-group (same tm,r)
        float4 v0 = acc[r][0], v1 = acc[r][1];
        v0.x += wl.x; v0.y += wl.y; v0.z += wl.z; v0.w += wl.w;
        v1.x += wh.x; v1.y += wh.y; v1.z += wh.z; v1.w += wh.w;
        float s  = v0.x + v0.y + v0.z + v0.w + v1.x + v1.y + v1.z + v1.w;
        float ss = v0.x*v0.x + v0.y*v0.y + v0.z*v0.z + v0.w*v0.w
                 + v1.x*v1.x + v1.y*v1.y + v1.z*v1.z + v1.w*v1.w;
        s  += __shfl_xor(s, 1, 64);  ss += __shfl_xor(ss, 1, 64);
        s  += __shfl_xor(s, 2, 64);  ss += __shfl_xor(ss, 2, 64);
        s  += __shfl_xor(s, 4, 64);  ss += __shfl_xor(ss, 4, 64);
        s  += __shfl_xor(s, 8, 64);  ss += __shfl_xor(ss, 8, 64);
        float mean = s * (1.0f / 128.0f);
        float var  = ss * (1.0f / 128.0f) - mean * mean;
        float rstd = 1.0f / sqrtf(var + EPS);
        float* fp = feats_all + (size_t)gm * 768 + layer * 128;
        float4 f0 = *(const float4*)(fp + cl);
        float4 f1 = *(const float4*)(fp + chh);
        float4 o0, o1;
        o0.x = f0.x + (v0.x - mean) * rstd * gl.x + bl.x;
        o0.y = f0.y + (v0.y - mean) * rstd * gl.y + bl.y;
        o0.z = f0.z + (v0.z - mean) * rstd * gl.z + bl.z;
        o0.w = f0.w + (v0.w - mean) * rstd * gl.w + bl.w;
        o1.x = f1.x + (v1.x - mean) * rstd * gh.x + bh.x;
        o1.y = f1.y + (v1.y - mean) * rstd * gh.y + bh.y;
        o1.z = f1.z + (v1.z - mean) * rstd * gh.z + bh.z;
        o1.w = f1.w + (v1.w - mean) * rstd * gh.w + bh.w;
        float* op = feats_all + (size_t)gm * 768 + (layer + 1) * 128;
        *(float4*)(op + cl)  = o0;
        *(float4*)(op + chh) = o1;
    }
}

// ---------------- fused edge kernel (v12): i0-sort, CSR store epilogue, BF16 Pab ----------------
__global__ __launch_bounds__(256, 3) void k_edge(const int* __restrict__ ssiP,
                                                 const int* __restrict__ dsiP,
                                                 const int* __restrict__ i0P,
                                                 const float* __restrict__ frP,
                                                 const float* __restrict__ T,     // [TROWS][648]
                                                 const unsigned short* __restrict__ Pab, // [N_NODES][1296] bf16
                                                 const float* __restrict__ W2p,   // [768][32]
                                                 const float* __restrict__ b2,
                                                 const float* __restrict__ eng,
                                                 const float* __restrict__ enb,
                                                 float* __restrict__ S,
                                                 float* __restrict__ Mout,
                                                 int csr) {
    __shared__ float Zs[64 * 70];        // 17920 B; overlaid by m2s[64][36] in epilogue
    __shared__ float W2s[64 * 36];       // single-buffered W2 chunk, 9216 B
    __shared__ int dsi[EPB], ssi[EPB], i0s[EPB];
    __shared__ float frs[EPB];
    __shared__ float cpar[96];

    const int tid = threadIdx.x;
    // XCD-chunked bijective swizzle (nwg=2500, 8 XCDs: q=312, r=4 -> first 4 XCDs 313 blocks)
    const int bid = blockIdx.x;
    const int xcd = bid & 7, bpos = bid >> 3;
    const int wg = (xcd < 4) ? xcd * 313 + bpos : 1252 + (xcd - 4) * 312 + bpos;
    const int eb = wg * EPB;
    const int lane = tid & 31;           // edge-pair index (both phases)
    const int grp = tid >> 5;            // col group: phase-1 8 cols, phase-2 4 out-cols

    if (tid < EPB) {
        ssi[tid] = ssiP[eb + tid];
        dsi[tid] = dsiP[eb + tid];
        i0s[tid] = i0P[eb + tid];
        frs[tid] = frP[eb + tid];
    }
    if (tid < 32) cpar[tid] = b2[tid];
    else if (tid < 64) cpar[tid] = eng[tid - 32];
    else if (tid < 96) cpar[tid] = enb[tid - 64];
    __syncthreads();

    int dsr[2], ssr[2], i0r[2];
    float frr[2];
    #pragma unroll
    for (int i = 0; i < 2; ++i) {
        int e = 2 * lane + i;
        dsr[i] = dsi[e]; ssr[i] = ssi[e];
        i0r[i] = i0s[e]; frr[i] = frs[e];
    }

    float4 accm[2];
    accm[0] = make_float4(0,0,0,0);
    accm[1] = make_float4(0,0,0,0);

    float4 rA0[2], rA1[2], rB0[2], rB1[2];
    uint4 rp[2], rq[2];                  // 8 bf16 each (Pa / Pb slices)
    float4 rw0, rw1;

#define PREFETCH(cn) do { \
    const int colb_ = 64 * (cn) + 8 * grp; \
    if (colb_ < TCOLS) { \
        _Pragma("unroll") \
        for (int i_ = 0; i_ < 2; ++i_) { \
            const float* t0_ = T + (size_t)i0r[i_] * TCOLS + colb_; \
            rA0[i_] = *(const float4*)t0_; \
            rA1[i_] = *(const float4*)(t0_ + 4); \
            rB0[i_] = *(const float4*)(t0_ + TCOLS); \
            rB1[i_] = *(const float4*)(t0_ + TCOLS + 4); \
            rp[i_] = *(const uint4*)(Pab + (size_t)dsr[i_] * PSTRIDE + colb_); \
            rq[i_] = *(const uint4*)(Pab + (size_t)ssr[i_] * PSTRIDE + JP + colb_); \
        } \
    } \
    const float* ws_ = W2p + (size_t)(64 * (cn)) * 32 + 8 * tid; \
    rw0 = *(const float4*)ws_; rw1 = *(const float4*)(ws_ + 4); \
} while (0)

    PREFETCH(0);

    for (int ch = 0; ch < 11; ++ch) {
        const int colb = 64 * ch + 8 * grp;

        float qa[2][8];
        if (colb < TCOLS) {
            #pragma unroll
            for (int i = 0; i < 2; ++i) {
                float f = frr[i];
                float pa[8], pb[8];
                pa[0] = __uint_as_float(rp[i].x << 16); pa[1] = __uint_as_float(rp[i].x & 0xFFFF0000u);
                pa[2] = __uint_as_float(rp[i].y << 16); pa[3] = __uint_as_float(rp[i].y & 0xFFFF0000u);
                pa[4] = __uint_as_float(rp[i].z << 16); pa[5] = __uint_as_float(rp[i].z & 0xFFFF0000u);
                pa[6] = __uint_as_float(rp[i].w << 16); pa[7] = __uint_as_float(rp[i].w & 0xFFFF0000u);
                pb[0] = __uint_as_float(rq[i].x << 16); pb[1] = __uint_as_float(rq[i].x & 0xFFFF0000u);
                pb[2] = __uint_as_float(rq[i].y << 16); pb[3] = __uint_as_float(rq[i].y & 0xFFFF0000u);
                pb[4] = __uint_as_float(rq[i].z << 16); pb[5] = __uint_as_float(rq[i].z & 0xFFFF0000u);
                pb[6] = __uint_as_float(rq[i].w << 16); pb[7] = __uint_as_float(rq[i].w & 0xFFFF0000u);
                qa[i][0] = silu(fmaf(f, rB0[i].x - rA0[i].x, rA0[i].x) + pa[0] + pb[0]);
                qa[i][1] = silu(fmaf(f, rB0[i].y - rA0[i].y, rA0[i].y) + pa[1] + pb[1]);
                qa[i][2] = silu(fmaf(f, rB0[i].z - rA0[i].z, rA0[i].z) + pa[2] + pb[2]);
                qa[i][3] = silu(fmaf(f, rB0[i].w - rA0[i].w, rA0[i].w) + pa[3] + pb[3]);
                qa[i][4] = silu(fmaf(f, rB1[i].x - rA1[i].x, rA1[i].x) + pa[4] + pb[4]);
                qa[i][5] = silu(fmaf(f, rB1[i].y - rA1[i].y, rA1[i].y) + pa[5] + pb[5]);
                qa[i][6] = silu(fmaf(f, rB1[i].z - rA1[i].z, rA1[i].z) + pa[6] + pb[6]);
                qa[i][7] = silu(fmaf(f, rB1[i].w - rA1[i].w, rA1[i].w) + pa[7] + pb[7]);
            }
        } else {
            #pragma unroll
            for (int i = 0; i < 2; ++i)
                #pragma unroll
                for (int c = 0; c < 8; ++c) qa[i][c] = 0.f;
        }

        __syncthreads();   // bA: previous FMA done -> Zs + W2s free for overwrite

        #pragma unroll
        for (int jj = 0; jj < 8; ++jj) {
            float2 z2;
            z2.x = qa[0][jj]; z2.y = qa[1][jj];
            *(float2*)&Zs[(8 * grp + jj) * 70 + 2 * lane] = z2;
        }
        {
            int wrow = tid >> 2;
            int wc0 = (2 * tid) & 7;
            *(float4*)&W2s[wrow * 36 + 4 * wc0] = rw0;
            *(float4*)&W2s[wrow * 36 + 4 * (wc0 + 1)] = rw1;
        }

        __syncthreads();   // bB: Zs + W2s published

        if (ch < 10) PREFETCH(ch + 1);   // issued BEFORE FMA -> in flight during it

        #pragma unroll 8
        for (int kk = 0; kk < 64; ++kk) {
            float2 z2 = *(const float2*)&Zs[kk * 70 + 2 * lane];
            float4 w4 = *(const float4*)&W2s[kk * 36 + 4 * grp];
            accm[0] = f4fma(z2.x, w4, accm[0]);
            accm[1] = f4fma(z2.y, w4, accm[1]);
        }
    }
#undef PREFETCH

    // ---- epilogue: m2 = silu(accm + b2), LN, store (CSR) / scatter (fallback) ----
    __syncthreads();
    float* m2s = Zs;
    {
        float4 bb2 = *(const float4*)&cpar[4 * grp];
        #pragma unroll
        for (int i = 0; i < 2; ++i) {
            int e = 2 * lane + i;
            float4 o;
            o.x = silu(accm[i].x + bb2.x);
            o.y = silu(accm[i].y + bb2.y);
            o.z = silu(accm[i].z + bb2.z);
            o.w = silu(accm[i].w + bb2.w);
            *(float4*)&m2s[e * 36 + 4 * grp] = o;
        }
    }
    __syncthreads();
    {
        int e = tid >> 2, q = tid & 3;
        float4 v0 = *(const float4*)&m2s[e * 36 + 8 * q];
        float4 v1 = *(const float4*)&m2s[e * 36 + 8 * q + 4];
        float s  = v0.x + v0.y + v0.z + v0.w + v1.x + v1.y + v1.z + v1.w;
        float ss = v0.x*v0.x + v0.y*v0.y + v0.z*v0.z + v0.w*v0.w
                 + v1.x*v1.x + v1.y*v1.y + v1.z*v1.z + v1.w*v1.w;
        s  += __shfl_xor(s, 1, 64);  ss += __shfl_xor(ss, 1, 64);
        s  += __shfl_xor(s, 2, 64);  ss += __shfl_xor(ss, 2, 64);
        float mean = s * 0.03125f;
        float var = ss * 0.03125f - mean * mean;
        float rstd = 1.0f / sqrtf(var + EPS);
        const float* gg = cpar + 32 + 8 * q;
        const float* bbv = cpar + 64 + 8 * q;
        float vv[8] = {v0.x, v0.y, v0.z, v0.w, v1.x, v1.y, v1.z, v1.w};
        float o[8];
        #pragma unroll
        for (int c = 0; c < 8; ++c) o[c] = (vv[c] - mean) * rstd * gg[c] + bbv[c];
        if (csr) {
            float* Mp = Mout + (size_t)(eb + e) * 32 + 8 * q;
            *(float4*)Mp       = make_float4(o[0], o[1], o[2], o[3]);
            *(float4*)(Mp + 4) = make_float4(o[4], o[5], o[6], o[7]);
        } else {
            int d = dsi[e];
            float* Sp = S + (size_t)d * 32 + 8 * q;
            #pragma unroll
            for (int c = 0; c < 8; ++c) atomicAdd(&Sp[c], o[c]);
        }
    }
}

// ---------------- node prep: H0[:,0:128] = LN(feats) ----------------
__global__ __launch_bounds__(128) void k_prep(const float* __restrict__ featsk,
                                              const float* __restrict__ nn1g,
                                              const float* __restrict__ nn1b,
                                              float* __restrict__ H0) {
    int n = blockIdx.x, tid = threadIdx.x;
    __shared__ float red[4];
    float x = featsk[(size_t)n * 768 + tid];
    float s = wave_sum64(x), ss = wave_sum64(x * x);
    if ((tid & 63) == 0) { red[(tid >> 6) * 2] = s; red[(tid >> 6) * 2 + 1] = ss; }
    __syncthreads();
    float S1 = red[0] + red[2], S2 = red[1] + red[3];
    float mean = S1 * (1.0f / 128.0f);
    float var = S2 * (1.0f / 128.0f) - mean * mean;
    float rstd = 1.0f / sqrtf(var + EPS);
    H0[(size_t)n * 160 + tid] = (x - mean) * rstd * nn1g[tid] + nn1b[tid];
}

// ---------------- graph pooling (batch sorted -> run-length accum) ----------------
__global__ __launch_bounds__(256) void k_pool(const float* __restrict__ F,
                                              const int* __restrict__ batch,
                                              float* __restrict__ G,
                                              float* __restrict__ cntg) {
    __shared__ int bL[32];
    int b0 = blockIdx.x * 32;
    int tid = threadIdx.x;
    int nmax = min(32, N_NODES - b0);
    if (nmax <= 0) return;
    if (tid < nmax) bL[tid] = batch[b0 + tid];
    __syncthreads();
    float accv = 0.f;
    int cur = -1;
    for (int i = 0; i < nmax; ++i) {
        int g = bL[i];
        if (g != cur) {
            if (cur >= 0) atomicAdd(&G[(size_t)cur * 256 + tid], accv);
            cur = g; accv = 0.f;
        }
        accv += F[(size_t)(b0 + i) * 256 + tid];
    }
    if (cur >= 0) atomicAdd(&G[(size_t)cur * 256 + tid], accv);
    if (tid == 0)
        for (int i = 0; i < nmax; ++i) atomicAdd(&cntg[bL[i]], 1.0f);
}

// ---------------- per-graph MLP head ----------------
__global__ __launch_bounds__(256) void k_graph(const float* __restrict__ G,
                                               const float* __restrict__ cntg,
                                               const float* __restrict__ g1W,
                                               const float* __restrict__ g1b,
                                               const float* __restrict__ g2W,
                                               const float* __restrict__ g2b,
                                               const float* __restrict__ g3W,
                                               const float* __restrict__ g3b,
                                               float* __restrict__ out) {
    __shared__ float X[256], Y[256], red[4];
    int g = blockIdx.x, tid = threadIdx.x;
    float inv = 1.0f / fmaxf(cntg[g], 1.0f);
    X[tid] = G[(size_t)g * 256 + tid] * inv;
    __syncthreads();
    float a = g1b[tid];
    for (int j = 0; j < 256; ++j) a = fmaf(X[j], g1W[(size_t)j * 256 + tid], a);
    Y[tid] = silu(a);
    __syncthreads();
    a = g2b[tid];
    for (int j = 0; j < 256; ++j) a = fmaf(Y[j], g2W[(size_t)j * 256 + tid], a);
    float z = silu(a);
    float p = z * g3W[tid];
    p = wave_sum64(p);
    if ((tid & 63) == 0) red[tid >> 6] = p;
    __syncthreads();
    if (tid == 0) out[g] = red[0] + red[1] + red[2] + red[3] + g3b[0];
}

extern "C" void kernel_launch(void* const* d_in, const int* in_sizes, int n_in,
                              void* d_out, int out_size, void* d_ws, size_t ws_size,
                              hipStream_t stream) {
    const int*   atomids = (const int*)d_in[0];
    const float* coords  = (const float*)d_in[1];
    const int*   eidx    = (const int*)d_in[2];
    const int*   batch   = (const int*)d_in[3];
    const float* emb_w   = (const float*)d_in[4];
    const float* eW1     = (const float*)d_in[5];
    const float* eb1     = (const float*)d_in[6];
    const float* eW2     = (const float*)d_in[7];
    const float* eb2     = (const float*)d_in[8];
    const float* en_g    = (const float*)d_in[9];
    const float* en_b    = (const float*)d_in[10];
    const float* nn1_g   = (const float*)d_in[11];
    const float* nn1_b   = (const float*)d_in[12];
    const float* nW1     = (const float*)d_in[13];
    const float* nb1     = (const float*)d_in[14];
    const float* nW2     = (const float*)d_in[15];
    const float* nb2     = (const float*)d_in[16];
    const float* nn2_g   = (const float*)d_in[17];
    const float* nn2_b   = (const float*)d_in[18];
    const float* f1W     = (const float*)d_in[19];
    const float* f1b     = (const float*)d_in[20];
    const float* f2W     = (const float*)d_in[21];
    const float* f2b     = (const float*)d_in[22];
    const float* f3W     = (const float*)d_in[23];
    const float* f3b     = (const float*)d_in[24];
    const float* g1W     = (const float*)d_in[25];
    const float* g1b     = (const float*)d_in[26];
    const float* g2W     = (const float*)d_in[27];
    const float* g2b     = (const float*)d_in[28];
    const float* g3W     = (const float*)d_in[29];
    const float* g3b     = (const float*)d_in[30];
    float* out = (float*)d_out;

    float* ws = (float*)d_ws;
    float* feats_all = ws;                        // [10000][768]
    float* d2g   = ws + 7680000;                  // [160000]
    float* Pab   = ws + 7840000;                  // region: bf16 [10000][1296] = 25.9MB of 51.8MB
    float* S     = ws + 20800000;                 // [10000][32] (fallback path only)
    float* cnt   = ws + 21120000;                 // [10000]
    float* W1ab5 = ws + 21130000;                 // [5][128][1296] fp32 (fallback only; overlaid by MFMA3 packs)
    float* W1cp5 = ws + 21959440;                 // [5][65][768]
    float* b1p5  = ws + 22209040;                 // [5][768]
    float* W2p5  = ws + 22212880;                 // [5][768][32]
    float* feG   = ws + 22335760;                 // [12289][68]
    float* T     = ws + 23171412;                 // [12289][648]
    float* G     = ws + 31134684;                 // [64][256]
    float* cntg  = ws + 31151068;                 // [64]
    int*   histI = (int*)(ws + 31151132);         // [12304]
    int*   offs  = (int*)(ws + 31163436);         // [12304] (persists as dst-CSR offsD)
    int*   cursor= (int*)(ws + 31175740);         // [12304]
    int*   ssiP  = (int*)(ws + 31188044);         // [160000]
    int*   dsiP  = (int*)(ws + 31348044);         // [160000]
    int*   i0P   = (int*)(ws + 31508044);         // [160000]
    float* frP   = ws + 31668044;                 // [160000]
    int*   eixD  = (int*)(ws + 31828044);         // [160000]
    float* Mbuf  = ws + 31988044;                 // [160000][32] (end 37,108,044)
    unsigned short* Bp5U  = (unsigned short*)(ws + 37108044);  // [5][16][1296][8] bf16 (414,720 fl)
    unsigned short* ApackU= (unsigned short*)(ws + 37522764);  // [16][10000][8] bf16 (640,000 fl)
    unsigned short* nW1p5 = (unsigned short*)(ws + 38162764);  // 5 x [20][256][8] bf16 (102,400 fl)
    unsigned short* f1Wp  = (unsigned short*)(ws + 38265164);  // [96][256][8] bf16 (98,304 fl)
    unsigned short* f2Wp  = (unsigned short*)(ws + 38363468);  // [32][256][8] bf16 (32,768 fl)
    unsigned short* f3Wp  = (unsigned short*)(ws + 38396236);  // [32][256][8] bf16 (32,768 fl; end 38,429,004)
    const int useCSR   = (ws_size >= (size_t)(31988044 + 5120000) * sizeof(float)) ? 1 : 0;
    const int useMFMA  = (ws_size >= (size_t)38162764 * sizeof(float)) ? 1 : 0;
    const int useMFMA2 = (ws_size >= (size_t)38429004 * sizeof(float)) ? 1 : 0;
    // k_tab MFMA packs overlay the dead fp32 W1ab5 region (only used when !useMFMA):
    //   feGp: [12][12289][8] bf16 = 589,872 fl at 21,130,000
    //   Bt5 : [5][12][648][8] bf16 = 155,520 fl at 21,719,872 (end 21,875,392 < 21,959,440)
    unsigned short* feGp = (unsigned short*)(ws + 21130000);
    unsigned short* Bt5  = (unsigned short*)(ws + 21719872);
    const int useMFMA3 = (useMFMA && useMFMA2) ? 1 : 0;
    unsigned short* PabU = (unsigned short*)Pab;  // bf16 view
    // node-phase temporaries overlay Pab region (dead between phases)
    float* H0 = Pab;                              // [10000][160]
    float* H1 = Pab + 1600000;                    // [10000][256]
    float* F1 = Pab;                              // [10000][256]
    float* F2 = Pab + 2560000;                    // [10000][256]
    float* F3 = Pab + 5120000;                    // [10000][256]
    // Ap2 scratch for N=256 MFMA A-packs: overlays free top of Pab region
    unsigned short* Ap2 = (unsigned short*)(Pab + 7680000);   // up to [96][10000][8] bf16

    k_embed<<<N_NODES, 128, 0, stream>>>(atomids, emb_w, feats_all);
    k_d2<<<(N_EDGES + 255) / 256, 256, 0, stream>>>(coords, eidx, d2g);
    hipMemsetAsync(cnt, 0, 10000 * sizeof(float), stream);
    k_cnt<<<(N_EDGES + 255) / 256, 256, 0, stream>>>(eidx, cnt);
    hipMemsetAsync(histI, 0, 12304 * sizeof(int), stream);
    k_hist<<<(N_EDGES + 255) / 256, 256, 0, stream>>>(d2g, histI);
    k_scan<<<1, 256, 0, stream>>>(histI, offs);
    k_copyi<<<(TROWS + 255) / 256, 256, 0, stream>>>(offs, cursor);
    k_scatter<<<(N_EDGES + 255) / 256, 256, 0, stream>>>(eidx, d2g, cursor,
                                                         ssiP, dsiP, i0P, frP);
    if (useCSR) {
        hipMemsetAsync(histI, 0, 12304 * sizeof(int), stream);
        k_hist_d<<<(N_EDGES + 255) / 256, 256, 0, stream>>>(dsiP, histI);
        k_scan<<<1, 256, 0, stream>>>(histI, offs);
        k_copyi<<<(TROWS + 255) / 256, 256, 0, stream>>>(offs, cursor);
        k_scatter_d<<<(N_EDGES + 255) / 256, 256, 0, stream>>>(dsiP, cursor, eixD);
    }
    k_feg<<<(TROWS + 255) / 256, 256, 0, stream>>>(feG);
    if (useMFMA)
        k_bpack5<<<dim3(648, 5), 256, 0, stream>>>(eW1, Bp5U);
    else
        k_w1ab5<<<dim3(648, 5), 256, 0, stream>>>(eW1, W1ab5);
    k_wpre5<<<dim3(294, 5), 256, 0, stream>>>(eW1, eb1, eW2, W1cp5, b1p5, W2p5);
    if (useMFMA2) {
        for (int k = 0; k < NK; ++k)
            k_bpack2<<<160, 256, 0, stream>>>(nW1 + (size_t)k * 160 * 256, 160,
                                              nW1p5 + (size_t)k * 40960);
        k_bpack2<<<768, 256, 0, stream>>>(f1W, 768, f1Wp);
        k_bpack2<<<256, 256, 0, stream>>>(f2W, 256, f2Wp);
        k_bpack2<<<256, 256, 0, stream>>>(f3W, 256, f3Wp);
    }
    if (useMFMA3) {
        k_apack3<<<(TROWS * 12 + 255) / 256, 256, 0, stream>>>(feG, feGp);
        k_bpack3<<<dim3(243, 5), 256, 0, stream>>>(W1cp5, Bt5);
    }

    for (int k = 0; k < NK; ++k) {
        const float* eb2k = eb2 + (size_t)k * 32;
        const float* engk = en_g + (size_t)k * 32;
        const float* enbk = en_b + (size_t)k * 32;
        const float* nn1gk = nn1_g + (size_t)k * 128;
        const float* nn1bk = nn1_b + (size_t)k * 128;
        const float* nW1k = nW1 + (size_t)k * 160 * 256;
        const float* nb1k = nb1 + (size_t)k * 256;
        const float* nW2k = nW2 + (size_t)k * 256 * 128;
        const float* nb2k = nb2 + (size_t)k * 128;
        const float* nn2gk = nn2_g + (size_t)k * 128;
        const float* nn2bk = nn2_b + (size_t)k * 128;

        if (useMFMA3)
            k_gemm_mfma3<<<dim3(193, 11), 256, 0, stream>>>(feGp, Bt5 + (size_t)k * 62208,
                                                            b1p5 + (size_t)k * 768, T);
        else
            k_tab<<<(TROWS + 31) / 32, 256, 0, stream>>>(feG,
                                                         W1cp5 + (size_t)k * 65 * 768,
                                                         b1p5 + (size_t)k * 768, T);
        // MUST write all 1296 Pab columns (k_edge reads zero-padding up to col 1295)
        if (useMFMA) {
            k_apack<<<(N_NODES * 16 + 255) / 256, 256, 0, stream>>>(feats_all + k * 128, ApackU);
            k_gemm_mfma<<<dim3(157, 21), 256, 0, stream>>>(ApackU, Bp5U + (size_t)k * 165888,
                                                           PabU, N_NODES);
        } else {
            k_gemm<<<dim3(79, 11), 256, 0, stream>>>(feats_all + k * 128, 768,
                                                     W1ab5 + (size_t)k * 128 * 1296, 1296,
                                                     nullptr, Pab, 1296, N_NODES, 1296, 128, 0, 0);
        }
        if (!useCSR)
            hipMemsetAsync(S, 0, (size_t)320000 * sizeof(float), stream);
        k_edge<<<N_EDGES / EPB, 256, 0, stream>>>(ssiP, dsiP, i0P, frP, T, PabU,
                                                  W2p5 + (size_t)k * 768 * 32,
                                                  eb2k, engk, enbk, S, Mbuf, useCSR);
        if (useCSR)
            k_agg_ln<<<(N_NODES + 3) / 4, 128, 0, stream>>>(Mbuf, offs, eixD, cnt,
                                                            engk, enbk, H0);
        else
            k_s_ln<<<(N_NODES + 3) / 4, 128, 0, stream>>>(S, cnt, engk, enbk, H0);
        k_prep<<<N_NODES, 128, 0, stream>>>(feats_all + k * 128, nn1gk, nn1bk, H0);
        if (useMFMA2) {
            k_apack2<<<(N_NODES * 20 + 255) / 256, 256, 0, stream>>>(H0, 160, 20, 0, Ap2);
            k_gemm_mfma2<<<dim3(157, 4), 256, 0, stream>>>(Ap2, nW1p5 + (size_t)k * 40960,
                                                           nb1k, H1, N_NODES, 5);
        } else {
            k_gemm64<<<dim3(157, 2), 256, 0, stream>>>(H0, 160, nW1k, 256, nb1k, H1, 256,
                                                       N_NODES, 256, 160, 0, 1);
        }
        k_gemm_ln<<<dim3(157), 256, 0, stream>>>(H1, nW2k, nb2k, feats_all, k,
                                                 nn2gk, nn2bk, N_NODES, 256);
    }

    // final node MLP (F1/F2/F3 overlay Pab)
    if (useMFMA2) {
        k_apack2<<<(N_NODES * 96 + 255) / 256, 256, 0, stream>>>(feats_all, 768, 96, 1, Ap2);
        k_gemm_mfma2<<<dim3(157, 4), 256, 0, stream>>>(Ap2, f1Wp, f1b, F1, N_NODES, 24);
        k_apack2<<<(N_NODES * 32 + 255) / 256, 256, 0, stream>>>(F1, 256, 32, 0, Ap2);
        k_gemm_mfma2<<<dim3(157, 4), 256, 0, stream>>>(Ap2, f2Wp, f2b, F2, N_NODES, 8);
        k_apack2<<<(N_NODES * 32 + 255) / 256, 256, 0, stream>>>(F2, 256, 32, 0, Ap2);
        k_gemm_mfma2<<<dim3(157, 4), 256, 0, stream>>>(Ap2, f3Wp, f3b, F3, N_NODES, 8);
    } else {
        k_gemm64<<<dim3(157, 2), 256, 0, stream>>>(feats_all, 768, f1W, 256, f1b, F1, 256,
                                                   N_NODES, 256, 768, 1, 1);
        k_gemm64<<<dim3(157, 2), 256, 0, stream>>>(F1, 256, f2W, 256, f2b, F2, 256,
                                                   N_NODES, 256, 256, 0, 1);
        k_gemm64<<<dim3(157, 2), 256, 0, stream>>>(F2, 256, f3W, 256, f3b, F3, 256,
                                                   N_NODES, 256, 256, 0, 1);
    }

    hipMemsetAsync(G, 0, (size_t)(16384 + 64) * sizeof(float), stream);
    k_pool<<<313, 256, 0, stream>>>(F3, batch, G, cntg);
    k_graph<<<N_GRAPHS, 256, 0, stream>>>(G, cntg, g1W, g1b, g2W, g2b, g3W, g3b, out);
}

// Round 19
// 1716.438 us; speedup vs baseline: 1.5984x; 1.2349x over previous
//
#include <hip/hip_runtime.h>
#include <hip/hip_bf16.h>

#define N_NODES 10000
#define N_EDGES 160000
#define N_GRAPHS 64
#define NK 5
#define EPS 1e-5f
#define EPB 64           // edges per block (256 threads)
#define JP 648           // packed width for Pab halves
#define PSTRIDE 1296     // Pab row stride (bf16 elems): [Pa 648 | Pb 648]
#define TCOLS 648        // table row width (642 -> 648)
#define TROWS 12289      // d2 grid [0,96], h=1/128
#define IMAX 12287

// MFMA fragment types: gfx950 mfma_f32_16x16x32_bf16 takes v8bf16 operands.
typedef __attribute__((ext_vector_type(8))) __bf16 bf16v8;
typedef __attribute__((ext_vector_type(4))) float f32x4;

__device__ __forceinline__ float silu(float x) { return x / (1.0f + __expf(-x)); }
__device__ __forceinline__ float4 f4fma(float s, float4 w, float4 a) {
    a.x = fmaf(s, w.x, a.x); a.y = fmaf(s, w.y, a.y);
    a.z = fmaf(s, w.z, a.z); a.w = fmaf(s, w.w, a.w);
    return a;
}
__device__ __forceinline__ float wave_sum64(float v) {
    #pragma unroll
    for (int off = 32; off > 0; off >>= 1) v += __shfl_xor(v, off, 64);
    return v;
}
// fp32 -> bf16 (round to nearest even), returned as raw bits
__device__ __forceinline__ unsigned short f2bf(float f) {
    unsigned int u = __float_as_uint(f);
    unsigned int r = u + 0x7FFFu + ((u >> 16) & 1u);
    return (unsigned short)(r >> 16);
}

// ---------------- embedding ----------------
__global__ __launch_bounds__(128) void k_embed(const int* __restrict__ atomids,
                                               const float* __restrict__ emb_w,
                                               float* __restrict__ feats_all) {
    int n = blockIdx.x, tid = threadIdx.x;
    feats_all[(size_t)n * 768 + tid] = emb_w[(size_t)atomids[n] * 128 + tid];
}

// ---------------- per-edge squared distance ----------------
__global__ __launch_bounds__(256) void k_d2(const float* __restrict__ coords,
                                            const int* __restrict__ eidx,
                                            float* __restrict__ d2g) {
    int e = blockIdx.x * 256 + threadIdx.x;
    if (e >= N_EDGES) return;
    int s = eidx[e], d = eidx[N_EDGES + e];
    float dx = coords[s * 3 + 0] - coords[d * 3 + 0];
    float dy = coords[s * 3 + 1] - coords[d * 3 + 1];
    float dz = coords[s * 3 + 2] - coords[d * 3 + 2];
    d2g[e] = dx * dx + dy * dy + dz * dz;
}

// ---------------- in-degree (layer-invariant) ----------------
__global__ __launch_bounds__(256) void k_cnt(const int* __restrict__ eidx,
                                             float* __restrict__ cnt) {
    int e = blockIdx.x * 256 + threadIdx.x;
    if (e >= N_EDGES) return;
    atomicAdd(&cnt[eidx[N_EDGES + e]], 1.0f);
}

// ---------------- counting sort of edges by i0 (T-row index) ----------------
__global__ __launch_bounds__(256) void k_hist(const float* __restrict__ d2g,
                                              int* __restrict__ hist) {
    int e = blockIdx.x * 256 + threadIdx.x;
    if (e >= N_EDGES) return;
    int i0 = (int)(d2g[e] * 128.0f);
    if (i0 > IMAX) i0 = IMAX;
    atomicAdd(&hist[i0], 1);
}

__global__ __launch_bounds__(256) void k_scan(const int* __restrict__ hist,
                                              int* __restrict__ offs) {
    __shared__ int buf[256];
    __shared__ int carryS;
    int tid = threadIdx.x;
    if (tid == 0) carryS = 0;
    __syncthreads();
    for (int base = 0; base < TROWS; base += 256) {
        int v = (base + tid < TROWS) ? hist[base + tid] : 0;
        buf[tid] = v;
        __syncthreads();
        for (int off = 1; off < 256; off <<= 1) {
            int t = (tid >= off) ? buf[tid - off] : 0;
            __syncthreads();
            buf[tid] += t;
            __syncthreads();
        }
        if (base + tid < TROWS) offs[base + tid] = carryS + buf[tid] - v;  // exclusive
        __syncthreads();
        if (tid == 0) carryS += buf[255];
        __syncthreads();
    }
}

__global__ __launch_bounds__(256) void k_copyi(const int* __restrict__ a,
                                               int* __restrict__ b) {
    int i = blockIdx.x * 256 + threadIdx.x;
    if (i < TROWS) b[i] = a[i];
}

__global__ __launch_bounds__(256) void k_scatter(const int* __restrict__ eidx,
                                                 const float* __restrict__ d2g,
                                                 int* __restrict__ cursor,
                                                 int* __restrict__ ssiP,
                                                 int* __restrict__ dsiP,
                                                 int* __restrict__ i0P,
                                                 float* __restrict__ frP) {
    int e = blockIdx.x * 256 + threadIdx.x;
    if (e >= N_EDGES) return;
    float t = d2g[e] * 128.0f;
    int i0 = (int)t;
    if (i0 > IMAX) i0 = IMAX;
    float fr = t - (float)i0;
    int pos = atomicAdd(&cursor[i0], 1);
    ssiP[pos] = eidx[e];
    dsiP[pos] = eidx[N_EDGES + e];
    i0P[pos] = i0;
    frP[pos] = fr;
}

// ---------------- dst-CSR over sorted positions (for atomic-free S aggregation) ----------------
__global__ __launch_bounds__(256) void k_hist_d(const int* __restrict__ dsiP,
                                                int* __restrict__ hist) {
    int p = blockIdx.x * 256 + threadIdx.x;
    if (p >= N_EDGES) return;
    atomicAdd(&hist[dsiP[p]], 1);
}

__global__ __launch_bounds__(256) void k_scatter_d(const int* __restrict__ dsiP,
                                                   int* __restrict__ cursorD,
                                                   int* __restrict__ eixD) {
    int p = blockIdx.x * 256 + threadIdx.x;
    if (p >= N_EDGES) return;
    int pos = atomicAdd(&cursorD[dsiP[p]], 1);
    eixD[pos] = p;
}

// ---------------- CSR aggregation fused with mean + LN: writes H0[:,128:160] ----------------
__global__ __launch_bounds__(128) void k_agg_ln(const float* __restrict__ M,
                                                const int* __restrict__ offsD,
                                                const int* __restrict__ eixD,
                                                const float* __restrict__ cnt,
                                                const float* __restrict__ eng,
                                                const float* __restrict__ enb,
                                                float* __restrict__ H0) {
    int n = blockIdx.x * 4 + (threadIdx.x >> 5);
    int col = threadIdx.x & 31;
    if (n >= N_NODES) return;
    float acc = 0.f;
    int p0 = offsD[n], p1 = offsD[n + 1];
    for (int p = p0; p < p1; ++p)
        acc += M[(size_t)eixD[p] * 32 + col];
    float inv = 1.0f / fmaxf(cnt[n], 1.0f);
    float v = acc * inv;
    float s = v, q = v * v;
    #pragma unroll
    for (int off = 16; off > 0; off >>= 1) {
        s += __shfl_xor(s, off, 64);
        q += __shfl_xor(q, off, 64);
    }
    float m2 = s * (1.0f / 32.0f);
    float va = q * (1.0f / 32.0f) - m2 * m2;
    float rs = 1.0f / sqrtf(va + EPS);
    H0[(size_t)n * 160 + 128 + col] = (v - m2) * rs * eng[col] + enb[col];
}

// ---------------- fallback (no-CSR): S -> mean -> LN -> H0[:,128:160] ----------------
__global__ __launch_bounds__(128) void k_s_ln(const float* __restrict__ S,
                                              const float* __restrict__ cnt,
                                              const float* __restrict__ eng,
                                              const float* __restrict__ enb,
                                              float* __restrict__ H0) {
    int n = blockIdx.x * 4 + (threadIdx.x >> 5);
    int col = threadIdx.x & 31;
    if (n >= N_NODES) return;
    float inv = 1.0f / fmaxf(cnt[n], 1.0f);
    float v = S[(size_t)n * 32 + col] * inv;
    float s = v, q = v * v;
    #pragma unroll
    for (int off = 16; off > 0; off >>= 1) {
        s += __shfl_xor(s, off, 64);
        q += __shfl_xor(q, off, 64);
    }
    float m2 = s * (1.0f / 32.0f);
    float va = q * (1.0f / 32.0f) - m2 * m2;
    float rs = 1.0f / sqrtf(va + EPS);
    H0[(size_t)n * 160 + 128 + col] = (v - m2) * rs * eng[col] + enb[col];
}

// ---------------- fourier features on the d2 GRID (once) ----------------
__global__ __launch_bounds__(256) void k_feg(float* __restrict__ feG) {  // [TROWS][68]
    int g = blockIdx.x * 256 + threadIdx.x;
    if (g >= TROWS) return;
    float d2v = (float)g * 0.0078125f;   // g / 128, exact
    float* o = feG + (size_t)g * 68;
    float sc = 1.0f;
    #pragma unroll
    for (int i = 0; i < 32; ++i) {
        float x = d2v * sc;
        o[i] = sinf(x);
        o[32 + i] = cosf(x);
        sc *= 0.5f;
    }
    o[64] = d2v;
}

// ---------------- per-layer q-table (fp32 fallback): T[g][j] = fe(g/128) @ W1c + b1 ----------------
__global__ __launch_bounds__(256) void k_tab(const float* __restrict__ feG,   // [TROWS][68]
                                             const float* __restrict__ W1cp,  // [65][768]
                                             const float* __restrict__ b1p,   // [768]
                                             float* __restrict__ T) {         // [TROWS][648]
    __shared__ float feGs[32 * 68];
    __shared__ float W1s[65 * 36];
    const int tid = threadIdx.x;
    const int g0 = blockIdx.x * 32;
    for (int idx = tid; idx < 32 * 17; idx += 256) {
        int r = idx / 17, c = idx - r * 17;
        int gi = g0 + r;
        float4 v = make_float4(0, 0, 0, 0);
        if (gi < TROWS) v = *(const float4*)(feG + (size_t)gi * 68 + 4 * c);
        *(float4*)&feGs[r * 68 + 4 * c] = v;
    }
    const int gt = tid >> 3, ct = tid & 7;
    for (int jc = 0; jc < TCOLS; jc += 32) {
        __syncthreads();
        for (int idx = tid; idx < 65 * 32; idx += 256) {
            int k = idx >> 5, j = idx & 31;
            W1s[k * 36 + j] = W1cp[(size_t)k * 768 + jc + j];
        }
        __syncthreads();
        int gj = jc + 4 * ct;
        float4 q = *(const float4*)(b1p + gj);
        #pragma unroll 5
        for (int k = 0; k < 65; ++k) {
            float f = feGs[gt * 68 + k];
            float4 w = *(const float4*)&W1s[k * 36 + 4 * ct];
            q = f4fma(f, w, q);
        }
        int g = g0 + gt;
        if (g < TROWS && gj < TCOLS)
            *(float4*)(T + (size_t)g * TCOLS + gj) = q;
    }
}

// ---------------- W1ab prestage (fp32, fallback path only) ----------------
__global__ __launch_bounds__(256) void k_w1ab5(const float* __restrict__ eW1,
                                               float* __restrict__ W1ab5) {
    int k = blockIdx.y;
    const float* W1 = eW1 + (size_t)k * 321 * 642;
    float* W1ab = W1ab5 + (size_t)k * 128 * 1296;
    int idx = blockIdx.x * 256 + threadIdx.x;
    if (idx >= 128 * 1296) return;
    int r = idx / 1296;
    int j = idx - r * 1296;
    float v = 0.f;
    if (j < 642) v = W1[(size_t)r * 642 + j];
    else if (j >= 648 && j < 1290) v = W1[(size_t)(128 + r) * 642 + (j - 648)];
    W1ab[idx] = v;
}

// ---------------- MFMA B-fragment prestage: Bpack[5][16][1296][8] bf16 ----------------
__global__ __launch_bounds__(256) void k_bpack5(const float* __restrict__ eW1,
                                                unsigned short* __restrict__ Bp5) {
    int idx = blockIdx.x * 256 + threadIdx.x;
    if (idx >= 16 * 1296 * 8) return;
    int k = blockIdx.y;
    int kg = idx / (1296 * 8);
    int rem = idx - kg * (1296 * 8);
    int c = rem >> 3, jj = rem & 7;
    int r = kg * 8 + jj;             // K index 0..127
    const float* W1 = eW1 + (size_t)k * 321 * 642;
    float v = 0.f;
    if (c < 642) v = W1[(size_t)r * 642 + c];
    else if (c >= 648 && c < 1290) v = W1[(size_t)(128 + r) * 642 + (c - 648)];
    Bp5[(size_t)k * 165888 + idx] = f2bf(v);
}

// ---------------- generic MFMA B-pack for N=256 weights: dst[kg][256][8] ----------------
__global__ __launch_bounds__(256) void k_bpack2(const float* __restrict__ W,   // [K][256]
                                                int K,
                                                unsigned short* __restrict__ dst) {
    int idx = blockIdx.x * 256 + threadIdx.x;
    if (idx >= K * 256) return;
    int kg = idx / (256 * 8);
    int rem = idx - kg * (256 * 8);
    int c = rem >> 3, jj = rem & 7;
    int r = kg * 8 + jj;
    dst[idx] = f2bf(W[(size_t)r * 256 + c]);
}

// ---------------- k_tab MFMA B-pack: Bt[5][12][648][8] from W1cp5 (rows>=65 zero) ----------------
__global__ __launch_bounds__(256) void k_bpack3(const float* __restrict__ W1cp5,
                                                unsigned short* __restrict__ Bt5) {
    int idx = blockIdx.x * 256 + threadIdx.x;
    if (idx >= 12 * 648 * 8) return;
    int k = blockIdx.y;
    int kg = idx / (648 * 8);
    int rem = idx - kg * (648 * 8);
    int c = rem >> 3, jj = rem & 7;
    int r = kg * 8 + jj;
    float v = (r < 65) ? W1cp5[(size_t)k * 65 * 768 + (size_t)r * 768 + c] : 0.f;
    Bt5[(size_t)k * 62208 + idx] = f2bf(v);
}

// ---------------- k_tab MFMA A-pack: Ag[12][TROWS][8] from feG (k>=68 zero), once ----------------
__global__ __launch_bounds__(256) void k_apack3(const float* __restrict__ feG,
                                                unsigned short* __restrict__ Ag) {
    int t = blockIdx.x * 256 + threadIdx.x;
    if (t >= TROWS * 12) return;
    int kg = t / TROWS, m = t - kg * TROWS;
    const float* s = feG + (size_t)m * 68;
    unsigned short* d = Ag + ((size_t)kg * TROWS + m) * 8;
    #pragma unroll
    for (int j = 0; j < 8; ++j) {
        int kk = kg * 8 + j;
        d[j] = (kk < 68) ? f2bf(s[kk]) : (unsigned short)0;
    }
}

// ---------------- k_edge MFMA W2-pack: W2k[5][88][32][8] bf16 from W2p5 [768][32] ----------------
// kg covers K 0..703 (648 padded to 704); rows >= 642 are already zero in W2p5.
__global__ __launch_bounds__(256) void k_wpack(const float* __restrict__ W2p5,
                                               unsigned short* __restrict__ W2k5) {
    int idx = blockIdx.x * 256 + threadIdx.x;
    if (idx >= 88 * 32 * 8) return;
    int k = blockIdx.y;
    int kg = idx >> 8;
    int rem = idx & 255;
    int c = rem >> 3, j = rem & 7;
    int row = kg * 8 + j;            // 0..703 < 768
    W2k5[(size_t)k * 22528 + idx] = f2bf(W2p5[(size_t)k * 768 * 32 + (size_t)row * 32 + c]);
}

// ---------------- generic MFMA A-pack: dst[kg][M][8] from fp32 [M][stride], optional silu ----------------
__global__ __launch_bounds__(256) void k_apack2(const float* __restrict__ src, int stride,
                                                int Kg, int doSilu,
                                                unsigned short* __restrict__ dst) {
    int t = blockIdx.x * 256 + threadIdx.x;
    if (t >= N_NODES * Kg) return;
    int kg = t / N_NODES, m = t - kg * N_NODES;
    const float* s = src + (size_t)m * stride + kg * 8;
    unsigned short* d = dst + ((size_t)kg * N_NODES + m) * 8;
    #pragma unroll
    for (int j = 0; j < 8; ++j) {
        float v = s[j];
        if (doSilu) v = silu(v);
        d[j] = f2bf(v);
    }
}

// ---------------- MFMA A-fragment staging (per layer): Apack[16][10000][8] bf16 ----------------
__global__ __launch_bounds__(256) void k_apack(const float* __restrict__ feats, // + k*128, stride 768
                                               unsigned short* __restrict__ Ap) {
    int t = blockIdx.x * 256 + threadIdx.x;   // t: m = t>>4, kg = t&15
    if (t >= N_NODES * 16) return;
    int m = t >> 4, kg = t & 15;
    const float* src = feats + (size_t)m * 768 + kg * 8;
    unsigned short* dst = Ap + ((size_t)kg * N_NODES + m) * 8;
    #pragma unroll
    for (int j = 0; j < 8; ++j) dst[j] = f2bf(src[j]);
}

// ---------------- Pab GEMM on matrix cores: bf16 in, fp32 MFMA accum, bf16 out ----------------
__global__ __launch_bounds__(256) void k_gemm_mfma(const unsigned short* __restrict__ Ap, // [16][M][8]
                                                   const unsigned short* __restrict__ Bp, // [16][1296][8]
                                                   unsigned short* __restrict__ C,        // [M][1296] bf16
                                                   int M) {
    const int tid = threadIdx.x;
    const int w = tid >> 6, l = tid & 63;
    const int m0 = blockIdx.x * 64 + (w >> 1) * 32;
    const int n0 = blockIdx.y * 64 + (w & 1) * 32;
    const int lr = l & 15, lg = l >> 4;

    f32x4 acc[2][2] = {};
    for (int kb = 0; kb < 4; ++kb) {
        const int kg = kb * 4 + lg;
        bf16v8 a[2], b[2];
        #pragma unroll
        for (int i = 0; i < 2; ++i) {
            int mrow = m0 + i * 16 + lr; if (mrow >= M) mrow = M - 1;
            a[i] = *(const bf16v8*)(Ap + ((size_t)kg * M + mrow) * 8);
            int ncol = n0 + i * 16 + lr; if (ncol > 1295) ncol = 1295;
            b[i] = *(const bf16v8*)(Bp + ((size_t)kg * 1296 + ncol) * 8);
        }
        #pragma unroll
        for (int mi = 0; mi < 2; ++mi)
            #pragma unroll
            for (int ni = 0; ni < 2; ++ni)
                acc[mi][ni] = __builtin_amdgcn_mfma_f32_16x16x32_bf16(a[mi], b[ni], acc[mi][ni], 0, 0, 0);
    }
    #pragma unroll
    for (int mi = 0; mi < 2; ++mi)
        #pragma unroll
        for (int ni = 0; ni < 2; ++ni)
            #pragma unroll
            for (int j = 0; j < 4; ++j) {
                int gm = m0 + mi * 16 + lg * 4 + j;
                int gn = n0 + ni * 16 + lr;
                if (gm < M && gn < 1296)
                    C[(size_t)gm * 1296 + gn] = f2bf(acc[mi][ni][j]);
            }
}

// ---------------- generic MFMA GEMM, N=256, fp32 out: C = silu(A@B + bias) ----------------
__global__ __launch_bounds__(256) void k_gemm_mfma2(const unsigned short* __restrict__ Ap, // [Kg][M][8]
                                                    const unsigned short* __restrict__ Bp, // [Kg][256][8]
                                                    const float* __restrict__ bias,        // [256]
                                                    float* __restrict__ C,                 // [M][256]
                                                    int M, int KB) {
    const int tid = threadIdx.x;
    const int w = tid >> 6, l = tid & 63;
    const int m0 = blockIdx.x * 64 + (w >> 1) * 32;
    const int n0 = blockIdx.y * 64 + (w & 1) * 32;
    const int lr = l & 15, lg = l >> 4;

    f32x4 acc[2][2] = {};
    for (int kb = 0; kb < KB; ++kb) {
        const int kg = kb * 4 + lg;
        bf16v8 a[2], b[2];
        #pragma unroll
        for (int i = 0; i < 2; ++i) {
            int mrow = m0 + i * 16 + lr; if (mrow >= M) mrow = M - 1;
            a[i] = *(const bf16v8*)(Ap + ((size_t)kg * M + mrow) * 8);
            int ncol = n0 + i * 16 + lr;   // always < 256
            b[i] = *(const bf16v8*)(Bp + ((size_t)kg * 256 + ncol) * 8);
        }
        #pragma unroll
        for (int mi = 0; mi < 2; ++mi)
            #pragma unroll
            for (int ni = 0; ni < 2; ++ni)
                acc[mi][ni] = __builtin_amdgcn_mfma_f32_16x16x32_bf16(a[mi], b[ni], acc[mi][ni], 0, 0, 0);
    }
    #pragma unroll
    for (int mi = 0; mi < 2; ++mi)
        #pragma unroll
        for (int ni = 0; ni < 2; ++ni)
            #pragma unroll
            for (int j = 0; j < 4; ++j) {
                int gm = m0 + mi * 16 + lg * 4 + j;
                int gn = n0 + ni * 16 + lr;
                if (gm < M)
                    C[(size_t)gm * 256 + gn] = silu(acc[mi][ni][j] + bias[gn]);
            }
}

// ---------------- k_tab MFMA GEMM: T[TROWS][648] = Ag @ Bt + b1 (fp32 out) ----------------
__global__ __launch_bounds__(256) void k_gemm_mfma3(const unsigned short* __restrict__ Ag, // [12][TROWS][8]
                                                    const unsigned short* __restrict__ Bt, // [12][648][8]
                                                    const float* __restrict__ bias,        // [768] (b1p)
                                                    float* __restrict__ T) {               // [TROWS][648]
    const int tid = threadIdx.x;
    const int w = tid >> 6, l = tid & 63;
    const int m0 = blockIdx.x * 64 + (w >> 1) * 32;
    const int n0 = blockIdx.y * 64 + (w & 1) * 32;
    const int lr = l & 15, lg = l >> 4;

    f32x4 acc[2][2] = {};
    for (int kb = 0; kb < 3; ++kb) {
        const int kg = kb * 4 + lg;
        bf16v8 a[2], b[2];
        #pragma unroll
        for (int i = 0; i < 2; ++i) {
            int mrow = m0 + i * 16 + lr; if (mrow >= TROWS) mrow = TROWS - 1;
            a[i] = *(const bf16v8*)(Ag + ((size_t)kg * TROWS + mrow) * 8);
            int ncol = n0 + i * 16 + lr; if (ncol > 647) ncol = 647;
            b[i] = *(const bf16v8*)(Bt + ((size_t)kg * 648 + ncol) * 8);
        }
        #pragma unroll
        for (int mi = 0; mi < 2; ++mi)
            #pragma unroll
            for (int ni = 0; ni < 2; ++ni)
                acc[mi][ni] = __builtin_amdgcn_mfma_f32_16x16x32_bf16(a[mi], b[ni], acc[mi][ni], 0, 0, 0);
    }
    #pragma unroll
    for (int mi = 0; mi < 2; ++mi)
        #pragma unroll
        for (int ni = 0; ni < 2; ++ni)
            #pragma unroll
            for (int j = 0; j < 4; ++j) {
                int gm = m0 + mi * 16 + lg * 4 + j;
                int gn = n0 + ni * 16 + lr;
                if (gm < TROWS && gn < TCOLS)
                    T[(size_t)gm * TCOLS + gn] = acc[mi][ni][j] + bias[gn];
            }
}

// ---------------- padded edge-weight prestage (all 5 layers) ----------------
__global__ __launch_bounds__(256) void k_wpre5(const float* __restrict__ eW1,
                                               const float* __restrict__ eb1,
                                               const float* __restrict__ eW2,
                                               float* __restrict__ W1cp5,   // [5][65][768]
                                               float* __restrict__ b1p5,    // [5][768]
                                               float* __restrict__ W2p5) {  // [5][768][32]
    int k = blockIdx.y;
    const float* W1 = eW1 + (size_t)k * 321 * 642;
    const float* b1 = eb1 + (size_t)k * 642;
    const float* W2 = eW2 + (size_t)k * 642 * 32;
    float* W1cp = W1cp5 + (size_t)k * 65 * 768;
    float* b1p  = b1p5 + (size_t)k * 768;
    float* W2p  = W2p5 + (size_t)k * 768 * 32;
    int idx = blockIdx.x * 256 + threadIdx.x;
    if (idx < 65 * 768) {
        int r = idx / 768, j = idx - r * 768;
        W1cp[idx] = (j < 642) ? W1[(size_t)(256 + r) * 642 + j] : 0.f;
    } else if (idx < 65 * 768 + 768) {
        int j = idx - 65 * 768;
        b1p[j] = (j < 642) ? b1[j] : 0.f;
    } else if (idx < 65 * 768 + 768 + 768 * 32) {
        int t = idx - (65 * 768 + 768);
        int j = t >> 5, c = t & 31;
        W2p[t] = (j < 642) ? W2[(size_t)j * 32 + c] : 0.f;
    }
}

// ---------------- fp32 GEMM 128x128 tile, BF16 OUTPUT (Pab fallback path) ----------------
__global__ __launch_bounds__(256) void k_gemm(const float* __restrict__ A, int lda,
                                              const float* __restrict__ B, int ldb,
                                              const float* __restrict__ bias,
                                              float* __restrict__ C, int ldc,  // treated as ushort*
                                              int M, int N, int K, int siluA, int siluOut) {
    __shared__ float As[32 * 132];
    __shared__ float Bs[32 * 132];
    const int tid = threadIdx.x;
    const int m0 = blockIdx.x * 128, n0 = blockIdx.y * 128;
    const int tm = tid >> 4, tn = tid & 15;

    float4 acc[8][2];
    #pragma unroll
    for (int r = 0; r < 8; ++r) { acc[r][0] = make_float4(0,0,0,0); acc[r][1] = make_float4(0,0,0,0); }

    float4 ra[4], rb[4];

#define GLOAD(kc_) do { \
    _Pragma("unroll") \
    for (int i_ = 0; i_ < 4; ++i_) { \
        int idx_ = tid + i_ * 256; \
        int m_ = idx_ >> 3, kq_ = idx_ & 7; \
        int gm_ = m0 + m_; \
        int cm_ = (gm_ < M) ? gm_ : (M - 1); \
        float4 a_ = *(const float4*)(A + (size_t)cm_ * lda + (kc_) + 4 * kq_); \
        if (gm_ >= M) a_ = make_float4(0,0,0,0); \
        ra[i_] = a_; \
    } \
    _Pragma("unroll") \
    for (int i_ = 0; i_ < 4; ++i_) { \
        int idx_ = tid + i_ * 256; \
        int r_ = idx_ >> 5, cq_ = idx_ & 31; \
        int gn_ = n0 + 4 * cq_; \
        float4 b_ = make_float4(0,0,0,0); \
        if (gn_ < N) b_ = *(const float4*)(B + (size_t)((kc_) + r_) * ldb + gn_); \
        rb[i_] = b_; \
    } \
} while (0)

    GLOAD(0);

    for (int kc = 0; kc < K; kc += 32) {
        #pragma unroll
        for (int i = 0; i < 4; ++i) {
            int idx = tid + i * 256;
            int m = idx >> 3, kq = idx & 7;
            float4 a = ra[i];
            if (siluA) { a.x = silu(a.x); a.y = silu(a.y); a.z = silu(a.z); a.w = silu(a.w); }
            As[(4 * kq + 0) * 132 + m] = a.x;
            As[(4 * kq + 1) * 132 + m] = a.y;
            As[(4 * kq + 2) * 132 + m] = a.z;
            As[(4 * kq + 3) * 132 + m] = a.w;
        }
        #pragma unroll
        for (int i = 0; i < 4; ++i) {
            int idx = tid + i * 256;
            int r = idx >> 5, cq = idx & 31;
            *(float4*)&Bs[r * 132 + 4 * cq] = rb[i];
        }
        __syncthreads();
        if (kc + 32 < K) GLOAD(kc + 32);   // in flight during FMA below
        #pragma unroll 4
        for (int kk = 0; kk < 32; ++kk) {
            float4 a0 = *(const float4*)&As[kk * 132 + 8 * tm];
            float4 a1 = *(const float4*)&As[kk * 132 + 8 * tm + 4];
            float4 b0 = *(const float4*)&Bs[kk * 132 + 4 * tn];
            float4 b1 = *(const float4*)&Bs[kk * 132 + 64 + 4 * tn];
            acc[0][0] = f4fma(a0.x, b0, acc[0][0]); acc[0][1] = f4fma(a0.x, b1, acc[0][1]);
            acc[1][0] = f4fma(a0.y, b0, acc[1][0]); acc[1][1] = f4fma(a0.y, b1, acc[1][1]);
            acc[2][0] = f4fma(a0.z, b0, acc[2][0]); acc[2][1] = f4fma(a0.z, b1, acc[2][1]);
            acc[3][0] = f4fma(a0.w, b0, acc[3][0]); acc[3][1] = f4fma(a0.w, b1, acc[3][1]);
            acc[4][0] = f4fma(a1.x, b0, acc[4][0]); acc[4][1] = f4fma(a1.x, b1, acc[4][1]);
            acc[5][0] = f4fma(a1.y, b0, acc[5][0]); acc[5][1] = f4fma(a1.y, b1, acc[5][1]);
            acc[6][0] = f4fma(a1.z, b0, acc[6][0]); acc[6][1] = f4fma(a1.z, b1, acc[6][1]);
            acc[7][0] = f4fma(a1.w, b0, acc[7][0]); acc[7][1] = f4fma(a1.w, b1, acc[7][1]);
        }
        __syncthreads();
    }
#undef GLOAD

    unsigned short* C16 = (unsigned short*)C;
    const int gnl = n0 + 4 * tn, gnh = n0 + 64 + 4 * tn;
    #pragma unroll
    for (int r = 0; r < 8; ++r) {
        int gm = m0 + 8 * tm + r;
        if (gm >= M) continue;
        float4 v0 = acc[r][0], v1 = acc[r][1];
        if (gnl < N) {
            if (bias) { v0.x += bias[gnl+0]; v0.y += bias[gnl+1]; v0.z += bias[gnl+2]; v0.w += bias[gnl+3]; }
            if (siluOut) { v0.x = silu(v0.x); v0.y = silu(v0.y); v0.z = silu(v0.z); v0.w = silu(v0.w); }
            ushort4 s0; s0.x = f2bf(v0.x); s0.y = f2bf(v0.y); s0.z = f2bf(v0.z); s0.w = f2bf(v0.w);
            *(ushort4*)&C16[(size_t)gm * ldc + gnl] = s0;
        }
        if (gnh < N) {
            if (bias) { v1.x += bias[gnh+0]; v1.y += bias[gnh+1]; v1.z += bias[gnh+2]; v1.w += bias[gnh+3]; }
            if (siluOut) { v1.x = silu(v1.x); v1.y = silu(v1.y); v1.z = silu(v1.z); v1.w = silu(v1.w); }
            ushort4 s1; s1.x = f2bf(v1.x); s1.y = f2bf(v1.y); s1.z = f2bf(v1.z); s1.w = f2bf(v1.w);
            *(ushort4*)&C16[(size_t)gm * ldc + gnh] = s1;
        }
    }
}

// ---------------- fp32 GEMM 64x128 tile (fallback for small-N dispatches) ----------------
__global__ __launch_bounds__(256) void k_gemm64(const float* __restrict__ A, int lda,
                                                const float* __restrict__ B, int ldb,
                                                const float* __restrict__ bias,
                                                float* __restrict__ C, int ldc,
                                                int M, int N, int K, int siluA, int siluOut) {
    __shared__ float As[32 * 68];
    __shared__ float Bs[32 * 132];
    const int tid = threadIdx.x;
    const int m0 = blockIdx.x * 64, n0 = blockIdx.y * 128;
    const int tm = tid >> 4, tn = tid & 15;

    float4 acc[4][2];
    #pragma unroll
    for (int r = 0; r < 4; ++r) { acc[r][0] = make_float4(0,0,0,0); acc[r][1] = make_float4(0,0,0,0); }

    float4 ra[2], rb[4];

#define GLOAD64(kc_) do { \
    _Pragma("unroll") \
    for (int i_ = 0; i_ < 2; ++i_) { \
        int idx_ = tid + i_ * 256; \
        int m_ = idx_ >> 3, kq_ = idx_ & 7; \
        int gm_ = m0 + m_; \
        int cm_ = (gm_ < M) ? gm_ : (M - 1); \
        float4 a_ = *(const float4*)(A + (size_t)cm_ * lda + (kc_) + 4 * kq_); \
        if (gm_ >= M) a_ = make_float4(0,0,0,0); \
        ra[i_] = a_; \
    } \
    _Pragma("unroll") \
    for (int i_ = 0; i_ < 4; ++i_) { \
        int idx_ = tid + i_ * 256; \
        int r_ = idx_ >> 5, cq_ = idx_ & 31; \
        int gn_ = n0 + 4 * cq_; \
        float4 b_ = make_float4(0,0,0,0); \
        if (gn_ < N) b_ = *(const float4*)(B + (size_t)((kc_) + r_) * ldb + gn_); \
        rb[i_] = b_; \
    } \
} while (0)

    GLOAD64(0);

    for (int kc = 0; kc < K; kc += 32) {
        #pragma unroll
        for (int i = 0; i < 2; ++i) {
            int idx = tid + i * 256;
            int m = idx >> 3, kq = idx & 7;
            float4 a = ra[i];
            if (siluA) { a.x = silu(a.x); a.y = silu(a.y); a.z = silu(a.z); a.w = silu(a.w); }
            As[(4 * kq + 0) * 68 + m] = a.x;
            As[(4 * kq + 1) * 68 + m] = a.y;
            As[(4 * kq + 2) * 68 + m] = a.z;
            As[(4 * kq + 3) * 68 + m] = a.w;
        }
        #pragma unroll
        for (int i = 0; i < 4; ++i) {
            int idx = tid + i * 256;
            int r = idx >> 5, cq = idx & 31;
            *(float4*)&Bs[r * 132 + 4 * cq] = rb[i];
        }
        __syncthreads();
        if (kc + 32 < K) GLOAD64(kc + 32);   // in flight during FMA below
        #pragma unroll 4
        for (int kk = 0; kk < 32; ++kk) {
            float4 av = *(const float4*)&As[kk * 68 + 4 * tm];
            float4 b0 = *(const float4*)&Bs[kk * 132 + 4 * tn];
            float4 b1 = *(const float4*)&Bs[kk * 132 + 64 + 4 * tn];
            acc[0][0] = f4fma(av.x, b0, acc[0][0]); acc[0][1] = f4fma(av.x, b1, acc[0][1]);
            acc[1][0] = f4fma(av.y, b0, acc[1][0]); acc[1][1] = f4fma(av.y, b1, acc[1][1]);
            acc[2][0] = f4fma(av.z, b0, acc[2][0]); acc[2][1] = f4fma(av.z, b1, acc[2][1]);
            acc[3][0] = f4fma(av.w, b0, acc[3][0]); acc[3][1] = f4fma(av.w, b1, acc[3][1]);
        }
        __syncthreads();
    }
#undef GLOAD64

    const int gnl = n0 + 4 * tn, gnh = n0 + 64 + 4 * tn;
    #pragma unroll
    for (int r = 0; r < 4; ++r) {
        int gm = m0 + 4 * tm + r;
        if (gm >= M) continue;
        float4 v0 = acc[r][0], v1 = acc[r][1];
        if (gnl < N) {
            if (bias) { v0.x += bias[gnl+0]; v0.y += bias[gnl+1]; v0.z += bias[gnl+2]; v0.w += bias[gnl+3]; }
            if (siluOut) { v0.x = silu(v0.x); v0.y = silu(v0.y); v0.z = silu(v0.z); v0.w = silu(v0.w); }
            *(float4*)&C[(size_t)gm * ldc + gnl] = v0;
        }
        if (gnh < N) {
            if (bias) { v1.x += bias[gnh+0]; v1.y += bias[gnh+1]; v1.z += bias[gnh+2]; v1.w += bias[gnh+3]; }
            if (siluOut) { v1.x = silu(v1.x); v1.y = silu(v1.y); v1.z = silu(v1.z); v1.w = silu(v1.w); }
            *(float4*)&C[(size_t)gm * ldc + gnh] = v1;
        }
    }
}

// ---------------- fused H2 GEMM + LN + residual ----------------
__global__ __launch_bounds__(256) void k_gemm_ln(const float* __restrict__ A,   // H1 [M][256]
                                                 const float* __restrict__ B,   // nW2 [256][128]
                                                 const float* __restrict__ bias,// nb2 [128]
                                                 float* __restrict__ feats_all, int layer,
                                                 const float* __restrict__ g,
                                                 const float* __restrict__ b,
                                                 int M, int K) {
    __shared__ float As[32 * 68];
    __shared__ float Bs[32 * 132];
    const int tid = threadIdx.x;
    const int m0 = blockIdx.x * 64;
    const int tm = tid >> 4, tn = tid & 15;

    float4 acc[4][2];
    #pragma unroll
    for (int r = 0; r < 4; ++r) { acc[r][0] = make_float4(0,0,0,0); acc[r][1] = make_float4(0,0,0,0); }

    float4 ra[2], rb[4];

#define GLOADL(kc_) do { \
    _Pragma("unroll") \
    for (int i_ = 0; i_ < 2; ++i_) { \
        int idx_ = tid + i_ * 256; \
        int m_ = idx_ >> 3, kq_ = idx_ & 7; \
        int gm_ = m0 + m_; \
        int cm_ = (gm_ < M) ? gm_ : (M - 1); \
        float4 a_ = *(const float4*)(A + (size_t)cm_ * 256 + (kc_) + 4 * kq_); \
        if (gm_ >= M) a_ = make_float4(0,0,0,0); \
        ra[i_] = a_; \
    } \
    _Pragma("unroll") \
    for (int i_ = 0; i_ < 4; ++i_) { \
        int idx_ = tid + i_ * 256; \
        int r_ = idx_ >> 5, cq_ = idx_ & 31; \
        float4 b_ = make_float4(0,0,0,0); \
        if (4 * cq_ < 128) b_ = *(const float4*)(B + (size_t)((kc_) + r_) * 128 + 4 * cq_); \
        rb[i_] = b_; \
    } \
} while (0)

    GLOADL(0);

    for (int kc = 0; kc < K; kc += 32) {
        #pragma unroll
        for (int i = 0; i < 2; ++i) {
            int idx = tid + i * 256;
            int m = idx >> 3, kq = idx & 7;
            float4 a = ra[i];
            As[(4 * kq + 0) * 68 + m] = a.x;
            As[(4 * kq + 1) * 68 + m] = a.y;
            As[(4 * kq + 2) * 68 + m] = a.z;
            As[(4 * kq + 3) * 68 + m] = a.w;
        }
        #pragma unroll
        for (int i = 0; i < 4; ++i) {
            int idx = tid + i * 256;
            int r = idx >> 5, cq = idx & 31;
            if (cq < 32) *(float4*)&Bs[r * 132 + 4 * cq] = rb[i];
        }
        __syncthreads();
        if (kc + 32 < K) GLOADL(kc + 32);
        #pragma unroll 4
        for (int kk = 0; kk < 32; ++kk) {
            float4 av = *(const float4*)&As[kk * 68 + 4 * tm];
            float4 b0 = *(const float4*)&Bs[kk * 132 + 4 * tn];
            float4 b1 = *(const float4*)&Bs[kk * 132 + 64 + 4 * tn];
            acc[0][0] = f4fma(av.x, b0, acc[0][0]); acc[0][1] = f4fma(av.x, b1, acc[0][1]);
            acc[1][0] = f4fma(av.y, b0, acc[1][0]); acc[1][1] = f4fma(av.y, b1, acc[1][1]);
            acc[2][0] = f4fma(av.z, b0, acc[2][0]); acc[2][1] = f4fma(av.z, b1, acc[2][1]);
            acc[3][0] = f4fma(av.w, b0, acc[3][0]); acc[3][1] = f4fma(av.w, b1, acc[3][1]);
        }
        __syncthreads();
    }
#undef GLOADL

    const int cl = 4 * tn, chh = 64 + 4 * tn;
    float4 gl = *(const float4*)(g + cl),  gh = *(const float4*)(g + chh);
    float4 bl = *(const float4*)(b + cl),  bh = *(const float4*)(b + chh);
    float4 wl = *(const float4*)(bias + cl), wh = *(const float4*)(bias + chh);
    #pragma unroll
    for (int r = 0; r < 4; ++r) {
        int gm = m0 + 4 * tm + r;
        if (gm >= M) continue;   // uniform across the 16-lane tn-group (same tm,r)
        float4 v0 = acc[r][0], v1 = acc[r][1];
        v0.x += wl.x; v0.y += wl.y; v0.z += wl.z; v0.w += wl.w;
        v1.x += wh.x; v1.y += wh.y; v1.z += wh.z; v1.w += wh.w;
        float s  = v0.x + v0.y + v0.z + v0.w + v1.x + v1.y + v1.z + v1.w;
        float ss = v0.x*v0.x + v0.y*v0.y + v0.z*v0.z + v0.w*v0.w
                 + v1.x*v1.x + v1.y*v1.y + v1.z*v1.z + v1.w*v1.w;
        s  += __shfl_xor(s, 1, 64);  ss += __shfl_xor(ss, 1, 64);
        s  += __shfl_xor(s, 2, 64);  ss += __shfl_xor(ss, 2, 64);
        s  += __shfl_xor(s, 4, 64);  ss += __shfl_xor(ss, 4, 64);
        s  += __shfl_xor(s, 8, 64);  ss += __shfl_xor(ss, 8, 64);
        float mean = s * (1.0f / 128.0f);
        float var  = ss * (1.0f / 128.0f) - mean * mean;
        float rstd = 1.0f / sqrtf(var + EPS);
        float* fp = feats_all + (size_t)gm * 768 + layer * 128;
        float4 f0 = *(const float4*)(fp + cl);
        float4 f1 = *(const float4*)(fp + chh);
        float4 o0, o1;
        o0.x = f0.x + (v0.x - mean) * rstd * gl.x + bl.x;
        o0.y = f0.y + (v0.y - mean) * rstd * gl.y + bl.y;
        o0.z = f0.z + (v0.z - mean) * rstd * gl.z + bl.z;
        o0.w = f0.w + (v0.w - mean) * rstd * gl.w + bl.w;
        o1.x = f1.x + (v1.x - mean) * rstd * gh.x + bh.x;
        o1.y = f1.y + (v1.y - mean) * rstd * gh.y + bh.y;
        o1.z = f1.z + (v1.z - mean) * rstd * gh.z + bh.z;
        o1.w = f1.w + (v1.w - mean) * rstd * gh.w + bh.w;
        float* op = feats_all + (size_t)gm * 768 + (layer + 1) * 128;
        *(float4*)(op + cl)  = o0;
        *(float4*)(op + chh) = o1;
    }
}

// ---------------- fused edge kernel (v12, fp32-VALU GEMM): fallback path ----------------
__global__ __launch_bounds__(256, 3) void k_edge(const int* __restrict__ ssiP,
                                                 const int* __restrict__ dsiP,
                                                 const int* __restrict__ i0P,
                                                 const float* __restrict__ frP,
                                                 const float* __restrict__ T,     // [TROWS][648]
                                                 const unsigned short* __restrict__ Pab, // [N_NODES][1296] bf16
                                                 const float* __restrict__ W2p,   // [768][32]
                                                 const float* __restrict__ b2,
                                                 const float* __restrict__ eng,
                                                 const float* __restrict__ enb,
                                                 float* __restrict__ S,
                                                 float* __restrict__ Mout,
                                                 int csr) {
    __shared__ float Zs[64 * 70];        // 17920 B; overlaid by m2s[64][36] in epilogue
    __shared__ float W2s[64 * 36];       // single-buffered W2 chunk, 9216 B
    __shared__ int dsi[EPB], ssi[EPB], i0s[EPB];
    __shared__ float frs[EPB];
    __shared__ float cpar[96];

    const int tid = threadIdx.x;
    const int bid = blockIdx.x;
    const int xcd = bid & 7, bpos = bid >> 3;
    const int wg = (xcd < 4) ? xcd * 313 + bpos : 1252 + (xcd - 4) * 312 + bpos;
    const int eb = wg * EPB;
    const int lane = tid & 31;
    const int grp = tid >> 5;

    if (tid < EPB) {
        ssi[tid] = ssiP[eb + tid];
        dsi[tid] = dsiP[eb + tid];
        i0s[tid] = i0P[eb + tid];
        frs[tid] = frP[eb + tid];
    }
    if (tid < 32) cpar[tid] = b2[tid];
    else if (tid < 64) cpar[tid] = eng[tid - 32];
    else if (tid < 96) cpar[tid] = enb[tid - 64];
    __syncthreads();

    int dsr[2], ssr[2], i0r[2];
    float frr[2];
    #pragma unroll
    for (int i = 0; i < 2; ++i) {
        int e = 2 * lane + i;
        dsr[i] = dsi[e]; ssr[i] = ssi[e];
        i0r[i] = i0s[e]; frr[i] = frs[e];
    }

    float4 accm[2];
    accm[0] = make_float4(0,0,0,0);
    accm[1] = make_float4(0,0,0,0);

    float4 rA0[2], rA1[2], rB0[2], rB1[2];
    uint4 rp[2], rq[2];
    float4 rw0, rw1;

#define PREFETCH(cn) do { \
    const int colb_ = 64 * (cn) + 8 * grp; \
    if (colb_ < TCOLS) { \
        _Pragma("unroll") \
        for (int i_ = 0; i_ < 2; ++i_) { \
            const float* t0_ = T + (size_t)i0r[i_] * TCOLS + colb_; \
            rA0[i_] = *(const float4*)t0_; \
            rA1[i_] = *(const float4*)(t0_ + 4); \
            rB0[i_] = *(const float4*)(t0_ + TCOLS); \
            rB1[i_] = *(const float4*)(t0_ + TCOLS + 4); \
            rp[i_] = *(const uint4*)(Pab + (size_t)dsr[i_] * PSTRIDE + colb_); \
            rq[i_] = *(const uint4*)(Pab + (size_t)ssr[i_] * PSTRIDE + JP + colb_); \
        } \
    } \
    const float* ws_ = W2p + (size_t)(64 * (cn)) * 32 + 8 * tid; \
    rw0 = *(const float4*)ws_; rw1 = *(const float4*)(ws_ + 4); \
} while (0)

    PREFETCH(0);

    for (int ch = 0; ch < 11; ++ch) {
        const int colb = 64 * ch + 8 * grp;

        float qa[2][8];
        if (colb < TCOLS) {
            #pragma unroll
            for (int i = 0; i < 2; ++i) {
                float f = frr[i];
                float pa[8], pb[8];
                pa[0] = __uint_as_float(rp[i].x << 16); pa[1] = __uint_as_float(rp[i].x & 0xFFFF0000u);
                pa[2] = __uint_as_float(rp[i].y << 16); pa[3] = __uint_as_float(rp[i].y & 0xFFFF0000u);
                pa[4] = __uint_as_float(rp[i].z << 16); pa[5] = __uint_as_float(rp[i].z & 0xFFFF0000u);
                pa[6] = __uint_as_float(rp[i].w << 16); pa[7] = __uint_as_float(rp[i].w & 0xFFFF0000u);
                pb[0] = __uint_as_float(rq[i].x << 16); pb[1] = __uint_as_float(rq[i].x & 0xFFFF0000u);
                pb[2] = __uint_as_float(rq[i].y << 16); pb[3] = __uint_as_float(rq[i].y & 0xFFFF0000u);
                pb[4] = __uint_as_float(rq[i].z << 16); pb[5] = __uint_as_float(rq[i].z & 0xFFFF0000u);
                pb[6] = __uint_as_float(rq[i].w << 16); pb[7] = __uint_as_float(rq[i].w & 0xFFFF0000u);
                qa[i][0] = silu(fmaf(f, rB0[i].x - rA0[i].x, rA0[i].x) + pa[0] + pb[0]);
                qa[i][1] = silu(fmaf(f, rB0[i].y - rA0[i].y, rA0[i].y) + pa[1] + pb[1]);
                qa[i][2] = silu(fmaf(f, rB0[i].z - rA0[i].z, rA0[i].z) + pa[2] + pb[2]);
                qa[i][3] = silu(fmaf(f, rB0[i].w - rA0[i].w, rA0[i].w) + pa[3] + pb[3]);
                qa[i][4] = silu(fmaf(f, rB1[i].x - rA1[i].x, rA1[i].x) + pa[4] + pb[4]);
                qa[i][5] = silu(fmaf(f, rB1[i].y - rA1[i].y, rA1[i].y) + pa[5] + pb[5]);
                qa[i][6] = silu(fmaf(f, rB1[i].z - rA1[i].z, rA1[i].z) + pa[6] + pb[6]);
                qa[i][7] = silu(fmaf(f, rB1[i].w - rA1[i].w, rA1[i].w) + pa[7] + pb[7]);
            }
        } else {
            #pragma unroll
            for (int i = 0; i < 2; ++i)
                #pragma unroll
                for (int c = 0; c < 8; ++c) qa[i][c] = 0.f;
        }

        __syncthreads();

        #pragma unroll
        for (int jj = 0; jj < 8; ++jj) {
            float2 z2;
            z2.x = qa[0][jj]; z2.y = qa[1][jj];
            *(float2*)&Zs[(8 * grp + jj) * 70 + 2 * lane] = z2;
        }
        {
            int wrow = tid >> 2;
            int wc0 = (2 * tid) & 7;
            *(float4*)&W2s[wrow * 36 + 4 * wc0] = rw0;
            *(float4*)&W2s[wrow * 36 + 4 * (wc0 + 1)] = rw1;
        }

        __syncthreads();

        if (ch < 10) PREFETCH(ch + 1);

        #pragma unroll 8
        for (int kk = 0; kk < 64; ++kk) {
            float2 z2 = *(const float2*)&Zs[kk * 70 + 2 * lane];
            float4 w4 = *(const float4*)&W2s[kk * 36 + 4 * grp];
            accm[0] = f4fma(z2.x, w4, accm[0]);
            accm[1] = f4fma(z2.y, w4, accm[1]);
        }
    }
#undef PREFETCH

    __syncthreads();
    float* m2s = Zs;
    {
        float4 bb2 = *(const float4*)&cpar[4 * grp];
        #pragma unroll
        for (int i = 0; i < 2; ++i) {
            int e = 2 * lane + i;
            float4 o;
            o.x = silu(accm[i].x + bb2.x);
            o.y = silu(accm[i].y + bb2.y);
            o.z = silu(accm[i].z + bb2.z);
            o.w = silu(accm[i].w + bb2.w);
            *(float4*)&m2s[e * 36 + 4 * grp] = o;
        }
    }
    __syncthreads();
    {
        int e = tid >> 2, q = tid & 3;
        float4 v0 = *(const float4*)&m2s[e * 36 + 8 * q];
        float4 v1 = *(const float4*)&m2s[e * 36 + 8 * q + 4];
        float s  = v0.x + v0.y + v0.z + v0.w + v1.x + v1.y + v1.z + v1.w;
        float ss = v0.x*v0.x + v0.y*v0.y + v0.z*v0.z + v0.w*v0.w
                 + v1.x*v1.x + v1.y*v1.y + v1.z*v1.z + v1.w*v1.w;
        s  += __shfl_xor(s, 1, 64);  ss += __shfl_xor(ss, 1, 64);
        s  += __shfl_xor(s, 2, 64);  ss += __shfl_xor(ss, 2, 64);
        float mean = s * 0.03125f;
        float var = ss * 0.03125f - mean * mean;
        float rstd = 1.0f / sqrtf(var + EPS);
        const float* gg = cpar + 32 + 8 * q;
        const float* bbv = cpar + 64 + 8 * q;
        float vv[8] = {v0.x, v0.y, v0.z, v0.w, v1.x, v1.y, v1.z, v1.w};
        float o[8];
        #pragma unroll
        for (int c = 0; c < 8; ++c) o[c] = (vv[c] - mean) * rstd * gg[c] + bbv[c];
        if (csr) {
            float* Mp = Mout + (size_t)(eb + e) * 32 + 8 * q;
            *(float4*)Mp       = make_float4(o[0], o[1], o[2], o[3]);
            *(float4*)(Mp + 4) = make_float4(o[4], o[5], o[6], o[7]);
        } else {
            int d = dsi[e];
            float* Sp = S + (size_t)d * 32 + 8 * q;
            #pragma unroll
            for (int c = 0; c < 8; ++c) atomicAdd(&Sp[c], o[c]);
        }
    }
}

// ---------------- fused edge kernel v13: MFMA Z@W2 (CSR-only path) ----------------
// Per block: m2[64 edges][32] = Z[64][704 pad]@W2[704][32] on matrix cores.
// Z staged per 64-col chunk as bf16 in LDS [64 edges][64 cols], 16B-block XOR swizzle
// (blk ^= edge&7 on write, ^= row&7 on read) -> full LDS bandwidth both phases.
// W2 prepacked [88 kg][32][8] bf16 in global (22.5KB/layer, L2-hot). 4 waves: wave w
// owns edges 16w..16w+15, all 32 out-cols (2 B-frags). Fragment mapping identical to
// the verified k_gemm_mfma scheme. Epilogue (bias+silu -> LN -> CSR store) unchanged.
__global__ __launch_bounds__(256, 4) void k_edge_m(const int* __restrict__ ssiP,
                                                   const int* __restrict__ dsiP,
                                                   const int* __restrict__ i0P,
                                                   const float* __restrict__ frP,
                                                   const float* __restrict__ T,     // [TROWS][648]
                                                   const unsigned short* __restrict__ Pab, // [N_NODES][1296] bf16
                                                   const unsigned short* __restrict__ W2k, // [88][32][8] bf16
                                                   const float* __restrict__ b2,
                                                   const float* __restrict__ eng,
                                                   const float* __restrict__ enb,
                                                   float* __restrict__ Mout) {
    __shared__ float m2s[64 * 36];       // 9216 B; Zb (8192 B) overlays during chunk loop
    __shared__ int dsi[EPB], ssi[EPB], i0s[EPB];
    __shared__ float frs[EPB];
    __shared__ float cpar[96];
    unsigned short* Zb = (unsigned short*)m2s;   // [64 edges][64 cols] bf16, swizzled 16B blocks

    const int tid = threadIdx.x;
    const int bid = blockIdx.x;
    const int xcd = bid & 7, bpos = bid >> 3;
    const int wg = (xcd < 4) ? xcd * 313 + bpos : 1252 + (xcd - 4) * 312 + bpos;
    const int eb = wg * EPB;
    const int lane = tid & 31;           // edge-pair index (qa phase)
    const int grp = tid >> 5;            // col group (qa phase)
    const int wv = tid >> 6, l64 = tid & 63;
    const int lr = l64 & 15, lg = l64 >> 4;   // MFMA fragment indices

    if (tid < EPB) {
        ssi[tid] = ssiP[eb + tid];
        dsi[tid] = dsiP[eb + tid];
        i0s[tid] = i0P[eb + tid];
        frs[tid] = frP[eb + tid];
    }
    if (tid < 32) cpar[tid] = b2[tid];
    else if (tid < 64) cpar[tid] = eng[tid - 32];
    else if (tid < 96) cpar[tid] = enb[tid - 64];
    __syncthreads();

    int dsr[2], ssr[2], i0r[2];
    float frr[2];
    #pragma unroll
    for (int i = 0; i < 2; ++i) {
        int e = 2 * lane + i;
        dsr[i] = dsi[e]; ssr[i] = ssi[e];
        i0r[i] = i0s[e]; frr[i] = frs[e];
    }

    f32x4 acc0 = {}, acc1 = {};          // out-cols 0-15 / 16-31 for this wave's 16 edges

    float4 rA0[2], rA1[2], rB0[2], rB1[2];
    uint4 rp[2], rq[2];

#define PREFETCHM(cn) do { \
    const int colb_ = 64 * (cn) + 8 * grp; \
    if (colb_ < TCOLS) { \
        _Pragma("unroll") \
        for (int i_ = 0; i_ < 2; ++i_) { \
            const float* t0_ = T + (size_t)i0r[i_] * TCOLS + colb_; \
            rA0[i_] = *(const float4*)t0_; \
            rA1[i_] = *(const float4*)(t0_ + 4); \
            rB0[i_] = *(const float4*)(t0_ + TCOLS); \
            rB1[i_] = *(const float4*)(t0_ + TCOLS + 4); \
            rp[i_] = *(const uint4*)(Pab + (size_t)dsr[i_] * PSTRIDE + colb_); \
            rq[i_] = *(const uint4*)(Pab + (size_t)ssr[i_] * PSTRIDE + JP + colb_); \
        } \
    } \
} while (0)

    PREFETCHM(0);

    for (int ch = 0; ch < 11; ++ch) {
        const int colb = 64 * ch + 8 * grp;

        float qa[2][8];
        if (colb < TCOLS) {
            #pragma unroll
            for (int i = 0; i < 2; ++i) {
                float f = frr[i];
                float pa[8], pb[8];
                pa[0] = __uint_as_float(rp[i].x << 16); pa[1] = __uint_as_float(rp[i].x & 0xFFFF0000u);
                pa[2] = __uint_as_float(rp[i].y << 16); pa[3] = __uint_as_float(rp[i].y & 0xFFFF0000u);
                pa[4] = __uint_as_float(rp[i].z << 16); pa[5] = __uint_as_float(rp[i].z & 0xFFFF0000u);
                pa[6] = __uint_as_float(rp[i].w << 16); pa[7] = __uint_as_float(rp[i].w & 0xFFFF0000u);
                pb[0] = __uint_as_float(rq[i].x << 16); pb[1] = __uint_as_float(rq[i].x & 0xFFFF0000u);
                pb[2] = __uint_as_float(rq[i].y << 16); pb[3] = __uint_as_float(rq[i].y & 0xFFFF0000u);
                pb[4] = __uint_as_float(rq[i].z << 16); pb[5] = __uint_as_float(rq[i].z & 0xFFFF0000u);
                pb[6] = __uint_as_float(rq[i].w << 16); pb[7] = __uint_as_float(rq[i].w & 0xFFFF0000u);
                qa[i][0] = silu(fmaf(f, rB0[i].x - rA0[i].x, rA0[i].x) + pa[0] + pb[0]);
                qa[i][1] = silu(fmaf(f, rB0[i].y - rA0[i].y, rA0[i].y) + pa[1] + pb[1]);
                qa[i][2] = silu(fmaf(f, rB0[i].z - rA0[i].z, rA0[i].z) + pa[2] + pb[2]);
                qa[i][3] = silu(fmaf(f, rB0[i].w - rA0[i].w, rA0[i].w) + pa[3] + pb[3]);
                qa[i][4] = silu(fmaf(f, rB1[i].x - rA1[i].x, rA1[i].x) + pa[4] + pb[4]);
                qa[i][5] = silu(fmaf(f, rB1[i].y - rA1[i].y, rA1[i].y) + pa[5] + pb[5]);
                qa[i][6] = silu(fmaf(f, rB1[i].z - rA1[i].z, rA1[i].z) + pa[6] + pb[6]);
                qa[i][7] = silu(fmaf(f, rB1[i].w - rA1[i].w, rA1[i].w) + pa[7] + pb[7]);
            }
        } else {
            #pragma unroll
            for (int i = 0; i < 2; ++i)
                #pragma unroll
                for (int c = 0; c < 8; ++c) qa[i][c] = 0.f;
        }

        __syncthreads();   // bA: previous chunk's MFMA done -> Zb free

        #pragma unroll
        for (int i = 0; i < 2; ++i) {
            int e = 2 * lane + i;
            uint4 zp;
            zp.x = (unsigned)f2bf(qa[i][0]) | ((unsigned)f2bf(qa[i][1]) << 16);
            zp.y = (unsigned)f2bf(qa[i][2]) | ((unsigned)f2bf(qa[i][3]) << 16);
            zp.z = (unsigned)f2bf(qa[i][4]) | ((unsigned)f2bf(qa[i][5]) << 16);
            zp.w = (unsigned)f2bf(qa[i][6]) | ((unsigned)f2bf(qa[i][7]) << 16);
            *(uint4*)&Zb[e * 64 + ((grp ^ (e & 7)) << 3)] = zp;
        }

        __syncthreads();   // bB: Zb published

        if (ch < 10) PREFETCHM(ch + 1);   // next-chunk loads in flight during MFMA

        #pragma unroll
        for (int h = 0; h < 2; ++h) {
            const int cq = 4 * h + lg;                 // col-quad 0..7 within chunk
            const int arow = 16 * wv + lr;
            bf16v8 a = *(const bf16v8*)&Zb[arow * 64 + ((cq ^ (arow & 7)) << 3)];
            const unsigned short* bp = W2k + ((size_t)(ch * 8 + cq) * 32) * 8;
            bf16v8 b0 = *(const bf16v8*)(bp + (size_t)lr * 8);
            bf16v8 b1 = *(const bf16v8*)(bp + (size_t)(16 + lr) * 8);
            acc0 = __builtin_amdgcn_mfma_f32_16x16x32_bf16(a, b0, acc0, 0, 0, 0);
            acc1 = __builtin_amdgcn_mfma_f32_16x16x32_bf16(a, b1, acc1, 0, 0, 0);
        }
    }
#undef PREFETCHM

    __syncthreads();   // all MFMA done reading Zb -> reuse as m2s
    // D-frag epilogue: edge = 16wv + lg*4 + j, col = {lr, 16+lr}
    #pragma unroll
    for (int j = 0; j < 4; ++j) {
        int e = 16 * wv + lg * 4 + j;
        m2s[e * 36 + lr]      = silu(acc0[j] + cpar[lr]);
        m2s[e * 36 + 16 + lr] = silu(acc1[j] + cpar[16 + lr]);
    }
    __syncthreads();
    {
        int e = tid >> 2, q = tid & 3;
        float4 v0 = *(const float4*)&m2s[e * 36 + 8 * q];
        float4 v1 = *(const float4*)&m2s[e * 36 + 8 * q + 4];
        float s  = v0.x + v0.y + v0.z + v0.w + v1.x + v1.y + v1.z + v1.w;
        float ss = v0.x*v0.x + v0.y*v0.y + v0.z*v0.z + v0.w*v0.w
                 + v1.x*v1.x + v1.y*v1.y + v1.z*v1.z + v1.w*v1.w;
        s  += __shfl_xor(s, 1, 64);  ss += __shfl_xor(ss, 1, 64);
        s  += __shfl_xor(s, 2, 64);  ss += __shfl_xor(ss, 2, 64);
        float mean = s * 0.03125f;
        float var = ss * 0.03125f - mean * mean;
        float rstd = 1.0f / sqrtf(var + EPS);
        const float* gg = cpar + 32 + 8 * q;
        const float* bbv = cpar + 64 + 8 * q;
        float vv[8] = {v0.x, v0.y, v0.z, v0.w, v1.x, v1.y, v1.z, v1.w};
        float o[8];
        #pragma unroll
        for (int c = 0; c < 8; ++c) o[c] = (vv[c] - mean) * rstd * gg[c] + bbv[c];
        float* Mp = Mout + (size_t)(eb + e) * 32 + 8 * q;
        *(float4*)Mp       = make_float4(o[0], o[1], o[2], o[3]);
        *(float4*)(Mp + 4) = make_float4(o[4], o[5], o[6], o[7]);
    }
}

// ---------------- node prep: H0[:,0:128] = LN(feats) ----------------
__global__ __launch_bounds__(128) void k_prep(const float* __restrict__ featsk,
                                              const float* __restrict__ nn1g,
                                              const float* __restrict__ nn1b,
                                              float* __restrict__ H0) {
    int n = blockIdx.x, tid = threadIdx.x;
    __shared__ float red[4];
    float x = featsk[(size_t)n * 768 + tid];
    float s = wave_sum64(x), ss = wave_sum64(x * x);
    if ((tid & 63) == 0) { red[(tid >> 6) * 2] = s; red[(tid >> 6) * 2 + 1] = ss; }
    __syncthreads();
    float S1 = red[0] + red[2], S2 = red[1] + red[3];
    float mean = S1 * (1.0f / 128.0f);
    float var = S2 * (1.0f / 128.0f) - mean * mean;
    float rstd = 1.0f / sqrtf(var + EPS);
    H0[(size_t)n * 160 + tid] = (x - mean) * rstd * nn1g[tid] + nn1b[tid];
}

// ---------------- graph pooling (batch sorted -> run-length accum) ----------------
__global__ __launch_bounds__(256) void k_pool(const float* __restrict__ F,
                                              const int* __restrict__ batch,
                                              float* __restrict__ G,
                                              float* __restrict__ cntg) {
    __shared__ int bL[32];
    int b0 = blockIdx.x * 32;
    int tid = threadIdx.x;
    int nmax = min(32, N_NODES - b0);
    if (nmax <= 0) return;
    if (tid < nmax) bL[tid] = batch[b0 + tid];
    __syncthreads();
    float accv = 0.f;
    int cur = -1;
    for (int i = 0; i < nmax; ++i) {
        int g = bL[i];
        if (g != cur) {
            if (cur >= 0) atomicAdd(&G[(size_t)cur * 256 + tid], accv);
            cur = g; accv = 0.f;
        }
        accv += F[(size_t)(b0 + i) * 256 + tid];
    }
    if (cur >= 0) atomicAdd(&G[(size_t)cur * 256 + tid], accv);
    if (tid == 0)
        for (int i = 0; i < nmax; ++i) atomicAdd(&cntg[bL[i]], 1.0f);
}

// ---------------- per-graph MLP head ----------------
__global__ __launch_bounds__(256) void k_graph(const float* __restrict__ G,
                                               const float* __restrict__ cntg,
                                               const float* __restrict__ g1W,
                                               const float* __restrict__ g1b,
                                               const float* __restrict__ g2W,
                                               const float* __restrict__ g2b,
                                               const float* __restrict__ g3W,
                                               const float* __restrict__ g3b,
                                               float* __restrict__ out) {
    __shared__ float X[256], Y[256], red[4];
    int g = blockIdx.x, tid = threadIdx.x;
    float inv = 1.0f / fmaxf(cntg[g], 1.0f);
    X[tid] = G[(size_t)g * 256 + tid] * inv;
    __syncthreads();
    float a = g1b[tid];
    for (int j = 0; j < 256; ++j) a = fmaf(X[j], g1W[(size_t)j * 256 + tid], a);
    Y[tid] = silu(a);
    __syncthreads();
    a = g2b[tid];
    for (int j = 0; j < 256; ++j) a = fmaf(Y[j], g2W[(size_t)j * 256 + tid], a);
    float z = silu(a);
    float p = z * g3W[tid];
    p = wave_sum64(p);
    if ((tid & 63) == 0) red[tid >> 6] = p;
    __syncthreads();
    if (tid == 0) out[g] = red[0] + red[1] + red[2] + red[3] + g3b[0];
}

extern "C" void kernel_launch(void* const* d_in, const int* in_sizes, int n_in,
                              void* d_out, int out_size, void* d_ws, size_t ws_size,
                              hipStream_t stream) {
    const int*   atomids = (const int*)d_in[0];
    const float* coords  = (const float*)d_in[1];
    const int*   eidx    = (const int*)d_in[2];
    const int*   batch   = (const int*)d_in[3];
    const float* emb_w   = (const float*)d_in[4];
    const float* eW1     = (const float*)d_in[5];
    const float* eb1     = (const float*)d_in[6];
    const float* eW2     = (const float*)d_in[7];
    const float* eb2     = (const float*)d_in[8];
    const float* en_g    = (const float*)d_in[9];
    const float* en_b    = (const float*)d_in[10];
    const float* nn1_g   = (const float*)d_in[11];
    const float* nn1_b   = (const float*)d_in[12];
    const float* nW1     = (const float*)d_in[13];
    const float* nb1     = (const float*)d_in[14];
    const float* nW2     = (const float*)d_in[15];
    const float* nb2     = (const float*)d_in[16];
    const float* nn2_g   = (const float*)d_in[17];
    const float* nn2_b   = (const float*)d_in[18];
    const float* f1W     = (const float*)d_in[19];
    const float* f1b     = (const float*)d_in[20];
    const float* f2W     = (const float*)d_in[21];
    const float* f2b     = (const float*)d_in[22];
    const float* f3W     = (const float*)d_in[23];
    const float* f3b     = (const float*)d_in[24];
    const float* g1W     = (const float*)d_in[25];
    const float* g1b     = (const float*)d_in[26];
    const float* g2W     = (const float*)d_in[27];
    const float* g2b     = (const float*)d_in[28];
    const float* g3W     = (const float*)d_in[29];
    const float* g3b     = (const float*)d_in[30];
    float* out = (float*)d_out;

    float* ws = (float*)d_ws;
    float* feats_all = ws;                        // [10000][768]
    float* d2g   = ws + 7680000;                  // [160000]
    float* Pab   = ws + 7840000;                  // region: bf16 [10000][1296] = 25.9MB of 51.8MB
    float* S     = ws + 20800000;                 // [10000][32] (fallback path only)
    float* cnt   = ws + 21120000;                 // [10000]
    float* W1ab5 = ws + 21130000;                 // [5][128][1296] fp32 (fallback only; overlaid by MFMA3 packs)
    float* W1cp5 = ws + 21959440;                 // [5][65][768]
    float* b1p5  = ws + 22209040;                 // [5][768]
    float* W2p5  = ws + 22212880;                 // [5][768][32]
    float* feG   = ws + 22335760;                 // [12289][68]
    float* T     = ws + 23171412;                 // [12289][648]
    float* G     = ws + 31134684;                 // [64][256]
    float* cntg  = ws + 31151068;                 // [64]
    int*   histI = (int*)(ws + 31151132);         // [12304]
    int*   offs  = (int*)(ws + 31163436);         // [12304] (persists as dst-CSR offsD)
    int*   cursor= (int*)(ws + 31175740);         // [12304]
    int*   ssiP  = (int*)(ws + 31188044);         // [160000]
    int*   dsiP  = (int*)(ws + 31348044);         // [160000]
    int*   i0P   = (int*)(ws + 31508044);         // [160000]
    float* frP   = ws + 31668044;                 // [160000]
    int*   eixD  = (int*)(ws + 31828044);         // [160000]
    float* Mbuf  = ws + 31988044;                 // [160000][32] (end 37,108,044)
    unsigned short* Bp5U  = (unsigned short*)(ws + 37108044);  // [5][16][1296][8] bf16 (414,720 fl)
    unsigned short* ApackU= (unsigned short*)(ws + 37522764);  // [16][10000][8] bf16 (640,000 fl)
    unsigned short* nW1p5 = (unsigned short*)(ws + 38162764);  // 5 x [20][256][8] bf16 (102,400 fl)
    unsigned short* f1Wp  = (unsigned short*)(ws + 38265164);  // [96][256][8] bf16 (98,304 fl)
    unsigned short* f2Wp  = (unsigned short*)(ws + 38363468);  // [32][256][8] bf16 (32,768 fl)
    unsigned short* f3Wp  = (unsigned short*)(ws + 38396236);  // [32][256][8] bf16 (32,768 fl; end 38,429,004)
    unsigned short* W2k5  = (unsigned short*)(ws + 38429004);  // [5][88][32][8] bf16 (56,320 fl; end 38,485,324)
    const int useCSR   = (ws_size >= (size_t)(31988044 + 5120000) * sizeof(float)) ? 1 : 0;
    const int useMFMA  = (ws_size >= (size_t)38162764 * sizeof(float)) ? 1 : 0;
    const int useMFMA2 = (ws_size >= (size_t)38429004 * sizeof(float)) ? 1 : 0;
    const int useMFMA3 = (useMFMA && useMFMA2) ? 1 : 0;
    const int useMFMA4 = (useMFMA3 && useCSR &&
                          ws_size >= (size_t)38485324 * sizeof(float)) ? 1 : 0;
    // k_tab MFMA packs overlay the dead fp32 W1ab5 region (only used when !useMFMA):
    unsigned short* feGp = (unsigned short*)(ws + 21130000);   // [12][12289][8] bf16
    unsigned short* Bt5  = (unsigned short*)(ws + 21719872);   // [5][12][648][8] bf16
    unsigned short* PabU = (unsigned short*)Pab;  // bf16 view
    // node-phase temporaries overlay Pab region (dead between phases)
    float* H0 = Pab;                              // [10000][160]
    float* H1 = Pab + 1600000;                    // [10000][256]
    float* F1 = Pab;                              // [10000][256]
    float* F2 = Pab + 2560000;                    // [10000][256]
    float* F3 = Pab + 5120000;                    // [10000][256]
    // Ap2 scratch for N=256 MFMA A-packs: overlays free top of Pab region
    unsigned short* Ap2 = (unsigned short*)(Pab + 7680000);   // up to [96][10000][8] bf16

    k_embed<<<N_NODES, 128, 0, stream>>>(atomids, emb_w, feats_all);
    k_d2<<<(N_EDGES + 255) / 256, 256, 0, stream>>>(coords, eidx, d2g);
    hipMemsetAsync(cnt, 0, 10000 * sizeof(float), stream);
    k_cnt<<<(N_EDGES + 255) / 256, 256, 0, stream>>>(eidx, cnt);
    hipMemsetAsync(histI, 0, 12304 * sizeof(int), stream);
    k_hist<<<(N_EDGES + 255) / 256, 256, 0, stream>>>(d2g, histI);
    k_scan<<<1, 256, 0, stream>>>(histI, offs);
    k_copyi<<<(TROWS + 255) / 256, 256, 0, stream>>>(offs, cursor);
    k_scatter<<<(N_EDGES + 255) / 256, 256, 0, stream>>>(eidx, d2g, cursor,
                                                         ssiP, dsiP, i0P, frP);
    if (useCSR) {
        hipMemsetAsync(histI, 0, 12304 * sizeof(int), stream);
        k_hist_d<<<(N_EDGES + 255) / 256, 256, 0, stream>>>(dsiP, histI);
        k_scan<<<1, 256, 0, stream>>>(histI, offs);
        k_copyi<<<(TROWS + 255) / 256, 256, 0, stream>>>(offs, cursor);
        k_scatter_d<<<(N_EDGES + 255) / 256, 256, 0, stream>>>(dsiP, cursor, eixD);
    }
    k_feg<<<(TROWS + 255) / 256, 256, 0, stream>>>(feG);
    if (useMFMA)
        k_bpack5<<<dim3(648, 5), 256, 0, stream>>>(eW1, Bp5U);
    else
        k_w1ab5<<<dim3(648, 5), 256, 0, stream>>>(eW1, W1ab5);
    k_wpre5<<<dim3(294, 5), 256, 0, stream>>>(eW1, eb1, eW2, W1cp5, b1p5, W2p5);
    if (useMFMA2) {
        for (int k = 0; k < NK; ++k)
            k_bpack2<<<160, 256, 0, stream>>>(nW1 + (size_t)k * 160 * 256, 160,
                                              nW1p5 + (size_t)k * 40960);
        k_bpack2<<<768, 256, 0, stream>>>(f1W, 768, f1Wp);
        k_bpack2<<<256, 256, 0, stream>>>(f2W, 256, f2Wp);
        k_bpack2<<<256, 256, 0, stream>>>(f3W, 256, f3Wp);
    }
    if (useMFMA3) {
        k_apack3<<<(TROWS * 12 + 255) / 256, 256, 0, stream>>>(feG, feGp);
        k_bpack3<<<dim3(243, 5), 256, 0, stream>>>(W1cp5, Bt5);
    }
    if (useMFMA4)
        k_wpack<<<dim3(88, 5), 256, 0, stream>>>(W2p5, W2k5);

    for (int k = 0; k < NK; ++k) {
        const float* eb2k = eb2 + (size_t)k * 32;
        const float* engk = en_g + (size_t)k * 32;
        const float* enbk = en_b + (size_t)k * 32;
        const float* nn1gk = nn1_g + (size_t)k * 128;
        const float* nn1bk = nn1_b + (size_t)k * 128;
        const float* nW1k = nW1 + (size_t)k * 160 * 256;
        const float* nb1k = nb1 + (size_t)k * 256;
        const float* nW2k = nW2 + (size_t)k * 256 * 128;
        const float* nb2k = nb2 + (size_t)k * 128;
        const float* nn2gk = nn2_g + (size_t)k * 128;
        const float* nn2bk = nn2_b + (size_t)k * 128;

        if (useMFMA3)
            k_gemm_mfma3<<<dim3(193, 11), 256, 0, stream>>>(feGp, Bt5 + (size_t)k * 62208,
                                                            b1p5 + (size_t)k * 768, T);
        else
            k_tab<<<(TROWS + 31) / 32, 256, 0, stream>>>(feG,
                                                         W1cp5 + (size_t)k * 65 * 768,
                                                         b1p5 + (size_t)k * 768, T);
        // MUST write all 1296 Pab columns (k_edge reads zero-padding up to col 1295)
        if (useMFMA) {
            k_apack<<<(N_NODES * 16 + 255) / 256, 256, 0, stream>>>(feats_all + k * 128, ApackU);
            k_gemm_mfma<<<dim3(157, 21), 256, 0, stream>>>(ApackU, Bp5U + (size_t)k * 165888,
                                                           PabU, N_NODES);
        } else {
            k_gemm<<<dim3(79, 11), 256, 0, stream>>>(feats_all + k * 128, 768,
                                                     W1ab5 + (size_t)k * 128 * 1296, 1296,
                                                     nullptr, Pab, 1296, N_NODES, 1296, 128, 0, 0);
        }
        if (!useCSR)
            hipMemsetAsync(S, 0, (size_t)320000 * sizeof(float), stream);
        if (useMFMA4)
            k_edge_m<<<N_EDGES / EPB, 256, 0, stream>>>(ssiP, dsiP, i0P, frP, T, PabU,
                                                        W2k5 + (size_t)k * 22528,
                                                        eb2k, engk, enbk, Mbuf);
        else
            k_edge<<<N_EDGES / EPB, 256, 0, stream>>>(ssiP, dsiP, i0P, frP, T, PabU,
                                                      W2p5 + (size_t)k * 768 * 32,
                                                      eb2k, engk, enbk, S, Mbuf, useCSR);
        if (useCSR)
            k_agg_ln<<<(N_NODES + 3) / 4, 128, 0, stream>>>(Mbuf, offs, eixD, cnt,
                                                            engk, enbk, H0);
        else
            k_s_ln<<<(N_NODES + 3) / 4, 128, 0, stream>>>(S, cnt, engk, enbk, H0);
        k_prep<<<N_NODES, 128, 0, stream>>>(feats_all + k * 128, nn1gk, nn1bk, H0);
        if (useMFMA2) {
            k_apack2<<<(N_NODES * 20 + 255) / 256, 256, 0, stream>>>(H0, 160, 20, 0, Ap2);
            k_gemm_mfma2<<<dim3(157, 4), 256, 0, stream>>>(Ap2, nW1p5 + (size_t)k * 40960,
                                                           nb1k, H1, N_NODES, 5);
        } else {
            k_gemm64<<<dim3(157, 2), 256, 0, stream>>>(H0, 160, nW1k, 256, nb1k, H1, 256,
                                                       N_NODES, 256, 160, 0, 1);
        }
        k_gemm_ln<<<dim3(157), 256, 0, stream>>>(H1, nW2k, nb2k, feats_all, k,
                                                 nn2gk, nn2bk, N_NODES, 256);
    }

    // final node MLP (F1/F2/F3 overlay Pab)
    if (useMFMA2) {
        k_apack2<<<(N_NODES * 96 + 255) / 256, 256, 0, stream>>>(feats_all, 768, 96, 1, Ap2);
        k_gemm_mfma2<<<dim3(157, 4), 256, 0, stream>>>(Ap2, f1Wp, f1b, F1, N_NODES, 24);
        k_apack2<<<(N_NODES * 32 + 255) / 256, 256, 0, stream>>>(F1, 256, 32, 0, Ap2);
        k_gemm_mfma2<<<dim3(157, 4), 256, 0, stream>>>(Ap2, f2Wp, f2b, F2, N_NODES, 8);
        k_apack2<<<(N_NODES * 32 + 255) / 256, 256, 0, stream>>>(F2, 256, 32, 0, Ap2);
        k_gemm_mfma2<<<dim3(157, 4), 256, 0, stream>>>(Ap2, f3Wp, f3b, F3, N_NODES, 8);
    } else {
        k_gemm64<<<dim3(157, 2), 256, 0, stream>>>(feats_all, 768, f1W, 256, f1b, F1, 256,
                                                   N_NODES, 256, 768, 1, 1);
        k_gemm64<<<dim3(157, 2), 256, 0, stream>>>(F1, 256, f2W, 256, f2b, F2, 256,
                                                   N_NODES, 256, 256, 0, 1);
        k_gemm64<<<dim3(157, 2), 256, 0, stream>>>(F2, 256, f3W, 256, f3b, F3, 256,
                                                   N_NODES, 256, 256, 0, 1);
    }

    hipMemsetAsync(G, 0, (size_t)(16384 + 64) * sizeof(float), stream);
    k_pool<<<313, 256, 0, stream>>>(F3, batch, G, cntg);
    k_graph<<<N_GRAPHS, 256, 0, stream>>>(G, cntg, g1W, g1b, g2W, g2b, g3W, g3b, out);
}

// Round 20
// 1506.802 us; speedup vs baseline: 1.8207x; 1.1391x over previous
//
#include <hip/hip_runtime.h>
#include <hip/hip_bf16.h>

#define N_NODES 10000
#define N_EDGES 160000
#define N_GRAPHS 64
#define NK 5
#define EPS 1e-5f
#define EPB 64           // edges per block (256 threads)
#define JP 648           // packed width for Pab halves
#define PSTRIDE 1296     // Pab row stride (bf16 elems): [Pa 648 | Pb 648]
#define TCOLS 648        // table row width (642 -> 648)
#define TROWS 12289      // d2 grid [0,96], h=1/128
#define IMAX 12287

// MFMA fragment types: gfx950 mfma_f32_16x16x32_bf16 takes v8bf16 operands.
typedef __attribute__((ext_vector_type(8))) __bf16 bf16v8;
typedef __attribute__((ext_vector_type(4))) float f32x4;

// fast silu: v_rcp_f32 (~1 ulp) instead of IEEE div sequence (no -ffast-math in harness)
__device__ __forceinline__ float silu(float x) {
    return x * __builtin_amdgcn_rcpf(1.0f + __expf(-x));
}
__device__ __forceinline__ float frsq(float x) { return __builtin_amdgcn_rsqf(x); }
__device__ __forceinline__ float frcp(float x) { return __builtin_amdgcn_rcpf(x); }
__device__ __forceinline__ float4 f4fma(float s, float4 w, float4 a) {
    a.x = fmaf(s, w.x, a.x); a.y = fmaf(s, w.y, a.y);
    a.z = fmaf(s, w.z, a.z); a.w = fmaf(s, w.w, a.w);
    return a;
}
__device__ __forceinline__ float wave_sum64(float v) {
    #pragma unroll
    for (int off = 32; off > 0; off >>= 1) v += __shfl_xor(v, off, 64);
    return v;
}
// fp32 -> bf16 (round to nearest even), returned as raw bits
__device__ __forceinline__ unsigned short f2bf(float f) {
    unsigned int u = __float_as_uint(f);
    unsigned int r = u + 0x7FFFu + ((u >> 16) & 1u);
    return (unsigned short)(r >> 16);
}

// ---------------- embedding ----------------
__global__ __launch_bounds__(128) void k_embed(const int* __restrict__ atomids,
                                               const float* __restrict__ emb_w,
                                               float* __restrict__ feats_all) {
    int n = blockIdx.x, tid = threadIdx.x;
    feats_all[(size_t)n * 768 + tid] = emb_w[(size_t)atomids[n] * 128 + tid];
}

// ---------------- per-edge squared distance ----------------
__global__ __launch_bounds__(256) void k_d2(const float* __restrict__ coords,
                                            const int* __restrict__ eidx,
                                            float* __restrict__ d2g) {
    int e = blockIdx.x * 256 + threadIdx.x;
    if (e >= N_EDGES) return;
    int s = eidx[e], d = eidx[N_EDGES + e];
    float dx = coords[s * 3 + 0] - coords[d * 3 + 0];
    float dy = coords[s * 3 + 1] - coords[d * 3 + 1];
    float dz = coords[s * 3 + 2] - coords[d * 3 + 2];
    d2g[e] = dx * dx + dy * dy + dz * dz;
}

// ---------------- in-degree (layer-invariant) ----------------
__global__ __launch_bounds__(256) void k_cnt(const int* __restrict__ eidx,
                                             float* __restrict__ cnt) {
    int e = blockIdx.x * 256 + threadIdx.x;
    if (e >= N_EDGES) return;
    atomicAdd(&cnt[eidx[N_EDGES + e]], 1.0f);
}

// ---------------- counting sort of edges by i0 (T-row index) ----------------
__global__ __launch_bounds__(256) void k_hist(const float* __restrict__ d2g,
                                              int* __restrict__ hist) {
    int e = blockIdx.x * 256 + threadIdx.x;
    if (e >= N_EDGES) return;
    int i0 = (int)(d2g[e] * 128.0f);
    if (i0 > IMAX) i0 = IMAX;
    atomicAdd(&hist[i0], 1);
}

__global__ __launch_bounds__(256) void k_scan(const int* __restrict__ hist,
                                              int* __restrict__ offs) {
    __shared__ int buf[256];
    __shared__ int carryS;
    int tid = threadIdx.x;
    if (tid == 0) carryS = 0;
    __syncthreads();
    for (int base = 0; base < TROWS; base += 256) {
        int v = (base + tid < TROWS) ? hist[base + tid] : 0;
        buf[tid] = v;
        __syncthreads();
        for (int off = 1; off < 256; off <<= 1) {
            int t = (tid >= off) ? buf[tid - off] : 0;
            __syncthreads();
            buf[tid] += t;
            __syncthreads();
        }
        if (base + tid < TROWS) offs[base + tid] = carryS + buf[tid] - v;  // exclusive
        __syncthreads();
        if (tid == 0) carryS += buf[255];
        __syncthreads();
    }
}

__global__ __launch_bounds__(256) void k_copyi(const int* __restrict__ a,
                                               int* __restrict__ b) {
    int i = blockIdx.x * 256 + threadIdx.x;
    if (i < TROWS) b[i] = a[i];
}

__global__ __launch_bounds__(256) void k_scatter(const int* __restrict__ eidx,
                                                 const float* __restrict__ d2g,
                                                 int* __restrict__ cursor,
                                                 int* __restrict__ ssiP,
                                                 int* __restrict__ dsiP,
                                                 int* __restrict__ i0P,
                                                 float* __restrict__ frP) {
    int e = blockIdx.x * 256 + threadIdx.x;
    if (e >= N_EDGES) return;
    float t = d2g[e] * 128.0f;
    int i0 = (int)t;
    if (i0 > IMAX) i0 = IMAX;
    float fr = t - (float)i0;
    int pos = atomicAdd(&cursor[i0], 1);
    ssiP[pos] = eidx[e];
    dsiP[pos] = eidx[N_EDGES + e];
    i0P[pos] = i0;
    frP[pos] = fr;
}

// ---------------- dst-CSR over sorted positions (for atomic-free S aggregation) ----------------
__global__ __launch_bounds__(256) void k_hist_d(const int* __restrict__ dsiP,
                                                int* __restrict__ hist) {
    int p = blockIdx.x * 256 + threadIdx.x;
    if (p >= N_EDGES) return;
    atomicAdd(&hist[dsiP[p]], 1);
}

__global__ __launch_bounds__(256) void k_scatter_d(const int* __restrict__ dsiP,
                                                   int* __restrict__ cursorD,
                                                   int* __restrict__ eixD) {
    int p = blockIdx.x * 256 + threadIdx.x;
    if (p >= N_EDGES) return;
    int pos = atomicAdd(&cursorD[dsiP[p]], 1);
    eixD[pos] = p;
}

// ---------------- CSR aggregation fused with mean + LN: writes H0[:,128:160] ----------------
__global__ __launch_bounds__(128) void k_agg_ln(const float* __restrict__ M,
                                                const int* __restrict__ offsD,
                                                const int* __restrict__ eixD,
                                                const float* __restrict__ cnt,
                                                const float* __restrict__ eng,
                                                const float* __restrict__ enb,
                                                float* __restrict__ H0) {
    int n = blockIdx.x * 4 + (threadIdx.x >> 5);
    int col = threadIdx.x & 31;
    if (n >= N_NODES) return;
    float acc = 0.f;
    int p0 = offsD[n], p1 = offsD[n + 1];
    for (int p = p0; p < p1; ++p)
        acc += M[(size_t)eixD[p] * 32 + col];
    float inv = frcp(fmaxf(cnt[n], 1.0f));
    float v = acc * inv;
    float s = v, q = v * v;
    #pragma unroll
    for (int off = 16; off > 0; off >>= 1) {
        s += __shfl_xor(s, off, 64);
        q += __shfl_xor(q, off, 64);
    }
    float m2 = s * (1.0f / 32.0f);
    float va = q * (1.0f / 32.0f) - m2 * m2;
    float rs = frsq(va + EPS);
    H0[(size_t)n * 160 + 128 + col] = (v - m2) * rs * eng[col] + enb[col];
}

// ---------------- fallback (no-CSR): S -> mean -> LN -> H0[:,128:160] ----------------
__global__ __launch_bounds__(128) void k_s_ln(const float* __restrict__ S,
                                              const float* __restrict__ cnt,
                                              const float* __restrict__ eng,
                                              const float* __restrict__ enb,
                                              float* __restrict__ H0) {
    int n = blockIdx.x * 4 + (threadIdx.x >> 5);
    int col = threadIdx.x & 31;
    if (n >= N_NODES) return;
    float inv = frcp(fmaxf(cnt[n], 1.0f));
    float v = S[(size_t)n * 32 + col] * inv;
    float s = v, q = v * v;
    #pragma unroll
    for (int off = 16; off > 0; off >>= 1) {
        s += __shfl_xor(s, off, 64);
        q += __shfl_xor(q, off, 64);
    }
    float m2 = s * (1.0f / 32.0f);
    float va = q * (1.0f / 32.0f) - m2 * m2;
    float rs = frsq(va + EPS);
    H0[(size_t)n * 160 + 128 + col] = (v - m2) * rs * eng[col] + enb[col];
}

// ---------------- fourier features on the d2 GRID (once) ----------------
__global__ __launch_bounds__(256) void k_feg(float* __restrict__ feG) {  // [TROWS][68]
    int g = blockIdx.x * 256 + threadIdx.x;
    if (g >= TROWS) return;
    float d2v = (float)g * 0.0078125f;   // g / 128, exact
    float* o = feG + (size_t)g * 68;
    float sc = 1.0f;
    #pragma unroll
    for (int i = 0; i < 32; ++i) {
        float x = d2v * sc;
        o[i] = sinf(x);
        o[32 + i] = cosf(x);
        sc *= 0.5f;
    }
    o[64] = d2v;
}

// ---------------- per-layer q-table (fp32 fallback): T[g][j] = fe(g/128) @ W1c + b1 ----------------
__global__ __launch_bounds__(256) void k_tab(const float* __restrict__ feG,   // [TROWS][68]
                                             const float* __restrict__ W1cp,  // [65][768]
                                             const float* __restrict__ b1p,   // [768]
                                             float* __restrict__ T) {         // [TROWS][648]
    __shared__ float feGs[32 * 68];
    __shared__ float W1s[65 * 36];
    const int tid = threadIdx.x;
    const int g0 = blockIdx.x * 32;
    for (int idx = tid; idx < 32 * 17; idx += 256) {
        int r = idx / 17, c = idx - r * 17;
        int gi = g0 + r;
        float4 v = make_float4(0, 0, 0, 0);
        if (gi < TROWS) v = *(const float4*)(feG + (size_t)gi * 68 + 4 * c);
        *(float4*)&feGs[r * 68 + 4 * c] = v;
    }
    const int gt = tid >> 3, ct = tid & 7;
    for (int jc = 0; jc < TCOLS; jc += 32) {
        __syncthreads();
        for (int idx = tid; idx < 65 * 32; idx += 256) {
            int k = idx >> 5, j = idx & 31;
            W1s[k * 36 + j] = W1cp[(size_t)k * 768 + jc + j];
        }
        __syncthreads();
        int gj = jc + 4 * ct;
        float4 q = *(const float4*)(b1p + gj);
        #pragma unroll 5
        for (int k = 0; k < 65; ++k) {
            float f = feGs[gt * 68 + k];
            float4 w = *(const float4*)&W1s[k * 36 + 4 * ct];
            q = f4fma(f, w, q);
        }
        int g = g0 + gt;
        if (g < TROWS && gj < TCOLS)
            *(float4*)(T + (size_t)g * TCOLS + gj) = q;
    }
}

// ---------------- W1ab prestage (fp32, fallback path only) ----------------
__global__ __launch_bounds__(256) void k_w1ab5(const float* __restrict__ eW1,
                                               float* __restrict__ W1ab5) {
    int k = blockIdx.y;
    const float* W1 = eW1 + (size_t)k * 321 * 642;
    float* W1ab = W1ab5 + (size_t)k * 128 * 1296;
    int idx = blockIdx.x * 256 + threadIdx.x;
    if (idx >= 128 * 1296) return;
    int r = idx / 1296;
    int j = idx - r * 1296;
    float v = 0.f;
    if (j < 642) v = W1[(size_t)r * 642 + j];
    else if (j >= 648 && j < 1290) v = W1[(size_t)(128 + r) * 642 + (j - 648)];
    W1ab[idx] = v;
}

// ---------------- MFMA B-fragment prestage: Bpack[5][16][1296][8] bf16 ----------------
__global__ __launch_bounds__(256) void k_bpack5(const float* __restrict__ eW1,
                                                unsigned short* __restrict__ Bp5) {
    int idx = blockIdx.x * 256 + threadIdx.x;
    if (idx >= 16 * 1296 * 8) return;
    int k = blockIdx.y;
    int kg = idx / (1296 * 8);
    int rem = idx - kg * (1296 * 8);
    int c = rem >> 3, jj = rem & 7;
    int r = kg * 8 + jj;             // K index 0..127
    const float* W1 = eW1 + (size_t)k * 321 * 642;
    float v = 0.f;
    if (c < 642) v = W1[(size_t)r * 642 + c];
    else if (c >= 648 && c < 1290) v = W1[(size_t)(128 + r) * 642 + (c - 648)];
    Bp5[(size_t)k * 165888 + idx] = f2bf(v);
}

// ---------------- generic MFMA B-pack for N=256 weights: dst[kg][256][8] ----------------
__global__ __launch_bounds__(256) void k_bpack2(const float* __restrict__ W,   // [K][256]
                                                int K,
                                                unsigned short* __restrict__ dst) {
    int idx = blockIdx.x * 256 + threadIdx.x;
    if (idx >= K * 256) return;
    int kg = idx / (256 * 8);
    int rem = idx - kg * (256 * 8);
    int c = rem >> 3, jj = rem & 7;
    int r = kg * 8 + jj;
    dst[idx] = f2bf(W[(size_t)r * 256 + c]);
}

// ---------------- k_tab MFMA B-pack: Bt[5][12][648][8] from W1cp5 (rows>=65 zero) ----------------
__global__ __launch_bounds__(256) void k_bpack3(const float* __restrict__ W1cp5,
                                                unsigned short* __restrict__ Bt5) {
    int idx = blockIdx.x * 256 + threadIdx.x;
    if (idx >= 12 * 648 * 8) return;
    int k = blockIdx.y;
    int kg = idx / (648 * 8);
    int rem = idx - kg * (648 * 8);
    int c = rem >> 3, jj = rem & 7;
    int r = kg * 8 + jj;
    float v = (r < 65) ? W1cp5[(size_t)k * 65 * 768 + (size_t)r * 768 + c] : 0.f;
    Bt5[(size_t)k * 62208 + idx] = f2bf(v);
}

// ---------------- k_tab MFMA A-pack: Ag[12][TROWS][8] from feG (k>=68 zero), once ----------------
__global__ __launch_bounds__(256) void k_apack3(const float* __restrict__ feG,
                                                unsigned short* __restrict__ Ag) {
    int t = blockIdx.x * 256 + threadIdx.x;
    if (t >= TROWS * 12) return;
    int kg = t / TROWS, m = t - kg * TROWS;
    const float* s = feG + (size_t)m * 68;
    unsigned short* d = Ag + ((size_t)kg * TROWS + m) * 8;
    #pragma unroll
    for (int j = 0; j < 8; ++j) {
        int kk = kg * 8 + j;
        d[j] = (kk < 68) ? f2bf(s[kk]) : (unsigned short)0;
    }
}

// ---------------- k_edge MFMA W2-pack: W2k[5][88][32][8] bf16 from W2p5 [768][32] ----------------
__global__ __launch_bounds__(256) void k_wpack(const float* __restrict__ W2p5,
                                               unsigned short* __restrict__ W2k5) {
    int idx = blockIdx.x * 256 + threadIdx.x;
    if (idx >= 88 * 32 * 8) return;
    int k = blockIdx.y;
    int kg = idx >> 8;
    int rem = idx & 255;
    int c = rem >> 3, j = rem & 7;
    int row = kg * 8 + j;            // 0..703 < 768
    W2k5[(size_t)k * 22528 + idx] = f2bf(W2p5[(size_t)k * 768 * 32 + (size_t)row * 32 + c]);
}

// ---------------- generic MFMA A-pack: dst[kg][M][8] from fp32 [M][stride], optional silu ----------------
__global__ __launch_bounds__(256) void k_apack2(const float* __restrict__ src, int stride,
                                                int Kg, int doSilu,
                                                unsigned short* __restrict__ dst) {
    int t = blockIdx.x * 256 + threadIdx.x;
    if (t >= N_NODES * Kg) return;
    int kg = t / N_NODES, m = t - kg * N_NODES;
    const float* s = src + (size_t)m * stride + kg * 8;
    unsigned short* d = dst + ((size_t)kg * N_NODES + m) * 8;
    #pragma unroll
    for (int j = 0; j < 8; ++j) {
        float v = s[j];
        if (doSilu) v = silu(v);
        d[j] = f2bf(v);
    }
}

// ---------------- MFMA A-fragment staging (per layer): Apack[16][10000][8] bf16 ----------------
__global__ __launch_bounds__(256) void k_apack(const float* __restrict__ feats, // + k*128, stride 768
                                               unsigned short* __restrict__ Ap) {
    int t = blockIdx.x * 256 + threadIdx.x;   // t: m = t>>4, kg = t&15
    if (t >= N_NODES * 16) return;
    int m = t >> 4, kg = t & 15;
    const float* src = feats + (size_t)m * 768 + kg * 8;
    unsigned short* dst = Ap + ((size_t)kg * N_NODES + m) * 8;
    #pragma unroll
    for (int j = 0; j < 8; ++j) dst[j] = f2bf(src[j]);
}

// ---------------- Pab GEMM on matrix cores: bf16 in, fp32 MFMA accum, bf16 out ----------------
__global__ __launch_bounds__(256) void k_gemm_mfma(const unsigned short* __restrict__ Ap, // [16][M][8]
                                                   const unsigned short* __restrict__ Bp, // [16][1296][8]
                                                   unsigned short* __restrict__ C,        // [M][1296] bf16
                                                   int M) {
    const int tid = threadIdx.x;
    const int w = tid >> 6, l = tid & 63;
    const int m0 = blockIdx.x * 64 + (w >> 1) * 32;
    const int n0 = blockIdx.y * 64 + (w & 1) * 32;
    const int lr = l & 15, lg = l >> 4;

    f32x4 acc[2][2] = {};
    for (int kb = 0; kb < 4; ++kb) {
        const int kg = kb * 4 + lg;
        bf16v8 a[2], b[2];
        #pragma unroll
        for (int i = 0; i < 2; ++i) {
            int mrow = m0 + i * 16 + lr; if (mrow >= M) mrow = M - 1;
            a[i] = *(const bf16v8*)(Ap + ((size_t)kg * M + mrow) * 8);
            int ncol = n0 + i * 16 + lr; if (ncol > 1295) ncol = 1295;
            b[i] = *(const bf16v8*)(Bp + ((size_t)kg * 1296 + ncol) * 8);
        }
        #pragma unroll
        for (int mi = 0; mi < 2; ++mi)
            #pragma unroll
            for (int ni = 0; ni < 2; ++ni)
                acc[mi][ni] = __builtin_amdgcn_mfma_f32_16x16x32_bf16(a[mi], b[ni], acc[mi][ni], 0, 0, 0);
    }
    #pragma unroll
    for (int mi = 0; mi < 2; ++mi)
        #pragma unroll
        for (int ni = 0; ni < 2; ++ni)
            #pragma unroll
            for (int j = 0; j < 4; ++j) {
                int gm = m0 + mi * 16 + lg * 4 + j;
                int gn = n0 + ni * 16 + lr;
                if (gm < M && gn < 1296)
                    C[(size_t)gm * 1296 + gn] = f2bf(acc[mi][ni][j]);
            }
}

// ---------------- generic MFMA GEMM, N=256, fp32 out: C = silu(A@B + bias) ----------------
__global__ __launch_bounds__(256) void k_gemm_mfma2(const unsigned short* __restrict__ Ap, // [Kg][M][8]
                                                    const unsigned short* __restrict__ Bp, // [Kg][256][8]
                                                    const float* __restrict__ bias,        // [256]
                                                    float* __restrict__ C,                 // [M][256]
                                                    int M, int KB) {
    const int tid = threadIdx.x;
    const int w = tid >> 6, l = tid & 63;
    const int m0 = blockIdx.x * 64 + (w >> 1) * 32;
    const int n0 = blockIdx.y * 64 + (w & 1) * 32;
    const int lr = l & 15, lg = l >> 4;

    f32x4 acc[2][2] = {};
    for (int kb = 0; kb < KB; ++kb) {
        const int kg = kb * 4 + lg;
        bf16v8 a[2], b[2];
        #pragma unroll
        for (int i = 0; i < 2; ++i) {
            int mrow = m0 + i * 16 + lr; if (mrow >= M) mrow = M - 1;
            a[i] = *(const bf16v8*)(Ap + ((size_t)kg * M + mrow) * 8);
            int ncol = n0 + i * 16 + lr;   // always < 256
            b[i] = *(const bf16v8*)(Bp + ((size_t)kg * 256 + ncol) * 8);
        }
        #pragma unroll
        for (int mi = 0; mi < 2; ++mi)
            #pragma unroll
            for (int ni = 0; ni < 2; ++ni)
                acc[mi][ni] = __builtin_amdgcn_mfma_f32_16x16x32_bf16(a[mi], b[ni], acc[mi][ni], 0, 0, 0);
    }
    #pragma unroll
    for (int mi = 0; mi < 2; ++mi)
        #pragma unroll
        for (int ni = 0; ni < 2; ++ni)
            #pragma unroll
            for (int j = 0; j < 4; ++j) {
                int gm = m0 + mi * 16 + lg * 4 + j;
                int gn = n0 + ni * 16 + lr;
                if (gm < M)
                    C[(size_t)gm * 256 + gn] = silu(acc[mi][ni][j] + bias[gn]);
            }
}

// ---------------- k_tab MFMA GEMM: T[TROWS][648] = Ag @ Bt + b1 (fp32 out) ----------------
__global__ __launch_bounds__(256) void k_gemm_mfma3(const unsigned short* __restrict__ Ag, // [12][TROWS][8]
                                                    const unsigned short* __restrict__ Bt, // [12][648][8]
                                                    const float* __restrict__ bias,        // [768] (b1p)
                                                    float* __restrict__ T) {               // [TROWS][648]
    const int tid = threadIdx.x;
    const int w = tid >> 6, l = tid & 63;
    const int m0 = blockIdx.x * 64 + (w >> 1) * 32;
    const int n0 = blockIdx.y * 64 + (w & 1) * 32;
    const int lr = l & 15, lg = l >> 4;

    f32x4 acc[2][2] = {};
    for (int kb = 0; kb < 3; ++kb) {
        const int kg = kb * 4 + lg;
        bf16v8 a[2], b[2];
        #pragma unroll
        for (int i = 0; i < 2; ++i) {
            int mrow = m0 + i * 16 + lr; if (mrow >= TROWS) mrow = TROWS - 1;
            a[i] = *(const bf16v8*)(Ag + ((size_t)kg * TROWS + mrow) * 8);
            int ncol = n0 + i * 16 + lr; if (ncol > 647) ncol = 647;
            b[i] = *(const bf16v8*)(Bt + ((size_t)kg * 648 + ncol) * 8);
        }
        #pragma unroll
        for (int mi = 0; mi < 2; ++mi)
            #pragma unroll
            for (int ni = 0; ni < 2; ++ni)
                acc[mi][ni] = __builtin_amdgcn_mfma_f32_16x16x32_bf16(a[mi], b[ni], acc[mi][ni], 0, 0, 0);
    }
    #pragma unroll
    for (int mi = 0; mi < 2; ++mi)
        #pragma unroll
        for (int ni = 0; ni < 2; ++ni)
            #pragma unroll
            for (int j = 0; j < 4; ++j) {
                int gm = m0 + mi * 16 + lg * 4 + j;
                int gn = n0 + ni * 16 + lr;
                if (gm < TROWS && gn < TCOLS)
                    T[(size_t)gm * TCOLS + gn] = acc[mi][ni][j] + bias[gn];
            }
}

// ---------------- padded edge-weight prestage (all 5 layers) ----------------
__global__ __launch_bounds__(256) void k_wpre5(const float* __restrict__ eW1,
                                               const float* __restrict__ eb1,
                                               const float* __restrict__ eW2,
                                               float* __restrict__ W1cp5,   // [5][65][768]
                                               float* __restrict__ b1p5,    // [5][768]
                                               float* __restrict__ W2p5) {  // [5][768][32]
    int k = blockIdx.y;
    const float* W1 = eW1 + (size_t)k * 321 * 642;
    const float* b1 = eb1 + (size_t)k * 642;
    const float* W2 = eW2 + (size_t)k * 642 * 32;
    float* W1cp = W1cp5 + (size_t)k * 65 * 768;
    float* b1p  = b1p5 + (size_t)k * 768;
    float* W2p  = W2p5 + (size_t)k * 768 * 32;
    int idx = blockIdx.x * 256 + threadIdx.x;
    if (idx < 65 * 768) {
        int r = idx / 768, j = idx - r * 768;
        W1cp[idx] = (j < 642) ? W1[(size_t)(256 + r) * 642 + j] : 0.f;
    } else if (idx < 65 * 768 + 768) {
        int j = idx - 65 * 768;
        b1p[j] = (j < 642) ? b1[j] : 0.f;
    } else if (idx < 65 * 768 + 768 + 768 * 32) {
        int t = idx - (65 * 768 + 768);
        int j = t >> 5, c = t & 31;
        W2p[t] = (j < 642) ? W2[(size_t)j * 32 + c] : 0.f;
    }
}

// ---------------- fp32 GEMM 128x128 tile, BF16 OUTPUT (Pab fallback path) ----------------
__global__ __launch_bounds__(256) void k_gemm(const float* __restrict__ A, int lda,
                                              const float* __restrict__ B, int ldb,
                                              const float* __restrict__ bias,
                                              float* __restrict__ C, int ldc,  // treated as ushort*
                                              int M, int N, int K, int siluA, int siluOut) {
    __shared__ float As[32 * 132];
    __shared__ float Bs[32 * 132];
    const int tid = threadIdx.x;
    const int m0 = blockIdx.x * 128, n0 = blockIdx.y * 128;
    const int tm = tid >> 4, tn = tid & 15;

    float4 acc[8][2];
    #pragma unroll
    for (int r = 0; r < 8; ++r) { acc[r][0] = make_float4(0,0,0,0); acc[r][1] = make_float4(0,0,0,0); }

    float4 ra[4], rb[4];

#define GLOAD(kc_) do { \
    _Pragma("unroll") \
    for (int i_ = 0; i_ < 4; ++i_) { \
        int idx_ = tid + i_ * 256; \
        int m_ = idx_ >> 3, kq_ = idx_ & 7; \
        int gm_ = m0 + m_; \
        int cm_ = (gm_ < M) ? gm_ : (M - 1); \
        float4 a_ = *(const float4*)(A + (size_t)cm_ * lda + (kc_) + 4 * kq_); \
        if (gm_ >= M) a_ = make_float4(0,0,0,0); \
        ra[i_] = a_; \
    } \
    _Pragma("unroll") \
    for (int i_ = 0; i_ < 4; ++i_) { \
        int idx_ = tid + i_ * 256; \
        int r_ = idx_ >> 5, cq_ = idx_ & 31; \
        int gn_ = n0 + 4 * cq_; \
        float4 b_ = make_float4(0,0,0,0); \
        if (gn_ < N) b_ = *(const float4*)(B + (size_t)((kc_) + r_) * ldb + gn_); \
        rb[i_] = b_; \
    } \
} while (0)

    GLOAD(0);

    for (int kc = 0; kc < K; kc += 32) {
        #pragma unroll
        for (int i = 0; i < 4; ++i) {
            int idx = tid + i * 256;
            int m = idx >> 3, kq = idx & 7;
            float4 a = ra[i];
            if (siluA) { a.x = silu(a.x); a.y = silu(a.y); a.z = silu(a.z); a.w = silu(a.w); }
            As[(4 * kq + 0) * 132 + m] = a.x;
            As[(4 * kq + 1) * 132 + m] = a.y;
            As[(4 * kq + 2) * 132 + m] = a.z;
            As[(4 * kq + 3) * 132 + m] = a.w;
        }
        #pragma unroll
        for (int i = 0; i < 4; ++i) {
            int idx = tid + i * 256;
            int r = idx >> 5, cq = idx & 31;
            *(float4*)&Bs[r * 132 + 4 * cq] = rb[i];
        }
        __syncthreads();
        if (kc + 32 < K) GLOAD(kc + 32);   // in flight during FMA below
        #pragma unroll 4
        for (int kk = 0; kk < 32; ++kk) {
            float4 a0 = *(const float4*)&As[kk * 132 + 8 * tm];
            float4 a1 = *(const float4*)&As[kk * 132 + 8 * tm + 4];
            float4 b0 = *(const float4*)&Bs[kk * 132 + 4 * tn];
            float4 b1 = *(const float4*)&Bs[kk * 132 + 64 + 4 * tn];
            acc[0][0] = f4fma(a0.x, b0, acc[0][0]); acc[0][1] = f4fma(a0.x, b1, acc[0][1]);
            acc[1][0] = f4fma(a0.y, b0, acc[1][0]); acc[1][1] = f4fma(a0.y, b1, acc[1][1]);
            acc[2][0] = f4fma(a0.z, b0, acc[2][0]); acc[2][1] = f4fma(a0.z, b1, acc[2][1]);
            acc[3][0] = f4fma(a0.w, b0, acc[3][0]); acc[3][1] = f4fma(a0.w, b1, acc[3][1]);
            acc[4][0] = f4fma(a1.x, b0, acc[4][0]); acc[4][1] = f4fma(a1.x, b1, acc[4][1]);
            acc[5][0] = f4fma(a1.y, b0, acc[5][0]); acc[5][1] = f4fma(a1.y, b1, acc[5][1]);
            acc[6][0] = f4fma(a1.z, b0, acc[6][0]); acc[6][1] = f4fma(a1.z, b1, acc[6][1]);
            acc[7][0] = f4fma(a1.w, b0, acc[7][0]); acc[7][1] = f4fma(a1.w, b1, acc[7][1]);
        }
        __syncthreads();
    }
#undef GLOAD

    unsigned short* C16 = (unsigned short*)C;
    const int gnl = n0 + 4 * tn, gnh = n0 + 64 + 4 * tn;
    #pragma unroll
    for (int r = 0; r < 8; ++r) {
        int gm = m0 + 8 * tm + r;
        if (gm >= M) continue;
        float4 v0 = acc[r][0], v1 = acc[r][1];
        if (gnl < N) {
            if (bias) { v0.x += bias[gnl+0]; v0.y += bias[gnl+1]; v0.z += bias[gnl+2]; v0.w += bias[gnl+3]; }
            if (siluOut) { v0.x = silu(v0.x); v0.y = silu(v0.y); v0.z = silu(v0.z); v0.w = silu(v0.w); }
            ushort4 s0; s0.x = f2bf(v0.x); s0.y = f2bf(v0.y); s0.z = f2bf(v0.z); s0.w = f2bf(v0.w);
            *(ushort4*)&C16[(size_t)gm * ldc + gnl] = s0;
        }
        if (gnh < N) {
            if (bias) { v1.x += bias[gnh+0]; v1.y += bias[gnh+1]; v1.z += bias[gnh+2]; v1.w += bias[gnh+3]; }
            if (siluOut) { v1.x = silu(v1.x); v1.y = silu(v1.y); v1.z = silu(v1.z); v1.w = silu(v1.w); }
            ushort4 s1; s1.x = f2bf(v1.x); s1.y = f2bf(v1.y); s1.z = f2bf(v1.z); s1.w = f2bf(v1.w);
            *(ushort4*)&C16[(size_t)gm * ldc + gnh] = s1;
        }
    }
}

// ---------------- fp32 GEMM 64x128 tile (fallback for small-N dispatches) ----------------
__global__ __launch_bounds__(256) void k_gemm64(const float* __restrict__ A, int lda,
                                                const float* __restrict__ B, int ldb,
                                                const float* __restrict__ bias,
                                                float* __restrict__ C, int ldc,
                                                int M, int N, int K, int siluA, int siluOut) {
    __shared__ float As[32 * 68];
    __shared__ float Bs[32 * 132];
    const int tid = threadIdx.x;
    const int m0 = blockIdx.x * 64, n0 = blockIdx.y * 128;
    const int tm = tid >> 4, tn = tid & 15;

    float4 acc[4][2];
    #pragma unroll
    for (int r = 0; r < 4; ++r) { acc[r][0] = make_float4(0,0,0,0); acc[r][1] = make_float4(0,0,0,0); }

    float4 ra[2], rb[4];

#define GLOAD64(kc_) do { \
    _Pragma("unroll") \
    for (int i_ = 0; i_ < 2; ++i_) { \
        int idx_ = tid + i_ * 256; \
        int m_ = idx_ >> 3, kq_ = idx_ & 7; \
        int gm_ = m0 + m_; \
        int cm_ = (gm_ < M) ? gm_ : (M - 1); \
        float4 a_ = *(const float4*)(A + (size_t)cm_ * lda + (kc_) + 4 * kq_); \
        if (gm_ >= M) a_ = make_float4(0,0,0,0); \
        ra[i_] = a_; \
    } \
    _Pragma("unroll") \
    for (int i_ = 0; i_ < 4; ++i_) { \
        int idx_ = tid + i_ * 256; \
        int r_ = idx_ >> 5, cq_ = idx_ & 31; \
        int gn_ = n0 + 4 * cq_; \
        float4 b_ = make_float4(0,0,0,0); \
        if (gn_ < N) b_ = *(const float4*)(B + (size_t)((kc_) + r_) * ldb + gn_); \
        rb[i_] = b_; \
    } \
} while (0)

    GLOAD64(0);

    for (int kc = 0; kc < K; kc += 32) {
        #pragma unroll
        for (int i = 0; i < 2; ++i) {
            int idx = tid + i * 256;
            int m = idx >> 3, kq = idx & 7;
            float4 a = ra[i];
            if (siluA) { a.x = silu(a.x); a.y = silu(a.y); a.z = silu(a.z); a.w = silu(a.w); }
            As[(4 * kq + 0) * 68 + m] = a.x;
            As[(4 * kq + 1) * 68 + m] = a.y;
            As[(4 * kq + 2) * 68 + m] = a.z;
            As[(4 * kq + 3) * 68 + m] = a.w;
        }
        #pragma unroll
        for (int i = 0; i < 4; ++i) {
            int idx = tid + i * 256;
            int r = idx >> 5, cq = idx & 31;
            *(float4*)&Bs[r * 132 + 4 * cq] = rb[i];
        }
        __syncthreads();
        if (kc + 32 < K) GLOAD64(kc + 32);   // in flight during FMA below
        #pragma unroll 4
        for (int kk = 0; kk < 32; ++kk) {
            float4 av = *(const float4*)&As[kk * 68 + 4 * tm];
            float4 b0 = *(const float4*)&Bs[kk * 132 + 4 * tn];
            float4 b1 = *(const float4*)&Bs[kk * 132 + 64 + 4 * tn];
            acc[0][0] = f4fma(av.x, b0, acc[0][0]); acc[0][1] = f4fma(av.x, b1, acc[0][1]);
            acc[1][0] = f4fma(av.y, b0, acc[1][0]); acc[1][1] = f4fma(av.y, b1, acc[1][1]);
            acc[2][0] = f4fma(av.z, b0, acc[2][0]); acc[2][1] = f4fma(av.z, b1, acc[2][1]);
            acc[3][0] = f4fma(av.w, b0, acc[3][0]); acc[3][1] = f4fma(av.w, b1, acc[3][1]);
        }
        __syncthreads();
    }
#undef GLOAD64

    const int gnl = n0 + 4 * tn, gnh = n0 + 64 + 4 * tn;
    #pragma unroll
    for (int r = 0; r < 4; ++r) {
        int gm = m0 + 4 * tm + r;
        if (gm >= M) continue;
        float4 v0 = acc[r][0], v1 = acc[r][1];
        if (gnl < N) {
            if (bias) { v0.x += bias[gnl+0]; v0.y += bias[gnl+1]; v0.z += bias[gnl+2]; v0.w += bias[gnl+3]; }
            if (siluOut) { v0.x = silu(v0.x); v0.y = silu(v0.y); v0.z = silu(v0.z); v0.w = silu(v0.w); }
            *(float4*)&C[(size_t)gm * ldc + gnl] = v0;
        }
        if (gnh < N) {
            if (bias) { v1.x += bias[gnh+0]; v1.y += bias[gnh+1]; v1.z += bias[gnh+2]; v1.w += bias[gnh+3]; }
            if (siluOut) { v1.x = silu(v1.x); v1.y = silu(v1.y); v1.z = silu(v1.z); v1.w = silu(v1.w); }
            *(float4*)&C[(size_t)gm * ldc + gnh] = v1;
        }
    }
}

// ---------------- fused H2 GEMM + LN + residual ----------------
__global__ __launch_bounds__(256) void k_gemm_ln(const float* __restrict__ A,   // H1 [M][256]
                                                 const float* __restrict__ B,   // nW2 [256][128]
                                                 const float* __restrict__ bias,// nb2 [128]
                                                 float* __restrict__ feats_all, int layer,
                                                 const float* __restrict__ g,
                                                 const float* __restrict__ b,
                                                 int M, int K) {
    __shared__ float As[32 * 68];
    __shared__ float Bs[32 * 132];
    const int tid = threadIdx.x;
    const int m0 = blockIdx.x * 64;
    const int tm = tid >> 4, tn = tid & 15;

    float4 acc[4][2];
    #pragma unroll
    for (int r = 0; r < 4; ++r) { acc[r][0] = make_float4(0,0,0,0); acc[r][1] = make_float4(0,0,0,0); }

    float4 ra[2], rb[4];

#define GLOADL(kc_) do { \
    _Pragma("unroll") \
    for (int i_ = 0; i_ < 2; ++i_) { \
        int idx_ = tid + i_ * 256; \
        int m_ = idx_ >> 3, kq_ = idx_ & 7; \
        int gm_ = m0 + m_; \
        int cm_ = (gm_ < M) ? gm_ : (M - 1); \
        float4 a_ = *(const float4*)(A + (size_t)cm_ * 256 + (kc_) + 4 * kq_); \
        if (gm_ >= M) a_ = make_float4(0,0,0,0); \
        ra[i_] = a_; \
    } \
    _Pragma("unroll") \
    for (int i_ = 0; i_ < 4; ++i_) { \
        int idx_ = tid + i_ * 256; \
        int r_ = idx_ >> 5, cq_ = idx_ & 31; \
        float4 b_ = make_float4(0,0,0,0); \
        if (4 * cq_ < 128) b_ = *(const float4*)(B + (size_t)((kc_) + r_) * 128 + 4 * cq_); \
        rb[i_] = b_; \
    } \
} while (0)

    GLOADL(0);

    for (int kc = 0; kc < K; kc += 32) {
        #pragma unroll
        for (int i = 0; i < 2; ++i) {
            int idx = tid + i * 256;
            int m = idx >> 3, kq = idx & 7;
            float4 a = ra[i];
            As[(4 * kq + 0) * 68 + m] = a.x;
            As[(4 * kq + 1) * 68 + m] = a.y;
            As[(4 * kq + 2) * 68 + m] = a.z;
            As[(4 * kq + 3) * 68 + m] = a.w;
        }
        #pragma unroll
        for (int i = 0; i < 4; ++i) {
            int idx = tid + i * 256;
            int r = idx >> 5, cq = idx & 31;
            if (cq < 32) *(float4*)&Bs[r * 132 + 4 * cq] = rb[i];
        }
        __syncthreads();
        if (kc + 32 < K) GLOADL(kc + 32);
        #pragma unroll 4
        for (int kk = 0; kk < 32; ++kk) {
            float4 av = *(const float4*)&As[kk * 68 + 4 * tm];
            float4 b0 = *(const float4*)&Bs[kk * 132 + 4 * tn];
            float4 b1 = *(const float4*)&Bs[kk * 132 + 64 + 4 * tn];
            acc[0][0] = f4fma(av.x, b0, acc[0][0]); acc[0][1] = f4fma(av.x, b1, acc[0][1]);
            acc[1][0] = f4fma(av.y, b0, acc[1][0]); acc[1][1] = f4fma(av.y, b1, acc[1][1]);
            acc[2][0] = f4fma(av.z, b0, acc[2][0]); acc[2][1] = f4fma(av.z, b1, acc[2][1]);
            acc[3][0] = f4fma(av.w, b0, acc[3][0]); acc[3][1] = f4fma(av.w, b1, acc[3][1]);
        }
        __syncthreads();
    }
#undef GLOADL

    const int cl = 4 * tn, chh = 64 + 4 * tn;
    float4 gl = *(const float4*)(g + cl),  gh = *(const float4*)(g + chh);
    float4 bl = *(const float4*)(b + cl),  bh = *(const float4*)(b + chh);
    float4 wl = *(const float4*)(bias + cl), wh = *(const float4*)(bias + chh);
    #pragma unroll
    for (int r = 0; r < 4; ++r) {
        int gm = m0 + 4 * tm + r;
        if (gm >= M) continue;   // uniform across the 16-lane tn-group (same tm,r)
        float4 v0 = acc[r][0], v1 = acc[r][1];
        v0.x += wl.x; v0.y += wl.y; v0.z += wl.z; v0.w += wl.w;
        v1.x += wh.x; v1.y += wh.y; v1.z += wh.z; v1.w += wh.w;
        float s  = v0.x + v0.y + v0.z + v0.w + v1.x + v1.y + v1.z + v1.w;
        float ss = v0.x*v0.x + v0.y*v0.y + v0.z*v0.z + v0.w*v0.w
                 + v1.x*v1.x + v1.y*v1.y + v1.z*v1.z + v1.w*v1.w;
        s  += __shfl_xor(s, 1, 64);  ss += __shfl_xor(ss, 1, 64);
        s  += __shfl_xor(s, 2, 64);  ss += __shfl_xor(ss, 2, 64);
        s  += __shfl_xor(s, 4, 64);  ss += __shfl_xor(ss, 4, 64);
        s  += __shfl_xor(s, 8, 64);  ss += __shfl_xor(ss, 8, 64);
        float mean = s * (1.0f / 128.0f);
        float var  = ss * (1.0f / 128.0f) - mean * mean;
        float rstd = frsq(var + EPS);
        float* fp = feats_all + (size_t)gm * 768 + layer * 128;
        float4 f0 = *(const float4*)(fp + cl);
        float4 f1 = *(const float4*)(fp + chh);
        float4 o0, o1;
        o0.x = f0.x + (v0.x - mean) * rstd * gl.x + bl.x;
        o0.y = f0.y + (v0.y - mean) * rstd * gl.y + bl.y;
        o0.z = f0.z + (v0.z - mean) * rstd * gl.z + bl.z;
        o0.w = f0.w + (v0.w - mean) * rstd * gl.w + bl.w;
        o1.x = f1.x + (v1.x - mean) * rstd * gh.x + bh.x;
        o1.y = f1.y + (v1.y - mean) * rstd * gh.y + bh.y;
        o1.z = f1.z + (v1.z - mean) * rstd * gh.z + bh.z;
        o1.w = f1.w + (v1.w - mean) * rstd * gh.w + bh.w;
        float* op = feats_all + (size_t)gm * 768 + (layer + 1) * 128;
        *(float4*)(op + cl)  = o0;
        *(float4*)(op + chh) = o1;
    }
}

// ---------------- fused edge kernel (v12, fp32-VALU GEMM): fallback path ----------------
__global__ __launch_bounds__(256, 3) void k_edge(const int* __restrict__ ssiP,
                                                 const int* __restrict__ dsiP,
                                                 const int* __restrict__ i0P,
                                                 const float* __restrict__ frP,
                                                 const float* __restrict__ T,     // [TROWS][648]
                                                 const unsigned short* __restrict__ Pab, // [N_NODES][1296] bf16
                                                 const float* __restrict__ W2p,   // [768][32]
                                                 const float* __restrict__ b2,
                                                 const float* __restrict__ eng,
                                                 const float* __restrict__ enb,
                                                 float* __restrict__ S,
                                                 float* __restrict__ Mout,
                                                 int csr) {
    __shared__ float Zs[64 * 70];        // 17920 B; overlaid by m2s[64][36] in epilogue
    __shared__ float W2s[64 * 36];       // single-buffered W2 chunk, 9216 B
    __shared__ int dsi[EPB], ssi[EPB], i0s[EPB];
    __shared__ float frs[EPB];
    __shared__ float cpar[96];

    const int tid = threadIdx.x;
    const int bid = blockIdx.x;
    const int xcd = bid & 7, bpos = bid >> 3;
    const int wg = (xcd < 4) ? xcd * 313 + bpos : 1252 + (xcd - 4) * 312 + bpos;
    const int eb = wg * EPB;
    const int lane = tid & 31;
    const int grp = tid >> 5;

    if (tid < EPB) {
        ssi[tid] = ssiP[eb + tid];
        dsi[tid] = dsiP[eb + tid];
        i0s[tid] = i0P[eb + tid];
        frs[tid] = frP[eb + tid];
    }
    if (tid < 32) cpar[tid] = b2[tid];
    else if (tid < 64) cpar[tid] = eng[tid - 32];
    else if (tid < 96) cpar[tid] = enb[tid - 64];
    __syncthreads();

    int dsr[2], ssr[2], i0r[2];
    float frr[2];
    #pragma unroll
    for (int i = 0; i < 2; ++i) {
        int e = 2 * lane + i;
        dsr[i] = dsi[e]; ssr[i] = ssi[e];
        i0r[i] = i0s[e]; frr[i] = frs[e];
    }

    float4 accm[2];
    accm[0] = make_float4(0,0,0,0);
    accm[1] = make_float4(0,0,0,0);

    float4 rA0[2], rA1[2], rB0[2], rB1[2];
    uint4 rp[2], rq[2];
    float4 rw0, rw1;

#define PREFETCH(cn) do { \
    const int colb_ = 64 * (cn) + 8 * grp; \
    if (colb_ < TCOLS) { \
        _Pragma("unroll") \
        for (int i_ = 0; i_ < 2; ++i_) { \
            const float* t0_ = T + (size_t)i0r[i_] * TCOLS + colb_; \
            rA0[i_] = *(const float4*)t0_; \
            rA1[i_] = *(const float4*)(t0_ + 4); \
            rB0[i_] = *(const float4*)(t0_ + TCOLS); \
            rB1[i_] = *(const float4*)(t0_ + TCOLS + 4); \
            rp[i_] = *(const uint4*)(Pab + (size_t)dsr[i_] * PSTRIDE + colb_); \
            rq[i_] = *(const uint4*)(Pab + (size_t)ssr[i_] * PSTRIDE + JP + colb_); \
        } \
    } \
    const float* ws_ = W2p + (size_t)(64 * (cn)) * 32 + 8 * tid; \
    rw0 = *(const float4*)ws_; rw1 = *(const float4*)(ws_ + 4); \
} while (0)

    PREFETCH(0);

    for (int ch = 0; ch < 11; ++ch) {
        const int colb = 64 * ch + 8 * grp;

        float qa[2][8];
        if (colb < TCOLS) {
            #pragma unroll
            for (int i = 0; i < 2; ++i) {
                float f = frr[i];
                float pa[8], pb[8];
                pa[0] = __uint_as_float(rp[i].x << 16); pa[1] = __uint_as_float(rp[i].x & 0xFFFF0000u);
                pa[2] = __uint_as_float(rp[i].y << 16); pa[3] = __uint_as_float(rp[i].y & 0xFFFF0000u);
                pa[4] = __uint_as_float(rp[i].z << 16); pa[5] = __uint_as_float(rp[i].z & 0xFFFF0000u);
                pa[6] = __uint_as_float(rp[i].w << 16); pa[7] = __uint_as_float(rp[i].w & 0xFFFF0000u);
                pb[0] = __uint_as_float(rq[i].x << 16); pb[1] = __uint_as_float(rq[i].x & 0xFFFF0000u);
                pb[2] = __uint_as_float(rq[i].y << 16); pb[3] = __uint_as_float(rq[i].y & 0xFFFF0000u);
                pb[4] = __uint_as_float(rq[i].z << 16); pb[5] = __uint_as_float(rq[i].z & 0xFFFF0000u);
                pb[6] = __uint_as_float(rq[i].w << 16); pb[7] = __uint_as_float(rq[i].w & 0xFFFF0000u);
                qa[i][0] = silu(fmaf(f, rB0[i].x - rA0[i].x, rA0[i].x) + pa[0] + pb[0]);
                qa[i][1] = silu(fmaf(f, rB0[i].y - rA0[i].y, rA0[i].y) + pa[1] + pb[1]);
                qa[i][2] = silu(fmaf(f, rB0[i].z - rA0[i].z, rA0[i].z) + pa[2] + pb[2]);
                qa[i][3] = silu(fmaf(f, rB0[i].w - rA0[i].w, rA0[i].w) + pa[3] + pb[3]);
                qa[i][4] = silu(fmaf(f, rB1[i].x - rA1[i].x, rA1[i].x) + pa[4] + pb[4]);
                qa[i][5] = silu(fmaf(f, rB1[i].y - rA1[i].y, rA1[i].y) + pa[5] + pb[5]);
                qa[i][6] = silu(fmaf(f, rB1[i].z - rA1[i].z, rA1[i].z) + pa[6] + pb[6]);
                qa[i][7] = silu(fmaf(f, rB1[i].w - rA1[i].w, rA1[i].w) + pa[7] + pb[7]);
            }
        } else {
            #pragma unroll
            for (int i = 0; i < 2; ++i)
                #pragma unroll
                for (int c = 0; c < 8; ++c) qa[i][c] = 0.f;
        }

        __syncthreads();

        #pragma unroll
        for (int jj = 0; jj < 8; ++jj) {
            float2 z2;
            z2.x = qa[0][jj]; z2.y = qa[1][jj];
            *(float2*)&Zs[(8 * grp + jj) * 70 + 2 * lane] = z2;
        }
        {
            int wrow = tid >> 2;
            int wc0 = (2 * tid) & 7;
            *(float4*)&W2s[wrow * 36 + 4 * wc0] = rw0;
            *(float4*)&W2s[wrow * 36 + 4 * (wc0 + 1)] = rw1;
        }

        __syncthreads();

        if (ch < 10) PREFETCH(ch + 1);

        #pragma unroll 8
        for (int kk = 0; kk < 64; ++kk) {
            float2 z2 = *(const float2*)&Zs[kk * 70 + 2 * lane];
            float4 w4 = *(const float4*)&W2s[kk * 36 + 4 * grp];
            accm[0] = f4fma(z2.x, w4, accm[0]);
            accm[1] = f4fma(z2.y, w4, accm[1]);
        }
    }
#undef PREFETCH

    __syncthreads();
    float* m2s = Zs;
    {
        float4 bb2 = *(const float4*)&cpar[4 * grp];
        #pragma unroll
        for (int i = 0; i < 2; ++i) {
            int e = 2 * lane + i;
            float4 o;
            o.x = silu(accm[i].x + bb2.x);
            o.y = silu(accm[i].y + bb2.y);
            o.z = silu(accm[i].z + bb2.z);
            o.w = silu(accm[i].w + bb2.w);
            *(float4*)&m2s[e * 36 + 4 * grp] = o;
        }
    }
    __syncthreads();
    {
        int e = tid >> 2, q = tid & 3;
        float4 v0 = *(const float4*)&m2s[e * 36 + 8 * q];
        float4 v1 = *(const float4*)&m2s[e * 36 + 8 * q + 4];
        float s  = v0.x + v0.y + v0.z + v0.w + v1.x + v1.y + v1.z + v1.w;
        float ss = v0.x*v0.x + v0.y*v0.y + v0.z*v0.z + v0.w*v0.w
                 + v1.x*v1.x + v1.y*v1.y + v1.z*v1.z + v1.w*v1.w;
        s  += __shfl_xor(s, 1, 64);  ss += __shfl_xor(ss, 1, 64);
        s  += __shfl_xor(s, 2, 64);  ss += __shfl_xor(ss, 2, 64);
        float mean = s * 0.03125f;
        float var = ss * 0.03125f - mean * mean;
        float rstd = frsq(var + EPS);
        const float* gg = cpar + 32 + 8 * q;
        const float* bbv = cpar + 64 + 8 * q;
        float vv[8] = {v0.x, v0.y, v0.z, v0.w, v1.x, v1.y, v1.z, v1.w};
        float o[8];
        #pragma unroll
        for (int c = 0; c < 8; ++c) o[c] = (vv[c] - mean) * rstd * gg[c] + bbv[c];
        if (csr) {
            float* Mp = Mout + (size_t)(eb + e) * 32 + 8 * q;
            *(float4*)Mp       = make_float4(o[0], o[1], o[2], o[3]);
            *(float4*)(Mp + 4) = make_float4(o[4], o[5], o[6], o[7]);
        } else {
            int d = dsi[e];
            float* Sp = S + (size_t)d * 32 + 8 * q;
            #pragma unroll
            for (int c = 0; c < 8; ++c) atomicAdd(&Sp[c], o[c]);
        }
    }
}

// ---------------- fused edge kernel v13: MFMA Z@W2 (CSR-only path) ----------------
__global__ __launch_bounds__(256, 4) void k_edge_m(const int* __restrict__ ssiP,
                                                   const int* __restrict__ dsiP,
                                                   const int* __restrict__ i0P,
                                                   const float* __restrict__ frP,
                                                   const float* __restrict__ T,     // [TROWS][648]
                                                   const unsigned short* __restrict__ Pab, // [N_NODES][1296] bf16
                                                   const unsigned short* __restrict__ W2k, // [88][32][8] bf16
                                                   const float* __restrict__ b2,
                                                   const float* __restrict__ eng,
                                                   const float* __restrict__ enb,
                                                   float* __restrict__ Mout) {
    __shared__ float m2s[64 * 36];       // 9216 B; Zb (8192 B) overlays during chunk loop
    __shared__ int dsi[EPB], ssi[EPB], i0s[EPB];
    __shared__ float frs[EPB];
    __shared__ float cpar[96];
    unsigned short* Zb = (unsigned short*)m2s;   // [64 edges][64 cols] bf16, swizzled 16B blocks

    const int tid = threadIdx.x;
    const int bid = blockIdx.x;
    const int xcd = bid & 7, bpos = bid >> 3;
    const int wg = (xcd < 4) ? xcd * 313 + bpos : 1252 + (xcd - 4) * 312 + bpos;
    const int eb = wg * EPB;
    const int lane = tid & 31;           // edge-pair index (qa phase)
    const int grp = tid >> 5;            // col group (qa phase)
    const int wv = tid >> 6, l64 = tid & 63;
    const int lr = l64 & 15, lg = l64 >> 4;   // MFMA fragment indices

    if (tid < EPB) {
        ssi[tid] = ssiP[eb + tid];
        dsi[tid] = dsiP[eb + tid];
        i0s[tid] = i0P[eb + tid];
        frs[tid] = frP[eb + tid];
    }
    if (tid < 32) cpar[tid] = b2[tid];
    else if (tid < 64) cpar[tid] = eng[tid - 32];
    else if (tid < 96) cpar[tid] = enb[tid - 64];
    __syncthreads();

    int dsr[2], ssr[2], i0r[2];
    float frr[2];
    #pragma unroll
    for (int i = 0; i < 2; ++i) {
        int e = 2 * lane + i;
        dsr[i] = dsi[e]; ssr[i] = ssi[e];
        i0r[i] = i0s[e]; frr[i] = frs[e];
    }

    f32x4 acc0 = {}, acc1 = {};          // out-cols 0-15 / 16-31 for this wave's 16 edges

    float4 rA0[2], rA1[2], rB0[2], rB1[2];
    uint4 rp[2], rq[2];

#define PREFETCHM(cn) do { \
    const int colb_ = 64 * (cn) + 8 * grp; \
    if (colb_ < TCOLS) { \
        _Pragma("unroll") \
        for (int i_ = 0; i_ < 2; ++i_) { \
            const float* t0_ = T + (size_t)i0r[i_] * TCOLS + colb_; \
            rA0[i_] = *(const float4*)t0_; \
            rA1[i_] = *(const float4*)(t0_ + 4); \
            rB0[i_] = *(const float4*)(t0_ + TCOLS); \
            rB1[i_] = *(const float4*)(t0_ + TCOLS + 4); \
            rp[i_] = *(const uint4*)(Pab + (size_t)dsr[i_] * PSTRIDE + colb_); \
            rq[i_] = *(const uint4*)(Pab + (size_t)ssr[i_] * PSTRIDE + JP + colb_); \
        } \
    } \
} while (0)

    PREFETCHM(0);

    for (int ch = 0; ch < 11; ++ch) {
        const int colb = 64 * ch + 8 * grp;

        float qa[2][8];
        if (colb < TCOLS) {
            #pragma unroll
            for (int i = 0; i < 2; ++i) {
                float f = frr[i];
                float pa[8], pb[8];
                pa[0] = __uint_as_float(rp[i].x << 16); pa[1] = __uint_as_float(rp[i].x & 0xFFFF0000u);
                pa[2] = __uint_as_float(rp[i].y << 16); pa[3] = __uint_as_float(rp[i].y & 0xFFFF0000u);
                pa[4] = __uint_as_float(rp[i].z << 16); pa[5] = __uint_as_float(rp[i].z & 0xFFFF0000u);
                pa[6] = __uint_as_float(rp[i].w << 16); pa[7] = __uint_as_float(rp[i].w & 0xFFFF0000u);
                pb[0] = __uint_as_float(rq[i].x << 16); pb[1] = __uint_as_float(rq[i].x & 0xFFFF0000u);
                pb[2] = __uint_as_float(rq[i].y << 16); pb[3] = __uint_as_float(rq[i].y & 0xFFFF0000u);
                pb[4] = __uint_as_float(rq[i].z << 16); pb[5] = __uint_as_float(rq[i].z & 0xFFFF0000u);
                pb[6] = __uint_as_float(rq[i].w << 16); pb[7] = __uint_as_float(rq[i].w & 0xFFFF0000u);
                qa[i][0] = silu(fmaf(f, rB0[i].x - rA0[i].x, rA0[i].x) + pa[0] + pb[0]);
                qa[i][1] = silu(fmaf(f, rB0[i].y - rA0[i].y, rA0[i].y) + pa[1] + pb[1]);
                qa[i][2] = silu(fmaf(f, rB0[i].z - rA0[i].z, rA0[i].z) + pa[2] + pb[2]);
                qa[i][3] = silu(fmaf(f, rB0[i].w - rA0[i].w, rA0[i].w) + pa[3] + pb[3]);
                qa[i][4] = silu(fmaf(f, rB1[i].x - rA1[i].x, rA1[i].x) + pa[4] + pb[4]);
                qa[i][5] = silu(fmaf(f, rB1[i].y - rA1[i].y, rA1[i].y) + pa[5] + pb[5]);
                qa[i][6] = silu(fmaf(f, rB1[i].z - rA1[i].z, rA1[i].z) + pa[6] + pb[6]);
                qa[i][7] = silu(fmaf(f, rB1[i].w - rA1[i].w, rA1[i].w) + pa[7] + pb[7]);
            }
        } else {
            #pragma unroll
            for (int i = 0; i < 2; ++i)
                #pragma unroll
                for (int c = 0; c < 8; ++c) qa[i][c] = 0.f;
        }

        __syncthreads();   // bA: previous chunk's MFMA done -> Zb free

        #pragma unroll
        for (int i = 0; i < 2; ++i) {
            int e = 2 * lane + i;
            uint4 zp;
            zp.x = (unsigned)f2bf(qa[i][0]) | ((unsigned)f2bf(qa[i][1]) << 16);
            zp.y = (unsigned)f2bf(qa[i][2]) | ((unsigned)f2bf(qa[i][3]) << 16);
            zp.z = (unsigned)f2bf(qa[i][4]) | ((unsigned)f2bf(qa[i][5]) << 16);
            zp.w = (unsigned)f2bf(qa[i][6]) | ((unsigned)f2bf(qa[i][7]) << 16);
            *(uint4*)&Zb[e * 64 + ((grp ^ (e & 7)) << 3)] = zp;
        }

        __syncthreads();   // bB: Zb published

        if (ch < 10) PREFETCHM(ch + 1);   // next-chunk loads in flight during MFMA

        #pragma unroll
        for (int h = 0; h < 2; ++h) {
            const int cq = 4 * h + lg;                 // col-quad 0..7 within chunk
            const int arow = 16 * wv + lr;
            bf16v8 a = *(const bf16v8*)&Zb[arow * 64 + ((cq ^ (arow & 7)) << 3)];
            const unsigned short* bp = W2k + ((size_t)(ch * 8 + cq) * 32) * 8;
            bf16v8 b0 = *(const bf16v8*)(bp + (size_t)lr * 8);
            bf16v8 b1 = *(const bf16v8*)(bp + (size_t)(16 + lr) * 8);
            acc0 = __builtin_amdgcn_mfma_f32_16x16x32_bf16(a, b0, acc0, 0, 0, 0);
            acc1 = __builtin_amdgcn_mfma_f32_16x16x32_bf16(a, b1, acc1, 0, 0, 0);
        }
    }
#undef PREFETCHM

    __syncthreads();   // all MFMA done reading Zb -> reuse as m2s
    // D-frag epilogue: edge = 16wv + lg*4 + j, col = {lr, 16+lr}
    #pragma unroll
    for (int j = 0; j < 4; ++j) {
        int e = 16 * wv + lg * 4 + j;
        m2s[e * 36 + lr]      = silu(acc0[j] + cpar[lr]);
        m2s[e * 36 + 16 + lr] = silu(acc1[j] + cpar[16 + lr]);
    }
    __syncthreads();
    {
        int e = tid >> 2, q = tid & 3;
        float4 v0 = *(const float4*)&m2s[e * 36 + 8 * q];
        float4 v1 = *(const float4*)&m2s[e * 36 + 8 * q + 4];
        float s  = v0.x + v0.y + v0.z + v0.w + v1.x + v1.y + v1.z + v1.w;
        float ss = v0.x*v0.x + v0.y*v0.y + v0.z*v0.z + v0.w*v0.w
                 + v1.x*v1.x + v1.y*v1.y + v1.z*v1.z + v1.w*v1.w;
        s  += __shfl_xor(s, 1, 64);  ss += __shfl_xor(ss, 1, 64);
        s  += __shfl_xor(s, 2, 64);  ss += __shfl_xor(ss, 2, 64);
        float mean = s * 0.03125f;
        float var = ss * 0.03125f - mean * mean;
        float rstd = frsq(var + EPS);
        const float* gg = cpar + 32 + 8 * q;
        const float* bbv = cpar + 64 + 8 * q;
        float vv[8] = {v0.x, v0.y, v0.z, v0.w, v1.x, v1.y, v1.z, v1.w};
        float o[8];
        #pragma unroll
        for (int c = 0; c < 8; ++c) o[c] = (vv[c] - mean) * rstd * gg[c] + bbv[c];
        float* Mp = Mout + (size_t)(eb + e) * 32 + 8 * q;
        *(float4*)Mp       = make_float4(o[0], o[1], o[2], o[3]);
        *(float4*)(Mp + 4) = make_float4(o[4], o[5], o[6], o[7]);
    }
}

// ---------------- node prep: H0[:,0:128] = LN(feats) ----------------
__global__ __launch_bounds__(128) void k_prep(const float* __restrict__ featsk,
                                              const float* __restrict__ nn1g,
                                              const float* __restrict__ nn1b,
                                              float* __restrict__ H0) {
    int n = blockIdx.x, tid = threadIdx.x;
    __shared__ float red[4];
    float x = featsk[(size_t)n * 768 + tid];
    float s = wave_sum64(x), ss = wave_sum64(x * x);
    if ((tid & 63) == 0) { red[(tid >> 6) * 2] = s; red[(tid >> 6) * 2 + 1] = ss; }
    __syncthreads();
    float S1 = red[0] + red[2], S2 = red[1] + red[3];
    float mean = S1 * (1.0f / 128.0f);
    float var = S2 * (1.0f / 128.0f) - mean * mean;
    float rstd = frsq(var + EPS);
    H0[(size_t)n * 160 + tid] = (x - mean) * rstd * nn1g[tid] + nn1b[tid];
}

// ---------------- graph pooling (batch sorted -> run-length accum) ----------------
__global__ __launch_bounds__(256) void k_pool(const float* __restrict__ F,
                                              const int* __restrict__ batch,
                                              float* __restrict__ G,
                                              float* __restrict__ cntg) {
    __shared__ int bL[32];
    int b0 = blockIdx.x * 32;
    int tid = threadIdx.x;
    int nmax = min(32, N_NODES - b0);
    if (nmax <= 0) return;
    if (tid < nmax) bL[tid] = batch[b0 + tid];
    __syncthreads();
    float accv = 0.f;
    int cur = -1;
    for (int i = 0; i < nmax; ++i) {
        int g = bL[i];
        if (g != cur) {
            if (cur >= 0) atomicAdd(&G[(size_t)cur * 256 + tid], accv);
            cur = g; accv = 0.f;
        }
        accv += F[(size_t)(b0 + i) * 256 + tid];
    }
    if (cur >= 0) atomicAdd(&G[(size_t)cur * 256 + tid], accv);
    if (tid == 0)
        for (int i = 0; i < nmax; ++i) atomicAdd(&cntg[bL[i]], 1.0f);
}

// ---------------- per-graph MLP head ----------------
__global__ __launch_bounds__(256) void k_graph(const float* __restrict__ G,
                                               const float* __restrict__ cntg,
                                               const float* __restrict__ g1W,
                                               const float* __restrict__ g1b,
                                               const float* __restrict__ g2W,
                                               const float* __restrict__ g2b,
                                               const float* __restrict__ g3W,
                                               const float* __restrict__ g3b,
                                               float* __restrict__ out) {
    __shared__ float X[256], Y[256], red[4];
    int g = blockIdx.x, tid = threadIdx.x;
    float inv = frcp(fmaxf(cntg[g], 1.0f));
    X[tid] = G[(size_t)g * 256 + tid] * inv;
    __syncthreads();
    float a = g1b[tid];
    for (int j = 0; j < 256; ++j) a = fmaf(X[j], g1W[(size_t)j * 256 + tid], a);
    Y[tid] = silu(a);
    __syncthreads();
    a = g2b[tid];
    for (int j = 0; j < 256; ++j) a = fmaf(Y[j], g2W[(size_t)j * 256 + tid], a);
    float z = silu(a);
    float p = z * g3W[tid];
    p = wave_sum64(p);
    if ((tid & 63) == 0) red[tid >> 6] = p;
    __syncthreads();
    if (tid == 0) out[g] = red[0] + red[1] + red[2] + red[3] + g3b[0];
}

extern "C" void kernel_launch(void* const* d_in, const int* in_sizes, int n_in,
                              void* d_out, int out_size, void* d_ws, size_t ws_size,
                              hipStream_t stream) {
    const int*   atomids = (const int*)d_in[0];
    const float* coords  = (const float*)d_in[1];
    const int*   eidx    = (const int*)d_in[2];
    const int*   batch   = (const int*)d_in[3];
    const float* emb_w   = (const float*)d_in[4];
    const float* eW1     = (const float*)d_in[5];
    const float* eb1     = (const float*)d_in[6];
    const float* eW2     = (const float*)d_in[7];
    const float* eb2     = (const float*)d_in[8];
    const float* en_g    = (const float*)d_in[9];
    const float* en_b    = (const float*)d_in[10];
    const float* nn1_g   = (const float*)d_in[11];
    const float* nn1_b   = (const float*)d_in[12];
    const float* nW1     = (const float*)d_in[13];
    const float* nb1     = (const float*)d_in[14];
    const float* nW2     = (const float*)d_in[15];
    const float* nb2     = (const float*)d_in[16];
    const float* nn2_g   = (const float*)d_in[17];
    const float* nn2_b   = (const float*)d_in[18];
    const float* f1W     = (const float*)d_in[19];
    const float* f1b     = (const float*)d_in[20];
    const float* f2W     = (const float*)d_in[21];
    const float* f2b     = (const float*)d_in[22];
    const float* f3W     = (const float*)d_in[23];
    const float* f3b     = (const float*)d_in[24];
    const float* g1W     = (const float*)d_in[25];
    const float* g1b     = (const float*)d_in[26];
    const float* g2W     = (const float*)d_in[27];
    const float* g2b     = (const float*)d_in[28];
    const float* g3W     = (const float*)d_in[29];
    const float* g3b     = (const float*)d_in[30];
    float* out = (float*)d_out;

    float* ws = (float*)d_ws;
    float* feats_all = ws;                        // [10000][768]
    float* d2g   = ws + 7680000;                  // [160000]
    float* Pab   = ws + 7840000;                  // region: bf16 [10000][1296] = 25.9MB of 51.8MB
    float* S     = ws + 20800000;                 // [10000][32] (fallback path only)
    float* cnt   = ws + 21120000;                 // [10000]
    float* W1ab5 = ws + 21130000;                 // [5][128][1296] fp32 (fallback only; overlaid by MFMA3 packs)
    float* W1cp5 = ws + 21959440;                 // [5][65][768]
    float* b1p5  = ws + 22209040;                 // [5][768]
    float* W2p5  = ws + 22212880;                 // [5][768][32]
    float* feG   = ws + 22335760;                 // [12289][68]
    float* T     = ws + 23171412;                 // [12289][648]
    float* G     = ws + 31134684;                 // [64][256]
    float* cntg  = ws + 31151068;                 // [64]
    int*   histI = (int*)(ws + 31151132);         // [12304]
    int*   offs  = (int*)(ws + 31163436);         // [12304] (persists as dst-CSR offsD)
    int*   cursor= (int*)(ws + 31175740);         // [12304]
    int*   ssiP  = (int*)(ws + 31188044);         // [160000]
    int*   dsiP  = (int*)(ws + 31348044);         // [160000]
    int*   i0P   = (int*)(ws + 31508044);         // [160000]
    float* frP   = ws + 31668044;                 // [160000]
    int*   eixD  = (int*)(ws + 31828044);         // [160000]
    float* Mbuf  = ws + 31988044;                 // [160000][32] (end 37,108,044)
    unsigned short* Bp5U  = (unsigned short*)(ws + 37108044);  // [5][16][1296][8] bf16 (414,720 fl)
    unsigned short* ApackU= (unsigned short*)(ws + 37522764);  // [16][10000][8] bf16 (640,000 fl)
    unsigned short* nW1p5 = (unsigned short*)(ws + 38162764);  // 5 x [20][256][8] bf16 (102,400 fl)
    unsigned short* f1Wp  = (unsigned short*)(ws + 38265164);  // [96][256][8] bf16 (98,304 fl)
    unsigned short* f2Wp  = (unsigned short*)(ws + 38363468);  // [32][256][8] bf16 (32,768 fl)
    unsigned short* f3Wp  = (unsigned short*)(ws + 38396236);  // [32][256][8] bf16 (32,768 fl; end 38,429,004)
    unsigned short* W2k5  = (unsigned short*)(ws + 38429004);  // [5][88][32][8] bf16 (56,320 fl; end 38,485,324)
    const int useCSR   = (ws_size >= (size_t)(31988044 + 5120000) * sizeof(float)) ? 1 : 0;
    const int useMFMA  = (ws_size >= (size_t)38162764 * sizeof(float)) ? 1 : 0;
    const int useMFMA2 = (ws_size >= (size_t)38429004 * sizeof(float)) ? 1 : 0;
    const int useMFMA3 = (useMFMA && useMFMA2) ? 1 : 0;
    const int useMFMA4 = (useMFMA3 && useCSR &&
                          ws_size >= (size_t)38485324 * sizeof(float)) ? 1 : 0;
    // k_tab MFMA packs overlay the dead fp32 W1ab5 region (only used when !useMFMA):
    unsigned short* feGp = (unsigned short*)(ws + 21130000);   // [12][12289][8] bf16
    unsigned short* Bt5  = (unsigned short*)(ws + 21719872);   // [5][12][648][8] bf16
    unsigned short* PabU = (unsigned short*)Pab;  // bf16 view
    // node-phase temporaries overlay Pab region (dead between phases)
    float* H0 = Pab;                              // [10000][160]
    float* H1 = Pab + 1600000;                    // [10000][256]
    float* F1 = Pab;                              // [10000][256]
    float* F2 = Pab + 2560000;                    // [10000][256]
    float* F3 = Pab + 5120000;                    // [10000][256]
    // Ap2 scratch for N=256 MFMA A-packs: overlays free top of Pab region
    unsigned short* Ap2 = (unsigned short*)(Pab + 7680000);   // up to [96][10000][8] bf16

    k_embed<<<N_NODES, 128, 0, stream>>>(atomids, emb_w, feats_all);
    k_d2<<<(N_EDGES + 255) / 256, 256, 0, stream>>>(coords, eidx, d2g);
    hipMemsetAsync(cnt, 0, 10000 * sizeof(float), stream);
    k_cnt<<<(N_EDGES + 255) / 256, 256, 0, stream>>>(eidx, cnt);
    hipMemsetAsync(histI, 0, 12304 * sizeof(int), stream);
    k_hist<<<(N_EDGES + 255) / 256, 256, 0, stream>>>(d2g, histI);
    k_scan<<<1, 256, 0, stream>>>(histI, offs);
    k_copyi<<<(TROWS + 255) / 256, 256, 0, stream>>>(offs, cursor);
    k_scatter<<<(N_EDGES + 255) / 256, 256, 0, stream>>>(eidx, d2g, cursor,
                                                         ssiP, dsiP, i0P, frP);
    if (useCSR) {
        hipMemsetAsync(histI, 0, 12304 * sizeof(int), stream);
        k_hist_d<<<(N_EDGES + 255) / 256, 256, 0, stream>>>(dsiP, histI);
        k_scan<<<1, 256, 0, stream>>>(histI, offs);
        k_copyi<<<(TROWS + 255) / 256, 256, 0, stream>>>(offs, cursor);
        k_scatter_d<<<(N_EDGES + 255) / 256, 256, 0, stream>>>(dsiP, cursor, eixD);
    }
    k_feg<<<(TROWS + 255) / 256, 256, 0, stream>>>(feG);
    if (useMFMA)
        k_bpack5<<<dim3(648, 5), 256, 0, stream>>>(eW1, Bp5U);
    else
        k_w1ab5<<<dim3(648, 5), 256, 0, stream>>>(eW1, W1ab5);
    k_wpre5<<<dim3(294, 5), 256, 0, stream>>>(eW1, eb1, eW2, W1cp5, b1p5, W2p5);
    if (useMFMA2) {
        for (int k = 0; k < NK; ++k)
            k_bpack2<<<160, 256, 0, stream>>>(nW1 + (size_t)k * 160 * 256, 160,
                                              nW1p5 + (size_t)k * 40960);
        k_bpack2<<<768, 256, 0, stream>>>(f1W, 768, f1Wp);
        k_bpack2<<<256, 256, 0, stream>>>(f2W, 256, f2Wp);
        k_bpack2<<<256, 256, 0, stream>>>(f3W, 256, f3Wp);
    }
    if (useMFMA3) {
        k_apack3<<<(TROWS * 12 + 255) / 256, 256, 0, stream>>>(feG, feGp);
        k_bpack3<<<dim3(243, 5), 256, 0, stream>>>(W1cp5, Bt5);
    }
    if (useMFMA4)
        k_wpack<<<dim3(88, 5), 256, 0, stream>>>(W2p5, W2k5);

    for (int k = 0; k < NK; ++k) {
        const float* eb2k = eb2 + (size_t)k * 32;
        const float* engk = en_g + (size_t)k * 32;
        const float* enbk = en_b + (size_t)k * 32;
        const float* nn1gk = nn1_g + (size_t)k * 128;
        const float* nn1bk = nn1_b + (size_t)k * 128;
        const float* nW1k = nW1 + (size_t)k * 160 * 256;
        const float* nb1k = nb1 + (size_t)k * 256;
        const float* nW2k = nW2 + (size_t)k * 256 * 128;
        const float* nb2k = nb2 + (size_t)k * 128;
        const float* nn2gk = nn2_g + (size_t)k * 128;
        const float* nn2bk = nn2_b + (size_t)k * 128;

        if (useMFMA3)
            k_gemm_mfma3<<<dim3(193, 11), 256, 0, stream>>>(feGp, Bt5 + (size_t)k * 62208,
                                                            b1p5 + (size_t)k * 768, T);
        else
            k_tab<<<(TROWS + 31) / 32, 256, 0, stream>>>(feG,
                                                         W1cp5 + (size_t)k * 65 * 768,
                                                         b1p5 + (size_t)k * 768, T);
        // MUST write all 1296 Pab columns (k_edge reads zero-padding up to col 1295)
        if (useMFMA) {
            k_apack<<<(N_NODES * 16 + 255) / 256, 256, 0, stream>>>(feats_all + k * 128, ApackU);
            k_gemm_mfma<<<dim3(157, 21), 256, 0, stream>>>(ApackU, Bp5U + (size_t)k * 165888,
                                                           PabU, N_NODES);
        } else {
            k_gemm<<<dim3(79, 11), 256, 0, stream>>>(feats_all + k * 128, 768,
                                                     W1ab5 + (size_t)k * 128 * 1296, 1296,
                                                     nullptr, Pab, 1296, N_NODES, 1296, 128, 0, 0);
        }
        if (!useCSR)
            hipMemsetAsync(S, 0, (size_t)320000 * sizeof(float), stream);
        if (useMFMA4)
            k_edge_m<<<N_EDGES / EPB, 256, 0, stream>>>(ssiP, dsiP, i0P, frP, T, PabU,
                                                        W2k5 + (size_t)k * 22528,
                                                        eb2k, engk, enbk, Mbuf);
        else
            k_edge<<<N_EDGES / EPB, 256, 0, stream>>>(ssiP, dsiP, i0P, frP, T, PabU,
                                                      W2p5 + (size_t)k * 768 * 32,
                                                      eb2k, engk, enbk, S, Mbuf, useCSR);
        if (useCSR)
            k_agg_ln<<<(N_NODES + 3) / 4, 128, 0, stream>>>(Mbuf, offs, eixD, cnt,
                                                            engk, enbk, H0);
        else
            k_s_ln<<<(N_NODES + 3) / 4, 128, 0, stream>>>(S, cnt, engk, enbk, H0);
        k_prep<<<N_NODES, 128, 0, stream>>>(feats_all + k * 128, nn1gk, nn1bk, H0);
        if (useMFMA2) {
            k_apack2<<<(N_NODES * 20 + 255) / 256, 256, 0, stream>>>(H0, 160, 20, 0, Ap2);
            k_gemm_mfma2<<<dim3(157, 4), 256, 0, stream>>>(Ap2, nW1p5 + (size_t)k * 40960,
                                                           nb1k, H1, N_NODES, 5);
        } else {
            k_gemm64<<<dim3(157, 2), 256, 0, stream>>>(H0, 160, nW1k, 256, nb1k, H1, 256,
                                                       N_NODES, 256, 160, 0, 1);
        }
        k_gemm_ln<<<dim3(157), 256, 0, stream>>>(H1, nW2k, nb2k, feats_all, k,
                                                 nn2gk, nn2bk, N_NODES, 256);
    }

    // final node MLP (F1/F2/F3 overlay Pab)
    if (useMFMA2) {
        k_apack2<<<(N_NODES * 96 + 255) / 256, 256, 0, stream>>>(feats_all, 768, 96, 1, Ap2);
        k_gemm_mfma2<<<dim3(157, 4), 256, 0, stream>>>(Ap2, f1Wp, f1b, F1, N_NODES, 24);
        k_apack2<<<(N_NODES * 32 + 255) / 256, 256, 0, stream>>>(F1, 256, 32, 0, Ap2);
        k_gemm_mfma2<<<dim3(157, 4), 256, 0, stream>>>(Ap2, f2Wp, f2b, F2, N_NODES, 8);
        k_apack2<<<(N_NODES * 32 + 255) / 256, 256, 0, stream>>>(F2, 256, 32, 0, Ap2);
        k_gemm_mfma2<<<dim3(157, 4), 256, 0, stream>>>(Ap2, f3Wp, f3b, F3, N_NODES, 8);
    } else {
        k_gemm64<<<dim3(157, 2), 256, 0, stream>>>(feats_all, 768, f1W, 256, f1b, F1, 256,
                                                   N_NODES, 256, 768, 1, 1);
        k_gemm64<<<dim3(157, 2), 256, 0, stream>>>(F1, 256, f2W, 256, f2b, F2, 256,
                                                   N_NODES, 256, 256, 0, 1);
        k_gemm64<<<dim3(157, 2), 256, 0, stream>>>(F2, 256, f3W, 256, f3b, F3, 256,
                                                   N_NODES, 256, 256, 0, 1);
    }

    hipMemsetAsync(G, 0, (size_t)(16384 + 64) * sizeof(float), stream);
    k_pool<<<313, 256, 0, stream>>>(F3, batch, G, cntg);
    k_graph<<<N_GRAPHS, 256, 0, stream>>>(G, cntg, g1W, g1b, g2W, g2b, g3W, g3b, out);
}